// Round 1
// 424.934 us; speedup vs baseline: 1.2470x; 1.2470x over previous
//
#include <hip/hip_runtime.h>
#include <hip/hip_bf16.h>
#include <math.h>

#define T_LEN 2048
#define EMB   512
#define NHEAD 8
#define HDIM  64
#define BHEADS 32
#define USEL  40

typedef __bf16 bf16v8 __attribute__((ext_vector_type(8)));
typedef _Float16 f16x8 __attribute__((ext_vector_type(8)));
typedef float f32x4 __attribute__((ext_vector_type(4)));
typedef unsigned short u16;

// Split a float4 into bf16 hi + lo halves, packed as uint2 (4 x u16 each).
__device__ __forceinline__ void cvt4_hilo(const float4 f, uint2& ph, uint2& pl)
{
    __hip_bfloat16 h0 = __float2bfloat16(f.x);
    __hip_bfloat16 h1 = __float2bfloat16(f.y);
    __hip_bfloat16 h2 = __float2bfloat16(f.z);
    __hip_bfloat16 h3 = __float2bfloat16(f.w);
    __hip_bfloat16 l0 = __float2bfloat16(f.x - __bfloat162float(h0));
    __hip_bfloat16 l1 = __float2bfloat16(f.y - __bfloat162float(h1));
    __hip_bfloat16 l2 = __float2bfloat16(f.z - __bfloat162float(h2));
    __hip_bfloat16 l3 = __float2bfloat16(f.w - __bfloat162float(h3));
    ph.x = (unsigned)*(const u16*)&h0 | ((unsigned)*(const u16*)&h1 << 16);
    ph.y = (unsigned)*(const u16*)&h2 | ((unsigned)*(const u16*)&h3 << 16);
    pl.x = (unsigned)*(const u16*)&l0 | ((unsigned)*(const u16*)&l1 << 16);
    pl.y = (unsigned)*(const u16*)&l2 | ((unsigned)*(const u16*)&l3 << 16);
}

// Split a float4 into FP16 hi + lo halves, packed as uint2 (4 x u16 each).
// fp16 has 11-bit mantissa: h+l captures ~22-24 bits, residual <= 2^-24*|x|.
// Dropped Al*Bl term in the 3-pass GEMM is <= 2^-24*|ab| -> the f16 hi/lo
// 3-pass GEMM is fp32-rounding-equivalent (~1e-6), unlike bf16 hi/lo (~2^-16).
__device__ __forceinline__ void cvt4_hilo_h(const float4 f, uint2& ph, uint2& pl)
{
    _Float16 h0 = (_Float16)f.x;
    _Float16 h1 = (_Float16)f.y;
    _Float16 h2 = (_Float16)f.z;
    _Float16 h3 = (_Float16)f.w;
    _Float16 l0 = (_Float16)(f.x - (float)h0);
    _Float16 l1 = (_Float16)(f.y - (float)h1);
    _Float16 l2 = (_Float16)(f.z - (float)h2);
    _Float16 l3 = (_Float16)(f.w - (float)h3);
    ph.x = (unsigned)*(const u16*)&h0 | ((unsigned)*(const u16*)&h1 << 16);
    ph.y = (unsigned)*(const u16*)&h2 | ((unsigned)*(const u16*)&h3 << 16);
    pl.x = (unsigned)*(const u16*)&l0 | ((unsigned)*(const u16*)&l1 << 16);
    pl.y = (unsigned)*(const u16*)&l2 | ((unsigned)*(const u16*)&l3 << 16);
}

// ---------------------------------------------------------------------------
// Kernel A: fused QKV projection via FP16 hi+lo 3-pass MFMA (16x16x32_f16).
// Same geometry as out_proj (128x128 tile, BK=32, 4 waves, u16 stride 40).
// acc += Ah*Bh + Ah*Bl + Al*Bh; dropped Al*Bl ~2^-24 -> fp32-equivalent
// precision, so the top-k selection (rank-40/41 sparsity gap ~6.6e-3) is
// unaffected (perturbation ~1e-6, like any fp32 reassociation).
// Replaces the fp32 VALU GEMM (171 us, MfmaUtil=0, 48% of the 157TF vector
// ceiling) with matrix-pipe work. Epilogue writes split-head fp32 layout.
// ---------------------------------------------------------------------------
__global__ __launch_bounds__(256)
void qkv_proj_kernel(const float* __restrict__ X,
                     const float* __restrict__ Wq, const float* __restrict__ bq,
                     const float* __restrict__ Wk, const float* __restrict__ bk,
                     const float* __restrict__ Wv, const float* __restrict__ bv,
                     float* __restrict__ qo, float* __restrict__ ko, float* __restrict__ vo)
{
    alignas(16) __shared__ u16 Ah[128 * 40];
    alignas(16) __shared__ u16 Al[128 * 40];
    alignas(16) __shared__ u16 Bh[128 * 40];
    alignas(16) __shared__ u16 Bl[128 * 40];

    const int z = blockIdx.z;
    const float* W; const float* bias; float* dst; float scale;
    if (z == 0)      { W = Wq; bias = bq; dst = qo; scale = 0.125f; }
    else if (z == 1) { W = Wk; bias = bk; dst = ko; scale = 1.0f;   }
    else             { W = Wv; bias = bv; dst = vo; scale = 1.0f;   }

    const int tid = threadIdx.x;
    const int m0 = blockIdx.x * 128;
    const int n0 = blockIdx.y * 128;
    const int w = tid >> 6, lane = tid & 63;
    const int wm = w & 1, wn = w >> 1;
    const int lm = lane & 15, kq = lane >> 4;

    f32x4 acc[4][4];
    #pragma unroll
    for (int i = 0; i < 4; ++i)
        #pragma unroll
        for (int j = 0; j < 4; ++j)
            #pragma unroll
            for (int r = 0; r < 4; ++r) acc[i][j][r] = 0.0f;

    for (int kc = 0; kc < EMB; kc += 32) {
        __syncthreads();
        #pragma unroll
        for (int s = 0; s < 4; ++s) {
            int u = tid + 256 * s;        // 0..1023
            int row = u >> 3, c4 = u & 7; // row 0..127, c4 0..7 (k-quad)
            float4 fa = *(const float4*)&X[(size_t)(m0 + row) * EMB + kc + c4 * 4];
            float4 fb = *(const float4*)&W[(n0 + row) * EMB + kc + c4 * 4];
            uint2 ph, pl;
            cvt4_hilo_h(fa, ph, pl);
            *(uint2*)&Ah[row * 40 + c4 * 4] = ph;
            *(uint2*)&Al[row * 40 + c4 * 4] = pl;
            cvt4_hilo_h(fb, ph, pl);
            *(uint2*)&Bh[row * 40 + c4 * 4] = ph;
            *(uint2*)&Bl[row * 40 + c4 * 4] = pl;
        }
        __syncthreads();

        f16x8 ah[4], al[4], bh[4], bl[4];
        #pragma unroll
        for (int i = 0; i < 4; ++i) {
            int ra = (wm * 64 + i * 16 + lm) * 40 + kq * 8;
            ah[i] = *(const f16x8*)&Ah[ra];
            al[i] = *(const f16x8*)&Al[ra];
            int rb = (wn * 64 + i * 16 + lm) * 40 + kq * 8;
            bh[i] = *(const f16x8*)&Bh[rb];
            bl[i] = *(const f16x8*)&Bl[rb];
        }
        #pragma unroll
        for (int i = 0; i < 4; ++i)
            #pragma unroll
            for (int j = 0; j < 4; ++j) {
                acc[i][j] = __builtin_amdgcn_mfma_f32_16x16x32_f16(ah[i], bh[j], acc[i][j], 0, 0, 0);
                acc[i][j] = __builtin_amdgcn_mfma_f32_16x16x32_f16(ah[i], bl[j], acc[i][j], 0, 0, 0);
                acc[i][j] = __builtin_amdgcn_mfma_f32_16x16x32_f16(al[i], bh[j], acc[i][j], 0, 0, 0);
            }
    }

    // C/D layout: col = lane&15 (n), row = (lane>>4)*4 + r (m).
    #pragma unroll
    for (int j = 0; j < 4; ++j) {
        int ng = n0 + wn * 64 + j * 16 + lm;   // embed col = h*64 + d
        int h = ng >> 6, d = ng & 63;
        float bv_ = bias[ng];
        #pragma unroll
        for (int i = 0; i < 4; ++i) {
            #pragma unroll
            for (int r = 0; r < 4; ++r) {
                int mg = m0 + wm * 64 + i * 16 + kq * 4 + r;
                int b = mg >> 11, t = mg & 2047;
                dst[((size_t)((b * NHEAD + h) * T_LEN + t)) * HDIM + d] =
                    (acc[i][j][r] + bv_) * scale;
            }
        }
    }
}

// ---------------------------------------------------------------------------
// Kernel B1: count + compact distinct sampled indices (single block).
// ---------------------------------------------------------------------------
__global__ __launch_bounds__(256)
void count_compact_kernel(const int* __restrict__ idxs, int n,
                          int* __restrict__ count, int* __restrict__ klist,
                          int* __restrict__ ncp)
{
    __shared__ int cnt[T_LEN];
    __shared__ int th_tot[256];
    __shared__ int th_off[256];
    __shared__ int ncs;
    const int tid = threadIdx.x;
    for (int j = tid; j < T_LEN; j += 256) cnt[j] = 0;
    __syncthreads();
    for (int i = tid; i < n; i += 256) atomicAdd(&cnt[idxs[i] & (T_LEN - 1)], 1);
    __syncthreads();
    const int base = tid * 8;
    int flags[8]; int loc = 0;
    #pragma unroll
    for (int j = 0; j < 8; ++j) {
        int c = cnt[base + j];
        count[base + j] = c;
        flags[j] = (c > 0); loc += flags[j];
    }
    th_tot[tid] = loc;
    __syncthreads();
    if (tid == 0) {
        int run = 0;
        for (int i = 0; i < 256; ++i) { th_off[i] = run; run += th_tot[i]; }
        ncs = run;
        ncp[0] = run;
    }
    __syncthreads();
    int off = th_off[tid];
    #pragma unroll
    for (int j = 0; j < 8; ++j)
        if (flags[j]) klist[off++] = base + j;
    __syncthreads();
    const int nc = ncs;
    const int nt = (nc + 127) & ~127;
    const int k0 = klist[0];
    for (int j = nc + tid; j < nt; j += 256) klist[j] = k0;
}

// ---------------------------------------------------------------------------
// Kernel B2a: partial ksum/vsum per (bh, slice). Coalesced float4 streaming.
// ---------------------------------------------------------------------------
__global__ __launch_bounds__(256)
void ksum_vmean_part_kernel(const int* __restrict__ count,
                            const float* __restrict__ k, const float* __restrict__ v,
                            float* __restrict__ kpart, float* __restrict__ vpart)
{
    __shared__ int cs[256];
    alignas(16) __shared__ float rk[16 * 64];
    alignas(16) __shared__ float rv[16 * 64];

    const int sl = blockIdx.x, bh = blockIdx.y, tid = threadIdx.x;
    const int f4 = tid & 15, tg = tid >> 4;
    const int t0 = sl * 256;

    cs[tid] = count[t0 + tid];
    __syncthreads();

    const float4* k4 = (const float4*)(k + (size_t)bh * T_LEN * HDIM) + t0 * 16;
    const float4* v4 = (const float4*)(v + (size_t)bh * T_LEN * HDIM) + t0 * 16;

    float4 ak = {0.f, 0.f, 0.f, 0.f}, av = {0.f, 0.f, 0.f, 0.f};
    #pragma unroll
    for (int s = 0; s < 16; ++s) {
        int t = tg + s * 16;
        float c = (float)cs[t];
        float4 kf = k4[t * 16 + f4];
        float4 vf = v4[t * 16 + f4];
        ak.x = fmaf(c, kf.x, ak.x); ak.y = fmaf(c, kf.y, ak.y);
        ak.z = fmaf(c, kf.z, ak.z); ak.w = fmaf(c, kf.w, ak.w);
        av.x += vf.x; av.y += vf.y; av.z += vf.z; av.w += vf.w;
    }
    *(float4*)&rk[tg * 64 + f4 * 4] = ak;
    *(float4*)&rv[tg * 64 + f4 * 4] = av;
    __syncthreads();

    if (tid < 64) {
        float sk = 0.f, sv = 0.f;
        #pragma unroll
        for (int g = 0; g < 16; ++g) { sk += rk[g * 64 + tid]; sv += rv[g * 64 + tid]; }
        kpart[((size_t)bh * 8 + sl) * 64 + tid] = sk;
        vpart[((size_t)bh * 8 + sl) * 64 + tid] = sv;
    }
}

// ---------------------------------------------------------------------------
// Kernel B2b: reduce 8 slice-partials -> ksum[bh][d], vmean[bh][d].
// ---------------------------------------------------------------------------
__global__ __launch_bounds__(64)
void ksum_vmean_reduce_kernel(const float* __restrict__ kpart, const float* __restrict__ vpart,
                              float* __restrict__ ksum, float* __restrict__ vmean)
{
    const int bh = blockIdx.x, d = threadIdx.x;
    float sk = 0.f, sv = 0.f;
    #pragma unroll
    for (int sl = 0; sl < 8; ++sl) {
        sk += kpart[((size_t)bh * 8 + sl) * 64 + d];
        sv += vpart[((size_t)bh * 8 + sl) * 64 + d];
    }
    ksum[bh * 64 + d]  = sk;
    vmean[bh * 64 + d] = sv * (1.0f / 2048.0f);
}

// ---------------------------------------------------------------------------
// Kernel C: sparsity scan over compacted sampled keys (fp32, 128x128 tile).
// ---------------------------------------------------------------------------
__global__ __launch_bounds__(256)
void sparsity_scan_kernel(const float* __restrict__ q, const float* __restrict__ k,
                          const float* __restrict__ ksum, const int* __restrict__ klist,
                          const int* __restrict__ ncp, float* __restrict__ spars)
{
    alignas(16) __shared__ float qs[64 * 128];   // [d][qq]
    alignas(16) __shared__ float ks[64 * 128];   // [d][kk] (reused as reduce buf)
    __shared__ float ksm[64];

    const int tid = threadIdx.x;
    const int bh = blockIdx.y;
    const int q0 = blockIdx.x * 128;
    const int ti = tid >> 4, tj = tid & 15;

    const float* qb = q + ((size_t)bh * T_LEN + q0) * HDIM;
    const float* kb = k + (size_t)bh * T_LEN * HDIM;
    const int ntiles = (ncp[0] + 127) >> 7;

    #pragma unroll
    for (int s = 0; s < 8; ++s) {
        int u = tid + 256 * s;
        int qq = u & 127, c4 = u >> 7;
        float4 f = *(const float4*)&qb[qq * HDIM + c4 * 4];
        qs[(c4 * 4 + 0) * 128 + qq] = f.x;
        qs[(c4 * 4 + 1) * 128 + qq] = f.y;
        qs[(c4 * 4 + 2) * 128 + qq] = f.z;
        qs[(c4 * 4 + 3) * 128 + qq] = f.w;
    }
    if (tid < 64) ksm[tid] = ksum[bh * 64 + tid];

    float vmax[8];
    #pragma unroll
    for (int i = 0; i < 8; ++i) vmax[i] = -INFINITY;

    for (int kt = 0; kt < ntiles; ++kt) {
        __syncthreads();
        #pragma unroll
        for (int s = 0; s < 8; ++s) {
            int u = tid + 256 * s;
            int kk = u & 127, c4 = u >> 7;
            int row = klist[kt * 128 + kk];
            float4 f = *(const float4*)&kb[row * HDIM + c4 * 4];
            ks[(c4 * 4 + 0) * 128 + kk] = f.x;
            ks[(c4 * 4 + 1) * 128 + kk] = f.y;
            ks[(c4 * 4 + 2) * 128 + kk] = f.z;
            ks[(c4 * 4 + 3) * 128 + kk] = f.w;
        }
        __syncthreads();

        float dot[8][8];
        #pragma unroll
        for (int i = 0; i < 8; ++i)
            #pragma unroll
            for (int j = 0; j < 8; ++j) dot[i][j] = 0.0f;

        #pragma unroll 4
        for (int d = 0; d < 64; ++d) {
            float4 qa = *(const float4*)&qs[d * 128 + ti * 8];
            float4 qc = *(const float4*)&qs[d * 128 + ti * 8 + 4];
            float4 ka = *(const float4*)&ks[d * 128 + tj * 4];
            float4 kc = *(const float4*)&ks[d * 128 + 64 + tj * 4];
            float qv[8] = {qa.x, qa.y, qa.z, qa.w, qc.x, qc.y, qc.z, qc.w};
            float kv[8] = {ka.x, ka.y, ka.z, ka.w, kc.x, kc.y, kc.z, kc.w};
            #pragma unroll
            for (int i = 0; i < 8; ++i)
                #pragma unroll
                for (int j = 0; j < 8; ++j)
                    dot[i][j] = fmaf(qv[i], kv[j], dot[i][j]);
        }
        #pragma unroll
        for (int i = 0; i < 8; ++i) {
            float m8 = dot[i][0];
            #pragma unroll
            for (int j = 1; j < 8; ++j) m8 = fmaxf(m8, dot[i][j]);
            vmax[i] = fmaxf(vmax[i], m8);
        }
    }
    __syncthreads();

    float* red = ks;
    #pragma unroll
    for (int i = 0; i < 8; ++i) red[(ti * 8 + i) * 17 + tj] = vmax[i];
    __syncthreads();
    if (tid < 128) {
        float m = red[tid * 17];
        #pragma unroll
        for (int j = 1; j < 16; ++j) m = fmaxf(m, red[tid * 17 + j]);
        float sdot = 0.f;
        #pragma unroll
        for (int d = 0; d < 64; ++d) sdot = fmaf(qs[d * 128 + tid], ksm[d], sdot);
        spars[bh * T_LEN + q0 + tid] = m - sdot * (1.0f / 2048.0f);
    }
}

// ---------------------------------------------------------------------------
// Kernel D: top-40 per bh by iterative argmax (ties -> smaller index).
// ---------------------------------------------------------------------------
__global__ __launch_bounds__(256)
void topk_kernel(const float* __restrict__ spars, int* __restrict__ topi)
{
    __shared__ float vals[T_LEN];
    __shared__ float rv[256];
    __shared__ int   ri[256];
    const int bh = blockIdx.x, tid = threadIdx.x;
    for (int j = tid; j < T_LEN; j += 256) vals[j] = spars[bh * T_LEN + j];
    __syncthreads();
    for (int it = 0; it < USEL; ++it) {
        float bv = -INFINITY; int bi = 0;
        #pragma unroll
        for (int jj = 0; jj < 8; ++jj) {
            int j = tid * 8 + jj;
            float vv = vals[j];
            if (vv > bv) { bv = vv; bi = j; }
        }
        rv[tid] = bv; ri[tid] = bi;
        __syncthreads();
        for (int s = 128; s > 0; s >>= 1) {
            if (tid < s) {
                float ov = rv[tid + s]; int oi = ri[tid + s];
                if (ov > rv[tid] || (ov == rv[tid] && oi < ri[tid])) { rv[tid] = ov; ri[tid] = oi; }
            }
            __syncthreads();
        }
        if (tid == 0) {
            int win = ri[0] & (T_LEN - 1);
            topi[bh * USEL + it] = win;
            vals[win] = -INFINITY;
        }
        __syncthreads();
    }
}

// ---------------------------------------------------------------------------
// Kernel E1: gather selected q rows -> qsel[bh][u][d]. (q dead afterwards)
// ---------------------------------------------------------------------------
__global__ __launch_bounds__(256)
void gather_q_kernel(const float* __restrict__ q, const int* __restrict__ topi,
                     float* __restrict__ qsel)
{
    const int bh = blockIdx.x, tid = threadIdx.x;
    for (int i = tid; i < USEL * HDIM; i += 256) {
        int u = i >> 6, d = i & 63;
        int t = topi[bh * USEL + u] & (T_LEN - 1);
        qsel[(size_t)bh * USEL * HDIM + i] = q[((size_t)bh * T_LEN + t) * HDIM + d];
    }
}

// ---------------------------------------------------------------------------
// Kernel E2: S[bh][u][t] = qsel[bh][u] . k[bh][t]. Grid (8 t-slices, 32 bh).
// ---------------------------------------------------------------------------
__global__ __launch_bounds__(256)
void sel_scores_kernel(const float* __restrict__ qsel, const float* __restrict__ k,
                       float* __restrict__ S)
{
    __shared__ float qsT[64 * 41];    // [d][u] stride 41
    __shared__ float ksT[64 * 257];   // [d][t] stride 257

    const int sl = blockIdx.x, bh = blockIdx.y, tid = threadIdx.x;
    const int t0 = sl * 256;

    for (int i = tid; i < USEL * HDIM; i += 256) {
        int u = i >> 6, d = i & 63;
        qsT[d * 41 + u] = qsel[(size_t)bh * USEL * HDIM + i];
    }
    const float4* k4 = (const float4*)(k + (size_t)bh * T_LEN * HDIM);
    #pragma unroll
    for (int s = 0; s < 16; ++s) {
        int u = tid + 256 * s;          // 0..4095
        int c4 = u & 15, t = u >> 4;    // t 0..255
        float4 f = k4[(t0 + t) * 16 + c4];
        ksT[(c4 * 4 + 0) * 257 + t] = f.x;
        ksT[(c4 * 4 + 1) * 257 + t] = f.y;
        ksT[(c4 * 4 + 2) * 257 + t] = f.z;
        ksT[(c4 * 4 + 3) * 257 + t] = f.w;
    }
    __syncthreads();

    const int qg = tid >> 5;   // 0..7 -> 5 queries each
    const int kg = tid & 31;   // strided keys: kg + 32*j

    float acc[5][8];
    #pragma unroll
    for (int i = 0; i < 5; ++i)
        #pragma unroll
        for (int j = 0; j < 8; ++j) acc[i][j] = 0.0f;

    #pragma unroll 4
    for (int d = 0; d < 64; ++d) {
        float qv[5], kv[8];
        #pragma unroll
        for (int i = 0; i < 5; ++i) qv[i] = qsT[d * 41 + qg * 5 + i];
        #pragma unroll
        for (int j = 0; j < 8; ++j) kv[j] = ksT[d * 257 + kg + 32 * j];
        #pragma unroll
        for (int i = 0; i < 5; ++i)
            #pragma unroll
            for (int j = 0; j < 8; ++j)
                acc[i][j] = fmaf(qv[i], kv[j], acc[i][j]);
    }

    #pragma unroll
    for (int i = 0; i < 5; ++i) {
        float* sp = &S[((size_t)bh * USEL + qg * 5 + i) * T_LEN + t0 + kg];
        #pragma unroll
        for (int j = 0; j < 8; ++j) sp[32 * j] = acc[i][j];
    }
}

// ---------------------------------------------------------------------------
// Kernel E3: in-place softmax over each S row (1280 rows of 2048).
// ---------------------------------------------------------------------------
__global__ __launch_bounds__(256)
void sel_softmax_kernel(float* __restrict__ S)
{
    __shared__ float red[256];
    const int row = blockIdx.x, tid = threadIdx.x;
    float* sr = S + (size_t)row * T_LEN;

    float x[8];
    float m = -INFINITY;
    #pragma unroll
    for (int s = 0; s < 8; ++s) { x[s] = sr[tid + 256 * s]; m = fmaxf(m, x[s]); }
    red[tid] = m;
    __syncthreads();
    for (int s = 128; s > 0; s >>= 1) {
        if (tid < s) red[tid] = fmaxf(red[tid], red[tid + s]);
        __syncthreads();
    }
    m = red[0];
    __syncthreads();

    float sum = 0.f;
    #pragma unroll
    for (int s = 0; s < 8; ++s) { x[s] = __expf(x[s] - m); sum += x[s]; }
    red[tid] = sum;
    __syncthreads();
    for (int s = 128; s > 0; s >>= 1) {
        if (tid < s) red[tid] += red[tid + s];
        __syncthreads();
    }
    float inv = 1.0f / red[0];
    #pragma unroll
    for (int s = 0; s < 8; ++s) sr[tid + 256 * s] = x[s] * inv;
}

// ---------------------------------------------------------------------------
// Kernel E4: PV partial. Grid (16 t-slices, 32 bh).
// ---------------------------------------------------------------------------
__global__ __launch_bounds__(256)
void pv_part_kernel(const float* __restrict__ S, const float* __restrict__ v,
                    float* __restrict__ part)
{
    __shared__ float ps[USEL * 128];      // [q][t]
    __shared__ float vs[128 * 69];        // [t][d] stride 69
    __shared__ float obuf[128 * 20];

    const int sl = blockIdx.x, bh = blockIdx.y, tid = threadIdx.x;
    const int t0 = sl * 128;

    for (int i = tid; i < USEL * 128; i += 256) {
        int q = i >> 7, t = i & 127;
        ps[q * 128 + t] = S[((size_t)bh * USEL + q) * T_LEN + t0 + t];
    }
    const float4* v4 = (const float4*)(v + (size_t)bh * T_LEN * HDIM);
    #pragma unroll
    for (int s = 0; s < 8; ++s) {
        int u = tid + 256 * s;          // 0..2047
        int c4 = u & 15, t = u >> 4;    // t 0..127
        float4 f = v4[(t0 + t) * 16 + c4];
        vs[t * 69 + c4 * 4 + 0] = f.x;
        vs[t * 69 + c4 * 4 + 1] = f.y;
        vs[t * 69 + c4 * 4 + 2] = f.z;
        vs[t * 69 + c4 * 4 + 3] = f.w;
    }
    __syncthreads();

    const int qg = tid >> 5, r = tid & 31;
    const int dg = r >> 1, th = r & 1;
    const int tb = th * 64;

    float o[5][4];
    #pragma unroll
    for (int i = 0; i < 5; ++i)
        #pragma unroll
        for (int j = 0; j < 4; ++j) o[i][j] = 0.0f;

    #pragma unroll 4
    for (int tt = 0; tt < 64; ++tt) {
        int t = tb + tt;
        float pv[5];
        #pragma unroll
        for (int i = 0; i < 5; ++i) pv[i] = ps[(qg * 5 + i) * 128 + t];
        float4 vv = *(const float4*)&vs[t * 69 + dg * 4];
        #pragma unroll
        for (int i = 0; i < 5; ++i) {
            o[i][0] = fmaf(pv[i], vv.x, o[i][0]);
            o[i][1] = fmaf(pv[i], vv.y, o[i][1]);
            o[i][2] = fmaf(pv[i], vv.z, o[i][2]);
            o[i][3] = fmaf(pv[i], vv.w, o[i][3]);
        }
    }

    const int p = qg * 16 + dg;   // 0..127
    if (th == 1) {
        #pragma unroll
        for (int i = 0; i < 5; ++i)
            #pragma unroll
            for (int j = 0; j < 4; ++j) obuf[p * 20 + i * 4 + j] = o[i][j];
    }
    __syncthreads();
    if (th == 0) {
        float* pb = part + ((size_t)bh * 16 + sl) * (USEL * HDIM);
        #pragma unroll
        for (int i = 0; i < 5; ++i)
            #pragma unroll
            for (int j = 0; j < 4; ++j)
                pb[(qg * 5 + i) * HDIM + dg * 4 + j] = o[i][j] + obuf[p * 20 + i * 4 + j];
    }
}

// ---------------------------------------------------------------------------
// Kernel E5: deterministic merge of 16 PV partials -> attn[bh][u][d].
// ---------------------------------------------------------------------------
__global__ __launch_bounds__(256)
void pv_merge_kernel(const float* __restrict__ part, float* __restrict__ attn)
{
    const int bh = blockIdx.x, tid = threadIdx.x;
    for (int i = tid; i < USEL * HDIM; i += 256) {
        float s = 0.f;
        #pragma unroll
        for (int sl = 0; sl < 16; ++sl)
            s += part[((size_t)bh * 16 + sl) * (USEL * HDIM) + i];
        attn[(size_t)bh * USEL * HDIM + i] = s;
    }
}

// ---------------------------------------------------------------------------
// Kernel F1: fill context (B,T,E layout, fp32) with per-head vmean.
// ---------------------------------------------------------------------------
__global__ __launch_bounds__(256)
void ctx_fill_kernel(const float* __restrict__ vmean, float* __restrict__ ctx)
{
    int flat = blockIdx.x * 256 + threadIdx.x;
    int d = flat & 63, h = (flat >> 6) & 7, b = flat >> 20;
    int bh = (b << 3) | h;
    ctx[flat] = vmean[bh * 64 + d];
}

// ---------------------------------------------------------------------------
// Kernel F2: scatter attn rows into context at top_idx positions.
// ---------------------------------------------------------------------------
__global__ void ctx_scatter_kernel(const float* __restrict__ attn, const int* __restrict__ topi,
                                   float* __restrict__ ctx)
{
    const int u = blockIdx.x, bh = blockIdx.y, d = threadIdx.x;
    const int b = bh >> 3, h = bh & 7;
    const int t = topi[bh * USEL + u] & (T_LEN - 1);
    ctx[(size_t)(b * T_LEN + t) * EMB + h * 64 + d] =
        attn[((size_t)bh * USEL + u) * HDIM + d];
}

// ---------------------------------------------------------------------------
// Kernel G: out = ctx @ Wo^T + bo via bf16 hi+lo 3-pass MFMA (16x16x32).
// 128x128 tile, BK=32. acc += Ah*Bh + Ah*Bl + Al*Bh (drop Al*Bl ~2^-18).
// u16 tiles stride 40 (16B-aligned fragments, 2-way banks). C/D layout:
// col=lane&15 (n), row=(lane>>4)*4+r (m). Output tolerance 4.3e-3 >> 1e-5 err.
// Selection path (q/k/topk) untouched by this change.
// ---------------------------------------------------------------------------
__global__ __launch_bounds__(256)
void out_proj_kernel(const float* __restrict__ A, const float* __restrict__ Wo,
                     const float* __restrict__ bo, float* __restrict__ out)
{
    alignas(16) __shared__ u16 Ah[128 * 40];
    alignas(16) __shared__ u16 Al[128 * 40];
    alignas(16) __shared__ u16 Bh[128 * 40];
    alignas(16) __shared__ u16 Bl[128 * 40];

    const int tid = threadIdx.x;
    const int m0 = blockIdx.x * 128;
    const int n0 = blockIdx.y * 128;
    const int w = tid >> 6, lane = tid & 63;
    const int wm = w & 1, wn = w >> 1;
    const int lm = lane & 15, kq = lane >> 4;

    f32x4 acc[4][4];
    #pragma unroll
    for (int i = 0; i < 4; ++i)
        #pragma unroll
        for (int j = 0; j < 4; ++j)
            #pragma unroll
            for (int r = 0; r < 4; ++r) acc[i][j][r] = 0.0f;

    for (int kc = 0; kc < EMB; kc += 32) {
        __syncthreads();
        #pragma unroll
        for (int s = 0; s < 4; ++s) {
            int u = tid + 256 * s;        // 0..1023
            int row = u >> 3, c4 = u & 7; // row 0..127, c4 0..7 (k-quad)
            float4 fa = *(const float4*)&A[(size_t)(m0 + row) * EMB + kc + c4 * 4];
            float4 fb = *(const float4*)&Wo[(n0 + row) * EMB + kc + c4 * 4];
            uint2 ph, pl;
            cvt4_hilo(fa, ph, pl);
            *(uint2*)&Ah[row * 40 + c4 * 4] = ph;
            *(uint2*)&Al[row * 40 + c4 * 4] = pl;
            cvt4_hilo(fb, ph, pl);
            *(uint2*)&Bh[row * 40 + c4 * 4] = ph;
            *(uint2*)&Bl[row * 40 + c4 * 4] = pl;
        }
        __syncthreads();

        bf16v8 ah[4], al[4], bh[4], bl[4];
        #pragma unroll
        for (int i = 0; i < 4; ++i) {
            int ra = (wm * 64 + i * 16 + lm) * 40 + kq * 8;
            ah[i] = *(const bf16v8*)&Ah[ra];
            al[i] = *(const bf16v8*)&Al[ra];
            int rb = (wn * 64 + i * 16 + lm) * 40 + kq * 8;
            bh[i] = *(const bf16v8*)&Bh[rb];
            bl[i] = *(const bf16v8*)&Bl[rb];
        }
        #pragma unroll
        for (int i = 0; i < 4; ++i)
            #pragma unroll
            for (int j = 0; j < 4; ++j) {
                acc[i][j] = __builtin_amdgcn_mfma_f32_16x16x32_bf16(ah[i], bh[j], acc[i][j], 0, 0, 0);
                acc[i][j] = __builtin_amdgcn_mfma_f32_16x16x32_bf16(ah[i], bl[j], acc[i][j], 0, 0, 0);
                acc[i][j] = __builtin_amdgcn_mfma_f32_16x16x32_bf16(al[i], bh[j], acc[i][j], 0, 0, 0);
            }
    }

    #pragma unroll
    for (int j = 0; j < 4; ++j) {
        int ng = n0 + wn * 64 + j * 16 + lm;
        float bias = bo[ng];
        #pragma unroll
        for (int i = 0; i < 4; ++i)
            #pragma unroll
            for (int r = 0; r < 4; ++r) {
                int mg = m0 + wm * 64 + i * 16 + kq * 4 + r;
                out[(size_t)mg * EMB + ng] = acc[i][j][r] + bias;
            }
    }
}

// ---------------------------------------------------------------------------
// Diagnostic: if ws_size is too small, report it via d_out (absmax ~= MiB).
// ---------------------------------------------------------------------------
__global__ __launch_bounds__(256)
void ws_diag_kernel(float* __restrict__ out, int n, float mib)
{
    int flat = blockIdx.x * 256 + threadIdx.x;
    if (flat < n) out[flat] = mib;
}

// ---------------------------------------------------------------------------
extern "C" void kernel_launch(void* const* d_in, const int* in_sizes, int n_in,
                              void* d_out, int out_size, void* d_ws, size_t ws_size,
                              hipStream_t stream)
{
    // fp32 inputs/outputs in dict order (confirmed). Bind by size; same-size
    // tensors in encounter (=dict) order: Wq, Wk, Wv, Wo.
    const float* X = nullptr; const int* idxs = nullptr;
    const float* Wseen[4] = {nullptr, nullptr, nullptr, nullptr};
    const float* bseen[4] = {nullptr, nullptr, nullptr, nullptr};
    int nw = 0, nb = 0, u_part = 2048;
    for (int i = 0; i < n_in; ++i) {
        int sz = in_sizes[i];
        if (sz == EMB * EMB * 16) { if (!X) X = (const float*)d_in[i]; }
        else if (sz == T_LEN)     { if (!idxs) { idxs = (const int*)d_in[i]; u_part = sz; } }
        else if (sz == EMB * EMB) { if (nw < 4) Wseen[nw++] = (const float*)d_in[i]; }
        else if (sz == EMB)       { if (nb < 4) bseen[nb++] = (const float*)d_in[i]; }
    }
    if (!X || !idxs || nw < 4 || nb < 4) {
        X = (const float*)d_in[0]; idxs = (const int*)d_in[1];
        Wseen[0] = (const float*)d_in[2]; bseen[0] = (const float*)d_in[3];
        Wseen[1] = (const float*)d_in[4]; bseen[1] = (const float*)d_in[5];
        Wseen[2] = (const float*)d_in[6]; bseen[2] = (const float*)d_in[7];
        Wseen[3] = (const float*)d_in[8]; bseen[3] = (const float*)d_in[9];
        u_part = in_sizes[1];
    }
    const float *Wq = Wseen[0], *Wk = Wseen[1], *Wv = Wseen[2], *Wo = Wseen[3];
    const float *bq = bseen[0], *bk = bseen[1], *bv = bseen[2], *bo = bseen[3];

    // Workspace layout (peak 50,951,168 B, unchanged).
    const size_t NEED = 50951168ULL;
    if (ws_size < NEED) {
        ws_diag_kernel<<<(out_size + 255) / 256, 256, 0, stream>>>(
            (float*)d_out, out_size, (float)(ws_size >> 20));
        return;
    }

    float* ws    = (float*)d_ws;
    float* qw    = ws;                    // 4,194,304 floats
    float* kw    = qw + 4194304;
    float* vw    = kw + 4194304;
    float* tail  = vw + 4194304;
    float* slotA = tail;                  // 81920: qsel, later attn
    float* spars = tail + 81920;          // 65536
    int*   count = (int*)(tail + 147456); // 2048
    float* ksum  = tail + 149504;         // 2048
    float* vmean = tail + 151552;         // 2048
    int*   topi  = (int*)(tail + 153600); // 1280
    float* kpart = tail;                  // overlays in slotA (disjoint liveness)
    float* vpart = tail + 16384;
    int*   klist = (int*)(tail + 32768);
    int*   ncp   = (int*)(tail + 34816);
    float* S     = qw;                    // q dead after gather
    float* pvp   = qw + 2621440;
    float* qsel  = slotA;
    float* attn  = slotA;
    float* ctx   = (float*)d_ws;

    qkv_proj_kernel<<<dim3(64, 4, 3), 256, 0, stream>>>(X, Wq, bq, Wk, bk, Wv, bv, qw, kw, vw);
    count_compact_kernel<<<1, 256, 0, stream>>>(idxs, u_part, count, klist, ncp);
    ksum_vmean_part_kernel<<<dim3(8, 32), 256, 0, stream>>>(count, kw, vw, kpart, vpart);
    ksum_vmean_reduce_kernel<<<32, 64, 0, stream>>>(kpart, vpart, ksum, vmean);
    sparsity_scan_kernel<<<dim3(16, 32), 256, 0, stream>>>(qw, kw, ksum, klist, ncp, spars);
    topk_kernel<<<32, 256, 0, stream>>>(spars, topi);
    gather_q_kernel<<<32, 256, 0, stream>>>(qw, topi, qsel);
    // qw dead; S/pvp take over that region.
    sel_scores_kernel<<<dim3(8, 32), 256, 0, stream>>>(qsel, kw, S);
    sel_softmax_kernel<<<1280, 256, 0, stream>>>(S);
    pv_part_kernel<<<dim3(16, 32), 256, 0, stream>>>(S, vw, pvp);
    pv_merge_kernel<<<32, 256, 0, stream>>>(pvp, attn);
    // S/pvp dead; ctx takes over the whole front region.
    ctx_fill_kernel<<<16384, 256, 0, stream>>>(vmean, ctx);
    ctx_scatter_kernel<<<dim3(USEL, BHEADS), 64, 0, stream>>>(attn, topi, ctx);
    out_proj_kernel<<<dim3(64, 4), 256, 0, stream>>>(ctx, Wo, bo, (float*)d_out);
}

// Round 2
// 358.911 us; speedup vs baseline: 1.4765x; 1.1840x over previous
//
#include <hip/hip_runtime.h>
#include <hip/hip_bf16.h>
#include <math.h>

#define T_LEN 2048
#define EMB   512
#define NHEAD 8
#define HDIM  64
#define BHEADS 32
#define USEL  40

typedef __bf16 bf16v8 __attribute__((ext_vector_type(8)));
typedef _Float16 f16x8 __attribute__((ext_vector_type(8)));
typedef float f32x4 __attribute__((ext_vector_type(4)));
typedef unsigned short u16;

// Split a float4 into bf16 hi + lo halves, packed as uint2 (4 x u16 each).
__device__ __forceinline__ void cvt4_hilo(const float4 f, uint2& ph, uint2& pl)
{
    __hip_bfloat16 h0 = __float2bfloat16(f.x);
    __hip_bfloat16 h1 = __float2bfloat16(f.y);
    __hip_bfloat16 h2 = __float2bfloat16(f.z);
    __hip_bfloat16 h3 = __float2bfloat16(f.w);
    __hip_bfloat16 l0 = __float2bfloat16(f.x - __bfloat162float(h0));
    __hip_bfloat16 l1 = __float2bfloat16(f.y - __bfloat162float(h1));
    __hip_bfloat16 l2 = __float2bfloat16(f.z - __bfloat162float(h2));
    __hip_bfloat16 l3 = __float2bfloat16(f.w - __bfloat162float(h3));
    ph.x = (unsigned)*(const u16*)&h0 | ((unsigned)*(const u16*)&h1 << 16);
    ph.y = (unsigned)*(const u16*)&h2 | ((unsigned)*(const u16*)&h3 << 16);
    pl.x = (unsigned)*(const u16*)&l0 | ((unsigned)*(const u16*)&l1 << 16);
    pl.y = (unsigned)*(const u16*)&l2 | ((unsigned)*(const u16*)&l3 << 16);
}

// Split a float4 into FP16 hi + lo halves, packed as uint2 (4 x u16 each).
// fp16 has 11-bit mantissa: h+l captures ~22 bits, residual <= 2^-22*|x|.
// Dropped Al*Bl term in the 3-pass GEMM is <= 2^-22*|ab| -> the f16 hi/lo
// 3-pass GEMM is fp32-rounding-equivalent (~1e-6), unlike bf16 hi/lo (~2^-16).
__device__ __forceinline__ void cvt4_hilo_h(const float4 f, uint2& ph, uint2& pl)
{
    _Float16 h0 = (_Float16)f.x;
    _Float16 h1 = (_Float16)f.y;
    _Float16 h2 = (_Float16)f.z;
    _Float16 h3 = (_Float16)f.w;
    _Float16 l0 = (_Float16)(f.x - (float)h0);
    _Float16 l1 = (_Float16)(f.y - (float)h1);
    _Float16 l2 = (_Float16)(f.z - (float)h2);
    _Float16 l3 = (_Float16)(f.w - (float)h3);
    ph.x = (unsigned)*(const u16*)&h0 | ((unsigned)*(const u16*)&h1 << 16);
    ph.y = (unsigned)*(const u16*)&h2 | ((unsigned)*(const u16*)&h3 << 16);
    pl.x = (unsigned)*(const u16*)&l0 | ((unsigned)*(const u16*)&l1 << 16);
    pl.y = (unsigned)*(const u16*)&l2 | ((unsigned)*(const u16*)&l3 << 16);
}

// ---------------------------------------------------------------------------
// Kernel A: fused QKV projection via FP16 hi+lo 3-pass MFMA (16x16x32_f16).
// Same geometry as out_proj (128x128 tile, BK=32, 4 waves, u16 stride 40).
// acc += Ah*Bh + Ah*Bl + Al*Bh; dropped Al*Bl ~2^-22 -> fp32-equivalent
// precision, so the top-k selection (rank-40/41 sparsity gap ~6.6e-3) is
// unaffected (perturbation ~1e-6, like any fp32 reassociation).
// ---------------------------------------------------------------------------
__global__ __launch_bounds__(256)
void qkv_proj_kernel(const float* __restrict__ X,
                     const float* __restrict__ Wq, const float* __restrict__ bq,
                     const float* __restrict__ Wk, const float* __restrict__ bk,
                     const float* __restrict__ Wv, const float* __restrict__ bv,
                     float* __restrict__ qo, float* __restrict__ ko, float* __restrict__ vo)
{
    alignas(16) __shared__ u16 Ah[128 * 40];
    alignas(16) __shared__ u16 Al[128 * 40];
    alignas(16) __shared__ u16 Bh[128 * 40];
    alignas(16) __shared__ u16 Bl[128 * 40];

    const int z = blockIdx.z;
    const float* W; const float* bias; float* dst; float scale;
    if (z == 0)      { W = Wq; bias = bq; dst = qo; scale = 0.125f; }
    else if (z == 1) { W = Wk; bias = bk; dst = ko; scale = 1.0f;   }
    else             { W = Wv; bias = bv; dst = vo; scale = 1.0f;   }

    const int tid = threadIdx.x;
    const int m0 = blockIdx.x * 128;
    const int n0 = blockIdx.y * 128;
    const int w = tid >> 6, lane = tid & 63;
    const int wm = w & 1, wn = w >> 1;
    const int lm = lane & 15, kq = lane >> 4;

    f32x4 acc[4][4];
    #pragma unroll
    for (int i = 0; i < 4; ++i)
        #pragma unroll
        for (int j = 0; j < 4; ++j)
            #pragma unroll
            for (int r = 0; r < 4; ++r) acc[i][j][r] = 0.0f;

    for (int kc = 0; kc < EMB; kc += 32) {
        __syncthreads();
        #pragma unroll
        for (int s = 0; s < 4; ++s) {
            int u = tid + 256 * s;        // 0..1023
            int row = u >> 3, c4 = u & 7; // row 0..127, c4 0..7 (k-quad)
            float4 fa = *(const float4*)&X[(size_t)(m0 + row) * EMB + kc + c4 * 4];
            float4 fb = *(const float4*)&W[(n0 + row) * EMB + kc + c4 * 4];
            uint2 ph, pl;
            cvt4_hilo_h(fa, ph, pl);
            *(uint2*)&Ah[row * 40 + c4 * 4] = ph;
            *(uint2*)&Al[row * 40 + c4 * 4] = pl;
            cvt4_hilo_h(fb, ph, pl);
            *(uint2*)&Bh[row * 40 + c4 * 4] = ph;
            *(uint2*)&Bl[row * 40 + c4 * 4] = pl;
        }
        __syncthreads();

        f16x8 ah[4], al[4], bh[4], bl[4];
        #pragma unroll
        for (int i = 0; i < 4; ++i) {
            int ra = (wm * 64 + i * 16 + lm) * 40 + kq * 8;
            ah[i] = *(const f16x8*)&Ah[ra];
            al[i] = *(const f16x8*)&Al[ra];
            int rb = (wn * 64 + i * 16 + lm) * 40 + kq * 8;
            bh[i] = *(const f16x8*)&Bh[rb];
            bl[i] = *(const f16x8*)&Bl[rb];
        }
        #pragma unroll
        for (int i = 0; i < 4; ++i)
            #pragma unroll
            for (int j = 0; j < 4; ++j) {
                acc[i][j] = __builtin_amdgcn_mfma_f32_16x16x32_f16(ah[i], bh[j], acc[i][j], 0, 0, 0);
                acc[i][j] = __builtin_amdgcn_mfma_f32_16x16x32_f16(ah[i], bl[j], acc[i][j], 0, 0, 0);
                acc[i][j] = __builtin_amdgcn_mfma_f32_16x16x32_f16(al[i], bh[j], acc[i][j], 0, 0, 0);
            }
    }

    // C/D layout: col = lane&15 (n), row = (lane>>4)*4 + r (m).
    #pragma unroll
    for (int j = 0; j < 4; ++j) {
        int ng = n0 + wn * 64 + j * 16 + lm;   // embed col = h*64 + d
        int h = ng >> 6, d = ng & 63;
        float bv_ = bias[ng];
        #pragma unroll
        for (int i = 0; i < 4; ++i) {
            #pragma unroll
            for (int r = 0; r < 4; ++r) {
                int mg = m0 + wm * 64 + i * 16 + kq * 4 + r;
                int b = mg >> 11, t = mg & 2047;
                dst[((size_t)((b * NHEAD + h) * T_LEN + t)) * HDIM + d] =
                    (acc[i][j][r] + bv_) * scale;
            }
        }
    }
}

// ---------------------------------------------------------------------------
// Kernel B1: count + compact distinct sampled indices (single block).
// ---------------------------------------------------------------------------
__global__ __launch_bounds__(256)
void count_compact_kernel(const int* __restrict__ idxs, int n,
                          int* __restrict__ count, int* __restrict__ klist,
                          int* __restrict__ ncp)
{
    __shared__ int cnt[T_LEN];
    __shared__ int th_tot[256];
    __shared__ int th_off[256];
    __shared__ int ncs;
    const int tid = threadIdx.x;
    for (int j = tid; j < T_LEN; j += 256) cnt[j] = 0;
    __syncthreads();
    for (int i = tid; i < n; i += 256) atomicAdd(&cnt[idxs[i] & (T_LEN - 1)], 1);
    __syncthreads();
    const int base = tid * 8;
    int flags[8]; int loc = 0;
    #pragma unroll
    for (int j = 0; j < 8; ++j) {
        int c = cnt[base + j];
        count[base + j] = c;
        flags[j] = (c > 0); loc += flags[j];
    }
    th_tot[tid] = loc;
    __syncthreads();
    if (tid == 0) {
        int run = 0;
        for (int i = 0; i < 256; ++i) { th_off[i] = run; run += th_tot[i]; }
        ncs = run;
        ncp[0] = run;
    }
    __syncthreads();
    int off = th_off[tid];
    #pragma unroll
    for (int j = 0; j < 8; ++j)
        if (flags[j]) klist[off++] = base + j;
    __syncthreads();
    const int nc = ncs;
    const int nt = (nc + 127) & ~127;
    const int k0 = klist[0];
    for (int j = nc + tid; j < nt; j += 256) klist[j] = k0;
}

// ---------------------------------------------------------------------------
// Kernel B2a: partial ksum/vsum per (bh, slice). Coalesced float4 streaming.
// ---------------------------------------------------------------------------
__global__ __launch_bounds__(256)
void ksum_vmean_part_kernel(const int* __restrict__ count,
                            const float* __restrict__ k, const float* __restrict__ v,
                            float* __restrict__ kpart, float* __restrict__ vpart)
{
    __shared__ int cs[256];
    alignas(16) __shared__ float rk[16 * 64];
    alignas(16) __shared__ float rv[16 * 64];

    const int sl = blockIdx.x, bh = blockIdx.y, tid = threadIdx.x;
    const int f4 = tid & 15, tg = tid >> 4;
    const int t0 = sl * 256;

    cs[tid] = count[t0 + tid];
    __syncthreads();

    const float4* k4 = (const float4*)(k + (size_t)bh * T_LEN * HDIM) + t0 * 16;
    const float4* v4 = (const float4*)(v + (size_t)bh * T_LEN * HDIM) + t0 * 16;

    float4 ak = {0.f, 0.f, 0.f, 0.f}, av = {0.f, 0.f, 0.f, 0.f};
    #pragma unroll
    for (int s = 0; s < 16; ++s) {
        int t = tg + s * 16;
        float c = (float)cs[t];
        float4 kf = k4[t * 16 + f4];
        float4 vf = v4[t * 16 + f4];
        ak.x = fmaf(c, kf.x, ak.x); ak.y = fmaf(c, kf.y, ak.y);
        ak.z = fmaf(c, kf.z, ak.z); ak.w = fmaf(c, kf.w, ak.w);
        av.x += vf.x; av.y += vf.y; av.z += vf.z; av.w += vf.w;
    }
    *(float4*)&rk[tg * 64 + f4 * 4] = ak;
    *(float4*)&rv[tg * 64 + f4 * 4] = av;
    __syncthreads();

    if (tid < 64) {
        float sk = 0.f, sv = 0.f;
        #pragma unroll
        for (int g = 0; g < 16; ++g) { sk += rk[g * 64 + tid]; sv += rv[g * 64 + tid]; }
        kpart[((size_t)bh * 8 + sl) * 64 + tid] = sk;
        vpart[((size_t)bh * 8 + sl) * 64 + tid] = sv;
    }
}

// ---------------------------------------------------------------------------
// Kernel B2b: reduce 8 slice-partials -> ksum[bh][d], vmean[bh][d].
// ---------------------------------------------------------------------------
__global__ __launch_bounds__(64)
void ksum_vmean_reduce_kernel(const float* __restrict__ kpart, const float* __restrict__ vpart,
                              float* __restrict__ ksum, float* __restrict__ vmean)
{
    const int bh = blockIdx.x, d = threadIdx.x;
    float sk = 0.f, sv = 0.f;
    #pragma unroll
    for (int sl = 0; sl < 8; ++sl) {
        sk += kpart[((size_t)bh * 8 + sl) * 64 + d];
        sv += vpart[((size_t)bh * 8 + sl) * 64 + d];
    }
    ksum[bh * 64 + d]  = sk;
    vmean[bh * 64 + d] = sv * (1.0f / 2048.0f);
}

// ---------------------------------------------------------------------------
// Kernel C: sparsity scan via FP16 hi+lo 3-pass MFMA (16x16x32_f16).
// Grid (16 q-tiles, 32 bh) x 256 thr. Each wave owns 32 q rows x all 128
// gathered keys. q tile staged hi/lo once into stride-40 u16 LDS, A-frags
// hoisted to registers (LDS then reused for per-tile gathered K). Per k-tile:
// 8 n-blocks x (2m x 2kc x 3 passes) MFMA, max-folded immediately into
// vmax[2][4]; accumulators never cross tiles. C/D: col=lane&15,
// row=(lane>>4)*4+r. Row max: shfl_xor 1/2/4/8 over the lm group.
// sdot (mean term) from hi+lo q-frags (2^-22-exact) . fp32 ksum, reduced
// via shfl_xor 16/32 over kq groups. Perturbation ~1e-6 << 6.6e-3 rank gap.
// Replaces the fp32 VALU GEMM (155 us, MfmaUtil=0).
// ---------------------------------------------------------------------------
__global__ __launch_bounds__(256)
void sparsity_scan_kernel(const float* __restrict__ q, const float* __restrict__ k,
                          const float* __restrict__ ksum, const int* __restrict__ klist,
                          const int* __restrict__ ncp, float* __restrict__ spars)
{
    alignas(16) __shared__ u16 KH[256 * 40];   // [chunk][row][40]; q tile, then k tiles
    alignas(16) __shared__ u16 KL[256 * 40];
    __shared__ float ksm[64];
    __shared__ float smax[128];
    __shared__ float sdotL[128];

    const int tid = threadIdx.x;
    const int bh = blockIdx.y;
    const int q0 = blockIdx.x * 128;
    const int w = tid >> 6, lane = tid & 63;
    const int lm = lane & 15, kq = lane >> 4;

    const float* qb = q + ((size_t)bh * T_LEN + q0) * HDIM;
    const float4* kb4 = (const float4*)(k + (size_t)bh * T_LEN * HDIM);
    const int ntiles = (ncp[0] + 127) >> 7;

    if (tid < 64) ksm[tid] = ksum[bh * 64 + tid];

    // Stage q tile (128 rows x 64 d) as f16 hi/lo, chunked [c][row][40].
    #pragma unroll
    for (int s = 0; s < 8; ++s) {
        int u = tid + 256 * s;          // 0..2047 float4s
        int row = u >> 4, c4 = u & 15;  // row 0..127, c4 0..15
        float4 f = *(const float4*)&qb[row * HDIM + c4 * 4];
        uint2 ph, pl;
        cvt4_hilo_h(f, ph, pl);
        int base = ((c4 >> 3) * 128 + row) * 40 + (c4 & 7) * 4;
        *(uint2*)&KH[base] = ph;
        *(uint2*)&KL[base] = pl;
    }
    __syncthreads();

    // Each wave owns q rows w*32 .. w*32+31: hoist A-fragments to registers.
    f16x8 qh[2][2], ql[2][2];
    #pragma unroll
    for (int i = 0; i < 2; ++i)
        #pragma unroll
        for (int c = 0; c < 2; ++c) {
            int ra = (c * 128 + w * 32 + i * 16 + lm) * 40 + kq * 8;
            qh[i][c] = *(const f16x8*)&KH[ra];
            ql[i][c] = *(const f16x8*)&KL[ra];
        }

    // sdot = q . ksum for row w*32 + i*16 + lm (lane partial over its k-elems).
    {
        float4 k0a = *(const float4*)&ksm[kq * 8];
        float4 k0b = *(const float4*)&ksm[kq * 8 + 4];
        float4 k1a = *(const float4*)&ksm[32 + kq * 8];
        float4 k1b = *(const float4*)&ksm[32 + kq * 8 + 4];
        float kmv[2][8] = {{k0a.x, k0a.y, k0a.z, k0a.w, k0b.x, k0b.y, k0b.z, k0b.w},
                           {k1a.x, k1a.y, k1a.z, k1a.w, k1b.x, k1b.y, k1b.z, k1b.w}};
        #pragma unroll
        for (int i = 0; i < 2; ++i) {
            float sd = 0.f;
            #pragma unroll
            for (int c = 0; c < 2; ++c)
                #pragma unroll
                for (int e = 0; e < 8; ++e)
                    sd = fmaf((float)qh[i][c][e] + (float)ql[i][c][e], kmv[c][e], sd);
            sd += __shfl_xor(sd, 16, 64);
            sd += __shfl_xor(sd, 32, 64);
            if (kq == 0) sdotL[w * 32 + i * 16 + lm] = sd;
        }
    }

    float vmax[2][4];
    #pragma unroll
    for (int i = 0; i < 2; ++i)
        #pragma unroll
        for (int r = 0; r < 4; ++r) vmax[i][r] = -INFINITY;

    for (int kt = 0; kt < ntiles; ++kt) {
        __syncthreads();   // prior reads of KH/KL (incl. q-frag loads) done
        #pragma unroll
        for (int s = 0; s < 8; ++s) {
            int u = tid + 256 * s;
            int row = u >> 4, c4 = u & 15;
            int krow = klist[kt * 128 + row];
            float4 f = kb4[krow * 16 + c4];
            uint2 ph, pl;
            cvt4_hilo_h(f, ph, pl);
            int base = ((c4 >> 3) * 128 + row) * 40 + (c4 & 7) * 4;
            *(uint2*)&KH[base] = ph;
            *(uint2*)&KL[base] = pl;
        }
        __syncthreads();

        #pragma unroll
        for (int j = 0; j < 8; ++j) {
            int rb0 = (j * 16 + lm) * 40 + kq * 8;          // chunk 0
            int rb1 = (128 + j * 16 + lm) * 40 + kq * 8;    // chunk 1
            f16x8 bh0 = *(const f16x8*)&KH[rb0];
            f16x8 bl0 = *(const f16x8*)&KL[rb0];
            f16x8 bh1 = *(const f16x8*)&KH[rb1];
            f16x8 bl1 = *(const f16x8*)&KL[rb1];
            f32x4 a0 = {0.f, 0.f, 0.f, 0.f};
            f32x4 a1 = {0.f, 0.f, 0.f, 0.f};
            a0 = __builtin_amdgcn_mfma_f32_16x16x32_f16(qh[0][0], bh0, a0, 0, 0, 0);
            a1 = __builtin_amdgcn_mfma_f32_16x16x32_f16(qh[1][0], bh0, a1, 0, 0, 0);
            a0 = __builtin_amdgcn_mfma_f32_16x16x32_f16(qh[0][0], bl0, a0, 0, 0, 0);
            a1 = __builtin_amdgcn_mfma_f32_16x16x32_f16(qh[1][0], bl0, a1, 0, 0, 0);
            a0 = __builtin_amdgcn_mfma_f32_16x16x32_f16(ql[0][0], bh0, a0, 0, 0, 0);
            a1 = __builtin_amdgcn_mfma_f32_16x16x32_f16(ql[1][0], bh0, a1, 0, 0, 0);
            a0 = __builtin_amdgcn_mfma_f32_16x16x32_f16(qh[0][1], bh1, a0, 0, 0, 0);
            a1 = __builtin_amdgcn_mfma_f32_16x16x32_f16(qh[1][1], bh1, a1, 0, 0, 0);
            a0 = __builtin_amdgcn_mfma_f32_16x16x32_f16(qh[0][1], bl1, a0, 0, 0, 0);
            a1 = __builtin_amdgcn_mfma_f32_16x16x32_f16(qh[1][1], bl1, a1, 0, 0, 0);
            a0 = __builtin_amdgcn_mfma_f32_16x16x32_f16(ql[0][1], bh1, a0, 0, 0, 0);
            a1 = __builtin_amdgcn_mfma_f32_16x16x32_f16(ql[1][1], bh1, a1, 0, 0, 0);
            #pragma unroll
            for (int r = 0; r < 4; ++r) {
                vmax[0][r] = fmaxf(vmax[0][r], a0[r]);
                vmax[1][r] = fmaxf(vmax[1][r], a1[r]);
            }
        }
    }

    // Row max: fold over the 16 lm lanes (cols); row = w*32 + i*16 + kq*4 + r.
    #pragma unroll
    for (int i = 0; i < 2; ++i)
        #pragma unroll
        for (int r = 0; r < 4; ++r) {
            float m = vmax[i][r];
            m = fmaxf(m, __shfl_xor(m, 1, 64));
            m = fmaxf(m, __shfl_xor(m, 2, 64));
            m = fmaxf(m, __shfl_xor(m, 4, 64));
            m = fmaxf(m, __shfl_xor(m, 8, 64));
            if (lm == 0) smax[w * 32 + i * 16 + kq * 4 + r] = m;
        }
    __syncthreads();

    if (tid < 128)
        spars[bh * T_LEN + q0 + tid] = smax[tid] - sdotL[tid] * (1.0f / 2048.0f);
}

// ---------------------------------------------------------------------------
// Kernel D: top-40 per bh by iterative argmax (ties -> smaller index).
// ---------------------------------------------------------------------------
__global__ __launch_bounds__(256)
void topk_kernel(const float* __restrict__ spars, int* __restrict__ topi)
{
    __shared__ float vals[T_LEN];
    __shared__ float rv[256];
    __shared__ int   ri[256];
    const int bh = blockIdx.x, tid = threadIdx.x;
    for (int j = tid; j < T_LEN; j += 256) vals[j] = spars[bh * T_LEN + j];
    __syncthreads();
    for (int it = 0; it < USEL; ++it) {
        float bv = -INFINITY; int bi = 0;
        #pragma unroll
        for (int jj = 0; jj < 8; ++jj) {
            int j = tid * 8 + jj;
            float vv = vals[j];
            if (vv > bv) { bv = vv; bi = j; }
        }
        rv[tid] = bv; ri[tid] = bi;
        __syncthreads();
        for (int s = 128; s > 0; s >>= 1) {
            if (tid < s) {
                float ov = rv[tid + s]; int oi = ri[tid + s];
                if (ov > rv[tid] || (ov == rv[tid] && oi < ri[tid])) { rv[tid] = ov; ri[tid] = oi; }
            }
            __syncthreads();
        }
        if (tid == 0) {
            int win = ri[0] & (T_LEN - 1);
            topi[bh * USEL + it] = win;
            vals[win] = -INFINITY;
        }
        __syncthreads();
    }
}

// ---------------------------------------------------------------------------
// Kernel E1: gather selected q rows -> qsel[bh][u][d]. (q dead afterwards)
// ---------------------------------------------------------------------------
__global__ __launch_bounds__(256)
void gather_q_kernel(const float* __restrict__ q, const int* __restrict__ topi,
                     float* __restrict__ qsel)
{
    const int bh = blockIdx.x, tid = threadIdx.x;
    for (int i = tid; i < USEL * HDIM; i += 256) {
        int u = i >> 6, d = i & 63;
        int t = topi[bh * USEL + u] & (T_LEN - 1);
        qsel[(size_t)bh * USEL * HDIM + i] = q[((size_t)bh * T_LEN + t) * HDIM + d];
    }
}

// ---------------------------------------------------------------------------
// Kernel E2: S[bh][u][t] = qsel[bh][u] . k[bh][t]. Grid (8 t-slices, 32 bh).
// ---------------------------------------------------------------------------
__global__ __launch_bounds__(256)
void sel_scores_kernel(const float* __restrict__ qsel, const float* __restrict__ k,
                       float* __restrict__ S)
{
    __shared__ float qsT[64 * 41];    // [d][u] stride 41
    __shared__ float ksT[64 * 257];   // [d][t] stride 257

    const int sl = blockIdx.x, bh = blockIdx.y, tid = threadIdx.x;
    const int t0 = sl * 256;

    for (int i = tid; i < USEL * HDIM; i += 256) {
        int u = i >> 6, d = i & 63;
        qsT[d * 41 + u] = qsel[(size_t)bh * USEL * HDIM + i];
    }
    const float4* k4 = (const float4*)(k + (size_t)bh * T_LEN * HDIM);
    #pragma unroll
    for (int s = 0; s < 16; ++s) {
        int u = tid + 256 * s;          // 0..4095
        int c4 = u & 15, t = u >> 4;    // t 0..255
        float4 f = k4[(t0 + t) * 16 + c4];
        ksT[(c4 * 4 + 0) * 257 + t] = f.x;
        ksT[(c4 * 4 + 1) * 257 + t] = f.y;
        ksT[(c4 * 4 + 2) * 257 + t] = f.z;
        ksT[(c4 * 4 + 3) * 257 + t] = f.w;
    }
    __syncthreads();

    const int qg = tid >> 5;   // 0..7 -> 5 queries each
    const int kg = tid & 31;   // strided keys: kg + 32*j

    float acc[5][8];
    #pragma unroll
    for (int i = 0; i < 5; ++i)
        #pragma unroll
        for (int j = 0; j < 8; ++j) acc[i][j] = 0.0f;

    #pragma unroll 4
    for (int d = 0; d < 64; ++d) {
        float qv[5], kv[8];
        #pragma unroll
        for (int i = 0; i < 5; ++i) qv[i] = qsT[d * 41 + qg * 5 + i];
        #pragma unroll
        for (int j = 0; j < 8; ++j) kv[j] = ksT[d * 257 + kg + 32 * j];
        #pragma unroll
        for (int i = 0; i < 5; ++i)
            #pragma unroll
            for (int j = 0; j < 8; ++j)
                acc[i][j] = fmaf(qv[i], kv[j], acc[i][j]);
    }

    #pragma unroll
    for (int i = 0; i < 5; ++i) {
        float* sp = &S[((size_t)bh * USEL + qg * 5 + i) * T_LEN + t0 + kg];
        #pragma unroll
        for (int j = 0; j < 8; ++j) sp[32 * j] = acc[i][j];
    }
}

// ---------------------------------------------------------------------------
// Kernel E3: in-place softmax over each S row (1280 rows of 2048).
// ---------------------------------------------------------------------------
__global__ __launch_bounds__(256)
void sel_softmax_kernel(float* __restrict__ S)
{
    __shared__ float red[256];
    const int row = blockIdx.x, tid = threadIdx.x;
    float* sr = S + (size_t)row * T_LEN;

    float x[8];
    float m = -INFINITY;
    #pragma unroll
    for (int s = 0; s < 8; ++s) { x[s] = sr[tid + 256 * s]; m = fmaxf(m, x[s]); }
    red[tid] = m;
    __syncthreads();
    for (int s = 128; s > 0; s >>= 1) {
        if (tid < s) red[tid] = fmaxf(red[tid], red[tid + s]);
        __syncthreads();
    }
    m = red[0];
    __syncthreads();

    float sum = 0.f;
    #pragma unroll
    for (int s = 0; s < 8; ++s) { x[s] = __expf(x[s] - m); sum += x[s]; }
    red[tid] = sum;
    __syncthreads();
    for (int s = 128; s > 0; s >>= 1) {
        if (tid < s) red[tid] += red[tid + s];
        __syncthreads();
    }
    float inv = 1.0f / red[0];
    #pragma unroll
    for (int s = 0; s < 8; ++s) sr[tid + 256 * s] = x[s] * inv;
}

// ---------------------------------------------------------------------------
// Kernel E4: PV partial. Grid (16 t-slices, 32 bh).
// ---------------------------------------------------------------------------
__global__ __launch_bounds__(256)
void pv_part_kernel(const float* __restrict__ S, const float* __restrict__ v,
                    float* __restrict__ part)
{
    __shared__ float ps[USEL * 128];      // [q][t]
    __shared__ float vs[128 * 69];        // [t][d] stride 69
    __shared__ float obuf[128 * 20];

    const int sl = blockIdx.x, bh = blockIdx.y, tid = threadIdx.x;
    const int t0 = sl * 128;

    for (int i = tid; i < USEL * 128; i += 256) {
        int q = i >> 7, t = i & 127;
        ps[q * 128 + t] = S[((size_t)bh * USEL + q) * T_LEN + t0 + t];
    }
    const float4* v4 = (const float4*)(v + (size_t)bh * T_LEN * HDIM);
    #pragma unroll
    for (int s = 0; s < 8; ++s) {
        int u = tid + 256 * s;          // 0..2047
        int c4 = u & 15, t = u >> 4;    // t 0..127
        float4 f = v4[(t0 + t) * 16 + c4];
        vs[t * 69 + c4 * 4 + 0] = f.x;
        vs[t * 69 + c4 * 4 + 1] = f.y;
        vs[t * 69 + c4 * 4 + 2] = f.z;
        vs[t * 69 + c4 * 4 + 3] = f.w;
    }
    __syncthreads();

    const int qg = tid >> 5, r = tid & 31;
    const int dg = r >> 1, th = r & 1;
    const int tb = th * 64;

    float o[5][4];
    #pragma unroll
    for (int i = 0; i < 5; ++i)
        #pragma unroll
        for (int j = 0; j < 4; ++j) o[i][j] = 0.0f;

    #pragma unroll 4
    for (int tt = 0; tt < 64; ++tt) {
        int t = tb + tt;
        float pv[5];
        #pragma unroll
        for (int i = 0; i < 5; ++i) pv[i] = ps[(qg * 5 + i) * 128 + t];
        float4 vv = *(const float4*)&vs[t * 69 + dg * 4];
        #pragma unroll
        for (int i = 0; i < 5; ++i) {
            o[i][0] = fmaf(pv[i], vv.x, o[i][0]);
            o[i][1] = fmaf(pv[i], vv.y, o[i][1]);
            o[i][2] = fmaf(pv[i], vv.z, o[i][2]);
            o[i][3] = fmaf(pv[i], vv.w, o[i][3]);
        }
    }

    const int p = qg * 16 + dg;   // 0..127
    if (th == 1) {
        #pragma unroll
        for (int i = 0; i < 5; ++i)
            #pragma unroll
            for (int j = 0; j < 4; ++j) obuf[p * 20 + i * 4 + j] = o[i][j];
    }
    __syncthreads();
    if (th == 0) {
        float* pb = part + ((size_t)bh * 16 + sl) * (USEL * HDIM);
        #pragma unroll
        for (int i = 0; i < 5; ++i)
            #pragma unroll
            for (int j = 0; j < 4; ++j)
                pb[(qg * 5 + i) * HDIM + dg * 4 + j] = o[i][j] + obuf[p * 20 + i * 4 + j];
    }
}

// ---------------------------------------------------------------------------
// Kernel E5: deterministic merge of 16 PV partials -> attn[bh][u][d].
// ---------------------------------------------------------------------------
__global__ __launch_bounds__(256)
void pv_merge_kernel(const float* __restrict__ part, float* __restrict__ attn)
{
    const int bh = blockIdx.x, tid = threadIdx.x;
    for (int i = tid; i < USEL * HDIM; i += 256) {
        float s = 0.f;
        #pragma unroll
        for (int sl = 0; sl < 16; ++sl)
            s += part[((size_t)bh * 16 + sl) * (USEL * HDIM) + i];
        attn[(size_t)bh * USEL * HDIM + i] = s;
    }
}

// ---------------------------------------------------------------------------
// Kernel F1: fill context (B,T,E layout, fp32) with per-head vmean.
// ---------------------------------------------------------------------------
__global__ __launch_bounds__(256)
void ctx_fill_kernel(const float* __restrict__ vmean, float* __restrict__ ctx)
{
    int flat = blockIdx.x * 256 + threadIdx.x;
    int d = flat & 63, h = (flat >> 6) & 7, b = flat >> 20;
    int bh = (b << 3) | h;
    ctx[flat] = vmean[bh * 64 + d];
}

// ---------------------------------------------------------------------------
// Kernel F2: scatter attn rows into context at top_idx positions.
// ---------------------------------------------------------------------------
__global__ void ctx_scatter_kernel(const float* __restrict__ attn, const int* __restrict__ topi,
                                   float* __restrict__ ctx)
{
    const int u = blockIdx.x, bh = blockIdx.y, d = threadIdx.x;
    const int b = bh >> 3, h = bh & 7;
    const int t = topi[bh * USEL + u] & (T_LEN - 1);
    ctx[(size_t)(b * T_LEN + t) * EMB + h * 64 + d] =
        attn[((size_t)bh * USEL + u) * HDIM + d];
}

// ---------------------------------------------------------------------------
// Kernel G: out = ctx @ Wo^T + bo via bf16 hi+lo 3-pass MFMA (16x16x32).
// 128x128 tile, BK=32. acc += Ah*Bh + Ah*Bl + Al*Bh (drop Al*Bl ~2^-18).
// u16 tiles stride 40 (16B-aligned fragments, 2-way banks). C/D layout:
// col=lane&15 (n), row=(lane>>4)*4+r (m). Output tolerance 4.3e-3 >> 1e-5 err.
// ---------------------------------------------------------------------------
__global__ __launch_bounds__(256)
void out_proj_kernel(const float* __restrict__ A, const float* __restrict__ Wo,
                     const float* __restrict__ bo, float* __restrict__ out)
{
    alignas(16) __shared__ u16 Ah[128 * 40];
    alignas(16) __shared__ u16 Al[128 * 40];
    alignas(16) __shared__ u16 Bh[128 * 40];
    alignas(16) __shared__ u16 Bl[128 * 40];

    const int tid = threadIdx.x;
    const int m0 = blockIdx.x * 128;
    const int n0 = blockIdx.y * 128;
    const int w = tid >> 6, lane = tid & 63;
    const int wm = w & 1, wn = w >> 1;
    const int lm = lane & 15, kq = lane >> 4;

    f32x4 acc[4][4];
    #pragma unroll
    for (int i = 0; i < 4; ++i)
        #pragma unroll
        for (int j = 0; j < 4; ++j)
            #pragma unroll
            for (int r = 0; r < 4; ++r) acc[i][j][r] = 0.0f;

    for (int kc = 0; kc < EMB; kc += 32) {
        __syncthreads();
        #pragma unroll
        for (int s = 0; s < 4; ++s) {
            int u = tid + 256 * s;        // 0..1023
            int row = u >> 3, c4 = u & 7; // row 0..127, c4 0..7 (k-quad)
            float4 fa = *(const float4*)&A[(size_t)(m0 + row) * EMB + kc + c4 * 4];
            float4 fb = *(const float4*)&Wo[(n0 + row) * EMB + kc + c4 * 4];
            uint2 ph, pl;
            cvt4_hilo(fa, ph, pl);
            *(uint2*)&Ah[row * 40 + c4 * 4] = ph;
            *(uint2*)&Al[row * 40 + c4 * 4] = pl;
            cvt4_hilo(fb, ph, pl);
            *(uint2*)&Bh[row * 40 + c4 * 4] = ph;
            *(uint2*)&Bl[row * 40 + c4 * 4] = pl;
        }
        __syncthreads();

        bf16v8 ah[4], al[4], bh[4], bl[4];
        #pragma unroll
        for (int i = 0; i < 4; ++i) {
            int ra = (wm * 64 + i * 16 + lm) * 40 + kq * 8;
            ah[i] = *(const bf16v8*)&Ah[ra];
            al[i] = *(const bf16v8*)&Al[ra];
            int rb = (wn * 64 + i * 16 + lm) * 40 + kq * 8;
            bh[i] = *(const bf16v8*)&Bh[rb];
            bl[i] = *(const bf16v8*)&Bl[rb];
        }
        #pragma unroll
        for (int i = 0; i < 4; ++i)
            #pragma unroll
            for (int j = 0; j < 4; ++j) {
                acc[i][j] = __builtin_amdgcn_mfma_f32_16x16x32_bf16(ah[i], bh[j], acc[i][j], 0, 0, 0);
                acc[i][j] = __builtin_amdgcn_mfma_f32_16x16x32_bf16(ah[i], bl[j], acc[i][j], 0, 0, 0);
                acc[i][j] = __builtin_amdgcn_mfma_f32_16x16x32_bf16(al[i], bh[j], acc[i][j], 0, 0, 0);
            }
    }

    #pragma unroll
    for (int j = 0; j < 4; ++j) {
        int ng = n0 + wn * 64 + j * 16 + lm;
        float bias = bo[ng];
        #pragma unroll
        for (int i = 0; i < 4; ++i)
            #pragma unroll
            for (int r = 0; r < 4; ++r) {
                int mg = m0 + wm * 64 + i * 16 + kq * 4 + r;
                out[(size_t)mg * EMB + ng] = acc[i][j][r] + bias;
            }
    }
}

// ---------------------------------------------------------------------------
// Diagnostic: if ws_size is too small, report it via d_out (absmax ~= MiB).
// ---------------------------------------------------------------------------
__global__ __launch_bounds__(256)
void ws_diag_kernel(float* __restrict__ out, int n, float mib)
{
    int flat = blockIdx.x * 256 + threadIdx.x;
    if (flat < n) out[flat] = mib;
}

// ---------------------------------------------------------------------------
extern "C" void kernel_launch(void* const* d_in, const int* in_sizes, int n_in,
                              void* d_out, int out_size, void* d_ws, size_t ws_size,
                              hipStream_t stream)
{
    // fp32 inputs/outputs in dict order (confirmed). Bind by size; same-size
    // tensors in encounter (=dict) order: Wq, Wk, Wv, Wo.
    const float* X = nullptr; const int* idxs = nullptr;
    const float* Wseen[4] = {nullptr, nullptr, nullptr, nullptr};
    const float* bseen[4] = {nullptr, nullptr, nullptr, nullptr};
    int nw = 0, nb = 0, u_part = 2048;
    for (int i = 0; i < n_in; ++i) {
        int sz = in_sizes[i];
        if (sz == EMB * EMB * 16) { if (!X) X = (const float*)d_in[i]; }
        else if (sz == T_LEN)     { if (!idxs) { idxs = (const int*)d_in[i]; u_part = sz; } }
        else if (sz == EMB * EMB) { if (nw < 4) Wseen[nw++] = (const float*)d_in[i]; }
        else if (sz == EMB)       { if (nb < 4) bseen[nb++] = (const float*)d_in[i]; }
    }
    if (!X || !idxs || nw < 4 || nb < 4) {
        X = (const float*)d_in[0]; idxs = (const int*)d_in[1];
        Wseen[0] = (const float*)d_in[2]; bseen[0] = (const float*)d_in[3];
        Wseen[1] = (const float*)d_in[4]; bseen[1] = (const float*)d_in[5];
        Wseen[2] = (const float*)d_in[6]; bseen[2] = (const float*)d_in[7];
        Wseen[3] = (const float*)d_in[8]; bseen[3] = (const float*)d_in[9];
        u_part = in_sizes[1];
    }
    const float *Wq = Wseen[0], *Wk = Wseen[1], *Wv = Wseen[2], *Wo = Wseen[3];
    const float *bq = bseen[0], *bk = bseen[1], *bv = bseen[2], *bo = bseen[3];

    // Workspace layout (peak 50,951,168 B, unchanged).
    const size_t NEED = 50951168ULL;
    if (ws_size < NEED) {
        ws_diag_kernel<<<(out_size + 255) / 256, 256, 0, stream>>>(
            (float*)d_out, out_size, (float)(ws_size >> 20));
        return;
    }

    float* ws    = (float*)d_ws;
    float* qw    = ws;                    // 4,194,304 floats
    float* kw    = qw + 4194304;
    float* vw    = kw + 4194304;
    float* tail  = vw + 4194304;
    float* slotA = tail;                  // 81920: qsel, later attn
    float* spars = tail + 81920;          // 65536
    int*   count = (int*)(tail + 147456); // 2048
    float* ksum  = tail + 149504;         // 2048
    float* vmean = tail + 151552;         // 2048
    int*   topi  = (int*)(tail + 153600); // 1280
    float* kpart = tail;                  // overlays in slotA (disjoint liveness)
    float* vpart = tail + 16384;
    int*   klist = (int*)(tail + 32768);
    int*   ncp   = (int*)(tail + 34816);
    float* S     = qw;                    // q dead after gather
    float* pvp   = qw + 2621440;
    float* qsel  = slotA;
    float* attn  = slotA;
    float* ctx   = (float*)d_ws;

    qkv_proj_kernel<<<dim3(64, 4, 3), 256, 0, stream>>>(X, Wq, bq, Wk, bk, Wv, bv, qw, kw, vw);
    count_compact_kernel<<<1, 256, 0, stream>>>(idxs, u_part, count, klist, ncp);
    ksum_vmean_part_kernel<<<dim3(8, 32), 256, 0, stream>>>(count, kw, vw, kpart, vpart);
    ksum_vmean_reduce_kernel<<<32, 64, 0, stream>>>(kpart, vpart, ksum, vmean);
    sparsity_scan_kernel<<<dim3(16, 32), 256, 0, stream>>>(qw, kw, ksum, klist, ncp, spars);
    topk_kernel<<<32, 256, 0, stream>>>(spars, topi);
    gather_q_kernel<<<32, 256, 0, stream>>>(qw, topi, qsel);
    // qw dead; S/pvp take over that region.
    sel_scores_kernel<<<dim3(8, 32), 256, 0, stream>>>(qsel, kw, S);
    sel_softmax_kernel<<<1280, 256, 0, stream>>>(S);
    pv_part_kernel<<<dim3(16, 32), 256, 0, stream>>>(S, vw, pvp);
    pv_merge_kernel<<<32, 256, 0, stream>>>(pvp, attn);
    // S/pvp dead; ctx takes over the whole front region.
    ctx_fill_kernel<<<16384, 256, 0, stream>>>(vmean, ctx);
    ctx_scatter_kernel<<<dim3(USEL, BHEADS), 64, 0, stream>>>(attn, topi, ctx);
    out_proj_kernel<<<dim3(64, 4), 256, 0, stream>>>(ctx, Wo, bo, (float*)d_out);
}

// Round 3
// 344.811 us; speedup vs baseline: 1.5368x; 1.0409x over previous
//
#include <hip/hip_runtime.h>
#include <hip/hip_bf16.h>
#include <math.h>

#define T_LEN 2048
#define EMB   512
#define NHEAD 8
#define HDIM  64
#define BHEADS 32
#define USEL  40

typedef __bf16 bf16v8 __attribute__((ext_vector_type(8)));
typedef _Float16 f16x8 __attribute__((ext_vector_type(8)));
typedef float f32x4 __attribute__((ext_vector_type(4)));
typedef unsigned short u16;

// Split a float4 into bf16 hi + lo halves, packed as uint2 (4 x u16 each).
__device__ __forceinline__ void cvt4_hilo(const float4 f, uint2& ph, uint2& pl)
{
    __hip_bfloat16 h0 = __float2bfloat16(f.x);
    __hip_bfloat16 h1 = __float2bfloat16(f.y);
    __hip_bfloat16 h2 = __float2bfloat16(f.z);
    __hip_bfloat16 h3 = __float2bfloat16(f.w);
    __hip_bfloat16 l0 = __float2bfloat16(f.x - __bfloat162float(h0));
    __hip_bfloat16 l1 = __float2bfloat16(f.y - __bfloat162float(h1));
    __hip_bfloat16 l2 = __float2bfloat16(f.z - __bfloat162float(h2));
    __hip_bfloat16 l3 = __float2bfloat16(f.w - __bfloat162float(h3));
    ph.x = (unsigned)*(const u16*)&h0 | ((unsigned)*(const u16*)&h1 << 16);
    ph.y = (unsigned)*(const u16*)&h2 | ((unsigned)*(const u16*)&h3 << 16);
    pl.x = (unsigned)*(const u16*)&l0 | ((unsigned)*(const u16*)&l1 << 16);
    pl.y = (unsigned)*(const u16*)&l2 | ((unsigned)*(const u16*)&l3 << 16);
}

// Split a float4 into FP16 hi + lo halves, packed as uint2 (4 x u16 each).
// fp16 has 11-bit mantissa: h+l captures ~22 bits, residual <= 2^-22*|x|.
// Dropped Al*Bl term in the 3-pass GEMM is <= 2^-22*|ab| -> the f16 hi/lo
// 3-pass GEMM is fp32-rounding-equivalent (~1e-6), unlike bf16 hi/lo (~2^-16).
__device__ __forceinline__ void cvt4_hilo_h(const float4 f, uint2& ph, uint2& pl)
{
    _Float16 h0 = (_Float16)f.x;
    _Float16 h1 = (_Float16)f.y;
    _Float16 h2 = (_Float16)f.z;
    _Float16 h3 = (_Float16)f.w;
    _Float16 l0 = (_Float16)(f.x - (float)h0);
    _Float16 l1 = (_Float16)(f.y - (float)h1);
    _Float16 l2 = (_Float16)(f.z - (float)h2);
    _Float16 l3 = (_Float16)(f.w - (float)h3);
    ph.x = (unsigned)*(const u16*)&h0 | ((unsigned)*(const u16*)&h1 << 16);
    ph.y = (unsigned)*(const u16*)&h2 | ((unsigned)*(const u16*)&h3 << 16);
    pl.x = (unsigned)*(const u16*)&l0 | ((unsigned)*(const u16*)&l1 << 16);
    pl.y = (unsigned)*(const u16*)&l2 | ((unsigned)*(const u16*)&l3 << 16);
}

// ---------------------------------------------------------------------------
// Kernel A0: pack X and Wq/Wk/Wv into f16 hi/lo tiles, pre-blocked in MFMA
// fragment order so the GEMM stages them with linear global_load_lds.
// Tile = 128 rows x 32 k, stored [hi/lo][kq(4)][row(128)][e(8)] u16 = 16 KB.
// X: 64 mt x 16 kt tiles; W: 3 z x 4 nt x 16 kt tiles. Eliminates the 12x/64x
// redundant per-block cvt4_hilo that made qkv_proj 33% VALUBusy.
// ---------------------------------------------------------------------------
__global__ __launch_bounds__(256)
void pack_hilo_kernel(const float* __restrict__ X,
                      const float* __restrict__ Wq, const float* __restrict__ Wk,
                      const float* __restrict__ Wv,
                      u16* __restrict__ Xp, u16* __restrict__ Wp)
{
    alignas(16) __shared__ u16 th[4096];
    alignas(16) __shared__ u16 tl[4096];
    const int b = blockIdx.x, tid = threadIdx.x;

    const float* src; u16* dst;
    if (b < 1024) {                       // X tile: mt = b>>4, kt = b&15
        int mt = b >> 4, kt = b & 15;
        src = X + (size_t)(mt * 128) * EMB + kt * 32;
        dst = Xp + (size_t)b * 8192;
    } else {                              // W tile
        int wdx = b - 1024;               // wdx = (z*4 + nt)*16 + kt
        int z = wdx >> 6, nt = (wdx >> 4) & 3, kt = wdx & 15;
        const float* W = (z == 0) ? Wq : (z == 1) ? Wk : Wv;
        src = W + (size_t)(nt * 128) * EMB + kt * 32;
        dst = Wp + (size_t)wdx * 8192;
    }

    #pragma unroll
    for (int s = 0; s < 4; ++s) {
        int u = tid + 256 * s;            // 0..1023 float4s
        int row = u >> 3, c4 = u & 7;     // 128 rows x 8 float4
        float4 f = *(const float4*)&src[(size_t)row * EMB + c4 * 4];
        uint2 ph, pl;
        cvt4_hilo_h(f, ph, pl);
        int kq = c4 >> 1, e4 = (c4 & 1) * 4;
        *(uint2*)&th[kq * 1024 + row * 8 + e4] = ph;
        *(uint2*)&tl[kq * 1024 + row * 8 + e4] = pl;
    }
    __syncthreads();

    uint4* d4 = (uint4*)dst;
    const uint4* s4h = (const uint4*)th;
    const uint4* s4l = (const uint4*)tl;
    d4[tid]       = s4h[tid];
    d4[tid + 256] = s4h[tid + 256];
    d4[tid + 512] = s4l[tid];
    d4[tid + 768] = s4l[tid + 256];
}

// ---------------------------------------------------------------------------
// Kernel A1: QKV projection GEMM from pre-packed hi/lo tiles.
// 128x128 tile, BK=32, 4 waves; staging = 8 x global_load_lds(dwordx4) per
// wave (linear copy of one 8KB tile: w0->Ah, w1->Al, w2->Bh, w3->Bl) -> zero
// ds_writes, zero staging VALU, zero write bank-conflicts. Fragment reads at
// kq*2048 + row*16 B (2-way aliased = free). q,k: 3-pass hh+hl+lh, bitwise
// identical to the prior passing version (same operands, same MFMA order) ->
// selection unchanged. v: single-pass hh (error ~3e-4 << 4.3e-3 tolerance);
// waves 1/3 skip lo staging for z==2.
// ---------------------------------------------------------------------------
__global__ __launch_bounds__(256)
void qkv_mfma_kernel(const u16* __restrict__ Xp, const u16* __restrict__ Wp,
                     const float* __restrict__ bq, const float* __restrict__ bk,
                     const float* __restrict__ bv,
                     float* __restrict__ qo, float* __restrict__ ko, float* __restrict__ vo)
{
    alignas(16) __shared__ u16 Ah[4096];
    alignas(16) __shared__ u16 Al[4096];
    alignas(16) __shared__ u16 Bh[4096];
    alignas(16) __shared__ u16 Bl[4096];

    const int z = blockIdx.z;
    const float* bias; float* dst; float scale;
    if (z == 0)      { bias = bq; dst = qo; scale = 0.125f; }
    else if (z == 1) { bias = bk; dst = ko; scale = 1.0f;   }
    else             { bias = bv; dst = vo; scale = 1.0f;   }
    const bool three = (z != 2);

    const int tid = threadIdx.x;
    const int mt = blockIdx.x;            // m0 = mt*128
    const int nt = blockIdx.y;            // n0 = nt*128
    const int w = tid >> 6, lane = tid & 63;
    const int wm = w & 1, wn = w >> 1;
    const int lm = lane & 15, kq = lane >> 4;

    const u16* Abase = Xp + (size_t)mt * (16 * 8192);
    const u16* Bbase = Wp + (size_t)(z * 4 + nt) * (16 * 8192);

    f32x4 acc[4][4];
    #pragma unroll
    for (int i = 0; i < 4; ++i)
        #pragma unroll
        for (int j = 0; j < 4; ++j)
            #pragma unroll
            for (int r = 0; r < 4; ++r) acc[i][j][r] = 0.0f;

    for (int kt = 0; kt < 16; ++kt) {
        __syncthreads();                  // prior iteration's reads complete
        const u16* at = Abase + kt * 8192;
        const u16* bt = Bbase + kt * 8192;
        const u16* gsrc; u16* ldst;
        if (w == 0)      { gsrc = at;        ldst = Ah; }
        else if (w == 1) { gsrc = at + 4096; ldst = Al; }
        else if (w == 2) { gsrc = bt;        ldst = Bh; }
        else             { gsrc = bt + 4096; ldst = Bl; }
        if (three || (w & 1) == 0) {
            #pragma unroll
            for (int i = 0; i < 8; ++i)
                __builtin_amdgcn_global_load_lds(
                    (const __attribute__((address_space(1))) void*)(gsrc + (size_t)lane * 8 + i * 512),
                    (__attribute__((address_space(3))) void*)(ldst + i * 512),
                    16, 0, 0);
        }
        __syncthreads();                  // vmcnt(0) drained by compiler

        f16x8 ah[4], al[4], bh[4], bl[4];
        #pragma unroll
        for (int i = 0; i < 4; ++i) {
            int ar = (wm * 64 + i * 16 + lm) * 8 + kq * 1024;
            int br = (wn * 64 + i * 16 + lm) * 8 + kq * 1024;
            ah[i] = *(const f16x8*)&Ah[ar];
            bh[i] = *(const f16x8*)&Bh[br];
            if (three) {
                al[i] = *(const f16x8*)&Al[ar];
                bl[i] = *(const f16x8*)&Bl[br];
            }
        }
        #pragma unroll
        for (int i = 0; i < 4; ++i)
            #pragma unroll
            for (int j = 0; j < 4; ++j) {
                acc[i][j] = __builtin_amdgcn_mfma_f32_16x16x32_f16(ah[i], bh[j], acc[i][j], 0, 0, 0);
                if (three) {
                    acc[i][j] = __builtin_amdgcn_mfma_f32_16x16x32_f16(ah[i], bl[j], acc[i][j], 0, 0, 0);
                    acc[i][j] = __builtin_amdgcn_mfma_f32_16x16x32_f16(al[i], bh[j], acc[i][j], 0, 0, 0);
                }
            }
    }

    // C/D layout: col = lane&15 (n), row = (lane>>4)*4 + r (m).
    #pragma unroll
    for (int j = 0; j < 4; ++j) {
        int ng = nt * 128 + wn * 64 + j * 16 + lm;   // embed col = h*64 + d
        int h = ng >> 6, d = ng & 63;
        float bv_ = bias[ng];
        #pragma unroll
        for (int i = 0; i < 4; ++i) {
            #pragma unroll
            for (int r = 0; r < 4; ++r) {
                int mg = mt * 128 + wm * 64 + i * 16 + kq * 4 + r;
                int b = mg >> 11, t = mg & 2047;
                dst[((size_t)((b * NHEAD + h) * T_LEN + t)) * HDIM + d] =
                    (acc[i][j][r] + bv_) * scale;
            }
        }
    }
}

// ---------------------------------------------------------------------------
// Kernel A-fallback: prior f16 hi/lo 3-pass qkv (used when ws too small for
// the pack buffers). Identical to the round-2 passing version.
// ---------------------------------------------------------------------------
__global__ __launch_bounds__(256)
void qkv_proj_kernel(const float* __restrict__ X,
                     const float* __restrict__ Wq, const float* __restrict__ bq,
                     const float* __restrict__ Wk, const float* __restrict__ bk,
                     const float* __restrict__ Wv, const float* __restrict__ bv,
                     float* __restrict__ qo, float* __restrict__ ko, float* __restrict__ vo)
{
    alignas(16) __shared__ u16 Ah[128 * 40];
    alignas(16) __shared__ u16 Al[128 * 40];
    alignas(16) __shared__ u16 Bh[128 * 40];
    alignas(16) __shared__ u16 Bl[128 * 40];

    const int z = blockIdx.z;
    const float* W; const float* bias; float* dst; float scale;
    if (z == 0)      { W = Wq; bias = bq; dst = qo; scale = 0.125f; }
    else if (z == 1) { W = Wk; bias = bk; dst = ko; scale = 1.0f;   }
    else             { W = Wv; bias = bv; dst = vo; scale = 1.0f;   }

    const int tid = threadIdx.x;
    const int m0 = blockIdx.x * 128;
    const int n0 = blockIdx.y * 128;
    const int w = tid >> 6, lane = tid & 63;
    const int wm = w & 1, wn = w >> 1;
    const int lm = lane & 15, kq = lane >> 4;

    f32x4 acc[4][4];
    #pragma unroll
    for (int i = 0; i < 4; ++i)
        #pragma unroll
        for (int j = 0; j < 4; ++j)
            #pragma unroll
            for (int r = 0; r < 4; ++r) acc[i][j][r] = 0.0f;

    for (int kc = 0; kc < EMB; kc += 32) {
        __syncthreads();
        #pragma unroll
        for (int s = 0; s < 4; ++s) {
            int u = tid + 256 * s;
            int row = u >> 3, c4 = u & 7;
            float4 fa = *(const float4*)&X[(size_t)(m0 + row) * EMB + kc + c4 * 4];
            float4 fb = *(const float4*)&W[(n0 + row) * EMB + kc + c4 * 4];
            uint2 ph, pl;
            cvt4_hilo_h(fa, ph, pl);
            *(uint2*)&Ah[row * 40 + c4 * 4] = ph;
            *(uint2*)&Al[row * 40 + c4 * 4] = pl;
            cvt4_hilo_h(fb, ph, pl);
            *(uint2*)&Bh[row * 40 + c4 * 4] = ph;
            *(uint2*)&Bl[row * 40 + c4 * 4] = pl;
        }
        __syncthreads();

        f16x8 ah[4], al[4], bh[4], bl[4];
        #pragma unroll
        for (int i = 0; i < 4; ++i) {
            int ra = (wm * 64 + i * 16 + lm) * 40 + kq * 8;
            ah[i] = *(const f16x8*)&Ah[ra];
            al[i] = *(const f16x8*)&Al[ra];
            int rb = (wn * 64 + i * 16 + lm) * 40 + kq * 8;
            bh[i] = *(const f16x8*)&Bh[rb];
            bl[i] = *(const f16x8*)&Bl[rb];
        }
        #pragma unroll
        for (int i = 0; i < 4; ++i)
            #pragma unroll
            for (int j = 0; j < 4; ++j) {
                acc[i][j] = __builtin_amdgcn_mfma_f32_16x16x32_f16(ah[i], bh[j], acc[i][j], 0, 0, 0);
                acc[i][j] = __builtin_amdgcn_mfma_f32_16x16x32_f16(ah[i], bl[j], acc[i][j], 0, 0, 0);
                acc[i][j] = __builtin_amdgcn_mfma_f32_16x16x32_f16(al[i], bh[j], acc[i][j], 0, 0, 0);
            }
    }

    #pragma unroll
    for (int j = 0; j < 4; ++j) {
        int ng = n0 + wn * 64 + j * 16 + lm;
        int h = ng >> 6, d = ng & 63;
        float bv_ = bias[ng];
        #pragma unroll
        for (int i = 0; i < 4; ++i) {
            #pragma unroll
            for (int r = 0; r < 4; ++r) {
                int mg = m0 + wm * 64 + i * 16 + kq * 4 + r;
                int b = mg >> 11, t = mg & 2047;
                dst[((size_t)((b * NHEAD + h) * T_LEN + t)) * HDIM + d] =
                    (acc[i][j][r] + bv_) * scale;
            }
        }
    }
}

// ---------------------------------------------------------------------------
// Kernel B1: count + compact distinct sampled indices (single block).
// ---------------------------------------------------------------------------
__global__ __launch_bounds__(256)
void count_compact_kernel(const int* __restrict__ idxs, int n,
                          int* __restrict__ count, int* __restrict__ klist,
                          int* __restrict__ ncp)
{
    __shared__ int cnt[T_LEN];
    __shared__ int th_tot[256];
    __shared__ int th_off[256];
    __shared__ int ncs;
    const int tid = threadIdx.x;
    for (int j = tid; j < T_LEN; j += 256) cnt[j] = 0;
    __syncthreads();
    for (int i = tid; i < n; i += 256) atomicAdd(&cnt[idxs[i] & (T_LEN - 1)], 1);
    __syncthreads();
    const int base = tid * 8;
    int flags[8]; int loc = 0;
    #pragma unroll
    for (int j = 0; j < 8; ++j) {
        int c = cnt[base + j];
        count[base + j] = c;
        flags[j] = (c > 0); loc += flags[j];
    }
    th_tot[tid] = loc;
    __syncthreads();
    if (tid == 0) {
        int run = 0;
        for (int i = 0; i < 256; ++i) { th_off[i] = run; run += th_tot[i]; }
        ncs = run;
        ncp[0] = run;
    }
    __syncthreads();
    int off = th_off[tid];
    #pragma unroll
    for (int j = 0; j < 8; ++j)
        if (flags[j]) klist[off++] = base + j;
    __syncthreads();
    const int nc = ncs;
    const int nt = (nc + 127) & ~127;
    const int k0 = klist[0];
    for (int j = nc + tid; j < nt; j += 256) klist[j] = k0;
}

// ---------------------------------------------------------------------------
// Kernel B2a: partial ksum/vsum per (bh, slice). Coalesced float4 streaming.
// ---------------------------------------------------------------------------
__global__ __launch_bounds__(256)
void ksum_vmean_part_kernel(const int* __restrict__ count,
                            const float* __restrict__ k, const float* __restrict__ v,
                            float* __restrict__ kpart, float* __restrict__ vpart)
{
    __shared__ int cs[256];
    alignas(16) __shared__ float rk[16 * 64];
    alignas(16) __shared__ float rv[16 * 64];

    const int sl = blockIdx.x, bh = blockIdx.y, tid = threadIdx.x;
    const int f4 = tid & 15, tg = tid >> 4;
    const int t0 = sl * 256;

    cs[tid] = count[t0 + tid];
    __syncthreads();

    const float4* k4 = (const float4*)(k + (size_t)bh * T_LEN * HDIM) + t0 * 16;
    const float4* v4 = (const float4*)(v + (size_t)bh * T_LEN * HDIM) + t0 * 16;

    float4 ak = {0.f, 0.f, 0.f, 0.f}, av = {0.f, 0.f, 0.f, 0.f};
    #pragma unroll
    for (int s = 0; s < 16; ++s) {
        int t = tg + s * 16;
        float c = (float)cs[t];
        float4 kf = k4[t * 16 + f4];
        float4 vf = v4[t * 16 + f4];
        ak.x = fmaf(c, kf.x, ak.x); ak.y = fmaf(c, kf.y, ak.y);
        ak.z = fmaf(c, kf.z, ak.z); ak.w = fmaf(c, kf.w, ak.w);
        av.x += vf.x; av.y += vf.y; av.z += vf.z; av.w += vf.w;
    }
    *(float4*)&rk[tg * 64 + f4 * 4] = ak;
    *(float4*)&rv[tg * 64 + f4 * 4] = av;
    __syncthreads();

    if (tid < 64) {
        float sk = 0.f, sv = 0.f;
        #pragma unroll
        for (int g = 0; g < 16; ++g) { sk += rk[g * 64 + tid]; sv += rv[g * 64 + tid]; }
        kpart[((size_t)bh * 8 + sl) * 64 + tid] = sk;
        vpart[((size_t)bh * 8 + sl) * 64 + tid] = sv;
    }
}

// ---------------------------------------------------------------------------
// Kernel B2b: reduce 8 slice-partials -> ksum[bh][d], vmean[bh][d].
// ---------------------------------------------------------------------------
__global__ __launch_bounds__(64)
void ksum_vmean_reduce_kernel(const float* __restrict__ kpart, const float* __restrict__ vpart,
                              float* __restrict__ ksum, float* __restrict__ vmean)
{
    const int bh = blockIdx.x, d = threadIdx.x;
    float sk = 0.f, sv = 0.f;
    #pragma unroll
    for (int sl = 0; sl < 8; ++sl) {
        sk += kpart[((size_t)bh * 8 + sl) * 64 + d];
        sv += vpart[((size_t)bh * 8 + sl) * 64 + d];
    }
    ksum[bh * 64 + d]  = sk;
    vmean[bh * 64 + d] = sv * (1.0f / 2048.0f);
}

// ---------------------------------------------------------------------------
// Kernel C: sparsity scan via FP16 hi+lo 3-pass MFMA (16x16x32_f16).
// (unchanged from round 2 — bitwise-stable selection path)
// ---------------------------------------------------------------------------
__global__ __launch_bounds__(256)
void sparsity_scan_kernel(const float* __restrict__ q, const float* __restrict__ k,
                          const float* __restrict__ ksum, const int* __restrict__ klist,
                          const int* __restrict__ ncp, float* __restrict__ spars)
{
    alignas(16) __shared__ u16 KH[256 * 40];   // [chunk][row][40]; q tile, then k tiles
    alignas(16) __shared__ u16 KL[256 * 40];
    __shared__ float ksm[64];
    __shared__ float smax[128];
    __shared__ float sdotL[128];

    const int tid = threadIdx.x;
    const int bh = blockIdx.y;
    const int q0 = blockIdx.x * 128;
    const int w = tid >> 6, lane = tid & 63;
    const int lm = lane & 15, kq = lane >> 4;

    const float* qb = q + ((size_t)bh * T_LEN + q0) * HDIM;
    const float4* kb4 = (const float4*)(k + (size_t)bh * T_LEN * HDIM);
    const int ntiles = (ncp[0] + 127) >> 7;

    if (tid < 64) ksm[tid] = ksum[bh * 64 + tid];

    #pragma unroll
    for (int s = 0; s < 8; ++s) {
        int u = tid + 256 * s;
        int row = u >> 4, c4 = u & 15;
        float4 f = *(const float4*)&qb[row * HDIM + c4 * 4];
        uint2 ph, pl;
        cvt4_hilo_h(f, ph, pl);
        int base = ((c4 >> 3) * 128 + row) * 40 + (c4 & 7) * 4;
        *(uint2*)&KH[base] = ph;
        *(uint2*)&KL[base] = pl;
    }
    __syncthreads();

    f16x8 qh[2][2], ql[2][2];
    #pragma unroll
    for (int i = 0; i < 2; ++i)
        #pragma unroll
        for (int c = 0; c < 2; ++c) {
            int ra = (c * 128 + w * 32 + i * 16 + lm) * 40 + kq * 8;
            qh[i][c] = *(const f16x8*)&KH[ra];
            ql[i][c] = *(const f16x8*)&KL[ra];
        }

    {
        float4 k0a = *(const float4*)&ksm[kq * 8];
        float4 k0b = *(const float4*)&ksm[kq * 8 + 4];
        float4 k1a = *(const float4*)&ksm[32 + kq * 8];
        float4 k1b = *(const float4*)&ksm[32 + kq * 8 + 4];
        float kmv[2][8] = {{k0a.x, k0a.y, k0a.z, k0a.w, k0b.x, k0b.y, k0b.z, k0b.w},
                           {k1a.x, k1a.y, k1a.z, k1a.w, k1b.x, k1b.y, k1b.z, k1b.w}};
        #pragma unroll
        for (int i = 0; i < 2; ++i) {
            float sd = 0.f;
            #pragma unroll
            for (int c = 0; c < 2; ++c)
                #pragma unroll
                for (int e = 0; e < 8; ++e)
                    sd = fmaf((float)qh[i][c][e] + (float)ql[i][c][e], kmv[c][e], sd);
            sd += __shfl_xor(sd, 16, 64);
            sd += __shfl_xor(sd, 32, 64);
            if (kq == 0) sdotL[w * 32 + i * 16 + lm] = sd;
        }
    }

    float vmax[2][4];
    #pragma unroll
    for (int i = 0; i < 2; ++i)
        #pragma unroll
        for (int r = 0; r < 4; ++r) vmax[i][r] = -INFINITY;

    for (int kt = 0; kt < ntiles; ++kt) {
        __syncthreads();
        #pragma unroll
        for (int s = 0; s < 8; ++s) {
            int u = tid + 256 * s;
            int row = u >> 4, c4 = u & 15;
            int krow = klist[kt * 128 + row];
            float4 f = kb4[krow * 16 + c4];
            uint2 ph, pl;
            cvt4_hilo_h(f, ph, pl);
            int base = ((c4 >> 3) * 128 + row) * 40 + (c4 & 7) * 4;
            *(uint2*)&KH[base] = ph;
            *(uint2*)&KL[base] = pl;
        }
        __syncthreads();

        #pragma unroll
        for (int j = 0; j < 8; ++j) {
            int rb0 = (j * 16 + lm) * 40 + kq * 8;
            int rb1 = (128 + j * 16 + lm) * 40 + kq * 8;
            f16x8 bh0 = *(const f16x8*)&KH[rb0];
            f16x8 bl0 = *(const f16x8*)&KL[rb0];
            f16x8 bh1 = *(const f16x8*)&KH[rb1];
            f16x8 bl1 = *(const f16x8*)&KL[rb1];
            f32x4 a0 = {0.f, 0.f, 0.f, 0.f};
            f32x4 a1 = {0.f, 0.f, 0.f, 0.f};
            a0 = __builtin_amdgcn_mfma_f32_16x16x32_f16(qh[0][0], bh0, a0, 0, 0, 0);
            a1 = __builtin_amdgcn_mfma_f32_16x16x32_f16(qh[1][0], bh0, a1, 0, 0, 0);
            a0 = __builtin_amdgcn_mfma_f32_16x16x32_f16(qh[0][0], bl0, a0, 0, 0, 0);
            a1 = __builtin_amdgcn_mfma_f32_16x16x32_f16(qh[1][0], bl0, a1, 0, 0, 0);
            a0 = __builtin_amdgcn_mfma_f32_16x16x32_f16(ql[0][0], bh0, a0, 0, 0, 0);
            a1 = __builtin_amdgcn_mfma_f32_16x16x32_f16(ql[1][0], bh0, a1, 0, 0, 0);
            a0 = __builtin_amdgcn_mfma_f32_16x16x32_f16(qh[0][1], bh1, a0, 0, 0, 0);
            a1 = __builtin_amdgcn_mfma_f32_16x16x32_f16(qh[1][1], bh1, a1, 0, 0, 0);
            a0 = __builtin_amdgcn_mfma_f32_16x16x32_f16(qh[0][1], bl1, a0, 0, 0, 0);
            a1 = __builtin_amdgcn_mfma_f32_16x16x32_f16(qh[1][1], bl1, a1, 0, 0, 0);
            a0 = __builtin_amdgcn_mfma_f32_16x16x32_f16(ql[0][1], bh1, a0, 0, 0, 0);
            a1 = __builtin_amdgcn_mfma_f32_16x16x32_f16(ql[1][1], bh1, a1, 0, 0, 0);
            #pragma unroll
            for (int r = 0; r < 4; ++r) {
                vmax[0][r] = fmaxf(vmax[0][r], a0[r]);
                vmax[1][r] = fmaxf(vmax[1][r], a1[r]);
            }
        }
    }

    #pragma unroll
    for (int i = 0; i < 2; ++i)
        #pragma unroll
        for (int r = 0; r < 4; ++r) {
            float m = vmax[i][r];
            m = fmaxf(m, __shfl_xor(m, 1, 64));
            m = fmaxf(m, __shfl_xor(m, 2, 64));
            m = fmaxf(m, __shfl_xor(m, 4, 64));
            m = fmaxf(m, __shfl_xor(m, 8, 64));
            if (lm == 0) smax[w * 32 + i * 16 + kq * 4 + r] = m;
        }
    __syncthreads();

    if (tid < 128)
        spars[bh * T_LEN + q0 + tid] = smax[tid] - sdotL[tid] * (1.0f / 2048.0f);
}

// ---------------------------------------------------------------------------
// Kernel D: top-40 per bh by iterative argmax (ties -> smaller index).
// ---------------------------------------------------------------------------
__global__ __launch_bounds__(256)
void topk_kernel(const float* __restrict__ spars, int* __restrict__ topi)
{
    __shared__ float vals[T_LEN];
    __shared__ float rv[256];
    __shared__ int   ri[256];
    const int bh = blockIdx.x, tid = threadIdx.x;
    for (int j = tid; j < T_LEN; j += 256) vals[j] = spars[bh * T_LEN + j];
    __syncthreads();
    for (int it = 0; it < USEL; ++it) {
        float bv = -INFINITY; int bi = 0;
        #pragma unroll
        for (int jj = 0; jj < 8; ++jj) {
            int j = tid * 8 + jj;
            float vv = vals[j];
            if (vv > bv) { bv = vv; bi = j; }
        }
        rv[tid] = bv; ri[tid] = bi;
        __syncthreads();
        for (int s = 128; s > 0; s >>= 1) {
            if (tid < s) {
                float ov = rv[tid + s]; int oi = ri[tid + s];
                if (ov > rv[tid] || (ov == rv[tid] && oi < ri[tid])) { rv[tid] = ov; ri[tid] = oi; }
            }
            __syncthreads();
        }
        if (tid == 0) {
            int win = ri[0] & (T_LEN - 1);
            topi[bh * USEL + it] = win;
            vals[win] = -INFINITY;
        }
        __syncthreads();
    }
}

// ---------------------------------------------------------------------------
// Kernel E1: gather selected q rows -> qsel[bh][u][d]. (q dead afterwards)
// ---------------------------------------------------------------------------
__global__ __launch_bounds__(256)
void gather_q_kernel(const float* __restrict__ q, const int* __restrict__ topi,
                     float* __restrict__ qsel)
{
    const int bh = blockIdx.x, tid = threadIdx.x;
    for (int i = tid; i < USEL * HDIM; i += 256) {
        int u = i >> 6, d = i & 63;
        int t = topi[bh * USEL + u] & (T_LEN - 1);
        qsel[(size_t)bh * USEL * HDIM + i] = q[((size_t)bh * T_LEN + t) * HDIM + d];
    }
}

// ---------------------------------------------------------------------------
// Kernel E2: S[bh][u][t] = qsel[bh][u] . k[bh][t]. Grid (8 t-slices, 32 bh).
// ---------------------------------------------------------------------------
__global__ __launch_bounds__(256)
void sel_scores_kernel(const float* __restrict__ qsel, const float* __restrict__ k,
                       float* __restrict__ S)
{
    __shared__ float qsT[64 * 41];    // [d][u] stride 41
    __shared__ float ksT[64 * 257];   // [d][t] stride 257

    const int sl = blockIdx.x, bh = blockIdx.y, tid = threadIdx.x;
    const int t0 = sl * 256;

    for (int i = tid; i < USEL * HDIM; i += 256) {
        int u = i >> 6, d = i & 63;
        qsT[d * 41 + u] = qsel[(size_t)bh * USEL * HDIM + i];
    }
    const float4* k4 = (const float4*)(k + (size_t)bh * T_LEN * HDIM);
    #pragma unroll
    for (int s = 0; s < 16; ++s) {
        int u = tid + 256 * s;
        int c4 = u & 15, t = u >> 4;
        float4 f = k4[(t0 + t) * 16 + c4];
        ksT[(c4 * 4 + 0) * 257 + t] = f.x;
        ksT[(c4 * 4 + 1) * 257 + t] = f.y;
        ksT[(c4 * 4 + 2) * 257 + t] = f.z;
        ksT[(c4 * 4 + 3) * 257 + t] = f.w;
    }
    __syncthreads();

    const int qg = tid >> 5;
    const int kg = tid & 31;

    float acc[5][8];
    #pragma unroll
    for (int i = 0; i < 5; ++i)
        #pragma unroll
        for (int j = 0; j < 8; ++j) acc[i][j] = 0.0f;

    #pragma unroll 4
    for (int d = 0; d < 64; ++d) {
        float qv[5], kv[8];
        #pragma unroll
        for (int i = 0; i < 5; ++i) qv[i] = qsT[d * 41 + qg * 5 + i];
        #pragma unroll
        for (int j = 0; j < 8; ++j) kv[j] = ksT[d * 257 + kg + 32 * j];
        #pragma unroll
        for (int i = 0; i < 5; ++i)
            #pragma unroll
            for (int j = 0; j < 8; ++j)
                acc[i][j] = fmaf(qv[i], kv[j], acc[i][j]);
    }

    #pragma unroll
    for (int i = 0; i < 5; ++i) {
        float* sp = &S[((size_t)bh * USEL + qg * 5 + i) * T_LEN + t0 + kg];
        #pragma unroll
        for (int j = 0; j < 8; ++j) sp[32 * j] = acc[i][j];
    }
}

// ---------------------------------------------------------------------------
// Kernel E3: in-place softmax over each S row (1280 rows of 2048).
// ---------------------------------------------------------------------------
__global__ __launch_bounds__(256)
void sel_softmax_kernel(float* __restrict__ S)
{
    __shared__ float red[256];
    const int row = blockIdx.x, tid = threadIdx.x;
    float* sr = S + (size_t)row * T_LEN;

    float x[8];
    float m = -INFINITY;
    #pragma unroll
    for (int s = 0; s < 8; ++s) { x[s] = sr[tid + 256 * s]; m = fmaxf(m, x[s]); }
    red[tid] = m;
    __syncthreads();
    for (int s = 128; s > 0; s >>= 1) {
        if (tid < s) red[tid] = fmaxf(red[tid], red[tid + s]);
        __syncthreads();
    }
    m = red[0];
    __syncthreads();

    float sum = 0.f;
    #pragma unroll
    for (int s = 0; s < 8; ++s) { x[s] = __expf(x[s] - m); sum += x[s]; }
    red[tid] = sum;
    __syncthreads();
    for (int s = 128; s > 0; s >>= 1) {
        if (tid < s) red[tid] += red[tid + s];
        __syncthreads();
    }
    float inv = 1.0f / red[0];
    #pragma unroll
    for (int s = 0; s < 8; ++s) sr[tid + 256 * s] = x[s] * inv;
}

// ---------------------------------------------------------------------------
// Kernel E4: PV partial. Grid (16 t-slices, 32 bh).
// ---------------------------------------------------------------------------
__global__ __launch_bounds__(256)
void pv_part_kernel(const float* __restrict__ S, const float* __restrict__ v,
                    float* __restrict__ part)
{
    __shared__ float ps[USEL * 128];      // [q][t]
    __shared__ float vs[128 * 69];        // [t][d] stride 69
    __shared__ float obuf[128 * 20];

    const int sl = blockIdx.x, bh = blockIdx.y, tid = threadIdx.x;
    const int t0 = sl * 128;

    for (int i = tid; i < USEL * 128; i += 256) {
        int q = i >> 7, t = i & 127;
        ps[q * 128 + t] = S[((size_t)bh * USEL + q) * T_LEN + t0 + t];
    }
    const float4* v4 = (const float4*)(v + (size_t)bh * T_LEN * HDIM);
    #pragma unroll
    for (int s = 0; s < 8; ++s) {
        int u = tid + 256 * s;
        int c4 = u & 15, t = u >> 4;
        float4 f = v4[(t0 + t) * 16 + c4];
        vs[t * 69 + c4 * 4 + 0] = f.x;
        vs[t * 69 + c4 * 4 + 1] = f.y;
        vs[t * 69 + c4 * 4 + 2] = f.z;
        vs[t * 69 + c4 * 4 + 3] = f.w;
    }
    __syncthreads();

    const int qg = tid >> 5, r = tid & 31;
    const int dg = r >> 1, th = r & 1;
    const int tb = th * 64;

    float o[5][4];
    #pragma unroll
    for (int i = 0; i < 5; ++i)
        #pragma unroll
        for (int j = 0; j < 4; ++j) o[i][j] = 0.0f;

    #pragma unroll 4
    for (int tt = 0; tt < 64; ++tt) {
        int t = tb + tt;
        float pv[5];
        #pragma unroll
        for (int i = 0; i < 5; ++i) pv[i] = ps[(qg * 5 + i) * 128 + t];
        float4 vv = *(const float4*)&vs[t * 69 + dg * 4];
        #pragma unroll
        for (int i = 0; i < 5; ++i) {
            o[i][0] = fmaf(pv[i], vv.x, o[i][0]);
            o[i][1] = fmaf(pv[i], vv.y, o[i][1]);
            o[i][2] = fmaf(pv[i], vv.z, o[i][2]);
            o[i][3] = fmaf(pv[i], vv.w, o[i][3]);
        }
    }

    const int p = qg * 16 + dg;
    if (th == 1) {
        #pragma unroll
        for (int i = 0; i < 5; ++i)
            #pragma unroll
            for (int j = 0; j < 4; ++j) obuf[p * 20 + i * 4 + j] = o[i][j];
    }
    __syncthreads();
    if (th == 0) {
        float* pb = part + ((size_t)bh * 16 + sl) * (USEL * HDIM);
        #pragma unroll
        for (int i = 0; i < 5; ++i)
            #pragma unroll
            for (int j = 0; j < 4; ++j)
                pb[(qg * 5 + i) * HDIM + dg * 4 + j] = o[i][j] + obuf[p * 20 + i * 4 + j];
    }
}

// ---------------------------------------------------------------------------
// Kernel E5: deterministic merge of 16 PV partials -> attn[bh][u][d].
// ---------------------------------------------------------------------------
__global__ __launch_bounds__(256)
void pv_merge_kernel(const float* __restrict__ part, float* __restrict__ attn)
{
    const int bh = blockIdx.x, tid = threadIdx.x;
    for (int i = tid; i < USEL * HDIM; i += 256) {
        float s = 0.f;
        #pragma unroll
        for (int sl = 0; sl < 16; ++sl)
            s += part[((size_t)bh * 16 + sl) * (USEL * HDIM) + i];
        attn[(size_t)bh * USEL * HDIM + i] = s;
    }
}

// ---------------------------------------------------------------------------
// Kernel F1: fill context (B,T,E layout, fp32) with per-head vmean.
// ---------------------------------------------------------------------------
__global__ __launch_bounds__(256)
void ctx_fill_kernel(const float* __restrict__ vmean, float* __restrict__ ctx)
{
    int flat = blockIdx.x * 256 + threadIdx.x;
    int d = flat & 63, h = (flat >> 6) & 7, b = flat >> 20;
    int bh = (b << 3) | h;
    ctx[flat] = vmean[bh * 64 + d];
}

// ---------------------------------------------------------------------------
// Kernel F2: scatter attn rows into context at top_idx positions.
// ---------------------------------------------------------------------------
__global__ void ctx_scatter_kernel(const float* __restrict__ attn, const int* __restrict__ topi,
                                   float* __restrict__ ctx)
{
    const int u = blockIdx.x, bh = blockIdx.y, d = threadIdx.x;
    const int b = bh >> 3, h = bh & 7;
    const int t = topi[bh * USEL + u] & (T_LEN - 1);
    ctx[(size_t)(b * T_LEN + t) * EMB + h * 64 + d] =
        attn[((size_t)bh * USEL + u) * HDIM + d];
}

// ---------------------------------------------------------------------------
// Kernel G: out = ctx @ Wo^T + bo via bf16 hi+lo 3-pass MFMA (16x16x32).
// ---------------------------------------------------------------------------
__global__ __launch_bounds__(256)
void out_proj_kernel(const float* __restrict__ A, const float* __restrict__ Wo,
                     const float* __restrict__ bo, float* __restrict__ out)
{
    alignas(16) __shared__ u16 Ah[128 * 40];
    alignas(16) __shared__ u16 Al[128 * 40];
    alignas(16) __shared__ u16 Bh[128 * 40];
    alignas(16) __shared__ u16 Bl[128 * 40];

    const int tid = threadIdx.x;
    const int m0 = blockIdx.x * 128;
    const int n0 = blockIdx.y * 128;
    const int w = tid >> 6, lane = tid & 63;
    const int wm = w & 1, wn = w >> 1;
    const int lm = lane & 15, kq = lane >> 4;

    f32x4 acc[4][4];
    #pragma unroll
    for (int i = 0; i < 4; ++i)
        #pragma unroll
        for (int j = 0; j < 4; ++j)
            #pragma unroll
            for (int r = 0; r < 4; ++r) acc[i][j][r] = 0.0f;

    for (int kc = 0; kc < EMB; kc += 32) {
        __syncthreads();
        #pragma unroll
        for (int s = 0; s < 4; ++s) {
            int u = tid + 256 * s;
            int row = u >> 3, c4 = u & 7;
            float4 fa = *(const float4*)&A[(size_t)(m0 + row) * EMB + kc + c4 * 4];
            float4 fb = *(const float4*)&Wo[(n0 + row) * EMB + kc + c4 * 4];
            uint2 ph, pl;
            cvt4_hilo(fa, ph, pl);
            *(uint2*)&Ah[row * 40 + c4 * 4] = ph;
            *(uint2*)&Al[row * 40 + c4 * 4] = pl;
            cvt4_hilo(fb, ph, pl);
            *(uint2*)&Bh[row * 40 + c4 * 4] = ph;
            *(uint2*)&Bl[row * 40 + c4 * 4] = pl;
        }
        __syncthreads();

        bf16v8 ah[4], al[4], bh[4], bl[4];
        #pragma unroll
        for (int i = 0; i < 4; ++i) {
            int ra = (wm * 64 + i * 16 + lm) * 40 + kq * 8;
            ah[i] = *(const bf16v8*)&Ah[ra];
            al[i] = *(const bf16v8*)&Al[ra];
            int rb = (wn * 64 + i * 16 + lm) * 40 + kq * 8;
            bh[i] = *(const bf16v8*)&Bh[rb];
            bl[i] = *(const bf16v8*)&Bl[rb];
        }
        #pragma unroll
        for (int i = 0; i < 4; ++i)
            #pragma unroll
            for (int j = 0; j < 4; ++j) {
                acc[i][j] = __builtin_amdgcn_mfma_f32_16x16x32_bf16(ah[i], bh[j], acc[i][j], 0, 0, 0);
                acc[i][j] = __builtin_amdgcn_mfma_f32_16x16x32_bf16(ah[i], bl[j], acc[i][j], 0, 0, 0);
                acc[i][j] = __builtin_amdgcn_mfma_f32_16x16x32_bf16(al[i], bh[j], acc[i][j], 0, 0, 0);
            }
    }

    #pragma unroll
    for (int j = 0; j < 4; ++j) {
        int ng = n0 + wn * 64 + j * 16 + lm;
        float bias = bo[ng];
        #pragma unroll
        for (int i = 0; i < 4; ++i)
            #pragma unroll
            for (int r = 0; r < 4; ++r) {
                int mg = m0 + wm * 64 + i * 16 + kq * 4 + r;
                out[(size_t)mg * EMB + ng] = acc[i][j][r] + bias;
            }
    }
}

// ---------------------------------------------------------------------------
// Diagnostic: if ws_size is too small, report it via d_out (absmax ~= MiB).
// ---------------------------------------------------------------------------
__global__ __launch_bounds__(256)
void ws_diag_kernel(float* __restrict__ out, int n, float mib)
{
    int flat = blockIdx.x * 256 + threadIdx.x;
    if (flat < n) out[flat] = mib;
}

// ---------------------------------------------------------------------------
extern "C" void kernel_launch(void* const* d_in, const int* in_sizes, int n_in,
                              void* d_out, int out_size, void* d_ws, size_t ws_size,
                              hipStream_t stream)
{
    const float* X = nullptr; const int* idxs = nullptr;
    const float* Wseen[4] = {nullptr, nullptr, nullptr, nullptr};
    const float* bseen[4] = {nullptr, nullptr, nullptr, nullptr};
    int nw = 0, nb = 0, u_part = 2048;
    for (int i = 0; i < n_in; ++i) {
        int sz = in_sizes[i];
        if (sz == EMB * EMB * 16) { if (!X) X = (const float*)d_in[i]; }
        else if (sz == T_LEN)     { if (!idxs) { idxs = (const int*)d_in[i]; u_part = sz; } }
        else if (sz == EMB * EMB) { if (nw < 4) Wseen[nw++] = (const float*)d_in[i]; }
        else if (sz == EMB)       { if (nb < 4) bseen[nb++] = (const float*)d_in[i]; }
    }
    if (!X || !idxs || nw < 4 || nb < 4) {
        X = (const float*)d_in[0]; idxs = (const int*)d_in[1];
        Wseen[0] = (const float*)d_in[2]; bseen[0] = (const float*)d_in[3];
        Wseen[1] = (const float*)d_in[4]; bseen[1] = (const float*)d_in[5];
        Wseen[2] = (const float*)d_in[6]; bseen[2] = (const float*)d_in[7];
        Wseen[3] = (const float*)d_in[8]; bseen[3] = (const float*)d_in[9];
        u_part = in_sizes[1];
    }
    const float *Wq = Wseen[0], *Wk = Wseen[1], *Wv = Wseen[2], *Wo = Wseen[3];
    const float *bq = bseen[0], *bk = bseen[1], *bv = bseen[2], *bo = bseen[3];

    // Base workspace layout (peak 50,951,168 B, unchanged). Pack buffers for
    // the fast qkv path live beyond it: Xp 16 MB + Wp 3 MB.
    const size_t NEED      = 50951168ULL;
    const size_t NEED_BIG  = NEED + 16777216ULL + 3145728ULL;   // 70,874,112
    if (ws_size < NEED) {
        ws_diag_kernel<<<(out_size + 255) / 256, 256, 0, stream>>>(
            (float*)d_out, out_size, (float)(ws_size >> 20));
        return;
    }

    float* ws    = (float*)d_ws;
    float* qw    = ws;                    // 4,194,304 floats
    float* kw    = qw + 4194304;
    float* vw    = kw + 4194304;
    float* tail  = vw + 4194304;
    float* slotA = tail;                  // 81920: qsel, later attn
    float* spars = tail + 81920;          // 65536
    int*   count = (int*)(tail + 147456); // 2048
    float* ksum  = tail + 149504;         // 2048
    float* vmean = tail + 151552;         // 2048
    int*   topi  = (int*)(tail + 153600); // 1280
    float* kpart = tail;                  // overlays in slotA (disjoint liveness)
    float* vpart = tail + 16384;
    int*   klist = (int*)(tail + 32768);
    int*   ncp   = (int*)(tail + 34816);
    float* S     = qw;                    // q dead after gather
    float* pvp   = qw + 2621440;
    float* qsel  = slotA;
    float* attn  = slotA;
    float* ctx   = (float*)d_ws;
    u16*   Xp    = (u16*)((char*)d_ws + NEED);           // 8,388,608 u16
    u16*   Wp    = Xp + 8388608;                         // 1,572,864 u16

    if (ws_size >= NEED_BIG) {
        pack_hilo_kernel<<<1216, 256, 0, stream>>>(X, Wq, Wk, Wv, Xp, Wp);
        qkv_mfma_kernel<<<dim3(64, 4, 3), 256, 0, stream>>>(Xp, Wp, bq, bk, bv, qw, kw, vw);
    } else {
        qkv_proj_kernel<<<dim3(64, 4, 3), 256, 0, stream>>>(X, Wq, bq, Wk, bk, Wv, bv, qw, kw, vw);
    }
    count_compact_kernel<<<1, 256, 0, stream>>>(idxs, u_part, count, klist, ncp);
    ksum_vmean_part_kernel<<<dim3(8, 32), 256, 0, stream>>>(count, kw, vw, kpart, vpart);
    ksum_vmean_reduce_kernel<<<32, 64, 0, stream>>>(kpart, vpart, ksum, vmean);
    sparsity_scan_kernel<<<dim3(16, 32), 256, 0, stream>>>(qw, kw, ksum, klist, ncp, spars);
    topk_kernel<<<32, 256, 0, stream>>>(spars, topi);
    gather_q_kernel<<<32, 256, 0, stream>>>(qw, topi, qsel);
    // qw dead; S/pvp take over that region.
    sel_scores_kernel<<<dim3(8, 32), 256, 0, stream>>>(qsel, kw, S);
    sel_softmax_kernel<<<1280, 256, 0, stream>>>(S);
    pv_part_kernel<<<dim3(16, 32), 256, 0, stream>>>(S, vw, pvp);
    pv_merge_kernel<<<32, 256, 0, stream>>>(pvp, attn);
    // S/pvp dead; ctx takes over the whole front region.
    ctx_fill_kernel<<<16384, 256, 0, stream>>>(vmean, ctx);
    ctx_scatter_kernel<<<dim3(USEL, BHEADS), 64, 0, stream>>>(attn, topi, ctx);
    out_proj_kernel<<<dim3(64, 4), 256, 0, stream>>>(ctx, Wo, bo, (float*)d_out);
}

// Round 5
// 313.815 us; speedup vs baseline: 1.6886x; 1.0988x over previous
//
#include <hip/hip_runtime.h>
#include <hip/hip_bf16.h>
#include <math.h>

#define T_LEN 2048
#define EMB   512
#define NHEAD 8
#define HDIM  64
#define BHEADS 32
#define USEL  40

typedef __bf16 bf16v8 __attribute__((ext_vector_type(8)));
typedef _Float16 f16x8 __attribute__((ext_vector_type(8)));
typedef float f32x4 __attribute__((ext_vector_type(4)));
typedef unsigned short u16;

// Split a float4 into bf16 hi + lo halves, packed as uint2 (4 x u16 each).
__device__ __forceinline__ void cvt4_hilo(const float4 f, uint2& ph, uint2& pl)
{
    __hip_bfloat16 h0 = __float2bfloat16(f.x);
    __hip_bfloat16 h1 = __float2bfloat16(f.y);
    __hip_bfloat16 h2 = __float2bfloat16(f.z);
    __hip_bfloat16 h3 = __float2bfloat16(f.w);
    __hip_bfloat16 l0 = __float2bfloat16(f.x - __bfloat162float(h0));
    __hip_bfloat16 l1 = __float2bfloat16(f.y - __bfloat162float(h1));
    __hip_bfloat16 l2 = __float2bfloat16(f.z - __bfloat162float(h2));
    __hip_bfloat16 l3 = __float2bfloat16(f.w - __bfloat162float(h3));
    ph.x = (unsigned)*(const u16*)&h0 | ((unsigned)*(const u16*)&h1 << 16);
    ph.y = (unsigned)*(const u16*)&h2 | ((unsigned)*(const u16*)&h3 << 16);
    pl.x = (unsigned)*(const u16*)&l0 | ((unsigned)*(const u16*)&l1 << 16);
    pl.y = (unsigned)*(const u16*)&l2 | ((unsigned)*(const u16*)&l3 << 16);
}

// Split a float4 into FP16 hi + lo halves, packed as uint2 (4 x u16 each).
// fp16 has 11-bit mantissa: h+l captures ~22 bits, residual <= 2^-22*|x|.
// Dropped Al*Bl term in the 3-pass GEMM is <= 2^-22*|ab| -> the f16 hi/lo
// 3-pass GEMM is fp32-rounding-equivalent (~1e-6), unlike bf16 hi/lo (~2^-16).
__device__ __forceinline__ void cvt4_hilo_h(const float4 f, uint2& ph, uint2& pl)
{
    _Float16 h0 = (_Float16)f.x;
    _Float16 h1 = (_Float16)f.y;
    _Float16 h2 = (_Float16)f.z;
    _Float16 h3 = (_Float16)f.w;
    _Float16 l0 = (_Float16)(f.x - (float)h0);
    _Float16 l1 = (_Float16)(f.y - (float)h1);
    _Float16 l2 = (_Float16)(f.z - (float)h2);
    _Float16 l3 = (_Float16)(f.w - (float)h3);
    ph.x = (unsigned)*(const u16*)&h0 | ((unsigned)*(const u16*)&h1 << 16);
    ph.y = (unsigned)*(const u16*)&h2 | ((unsigned)*(const u16*)&h3 << 16);
    pl.x = (unsigned)*(const u16*)&l0 | ((unsigned)*(const u16*)&l1 << 16);
    pl.y = (unsigned)*(const u16*)&l2 | ((unsigned)*(const u16*)&l3 << 16);
}

// ---------------------------------------------------------------------------
// Kernel A0: pack X and Wq/Wk/Wv into f16 hi/lo tiles, pre-blocked in MFMA
// fragment order so the GEMM stages them with linear global_load_lds.
// ---------------------------------------------------------------------------
__global__ __launch_bounds__(256)
void pack_hilo_kernel(const float* __restrict__ X,
                      const float* __restrict__ Wq, const float* __restrict__ Wk,
                      const float* __restrict__ Wv,
                      u16* __restrict__ Xp, u16* __restrict__ Wp)
{
    alignas(16) __shared__ u16 th[4096];
    alignas(16) __shared__ u16 tl[4096];
    const int b = blockIdx.x, tid = threadIdx.x;

    const float* src; u16* dst;
    if (b < 1024) {                       // X tile: mt = b>>4, kt = b&15
        int mt = b >> 4, kt = b & 15;
        src = X + (size_t)(mt * 128) * EMB + kt * 32;
        dst = Xp + (size_t)b * 8192;
    } else {                              // W tile
        int wdx = b - 1024;               // wdx = (z*4 + nt)*16 + kt
        int z = wdx >> 6, nt = (wdx >> 4) & 3, kt = wdx & 15;
        const float* W = (z == 0) ? Wq : (z == 1) ? Wk : Wv;
        src = W + (size_t)(nt * 128) * EMB + kt * 32;
        dst = Wp + (size_t)wdx * 8192;
    }

    #pragma unroll
    for (int s = 0; s < 4; ++s) {
        int u = tid + 256 * s;            // 0..1023 float4s
        int row = u >> 3, c4 = u & 7;     // 128 rows x 8 float4
        float4 f = *(const float4*)&src[(size_t)row * EMB + c4 * 4];
        uint2 ph, pl;
        cvt4_hilo_h(f, ph, pl);
        int kq = c4 >> 1, e4 = (c4 & 1) * 4;
        *(uint2*)&th[kq * 1024 + row * 8 + e4] = ph;
        *(uint2*)&tl[kq * 1024 + row * 8 + e4] = pl;
    }
    __syncthreads();

    uint4* d4 = (uint4*)dst;
    const uint4* s4h = (const uint4*)th;
    const uint4* s4l = (const uint4*)tl;
    d4[tid]       = s4h[tid];
    d4[tid + 256] = s4h[tid + 256];
    d4[tid + 512] = s4l[tid];
    d4[tid + 768] = s4l[tid + 256];
}

// ---------------------------------------------------------------------------
// Kernel A1: QKV projection GEMM from pre-packed hi/lo tiles.
// ---------------------------------------------------------------------------
__global__ __launch_bounds__(256)
void qkv_mfma_kernel(const u16* __restrict__ Xp, const u16* __restrict__ Wp,
                     const float* __restrict__ bq, const float* __restrict__ bk,
                     const float* __restrict__ bv,
                     float* __restrict__ qo, float* __restrict__ ko, float* __restrict__ vo)
{
    alignas(16) __shared__ u16 Ah[4096];
    alignas(16) __shared__ u16 Al[4096];
    alignas(16) __shared__ u16 Bh[4096];
    alignas(16) __shared__ u16 Bl[4096];

    const int z = blockIdx.z;
    const float* bias; float* dst; float scale;
    if (z == 0)      { bias = bq; dst = qo; scale = 0.125f; }
    else if (z == 1) { bias = bk; dst = ko; scale = 1.0f;   }
    else             { bias = bv; dst = vo; scale = 1.0f;   }
    const bool three = (z != 2);

    const int tid = threadIdx.x;
    const int mt = blockIdx.x;
    const int nt = blockIdx.y;
    const int w = tid >> 6, lane = tid & 63;
    const int wm = w & 1, wn = w >> 1;
    const int lm = lane & 15, kq = lane >> 4;

    const u16* Abase = Xp + (size_t)mt * (16 * 8192);
    const u16* Bbase = Wp + (size_t)(z * 4 + nt) * (16 * 8192);

    f32x4 acc[4][4];
    #pragma unroll
    for (int i = 0; i < 4; ++i)
        #pragma unroll
        for (int j = 0; j < 4; ++j)
            #pragma unroll
            for (int r = 0; r < 4; ++r) acc[i][j][r] = 0.0f;

    for (int kt = 0; kt < 16; ++kt) {
        __syncthreads();
        const u16* at = Abase + kt * 8192;
        const u16* bt = Bbase + kt * 8192;
        const u16* gsrc; u16* ldst;
        if (w == 0)      { gsrc = at;        ldst = Ah; }
        else if (w == 1) { gsrc = at + 4096; ldst = Al; }
        else if (w == 2) { gsrc = bt;        ldst = Bh; }
        else             { gsrc = bt + 4096; ldst = Bl; }
        if (three || (w & 1) == 0) {
            #pragma unroll
            for (int i = 0; i < 8; ++i)
                __builtin_amdgcn_global_load_lds(
                    (const __attribute__((address_space(1))) void*)(gsrc + (size_t)lane * 8 + i * 512),
                    (__attribute__((address_space(3))) void*)(ldst + i * 512),
                    16, 0, 0);
        }
        __syncthreads();

        f16x8 ah[4], al[4], bh[4], bl[4];
        #pragma unroll
        for (int i = 0; i < 4; ++i) {
            int ar = (wm * 64 + i * 16 + lm) * 8 + kq * 1024;
            int br = (wn * 64 + i * 16 + lm) * 8 + kq * 1024;
            ah[i] = *(const f16x8*)&Ah[ar];
            bh[i] = *(const f16x8*)&Bh[br];
            if (three) {
                al[i] = *(const f16x8*)&Al[ar];
                bl[i] = *(const f16x8*)&Bl[br];
            }
        }
        #pragma unroll
        for (int i = 0; i < 4; ++i)
            #pragma unroll
            for (int j = 0; j < 4; ++j) {
                acc[i][j] = __builtin_amdgcn_mfma_f32_16x16x32_f16(ah[i], bh[j], acc[i][j], 0, 0, 0);
                if (three) {
                    acc[i][j] = __builtin_amdgcn_mfma_f32_16x16x32_f16(ah[i], bl[j], acc[i][j], 0, 0, 0);
                    acc[i][j] = __builtin_amdgcn_mfma_f32_16x16x32_f16(al[i], bh[j], acc[i][j], 0, 0, 0);
                }
            }
    }

    // C/D layout: col = lane&15 (n), row = (lane>>4)*4 + r (m).
    #pragma unroll
    for (int j = 0; j < 4; ++j) {
        int ng = nt * 128 + wn * 64 + j * 16 + lm;
        int h = ng >> 6, d = ng & 63;
        float bv_ = bias[ng];
        #pragma unroll
        for (int i = 0; i < 4; ++i) {
            #pragma unroll
            for (int r = 0; r < 4; ++r) {
                int mg = mt * 128 + wm * 64 + i * 16 + kq * 4 + r;
                int b = mg >> 11, t = mg & 2047;
                dst[((size_t)((b * NHEAD + h) * T_LEN + t)) * HDIM + d] =
                    (acc[i][j][r] + bv_) * scale;
            }
        }
    }
}

// ---------------------------------------------------------------------------
// Kernel A-fallback: prior f16 hi/lo 3-pass qkv (used when ws too small for
// the pack buffers).
// ---------------------------------------------------------------------------
__global__ __launch_bounds__(256)
void qkv_proj_kernel(const float* __restrict__ X,
                     const float* __restrict__ Wq, const float* __restrict__ bq,
                     const float* __restrict__ Wk, const float* __restrict__ bk,
                     const float* __restrict__ Wv, const float* __restrict__ bv,
                     float* __restrict__ qo, float* __restrict__ ko, float* __restrict__ vo)
{
    alignas(16) __shared__ u16 Ah[128 * 40];
    alignas(16) __shared__ u16 Al[128 * 40];
    alignas(16) __shared__ u16 Bh[128 * 40];
    alignas(16) __shared__ u16 Bl[128 * 40];

    const int z = blockIdx.z;
    const float* W; const float* bias; float* dst; float scale;
    if (z == 0)      { W = Wq; bias = bq; dst = qo; scale = 0.125f; }
    else if (z == 1) { W = Wk; bias = bk; dst = ko; scale = 1.0f;   }
    else             { W = Wv; bias = bv; dst = vo; scale = 1.0f;   }

    const int tid = threadIdx.x;
    const int m0 = blockIdx.x * 128;
    const int n0 = blockIdx.y * 128;
    const int w = tid >> 6, lane = tid & 63;
    const int wm = w & 1, wn = w >> 1;
    const int lm = lane & 15, kq = lane >> 4;

    f32x4 acc[4][4];
    #pragma unroll
    for (int i = 0; i < 4; ++i)
        #pragma unroll
        for (int j = 0; j < 4; ++j)
            #pragma unroll
            for (int r = 0; r < 4; ++r) acc[i][j][r] = 0.0f;

    for (int kc = 0; kc < EMB; kc += 32) {
        __syncthreads();
        #pragma unroll
        for (int s = 0; s < 4; ++s) {
            int u = tid + 256 * s;
            int row = u >> 3, c4 = u & 7;
            float4 fa = *(const float4*)&X[(size_t)(m0 + row) * EMB + kc + c4 * 4];
            float4 fb = *(const float4*)&W[(n0 + row) * EMB + kc + c4 * 4];
            uint2 ph, pl;
            cvt4_hilo_h(fa, ph, pl);
            *(uint2*)&Ah[row * 40 + c4 * 4] = ph;
            *(uint2*)&Al[row * 40 + c4 * 4] = pl;
            cvt4_hilo_h(fb, ph, pl);
            *(uint2*)&Bh[row * 40 + c4 * 4] = ph;
            *(uint2*)&Bl[row * 40 + c4 * 4] = pl;
        }
        __syncthreads();

        f16x8 ah[4], al[4], bh[4], bl[4];
        #pragma unroll
        for (int i = 0; i < 4; ++i) {
            int ra = (wm * 64 + i * 16 + lm) * 40 + kq * 8;
            ah[i] = *(const f16x8*)&Ah[ra];
            al[i] = *(const f16x8*)&Al[ra];
            int rb = (wn * 64 + i * 16 + lm) * 40 + kq * 8;
            bh[i] = *(const f16x8*)&Bh[rb];
            bl[i] = *(const f16x8*)&Bl[rb];
        }
        #pragma unroll
        for (int i = 0; i < 4; ++i)
            #pragma unroll
            for (int j = 0; j < 4; ++j) {
                acc[i][j] = __builtin_amdgcn_mfma_f32_16x16x32_f16(ah[i], bh[j], acc[i][j], 0, 0, 0);
                acc[i][j] = __builtin_amdgcn_mfma_f32_16x16x32_f16(ah[i], bl[j], acc[i][j], 0, 0, 0);
                acc[i][j] = __builtin_amdgcn_mfma_f32_16x16x32_f16(al[i], bh[j], acc[i][j], 0, 0, 0);
            }
    }

    #pragma unroll
    for (int j = 0; j < 4; ++j) {
        int ng = n0 + wn * 64 + j * 16 + lm;
        int h = ng >> 6, d = ng & 63;
        float bv_ = bias[ng];
        #pragma unroll
        for (int i = 0; i < 4; ++i) {
            #pragma unroll
            for (int r = 0; r < 4; ++r) {
                int mg = m0 + wm * 64 + i * 16 + kq * 4 + r;
                int b = mg >> 11, t = mg & 2047;
                dst[((size_t)((b * NHEAD + h) * T_LEN + t)) * HDIM + d] =
                    (acc[i][j][r] + bv_) * scale;
            }
        }
    }
}

// ---------------------------------------------------------------------------
// Kernel B1: count + compact distinct sampled indices (single block).
// ---------------------------------------------------------------------------
__global__ __launch_bounds__(256)
void count_compact_kernel(const int* __restrict__ idxs, int n,
                          int* __restrict__ count, int* __restrict__ klist,
                          int* __restrict__ ncp)
{
    __shared__ int cnt[T_LEN];
    __shared__ int th_tot[256];
    __shared__ int th_off[256];
    __shared__ int ncs;
    const int tid = threadIdx.x;
    for (int j = tid; j < T_LEN; j += 256) cnt[j] = 0;
    __syncthreads();
    for (int i = tid; i < n; i += 256) atomicAdd(&cnt[idxs[i] & (T_LEN - 1)], 1);
    __syncthreads();
    const int base = tid * 8;
    int flags[8]; int loc = 0;
    #pragma unroll
    for (int j = 0; j < 8; ++j) {
        int c = cnt[base + j];
        count[base + j] = c;
        flags[j] = (c > 0); loc += flags[j];
    }
    th_tot[tid] = loc;
    __syncthreads();
    if (tid == 0) {
        int run = 0;
        for (int i = 0; i < 256; ++i) { th_off[i] = run; run += th_tot[i]; }
        ncs = run;
        ncp[0] = run;
    }
    __syncthreads();
    int off = th_off[tid];
    #pragma unroll
    for (int j = 0; j < 8; ++j)
        if (flags[j]) klist[off++] = base + j;
    __syncthreads();
    const int nc = ncs;
    const int nt = (nc + 127) & ~127;
    const int k0 = klist[0];
    for (int j = nc + tid; j < nt; j += 256) klist[j] = k0;
}

// ---------------------------------------------------------------------------
// Kernel B2a: partial ksum/vsum per (bh, slice). Coalesced float4 streaming.
// ---------------------------------------------------------------------------
__global__ __launch_bounds__(256)
void ksum_vmean_part_kernel(const int* __restrict__ count,
                            const float* __restrict__ k, const float* __restrict__ v,
                            float* __restrict__ kpart, float* __restrict__ vpart)
{
    __shared__ int cs[256];
    alignas(16) __shared__ float rk[16 * 64];
    alignas(16) __shared__ float rv[16 * 64];

    const int sl = blockIdx.x, bh = blockIdx.y, tid = threadIdx.x;
    const int f4 = tid & 15, tg = tid >> 4;
    const int t0 = sl * 256;

    cs[tid] = count[t0 + tid];
    __syncthreads();

    const float4* k4 = (const float4*)(k + (size_t)bh * T_LEN * HDIM) + t0 * 16;
    const float4* v4 = (const float4*)(v + (size_t)bh * T_LEN * HDIM) + t0 * 16;

    float4 ak = {0.f, 0.f, 0.f, 0.f}, av = {0.f, 0.f, 0.f, 0.f};
    #pragma unroll
    for (int s = 0; s < 16; ++s) {
        int t = tg + s * 16;
        float c = (float)cs[t];
        float4 kf = k4[t * 16 + f4];
        float4 vf = v4[t * 16 + f4];
        ak.x = fmaf(c, kf.x, ak.x); ak.y = fmaf(c, kf.y, ak.y);
        ak.z = fmaf(c, kf.z, ak.z); ak.w = fmaf(c, kf.w, ak.w);
        av.x += vf.x; av.y += vf.y; av.z += vf.z; av.w += vf.w;
    }
    *(float4*)&rk[tg * 64 + f4 * 4] = ak;
    *(float4*)&rv[tg * 64 + f4 * 4] = av;
    __syncthreads();

    if (tid < 64) {
        float sk = 0.f, sv = 0.f;
        #pragma unroll
        for (int g = 0; g < 16; ++g) { sk += rk[g * 64 + tid]; sv += rv[g * 64 + tid]; }
        kpart[((size_t)bh * 8 + sl) * 64 + tid] = sk;
        vpart[((size_t)bh * 8 + sl) * 64 + tid] = sv;
    }
}

// ---------------------------------------------------------------------------
// Kernel B2b: reduce 8 slice-partials -> ksum[bh][d], vmean[bh][d].
// ---------------------------------------------------------------------------
__global__ __launch_bounds__(64)
void ksum_vmean_reduce_kernel(const float* __restrict__ kpart, const float* __restrict__ vpart,
                              float* __restrict__ ksum, float* __restrict__ vmean)
{
    const int bh = blockIdx.x, d = threadIdx.x;
    float sk = 0.f, sv = 0.f;
    #pragma unroll
    for (int sl = 0; sl < 8; ++sl) {
        sk += kpart[((size_t)bh * 8 + sl) * 64 + d];
        sv += vpart[((size_t)bh * 8 + sl) * 64 + d];
    }
    ksum[bh * 64 + d]  = sk;
    vmean[bh * 64 + d] = sv * (1.0f / 2048.0f);
}

// ---------------------------------------------------------------------------
// Kernel C0: pack gathered K rows ONCE per bh into f16 hi/lo fragment-order
// tiles [chunk(2)][kq(4)][row(128)][8] (hi 8192 u16, then lo 8192), so the
// scan stages them with linear global_load_lds. Lives in the dead Xp region.
// ---------------------------------------------------------------------------
__global__ __launch_bounds__(256)
void pack_k_kernel(const float* __restrict__ k, const int* __restrict__ klist,
                   const int* __restrict__ ncp, u16* __restrict__ Kp)
{
    alignas(16) __shared__ u16 th[8192];
    alignas(16) __shared__ u16 tl[8192];
    const int wg = blockIdx.x, tid = threadIdx.x;
    const int swz = (wg & 7) * 64 + (wg >> 3);   // XCD-chunked bijection (512%8==0)
    const int bh = swz >> 4, kt = swz & 15;
    const int ntiles = (ncp[0] + 127) >> 7;
    if (kt >= ntiles) return;

    const float4* kb4 = (const float4*)(k + (size_t)bh * T_LEN * HDIM);
    #pragma unroll
    for (int s = 0; s < 8; ++s) {
        int u = tid + 256 * s;            // 0..2047 float4s
        int row = u >> 4, c4 = u & 15;    // row 0..127, c4 0..15 (d-quad)
        int krow = klist[kt * 128 + row];
        float4 f = kb4[krow * 16 + c4];
        uint2 ph, pl;
        cvt4_hilo_h(f, ph, pl);
        int base = (c4 >> 3) * 4096 + ((c4 >> 1) & 3) * 1024 + row * 8 + (c4 & 1) * 4;
        *(uint2*)&th[base] = ph;
        *(uint2*)&tl[base] = pl;
    }
    __syncthreads();

    u16* dst = Kp + ((size_t)bh * 16 + kt) * 16384;
    uint4* d4 = (uint4*)dst;
    const uint4* s4h = (const uint4*)th;
    const uint4* s4l = (const uint4*)tl;
    #pragma unroll
    for (int i = 0; i < 4; ++i) d4[tid + 256 * i] = s4h[tid + 256 * i];
    #pragma unroll
    for (int i = 0; i < 4; ++i) d4[1024 + tid + 256 * i] = s4l[tid + 256 * i];
}

// ---------------------------------------------------------------------------
// Kernel C: sparsity scan from pre-packed K tiles. Q staging/hoist, sdot and
// the exact 12-MFMA sequence are unchanged from the passing round-2 version
// -> spars bitwise identical -> selection stable. K staging: each wave copies
// its 8 KB quarter with EIGHT global_load_lds(dwordx4) issues (64 lanes x
// 16 B = 1 KB per issue; round-3 bug was 4 issues = half the tile, leaving
// stale q bytes in the upper half -> 0.189 absmax). Zero cvt, zero ds_writes.
// 1D grid 512 with XCD-chunked swizzle: each bh's 16 q-tile blocks share one
// XCD's L2 (360 KB packed K per bh).
// ---------------------------------------------------------------------------
__global__ __launch_bounds__(256)
void sparsity_scan_kernel(const float* __restrict__ q, const u16* __restrict__ Kp,
                          const float* __restrict__ ksum,
                          const int* __restrict__ ncp, float* __restrict__ spars)
{
    alignas(16) __shared__ u16 KH[10240];   // q staging (256*40), then packed K hi (8192)
    alignas(16) __shared__ u16 KL[10240];
    __shared__ float ksm[64];
    __shared__ float smax[128];
    __shared__ float sdotL[128];

    const int tid = threadIdx.x;
    const int wg = blockIdx.x;
    const int swz = (wg & 7) * 64 + (wg >> 3);
    const int bh = swz >> 4;
    const int q0 = (swz & 15) * 128;
    const int w = tid >> 6, lane = tid & 63;
    const int lm = lane & 15, kq = lane >> 4;

    const float* qb = q + ((size_t)bh * T_LEN + q0) * HDIM;
    const int ntiles = (ncp[0] + 127) >> 7;

    if (tid < 64) ksm[tid] = ksum[bh * 64 + tid];

    // Stage q tile (128 rows x 64 d) as f16 hi/lo, chunked [c][row][40].
    #pragma unroll
    for (int s = 0; s < 8; ++s) {
        int u = tid + 256 * s;
        int row = u >> 4, c4 = u & 15;
        float4 f = *(const float4*)&qb[row * HDIM + c4 * 4];
        uint2 ph, pl;
        cvt4_hilo_h(f, ph, pl);
        int base = ((c4 >> 3) * 128 + row) * 40 + (c4 & 7) * 4;
        *(uint2*)&KH[base] = ph;
        *(uint2*)&KL[base] = pl;
    }
    __syncthreads();

    // Hoist A-fragments (32 q rows per wave) to registers.
    f16x8 qh[2][2], ql[2][2];
    #pragma unroll
    for (int i = 0; i < 2; ++i)
        #pragma unroll
        for (int c = 0; c < 2; ++c) {
            int ra = (c * 128 + w * 32 + i * 16 + lm) * 40 + kq * 8;
            qh[i][c] = *(const f16x8*)&KH[ra];
            ql[i][c] = *(const f16x8*)&KL[ra];
        }

    // sdot = q . ksum (hi+lo reconstruction, fp32 accumulate).
    {
        float4 k0a = *(const float4*)&ksm[kq * 8];
        float4 k0b = *(const float4*)&ksm[kq * 8 + 4];
        float4 k1a = *(const float4*)&ksm[32 + kq * 8];
        float4 k1b = *(const float4*)&ksm[32 + kq * 8 + 4];
        float kmv[2][8] = {{k0a.x, k0a.y, k0a.z, k0a.w, k0b.x, k0b.y, k0b.z, k0b.w},
                           {k1a.x, k1a.y, k1a.z, k1a.w, k1b.x, k1b.y, k1b.z, k1b.w}};
        #pragma unroll
        for (int i = 0; i < 2; ++i) {
            float sd = 0.f;
            #pragma unroll
            for (int c = 0; c < 2; ++c)
                #pragma unroll
                for (int e = 0; e < 8; ++e)
                    sd = fmaf((float)qh[i][c][e] + (float)ql[i][c][e], kmv[c][e], sd);
            sd += __shfl_xor(sd, 16, 64);
            sd += __shfl_xor(sd, 32, 64);
            if (kq == 0) sdotL[w * 32 + i * 16 + lm] = sd;
        }
    }

    float vmax[2][4];
    #pragma unroll
    for (int i = 0; i < 2; ++i)
        #pragma unroll
        for (int r = 0; r < 4; ++r) vmax[i][r] = -INFINITY;

    const u16* kpb = Kp + (size_t)bh * (16 * 16384);

    for (int kt = 0; kt < ntiles; ++kt) {
        __syncthreads();   // prior reads of KH/KL done
        const u16* kp = kpb + kt * 16384;
        const u16* gsrc; u16* ldst;
        if (w == 0)      { gsrc = kp;         ldst = KH; }
        else if (w == 1) { gsrc = kp + 4096;  ldst = KH + 4096; }
        else if (w == 2) { gsrc = kp + 8192;  ldst = KL; }
        else             { gsrc = kp + 12288; ldst = KL + 4096; }
        #pragma unroll
        for (int i = 0; i < 8; ++i)    // 8 x 1KB = the wave's full 8KB quarter
            __builtin_amdgcn_global_load_lds(
                (const __attribute__((address_space(1))) void*)(gsrc + (size_t)lane * 8 + i * 512),
                (__attribute__((address_space(3))) void*)(ldst + i * 512),
                16, 0, 0);
        __syncthreads();

        #pragma unroll
        for (int j = 0; j < 8; ++j) {
            int rb0 = kq * 1024 + (j * 16 + lm) * 8;          // chunk 0
            int rb1 = 4096 + kq * 1024 + (j * 16 + lm) * 8;   // chunk 1
            f16x8 bh0 = *(const f16x8*)&KH[rb0];
            f16x8 bl0 = *(const f16x8*)&KL[rb0];
            f16x8 bh1 = *(const f16x8*)&KH[rb1];
            f16x8 bl1 = *(const f16x8*)&KL[rb1];
            f32x4 a0 = {0.f, 0.f, 0.f, 0.f};
            f32x4 a1 = {0.f, 0.f, 0.f, 0.f};
            a0 = __builtin_amdgcn_mfma_f32_16x16x32_f16(qh[0][0], bh0, a0, 0, 0, 0);
            a1 = __builtin_amdgcn_mfma_f32_16x16x32_f16(qh[1][0], bh0, a1, 0, 0, 0);
            a0 = __builtin_amdgcn_mfma_f32_16x16x32_f16(qh[0][0], bl0, a0, 0, 0, 0);
            a1 = __builtin_amdgcn_mfma_f32_16x16x32_f16(qh[1][0], bl0, a1, 0, 0, 0);
            a0 = __builtin_amdgcn_mfma_f32_16x16x32_f16(ql[0][0], bh0, a0, 0, 0, 0);
            a1 = __builtin_amdgcn_mfma_f32_16x16x32_f16(ql[1][0], bh0, a1, 0, 0, 0);
            a0 = __builtin_amdgcn_mfma_f32_16x16x32_f16(qh[0][1], bh1, a0, 0, 0, 0);
            a1 = __builtin_amdgcn_mfma_f32_16x16x32_f16(qh[1][1], bh1, a1, 0, 0, 0);
            a0 = __builtin_amdgcn_mfma_f32_16x16x32_f16(qh[0][1], bl1, a0, 0, 0, 0);
            a1 = __builtin_amdgcn_mfma_f32_16x16x32_f16(qh[1][1], bl1, a1, 0, 0, 0);
            a0 = __builtin_amdgcn_mfma_f32_16x16x32_f16(ql[0][1], bh1, a0, 0, 0, 0);
            a1 = __builtin_amdgcn_mfma_f32_16x16x32_f16(ql[1][1], bh1, a1, 0, 0, 0);
            #pragma unroll
            for (int r = 0; r < 4; ++r) {
                vmax[0][r] = fmaxf(vmax[0][r], a0[r]);
                vmax[1][r] = fmaxf(vmax[1][r], a1[r]);
            }
        }
    }

    #pragma unroll
    for (int i = 0; i < 2; ++i)
        #pragma unroll
        for (int r = 0; r < 4; ++r) {
            float m = vmax[i][r];
            m = fmaxf(m, __shfl_xor(m, 1, 64));
            m = fmaxf(m, __shfl_xor(m, 2, 64));
            m = fmaxf(m, __shfl_xor(m, 4, 64));
            m = fmaxf(m, __shfl_xor(m, 8, 64));
            if (lm == 0) smax[w * 32 + i * 16 + kq * 4 + r] = m;
        }
    __syncthreads();

    if (tid < 128)
        spars[bh * T_LEN + q0 + tid] = smax[tid] - sdotL[tid] * (1.0f / 2048.0f);
}

// ---------------------------------------------------------------------------
// Kernel C-fallback: round-2 scan (gather+cvt per tile), used when ws too
// small for the pack buffers.
// ---------------------------------------------------------------------------
__global__ __launch_bounds__(256)
void sparsity_scan_fb_kernel(const float* __restrict__ q, const float* __restrict__ k,
                             const float* __restrict__ ksum, const int* __restrict__ klist,
                             const int* __restrict__ ncp, float* __restrict__ spars)
{
    alignas(16) __shared__ u16 KH[256 * 40];
    alignas(16) __shared__ u16 KL[256 * 40];
    __shared__ float ksm[64];
    __shared__ float smax[128];
    __shared__ float sdotL[128];

    const int tid = threadIdx.x;
    const int bh = blockIdx.y;
    const int q0 = blockIdx.x * 128;
    const int w = tid >> 6, lane = tid & 63;
    const int lm = lane & 15, kq = lane >> 4;

    const float* qb = q + ((size_t)bh * T_LEN + q0) * HDIM;
    const float4* kb4 = (const float4*)(k + (size_t)bh * T_LEN * HDIM);
    const int ntiles = (ncp[0] + 127) >> 7;

    if (tid < 64) ksm[tid] = ksum[bh * 64 + tid];

    #pragma unroll
    for (int s = 0; s < 8; ++s) {
        int u = tid + 256 * s;
        int row = u >> 4, c4 = u & 15;
        float4 f = *(const float4*)&qb[row * HDIM + c4 * 4];
        uint2 ph, pl;
        cvt4_hilo_h(f, ph, pl);
        int base = ((c4 >> 3) * 128 + row) * 40 + (c4 & 7) * 4;
        *(uint2*)&KH[base] = ph;
        *(uint2*)&KL[base] = pl;
    }
    __syncthreads();

    f16x8 qh[2][2], ql[2][2];
    #pragma unroll
    for (int i = 0; i < 2; ++i)
        #pragma unroll
        for (int c = 0; c < 2; ++c) {
            int ra = (c * 128 + w * 32 + i * 16 + lm) * 40 + kq * 8;
            qh[i][c] = *(const f16x8*)&KH[ra];
            ql[i][c] = *(const f16x8*)&KL[ra];
        }

    {
        float4 k0a = *(const float4*)&ksm[kq * 8];
        float4 k0b = *(const float4*)&ksm[kq * 8 + 4];
        float4 k1a = *(const float4*)&ksm[32 + kq * 8];
        float4 k1b = *(const float4*)&ksm[32 + kq * 8 + 4];
        float kmv[2][8] = {{k0a.x, k0a.y, k0a.z, k0a.w, k0b.x, k0b.y, k0b.z, k0b.w},
                           {k1a.x, k1a.y, k1a.z, k1a.w, k1b.x, k1b.y, k1b.z, k1b.w}};
        #pragma unroll
        for (int i = 0; i < 2; ++i) {
            float sd = 0.f;
            #pragma unroll
            for (int c = 0; c < 2; ++c)
                #pragma unroll
                for (int e = 0; e < 8; ++e)
                    sd = fmaf((float)qh[i][c][e] + (float)ql[i][c][e], kmv[c][e], sd);
            sd += __shfl_xor(sd, 16, 64);
            sd += __shfl_xor(sd, 32, 64);
            if (kq == 0) sdotL[w * 32 + i * 16 + lm] = sd;
        }
    }

    float vmax[2][4];
    #pragma unroll
    for (int i = 0; i < 2; ++i)
        #pragma unroll
        for (int r = 0; r < 4; ++r) vmax[i][r] = -INFINITY;

    for (int kt = 0; kt < ntiles; ++kt) {
        __syncthreads();
        #pragma unroll
        for (int s = 0; s < 8; ++s) {
            int u = tid + 256 * s;
            int row = u >> 4, c4 = u & 15;
            int krow = klist[kt * 128 + row];
            float4 f = kb4[krow * 16 + c4];
            uint2 ph, pl;
            cvt4_hilo_h(f, ph, pl);
            int base = ((c4 >> 3) * 128 + row) * 40 + (c4 & 7) * 4;
            *(uint2*)&KH[base] = ph;
            *(uint2*)&KL[base] = pl;
        }
        __syncthreads();

        #pragma unroll
        for (int j = 0; j < 8; ++j) {
            int rb0 = (j * 16 + lm) * 40 + kq * 8;
            int rb1 = (128 + j * 16 + lm) * 40 + kq * 8;
            f16x8 bh0 = *(const f16x8*)&KH[rb0];
            f16x8 bl0 = *(const f16x8*)&KL[rb0];
            f16x8 bh1 = *(const f16x8*)&KH[rb1];
            f16x8 bl1 = *(const f16x8*)&KL[rb1];
            f32x4 a0 = {0.f, 0.f, 0.f, 0.f};
            f32x4 a1 = {0.f, 0.f, 0.f, 0.f};
            a0 = __builtin_amdgcn_mfma_f32_16x16x32_f16(qh[0][0], bh0, a0, 0, 0, 0);
            a1 = __builtin_amdgcn_mfma_f32_16x16x32_f16(qh[1][0], bh0, a1, 0, 0, 0);
            a0 = __builtin_amdgcn_mfma_f32_16x16x32_f16(qh[0][0], bl0, a0, 0, 0, 0);
            a1 = __builtin_amdgcn_mfma_f32_16x16x32_f16(qh[1][0], bl0, a1, 0, 0, 0);
            a0 = __builtin_amdgcn_mfma_f32_16x16x32_f16(ql[0][0], bh0, a0, 0, 0, 0);
            a1 = __builtin_amdgcn_mfma_f32_16x16x32_f16(ql[1][0], bh0, a1, 0, 0, 0);
            a0 = __builtin_amdgcn_mfma_f32_16x16x32_f16(qh[0][1], bh1, a0, 0, 0, 0);
            a1 = __builtin_amdgcn_mfma_f32_16x16x32_f16(qh[1][1], bh1, a1, 0, 0, 0);
            a0 = __builtin_amdgcn_mfma_f32_16x16x32_f16(qh[0][1], bl1, a0, 0, 0, 0);
            a1 = __builtin_amdgcn_mfma_f32_16x16x32_f16(qh[1][1], bl1, a1, 0, 0, 0);
            a0 = __builtin_amdgcn_mfma_f32_16x16x32_f16(ql[0][1], bh1, a0, 0, 0, 0);
            a1 = __builtin_amdgcn_mfma_f32_16x16x32_f16(ql[1][1], bh1, a1, 0, 0, 0);
            #pragma unroll
            for (int r = 0; r < 4; ++r) {
                vmax[0][r] = fmaxf(vmax[0][r], a0[r]);
                vmax[1][r] = fmaxf(vmax[1][r], a1[r]);
            }
        }
    }

    #pragma unroll
    for (int i = 0; i < 2; ++i)
        #pragma unroll
        for (int r = 0; r < 4; ++r) {
            float m = vmax[i][r];
            m = fmaxf(m, __shfl_xor(m, 1, 64));
            m = fmaxf(m, __shfl_xor(m, 2, 64));
            m = fmaxf(m, __shfl_xor(m, 4, 64));
            m = fmaxf(m, __shfl_xor(m, 8, 64));
            if (lm == 0) smax[w * 32 + i * 16 + kq * 4 + r] = m;
        }
    __syncthreads();

    if (tid < 128)
        spars[bh * T_LEN + q0 + tid] = smax[tid] - sdotL[tid] * (1.0f / 2048.0f);
}

// ---------------------------------------------------------------------------
// Kernel D: top-40 per bh by iterative argmax (ties -> smaller index).
// ---------------------------------------------------------------------------
__global__ __launch_bounds__(256)
void topk_kernel(const float* __restrict__ spars, int* __restrict__ topi)
{
    __shared__ float vals[T_LEN];
    __shared__ float rv[256];
    __shared__ int   ri[256];
    const int bh = blockIdx.x, tid = threadIdx.x;
    for (int j = tid; j < T_LEN; j += 256) vals[j] = spars[bh * T_LEN + j];
    __syncthreads();
    for (int it = 0; it < USEL; ++it) {
        float bv = -INFINITY; int bi = 0;
        #pragma unroll
        for (int jj = 0; jj < 8; ++jj) {
            int j = tid * 8 + jj;
            float vv = vals[j];
            if (vv > bv) { bv = vv; bi = j; }
        }
        rv[tid] = bv; ri[tid] = bi;
        __syncthreads();
        for (int s = 128; s > 0; s >>= 1) {
            if (tid < s) {
                float ov = rv[tid + s]; int oi = ri[tid + s];
                if (ov > rv[tid] || (ov == rv[tid] && oi < ri[tid])) { rv[tid] = ov; ri[tid] = oi; }
            }
            __syncthreads();
        }
        if (tid == 0) {
            int win = ri[0] & (T_LEN - 1);
            topi[bh * USEL + it] = win;
            vals[win] = -INFINITY;
        }
        __syncthreads();
    }
}

// ---------------------------------------------------------------------------
// Kernel E1: gather selected q rows -> qsel[bh][u][d]. (q dead afterwards)
// ---------------------------------------------------------------------------
__global__ __launch_bounds__(256)
void gather_q_kernel(const float* __restrict__ q, const int* __restrict__ topi,
                     float* __restrict__ qsel)
{
    const int bh = blockIdx.x, tid = threadIdx.x;
    for (int i = tid; i < USEL * HDIM; i += 256) {
        int u = i >> 6, d = i & 63;
        int t = topi[bh * USEL + u] & (T_LEN - 1);
        qsel[(size_t)bh * USEL * HDIM + i] = q[((size_t)bh * T_LEN + t) * HDIM + d];
    }
}

// ---------------------------------------------------------------------------
// Kernel E2: S[bh][u][t] = qsel[bh][u] . k[bh][t]. Grid (8 t-slices, 32 bh).
// ---------------------------------------------------------------------------
__global__ __launch_bounds__(256)
void sel_scores_kernel(const float* __restrict__ qsel, const float* __restrict__ k,
                       float* __restrict__ S)
{
    __shared__ float qsT[64 * 41];    // [d][u] stride 41
    __shared__ float ksT[64 * 257];   // [d][t] stride 257

    const int sl = blockIdx.x, bh = blockIdx.y, tid = threadIdx.x;
    const int t0 = sl * 256;

    for (int i = tid; i < USEL * HDIM; i += 256) {
        int u = i >> 6, d = i & 63;
        qsT[d * 41 + u] = qsel[(size_t)bh * USEL * HDIM + i];
    }
    const float4* k4 = (const float4*)(k + (size_t)bh * T_LEN * HDIM);
    #pragma unroll
    for (int s = 0; s < 16; ++s) {
        int u = tid + 256 * s;
        int c4 = u & 15, t = u >> 4;
        float4 f = k4[(t0 + t) * 16 + c4];
        ksT[(c4 * 4 + 0) * 257 + t] = f.x;
        ksT[(c4 * 4 + 1) * 257 + t] = f.y;
        ksT[(c4 * 4 + 2) * 257 + t] = f.z;
        ksT[(c4 * 4 + 3) * 257 + t] = f.w;
    }
    __syncthreads();

    const int qg = tid >> 5;
    const int kg = tid & 31;

    float acc[5][8];
    #pragma unroll
    for (int i = 0; i < 5; ++i)
        #pragma unroll
        for (int j = 0; j < 8; ++j) acc[i][j] = 0.0f;

    #pragma unroll 4
    for (int d = 0; d < 64; ++d) {
        float qv[5], kv[8];
        #pragma unroll
        for (int i = 0; i < 5; ++i) qv[i] = qsT[d * 41 + qg * 5 + i];
        #pragma unroll
        for (int j = 0; j < 8; ++j) kv[j] = ksT[d * 257 + kg + 32 * j];
        #pragma unroll
        for (int i = 0; i < 5; ++i)
            #pragma unroll
            for (int j = 0; j < 8; ++j)
                acc[i][j] = fmaf(qv[i], kv[j], acc[i][j]);
    }

    #pragma unroll
    for (int i = 0; i < 5; ++i) {
        float* sp = &S[((size_t)bh * USEL + qg * 5 + i) * T_LEN + t0 + kg];
        #pragma unroll
        for (int j = 0; j < 8; ++j) sp[32 * j] = acc[i][j];
    }
}

// ---------------------------------------------------------------------------
// Kernel E3: in-place softmax over each S row (1280 rows of 2048).
// ---------------------------------------------------------------------------
__global__ __launch_bounds__(256)
void sel_softmax_kernel(float* __restrict__ S)
{
    __shared__ float red[256];
    const int row = blockIdx.x, tid = threadIdx.x;
    float* sr = S + (size_t)row * T_LEN;

    float x[8];
    float m = -INFINITY;
    #pragma unroll
    for (int s = 0; s < 8; ++s) { x[s] = sr[tid + 256 * s]; m = fmaxf(m, x[s]); }
    red[tid] = m;
    __syncthreads();
    for (int s = 128; s > 0; s >>= 1) {
        if (tid < s) red[tid] = fmaxf(red[tid], red[tid + s]);
        __syncthreads();
    }
    m = red[0];
    __syncthreads();

    float sum = 0.f;
    #pragma unroll
    for (int s = 0; s < 8; ++s) { x[s] = __expf(x[s] - m); sum += x[s]; }
    red[tid] = sum;
    __syncthreads();
    for (int s = 128; s > 0; s >>= 1) {
        if (tid < s) red[tid] += red[tid + s];
        __syncthreads();
    }
    float inv = 1.0f / red[0];
    #pragma unroll
    for (int s = 0; s < 8; ++s) sr[tid + 256 * s] = x[s] * inv;
}

// ---------------------------------------------------------------------------
// Kernel E4: PV partial. Grid (16 t-slices, 32 bh).
// ---------------------------------------------------------------------------
__global__ __launch_bounds__(256)
void pv_part_kernel(const float* __restrict__ S, const float* __restrict__ v,
                    float* __restrict__ part)
{
    __shared__ float ps[USEL * 128];      // [q][t]
    __shared__ float vs[128 * 69];        // [t][d] stride 69
    __shared__ float obuf[128 * 20];

    const int sl = blockIdx.x, bh = blockIdx.y, tid = threadIdx.x;
    const int t0 = sl * 128;

    for (int i = tid; i < USEL * 128; i += 256) {
        int q = i >> 7, t = i & 127;
        ps[q * 128 + t] = S[((size_t)bh * USEL + q) * T_LEN + t0 + t];
    }
    const float4* v4 = (const float4*)(v + (size_t)bh * T_LEN * HDIM);
    #pragma unroll
    for (int s = 0; s < 8; ++s) {
        int u = tid + 256 * s;
        int c4 = u & 15, t = u >> 4;
        float4 f = v4[(t0 + t) * 16 + c4];
        vs[t * 69 + c4 * 4 + 0] = f.x;
        vs[t * 69 + c4 * 4 + 1] = f.y;
        vs[t * 69 + c4 * 4 + 2] = f.z;
        vs[t * 69 + c4 * 4 + 3] = f.w;
    }
    __syncthreads();

    const int qg = tid >> 5, r = tid & 31;
    const int dg = r >> 1, th = r & 1;
    const int tb = th * 64;

    float o[5][4];
    #pragma unroll
    for (int i = 0; i < 5; ++i)
        #pragma unroll
        for (int j = 0; j < 4; ++j) o[i][j] = 0.0f;

    #pragma unroll 4
    for (int tt = 0; tt < 64; ++tt) {
        int t = tb + tt;
        float pv[5];
        #pragma unroll
        for (int i = 0; i < 5; ++i) pv[i] = ps[(qg * 5 + i) * 128 + t];
        float4 vv = *(const float4*)&vs[t * 69 + dg * 4];
        #pragma unroll
        for (int i = 0; i < 5; ++i) {
            o[i][0] = fmaf(pv[i], vv.x, o[i][0]);
            o[i][1] = fmaf(pv[i], vv.y, o[i][1]);
            o[i][2] = fmaf(pv[i], vv.z, o[i][2]);
            o[i][3] = fmaf(pv[i], vv.w, o[i][3]);
        }
    }

    const int p = qg * 16 + dg;
    if (th == 1) {
        #pragma unroll
        for (int i = 0; i < 5; ++i)
            #pragma unroll
            for (int j = 0; j < 4; ++j) obuf[p * 20 + i * 4 + j] = o[i][j];
    }
    __syncthreads();
    if (th == 0) {
        float* pb = part + ((size_t)bh * 16 + sl) * (USEL * HDIM);
        #pragma unroll
        for (int i = 0; i < 5; ++i)
            #pragma unroll
            for (int j = 0; j < 4; ++j)
                pb[(qg * 5 + i) * HDIM + dg * 4 + j] = o[i][j] + obuf[p * 20 + i * 4 + j];
    }
}

// ---------------------------------------------------------------------------
// Kernel E5: deterministic merge of 16 PV partials -> attn[bh][u][d].
// ---------------------------------------------------------------------------
__global__ __launch_bounds__(256)
void pv_merge_kernel(const float* __restrict__ part, float* __restrict__ attn)
{
    const int bh = blockIdx.x, tid = threadIdx.x;
    for (int i = tid; i < USEL * HDIM; i += 256) {
        float s = 0.f;
        #pragma unroll
        for (int sl = 0; sl < 16; ++sl)
            s += part[((size_t)bh * 16 + sl) * (USEL * HDIM) + i];
        attn[(size_t)bh * USEL * HDIM + i] = s;
    }
}

// ---------------------------------------------------------------------------
// Kernel F1: fill context (B,T,E layout, fp32) with per-head vmean.
// ---------------------------------------------------------------------------
__global__ __launch_bounds__(256)
void ctx_fill_kernel(const float* __restrict__ vmean, float* __restrict__ ctx)
{
    int flat = blockIdx.x * 256 + threadIdx.x;
    int d = flat & 63, h = (flat >> 6) & 7, b = flat >> 20;
    int bh = (b << 3) | h;
    ctx[flat] = vmean[bh * 64 + d];
}

// ---------------------------------------------------------------------------
// Kernel F2: scatter attn rows into context at top_idx positions.
// ---------------------------------------------------------------------------
__global__ void ctx_scatter_kernel(const float* __restrict__ attn, const int* __restrict__ topi,
                                   float* __restrict__ ctx)
{
    const int u = blockIdx.x, bh = blockIdx.y, d = threadIdx.x;
    const int b = bh >> 3, h = bh & 7;
    const int t = topi[bh * USEL + u] & (T_LEN - 1);
    ctx[(size_t)(b * T_LEN + t) * EMB + h * 64 + d] =
        attn[((size_t)bh * USEL + u) * HDIM + d];
}

// ---------------------------------------------------------------------------
// Kernel G: out = ctx @ Wo^T + bo via bf16 hi+lo 3-pass MFMA (16x16x32).
// ---------------------------------------------------------------------------
__global__ __launch_bounds__(256)
void out_proj_kernel(const float* __restrict__ A, const float* __restrict__ Wo,
                     const float* __restrict__ bo, float* __restrict__ out)
{
    alignas(16) __shared__ u16 Ah[128 * 40];
    alignas(16) __shared__ u16 Al[128 * 40];
    alignas(16) __shared__ u16 Bh[128 * 40];
    alignas(16) __shared__ u16 Bl[128 * 40];

    const int tid = threadIdx.x;
    const int m0 = blockIdx.x * 128;
    const int n0 = blockIdx.y * 128;
    const int w = tid >> 6, lane = tid & 63;
    const int wm = w & 1, wn = w >> 1;
    const int lm = lane & 15, kq = lane >> 4;

    f32x4 acc[4][4];
    #pragma unroll
    for (int i = 0; i < 4; ++i)
        #pragma unroll
        for (int j = 0; j < 4; ++j)
            #pragma unroll
            for (int r = 0; r < 4; ++r) acc[i][j][r] = 0.0f;

    for (int kc = 0; kc < EMB; kc += 32) {
        __syncthreads();
        #pragma unroll
        for (int s = 0; s < 4; ++s) {
            int u = tid + 256 * s;
            int row = u >> 3, c4 = u & 7;
            float4 fa = *(const float4*)&A[(size_t)(m0 + row) * EMB + kc + c4 * 4];
            float4 fb = *(const float4*)&Wo[(n0 + row) * EMB + kc + c4 * 4];
            uint2 ph, pl;
            cvt4_hilo(fa, ph, pl);
            *(uint2*)&Ah[row * 40 + c4 * 4] = ph;
            *(uint2*)&Al[row * 40 + c4 * 4] = pl;
            cvt4_hilo(fb, ph, pl);
            *(uint2*)&Bh[row * 40 + c4 * 4] = ph;
            *(uint2*)&Bl[row * 40 + c4 * 4] = pl;
        }
        __syncthreads();

        bf16v8 ah[4], al[4], bh[4], bl[4];
        #pragma unroll
        for (int i = 0; i < 4; ++i) {
            int ra = (wm * 64 + i * 16 + lm) * 40 + kq * 8;
            ah[i] = *(const bf16v8*)&Ah[ra];
            al[i] = *(const bf16v8*)&Al[ra];
            int rb = (wn * 64 + i * 16 + lm) * 40 + kq * 8;
            bh[i] = *(const bf16v8*)&Bh[rb];
            bl[i] = *(const bf16v8*)&Bl[rb];
        }
        #pragma unroll
        for (int i = 0; i < 4; ++i)
            #pragma unroll
            for (int j = 0; j < 4; ++j) {
                acc[i][j] = __builtin_amdgcn_mfma_f32_16x16x32_bf16(ah[i], bh[j], acc[i][j], 0, 0, 0);
                acc[i][j] = __builtin_amdgcn_mfma_f32_16x16x32_bf16(ah[i], bl[j], acc[i][j], 0, 0, 0);
                acc[i][j] = __builtin_amdgcn_mfma_f32_16x16x32_bf16(al[i], bh[j], acc[i][j], 0, 0, 0);
            }
    }

    #pragma unroll
    for (int j = 0; j < 4; ++j) {
        int ng = n0 + wn * 64 + j * 16 + lm;
        float bias = bo[ng];
        #pragma unroll
        for (int i = 0; i < 4; ++i)
            #pragma unroll
            for (int r = 0; r < 4; ++r) {
                int mg = m0 + wm * 64 + i * 16 + kq * 4 + r;
                out[(size_t)mg * EMB + ng] = acc[i][j][r] + bias;
            }
    }
}

// ---------------------------------------------------------------------------
// Diagnostic: if ws_size is too small, report it via d_out (absmax ~= MiB).
// ---------------------------------------------------------------------------
__global__ __launch_bounds__(256)
void ws_diag_kernel(float* __restrict__ out, int n, float mib)
{
    int flat = blockIdx.x * 256 + threadIdx.x;
    if (flat < n) out[flat] = mib;
}

// ---------------------------------------------------------------------------
extern "C" void kernel_launch(void* const* d_in, const int* in_sizes, int n_in,
                              void* d_out, int out_size, void* d_ws, size_t ws_size,
                              hipStream_t stream)
{
    const float* X = nullptr; const int* idxs = nullptr;
    const float* Wseen[4] = {nullptr, nullptr, nullptr, nullptr};
    const float* bseen[4] = {nullptr, nullptr, nullptr, nullptr};
    int nw = 0, nb = 0, u_part = 2048;
    for (int i = 0; i < n_in; ++i) {
        int sz = in_sizes[i];
        if (sz == EMB * EMB * 16) { if (!X) X = (const float*)d_in[i]; }
        else if (sz == T_LEN)     { if (!idxs) { idxs = (const int*)d_in[i]; u_part = sz; } }
        else if (sz == EMB * EMB) { if (nw < 4) Wseen[nw++] = (const float*)d_in[i]; }
        else if (sz == EMB)       { if (nb < 4) bseen[nb++] = (const float*)d_in[i]; }
    }
    if (!X || !idxs || nw < 4 || nb < 4) {
        X = (const float*)d_in[0]; idxs = (const int*)d_in[1];
        Wseen[0] = (const float*)d_in[2]; bseen[0] = (const float*)d_in[3];
        Wseen[1] = (const float*)d_in[4]; bseen[1] = (const float*)d_in[5];
        Wseen[2] = (const float*)d_in[6]; bseen[2] = (const float*)d_in[7];
        Wseen[3] = (const float*)d_in[8]; bseen[3] = (const float*)d_in[9];
        u_part = in_sizes[1];
    }
    const float *Wq = Wseen[0], *Wk = Wseen[1], *Wv = Wseen[2], *Wo = Wseen[3];
    const float *bq = bseen[0], *bk = bseen[1], *bv = bseen[2], *bo = bseen[3];

    // Base workspace layout (peak 50,951,168 B, unchanged). Pack buffers for
    // the fast paths live beyond it: Xp 16 MB (reused as packed K) + Wp 3 MB.
    const size_t NEED      = 50951168ULL;
    const size_t NEED_BIG  = NEED + 16777216ULL + 3145728ULL;   // 70,874,112
    if (ws_size < NEED) {
        ws_diag_kernel<<<(out_size + 255) / 256, 256, 0, stream>>>(
            (float*)d_out, out_size, (float)(ws_size >> 20));
        return;
    }

    float* ws    = (float*)d_ws;
    float* qw    = ws;                    // 4,194,304 floats
    float* kw    = qw + 4194304;
    float* vw    = kw + 4194304;
    float* tail  = vw + 4194304;
    float* slotA = tail;                  // 81920: qsel, later attn
    float* spars = tail + 81920;          // 65536
    int*   count = (int*)(tail + 147456); // 2048
    float* ksum  = tail + 149504;         // 2048
    float* vmean = tail + 151552;         // 2048
    int*   topi  = (int*)(tail + 153600); // 1280
    float* kpart = tail;                  // overlays in slotA (disjoint liveness)
    float* vpart = tail + 16384;
    int*   klist = (int*)(tail + 32768);
    int*   ncp   = (int*)(tail + 34816);
    float* S     = qw;                    // q dead after gather
    float* pvp   = qw + 2621440;
    float* qsel  = slotA;
    float* attn  = slotA;
    float* ctx   = (float*)d_ws;
    u16*   Xp    = (u16*)((char*)d_ws + NEED);   // 8,388,608 u16 (16 MB)
    u16*   Wp    = Xp + 8388608;                 // 1,572,864 u16 (3 MB)
    u16*   Kp    = Xp;                           // packed K overlays Xp (dead after qkv)

    const bool big = (ws_size >= NEED_BIG);

    if (big) {
        pack_hilo_kernel<<<1216, 256, 0, stream>>>(X, Wq, Wk, Wv, Xp, Wp);
        qkv_mfma_kernel<<<dim3(64, 4, 3), 256, 0, stream>>>(Xp, Wp, bq, bk, bv, qw, kw, vw);
    } else {
        qkv_proj_kernel<<<dim3(64, 4, 3), 256, 0, stream>>>(X, Wq, bq, Wk, bk, Wv, bv, qw, kw, vw);
    }
    count_compact_kernel<<<1, 256, 0, stream>>>(idxs, u_part, count, klist, ncp);
    ksum_vmean_part_kernel<<<dim3(8, 32), 256, 0, stream>>>(count, kw, vw, kpart, vpart);
    ksum_vmean_reduce_kernel<<<32, 64, 0, stream>>>(kpart, vpart, ksum, vmean);
    if (big) {
        pack_k_kernel<<<512, 256, 0, stream>>>(kw, klist, ncp, Kp);
        sparsity_scan_kernel<<<512, 256, 0, stream>>>(qw, Kp, ksum, ncp, spars);
    } else {
        sparsity_scan_fb_kernel<<<dim3(16, 32), 256, 0, stream>>>(qw, kw, ksum, klist, ncp, spars);
    }
    topk_kernel<<<32, 256, 0, stream>>>(spars, topi);
    gather_q_kernel<<<32, 256, 0, stream>>>(qw, topi, qsel);
    // qw dead; S/pvp take over that region.
    sel_scores_kernel<<<dim3(8, 32), 256, 0, stream>>>(qsel, kw, S);
    sel_softmax_kernel<<<1280, 256, 0, stream>>>(S);
    pv_part_kernel<<<dim3(16, 32), 256, 0, stream>>>(S, vw, pvp);
    pv_merge_kernel<<<32, 256, 0, stream>>>(pvp, attn);
    // S/pvp dead; ctx takes over the whole front region.
    ctx_fill_kernel<<<16384, 256, 0, stream>>>(vmean, ctx);
    ctx_scatter_kernel<<<dim3(USEL, BHEADS), 64, 0, stream>>>(attn, topi, ctx);
    out_proj_kernel<<<dim3(64, 4), 256, 0, stream>>>(ctx, Wo, bo, (float*)d_out);
}

// Round 6
// 279.978 us; speedup vs baseline: 1.8927x; 1.1209x over previous
//
#include <hip/hip_runtime.h>
#include <hip/hip_bf16.h>
#include <math.h>

#define T_LEN 2048
#define EMB   512
#define NHEAD 8
#define HDIM  64
#define BHEADS 32
#define USEL  40

typedef __bf16 bf16v8 __attribute__((ext_vector_type(8)));
typedef _Float16 f16x8 __attribute__((ext_vector_type(8)));
typedef float f32x4 __attribute__((ext_vector_type(4)));
typedef unsigned short u16;

// Split a float4 into bf16 hi + lo halves, packed as uint2 (4 x u16 each).
__device__ __forceinline__ void cvt4_hilo(const float4 f, uint2& ph, uint2& pl)
{
    __hip_bfloat16 h0 = __float2bfloat16(f.x);
    __hip_bfloat16 h1 = __float2bfloat16(f.y);
    __hip_bfloat16 h2 = __float2bfloat16(f.z);
    __hip_bfloat16 h3 = __float2bfloat16(f.w);
    __hip_bfloat16 l0 = __float2bfloat16(f.x - __bfloat162float(h0));
    __hip_bfloat16 l1 = __float2bfloat16(f.y - __bfloat162float(h1));
    __hip_bfloat16 l2 = __float2bfloat16(f.z - __bfloat162float(h2));
    __hip_bfloat16 l3 = __float2bfloat16(f.w - __bfloat162float(h3));
    ph.x = (unsigned)*(const u16*)&h0 | ((unsigned)*(const u16*)&h1 << 16);
    ph.y = (unsigned)*(const u16*)&h2 | ((unsigned)*(const u16*)&h3 << 16);
    pl.x = (unsigned)*(const u16*)&l0 | ((unsigned)*(const u16*)&l1 << 16);
    pl.y = (unsigned)*(const u16*)&l2 | ((unsigned)*(const u16*)&l3 << 16);
}

// Split a float4 into FP16 hi + lo halves, packed as uint2 (4 x u16 each).
// fp16 has 11-bit mantissa: h+l captures ~22 bits, residual <= 2^-22*|x|.
// Dropped Al*Bl term in the 3-pass GEMM is <= 2^-22*|ab| -> the f16 hi/lo
// 3-pass GEMM is fp32-rounding-equivalent (~1e-6), unlike bf16 hi/lo (~2^-16).
__device__ __forceinline__ void cvt4_hilo_h(const float4 f, uint2& ph, uint2& pl)
{
    _Float16 h0 = (_Float16)f.x;
    _Float16 h1 = (_Float16)f.y;
    _Float16 h2 = (_Float16)f.z;
    _Float16 h3 = (_Float16)f.w;
    _Float16 l0 = (_Float16)(f.x - (float)h0);
    _Float16 l1 = (_Float16)(f.y - (float)h1);
    _Float16 l2 = (_Float16)(f.z - (float)h2);
    _Float16 l3 = (_Float16)(f.w - (float)h3);
    ph.x = (unsigned)*(const u16*)&h0 | ((unsigned)*(const u16*)&h1 << 16);
    ph.y = (unsigned)*(const u16*)&h2 | ((unsigned)*(const u16*)&h3 << 16);
    pl.x = (unsigned)*(const u16*)&l0 | ((unsigned)*(const u16*)&l1 << 16);
    pl.y = (unsigned)*(const u16*)&l2 | ((unsigned)*(const u16*)&l3 << 16);
}

// ---------------------------------------------------------------------------
// Kernel A0: pack X and Wq/Wk/Wv into f16 hi/lo tiles, pre-blocked in MFMA
// fragment order so the GEMM stages them with linear global_load_lds.
// ---------------------------------------------------------------------------
__global__ __launch_bounds__(256)
void pack_hilo_kernel(const float* __restrict__ X,
                      const float* __restrict__ Wq, const float* __restrict__ Wk,
                      const float* __restrict__ Wv,
                      u16* __restrict__ Xp, u16* __restrict__ Wp)
{
    alignas(16) __shared__ u16 th[4096];
    alignas(16) __shared__ u16 tl[4096];
    const int b = blockIdx.x, tid = threadIdx.x;

    const float* src; u16* dst;
    if (b < 1024) {                       // X tile: mt = b>>4, kt = b&15
        int mt = b >> 4, kt = b & 15;
        src = X + (size_t)(mt * 128) * EMB + kt * 32;
        dst = Xp + (size_t)b * 8192;
    } else {                              // W tile
        int wdx = b - 1024;               // wdx = (z*4 + nt)*16 + kt
        int z = wdx >> 6, nt = (wdx >> 4) & 3, kt = wdx & 15;
        const float* W = (z == 0) ? Wq : (z == 1) ? Wk : Wv;
        src = W + (size_t)(nt * 128) * EMB + kt * 32;
        dst = Wp + (size_t)wdx * 8192;
    }

    #pragma unroll
    for (int s = 0; s < 4; ++s) {
        int u = tid + 256 * s;            // 0..1023 float4s
        int row = u >> 3, c4 = u & 7;     // 128 rows x 8 float4
        float4 f = *(const float4*)&src[(size_t)row * EMB + c4 * 4];
        uint2 ph, pl;
        cvt4_hilo_h(f, ph, pl);
        int kq = c4 >> 1, e4 = (c4 & 1) * 4;
        *(uint2*)&th[kq * 1024 + row * 8 + e4] = ph;
        *(uint2*)&tl[kq * 1024 + row * 8 + e4] = pl;
    }
    __syncthreads();

    uint4* d4 = (uint4*)dst;
    const uint4* s4h = (const uint4*)th;
    const uint4* s4l = (const uint4*)tl;
    d4[tid]       = s4h[tid];
    d4[tid + 256] = s4h[tid + 256];
    d4[tid + 512] = s4l[tid];
    d4[tid + 768] = s4l[tid + 256];
}

// ---------------------------------------------------------------------------
// Kernel A1: QKV projection GEMM from pre-packed hi/lo tiles.
// ---------------------------------------------------------------------------
__global__ __launch_bounds__(256)
void qkv_mfma_kernel(const u16* __restrict__ Xp, const u16* __restrict__ Wp,
                     const float* __restrict__ bq, const float* __restrict__ bk,
                     const float* __restrict__ bv,
                     float* __restrict__ qo, float* __restrict__ ko, float* __restrict__ vo)
{
    alignas(16) __shared__ u16 Ah[4096];
    alignas(16) __shared__ u16 Al[4096];
    alignas(16) __shared__ u16 Bh[4096];
    alignas(16) __shared__ u16 Bl[4096];

    const int z = blockIdx.z;
    const float* bias; float* dst; float scale;
    if (z == 0)      { bias = bq; dst = qo; scale = 0.125f; }
    else if (z == 1) { bias = bk; dst = ko; scale = 1.0f;   }
    else             { bias = bv; dst = vo; scale = 1.0f;   }
    const bool three = (z != 2);

    const int tid = threadIdx.x;
    const int mt = blockIdx.x;
    const int nt = blockIdx.y;
    const int w = tid >> 6, lane = tid & 63;
    const int wm = w & 1, wn = w >> 1;
    const int lm = lane & 15, kq = lane >> 4;

    const u16* Abase = Xp + (size_t)mt * (16 * 8192);
    const u16* Bbase = Wp + (size_t)(z * 4 + nt) * (16 * 8192);

    f32x4 acc[4][4];
    #pragma unroll
    for (int i = 0; i < 4; ++i)
        #pragma unroll
        for (int j = 0; j < 4; ++j)
            #pragma unroll
            for (int r = 0; r < 4; ++r) acc[i][j][r] = 0.0f;

    for (int kt = 0; kt < 16; ++kt) {
        __syncthreads();
        const u16* at = Abase + kt * 8192;
        const u16* bt = Bbase + kt * 8192;
        const u16* gsrc; u16* ldst;
        if (w == 0)      { gsrc = at;        ldst = Ah; }
        else if (w == 1) { gsrc = at + 4096; ldst = Al; }
        else if (w == 2) { gsrc = bt;        ldst = Bh; }
        else             { gsrc = bt + 4096; ldst = Bl; }
        if (three || (w & 1) == 0) {
            #pragma unroll
            for (int i = 0; i < 8; ++i)
                __builtin_amdgcn_global_load_lds(
                    (const __attribute__((address_space(1))) void*)(gsrc + (size_t)lane * 8 + i * 512),
                    (__attribute__((address_space(3))) void*)(ldst + i * 512),
                    16, 0, 0);
        }
        __syncthreads();

        f16x8 ah[4], al[4], bh[4], bl[4];
        #pragma unroll
        for (int i = 0; i < 4; ++i) {
            int ar = (wm * 64 + i * 16 + lm) * 8 + kq * 1024;
            int br = (wn * 64 + i * 16 + lm) * 8 + kq * 1024;
            ah[i] = *(const f16x8*)&Ah[ar];
            bh[i] = *(const f16x8*)&Bh[br];
            if (three) {
                al[i] = *(const f16x8*)&Al[ar];
                bl[i] = *(const f16x8*)&Bl[br];
            }
        }
        #pragma unroll
        for (int i = 0; i < 4; ++i)
            #pragma unroll
            for (int j = 0; j < 4; ++j) {
                acc[i][j] = __builtin_amdgcn_mfma_f32_16x16x32_f16(ah[i], bh[j], acc[i][j], 0, 0, 0);
                if (three) {
                    acc[i][j] = __builtin_amdgcn_mfma_f32_16x16x32_f16(ah[i], bl[j], acc[i][j], 0, 0, 0);
                    acc[i][j] = __builtin_amdgcn_mfma_f32_16x16x32_f16(al[i], bh[j], acc[i][j], 0, 0, 0);
                }
            }
    }

    // C/D layout: col = lane&15 (n), row = (lane>>4)*4 + r (m).
    #pragma unroll
    for (int j = 0; j < 4; ++j) {
        int ng = nt * 128 + wn * 64 + j * 16 + lm;
        int h = ng >> 6, d = ng & 63;
        float bv_ = bias[ng];
        #pragma unroll
        for (int i = 0; i < 4; ++i) {
            #pragma unroll
            for (int r = 0; r < 4; ++r) {
                int mg = mt * 128 + wm * 64 + i * 16 + kq * 4 + r;
                int b = mg >> 11, t = mg & 2047;
                dst[((size_t)((b * NHEAD + h) * T_LEN + t)) * HDIM + d] =
                    (acc[i][j][r] + bv_) * scale;
            }
        }
    }
}

// ---------------------------------------------------------------------------
// Kernel A-fallback: prior f16 hi/lo 3-pass qkv (used when ws too small for
// the pack buffers).
// ---------------------------------------------------------------------------
__global__ __launch_bounds__(256)
void qkv_proj_kernel(const float* __restrict__ X,
                     const float* __restrict__ Wq, const float* __restrict__ bq,
                     const float* __restrict__ Wk, const float* __restrict__ bk,
                     const float* __restrict__ Wv, const float* __restrict__ bv,
                     float* __restrict__ qo, float* __restrict__ ko, float* __restrict__ vo)
{
    alignas(16) __shared__ u16 Ah[128 * 40];
    alignas(16) __shared__ u16 Al[128 * 40];
    alignas(16) __shared__ u16 Bh[128 * 40];
    alignas(16) __shared__ u16 Bl[128 * 40];

    const int z = blockIdx.z;
    const float* W; const float* bias; float* dst; float scale;
    if (z == 0)      { W = Wq; bias = bq; dst = qo; scale = 0.125f; }
    else if (z == 1) { W = Wk; bias = bk; dst = ko; scale = 1.0f;   }
    else             { W = Wv; bias = bv; dst = vo; scale = 1.0f;   }

    const int tid = threadIdx.x;
    const int m0 = blockIdx.x * 128;
    const int n0 = blockIdx.y * 128;
    const int w = tid >> 6, lane = tid & 63;
    const int wm = w & 1, wn = w >> 1;
    const int lm = lane & 15, kq = lane >> 4;

    f32x4 acc[4][4];
    #pragma unroll
    for (int i = 0; i < 4; ++i)
        #pragma unroll
        for (int j = 0; j < 4; ++j)
            #pragma unroll
            for (int r = 0; r < 4; ++r) acc[i][j][r] = 0.0f;

    for (int kc = 0; kc < EMB; kc += 32) {
        __syncthreads();
        #pragma unroll
        for (int s = 0; s < 4; ++s) {
            int u = tid + 256 * s;
            int row = u >> 3, c4 = u & 7;
            float4 fa = *(const float4*)&X[(size_t)(m0 + row) * EMB + kc + c4 * 4];
            float4 fb = *(const float4*)&W[(n0 + row) * EMB + kc + c4 * 4];
            uint2 ph, pl;
            cvt4_hilo_h(fa, ph, pl);
            *(uint2*)&Ah[row * 40 + c4 * 4] = ph;
            *(uint2*)&Al[row * 40 + c4 * 4] = pl;
            cvt4_hilo_h(fb, ph, pl);
            *(uint2*)&Bh[row * 40 + c4 * 4] = ph;
            *(uint2*)&Bl[row * 40 + c4 * 4] = pl;
        }
        __syncthreads();

        f16x8 ah[4], al[4], bh[4], bl[4];
        #pragma unroll
        for (int i = 0; i < 4; ++i) {
            int ra = (wm * 64 + i * 16 + lm) * 40 + kq * 8;
            ah[i] = *(const f16x8*)&Ah[ra];
            al[i] = *(const f16x8*)&Al[ra];
            int rb = (wn * 64 + i * 16 + lm) * 40 + kq * 8;
            bh[i] = *(const f16x8*)&Bh[rb];
            bl[i] = *(const f16x8*)&Bl[rb];
        }
        #pragma unroll
        for (int i = 0; i < 4; ++i)
            #pragma unroll
            for (int j = 0; j < 4; ++j) {
                acc[i][j] = __builtin_amdgcn_mfma_f32_16x16x32_f16(ah[i], bh[j], acc[i][j], 0, 0, 0);
                acc[i][j] = __builtin_amdgcn_mfma_f32_16x16x32_f16(ah[i], bl[j], acc[i][j], 0, 0, 0);
                acc[i][j] = __builtin_amdgcn_mfma_f32_16x16x32_f16(al[i], bh[j], acc[i][j], 0, 0, 0);
            }
    }

    #pragma unroll
    for (int j = 0; j < 4; ++j) {
        int ng = n0 + wn * 64 + j * 16 + lm;
        int h = ng >> 6, d = ng & 63;
        float bv_ = bias[ng];
        #pragma unroll
        for (int i = 0; i < 4; ++i) {
            #pragma unroll
            for (int r = 0; r < 4; ++r) {
                int mg = m0 + wm * 64 + i * 16 + kq * 4 + r;
                int b = mg >> 11, t = mg & 2047;
                dst[((size_t)((b * NHEAD + h) * T_LEN + t)) * HDIM + d] =
                    (acc[i][j][r] + bv_) * scale;
            }
        }
    }
}

// ---------------------------------------------------------------------------
// Kernel B1: count + compact distinct sampled indices (single block).
// ---------------------------------------------------------------------------
__global__ __launch_bounds__(256)
void count_compact_kernel(const int* __restrict__ idxs, int n,
                          int* __restrict__ count, int* __restrict__ klist,
                          int* __restrict__ ncp)
{
    __shared__ int cnt[T_LEN];
    __shared__ int th_tot[256];
    __shared__ int th_off[256];
    __shared__ int ncs;
    const int tid = threadIdx.x;
    for (int j = tid; j < T_LEN; j += 256) cnt[j] = 0;
    __syncthreads();
    for (int i = tid; i < n; i += 256) atomicAdd(&cnt[idxs[i] & (T_LEN - 1)], 1);
    __syncthreads();
    const int base = tid * 8;
    int flags[8]; int loc = 0;
    #pragma unroll
    for (int j = 0; j < 8; ++j) {
        int c = cnt[base + j];
        count[base + j] = c;
        flags[j] = (c > 0); loc += flags[j];
    }
    th_tot[tid] = loc;
    __syncthreads();
    if (tid == 0) {
        int run = 0;
        for (int i = 0; i < 256; ++i) { th_off[i] = run; run += th_tot[i]; }
        ncs = run;
        ncp[0] = run;
    }
    __syncthreads();
    int off = th_off[tid];
    #pragma unroll
    for (int j = 0; j < 8; ++j)
        if (flags[j]) klist[off++] = base + j;
    __syncthreads();
    const int nc = ncs;
    const int nt = (nc + 127) & ~127;
    const int k0 = klist[0];
    for (int j = nc + tid; j < nt; j += 256) klist[j] = k0;
}

// ---------------------------------------------------------------------------
// Kernel B2a: partial ksum/vsum per (bh, slice). Coalesced float4 streaming.
// ---------------------------------------------------------------------------
__global__ __launch_bounds__(256)
void ksum_vmean_part_kernel(const int* __restrict__ count,
                            const float* __restrict__ k, const float* __restrict__ v,
                            float* __restrict__ kpart, float* __restrict__ vpart)
{
    __shared__ int cs[256];
    alignas(16) __shared__ float rk[16 * 64];
    alignas(16) __shared__ float rv[16 * 64];

    const int sl = blockIdx.x, bh = blockIdx.y, tid = threadIdx.x;
    const int f4 = tid & 15, tg = tid >> 4;
    const int t0 = sl * 256;

    cs[tid] = count[t0 + tid];
    __syncthreads();

    const float4* k4 = (const float4*)(k + (size_t)bh * T_LEN * HDIM) + t0 * 16;
    const float4* v4 = (const float4*)(v + (size_t)bh * T_LEN * HDIM) + t0 * 16;

    float4 ak = {0.f, 0.f, 0.f, 0.f}, av = {0.f, 0.f, 0.f, 0.f};
    #pragma unroll
    for (int s = 0; s < 16; ++s) {
        int t = tg + s * 16;
        float c = (float)cs[t];
        float4 kf = k4[t * 16 + f4];
        float4 vf = v4[t * 16 + f4];
        ak.x = fmaf(c, kf.x, ak.x); ak.y = fmaf(c, kf.y, ak.y);
        ak.z = fmaf(c, kf.z, ak.z); ak.w = fmaf(c, kf.w, ak.w);
        av.x += vf.x; av.y += vf.y; av.z += vf.z; av.w += vf.w;
    }
    *(float4*)&rk[tg * 64 + f4 * 4] = ak;
    *(float4*)&rv[tg * 64 + f4 * 4] = av;
    __syncthreads();

    if (tid < 64) {
        float sk = 0.f, sv = 0.f;
        #pragma unroll
        for (int g = 0; g < 16; ++g) { sk += rk[g * 64 + tid]; sv += rv[g * 64 + tid]; }
        kpart[((size_t)bh * 8 + sl) * 64 + tid] = sk;
        vpart[((size_t)bh * 8 + sl) * 64 + tid] = sv;
    }
}

// ---------------------------------------------------------------------------
// Kernel B2b: reduce 8 slice-partials -> ksum[bh][d], vmean[bh][d].
// ---------------------------------------------------------------------------
__global__ __launch_bounds__(64)
void ksum_vmean_reduce_kernel(const float* __restrict__ kpart, const float* __restrict__ vpart,
                              float* __restrict__ ksum, float* __restrict__ vmean)
{
    const int bh = blockIdx.x, d = threadIdx.x;
    float sk = 0.f, sv = 0.f;
    #pragma unroll
    for (int sl = 0; sl < 8; ++sl) {
        sk += kpart[((size_t)bh * 8 + sl) * 64 + d];
        sv += vpart[((size_t)bh * 8 + sl) * 64 + d];
    }
    ksum[bh * 64 + d]  = sk;
    vmean[bh * 64 + d] = sv * (1.0f / 2048.0f);
}

// ---------------------------------------------------------------------------
// Kernel C0: pack gathered K rows ONCE per bh into f16 hi/lo fragment-order
// tiles [chunk(2)][kq(4)][row(128)][8] (hi 8192 u16, then lo 8192), so the
// scan stages them with linear global_load_lds. Lives in the dead Xp region.
// ---------------------------------------------------------------------------
__global__ __launch_bounds__(256)
void pack_k_kernel(const float* __restrict__ k, const int* __restrict__ klist,
                   const int* __restrict__ ncp, u16* __restrict__ Kp)
{
    alignas(16) __shared__ u16 th[8192];
    alignas(16) __shared__ u16 tl[8192];
    const int wg = blockIdx.x, tid = threadIdx.x;
    const int swz = (wg & 7) * 64 + (wg >> 3);   // XCD-chunked bijection (512%8==0)
    const int bh = swz >> 4, kt = swz & 15;
    const int ntiles = (ncp[0] + 127) >> 7;
    if (kt >= ntiles) return;

    const float4* kb4 = (const float4*)(k + (size_t)bh * T_LEN * HDIM);
    #pragma unroll
    for (int s = 0; s < 8; ++s) {
        int u = tid + 256 * s;            // 0..2047 float4s
        int row = u >> 4, c4 = u & 15;    // row 0..127, c4 0..15 (d-quad)
        int krow = klist[kt * 128 + row];
        float4 f = kb4[krow * 16 + c4];
        uint2 ph, pl;
        cvt4_hilo_h(f, ph, pl);
        int base = (c4 >> 3) * 4096 + ((c4 >> 1) & 3) * 1024 + row * 8 + (c4 & 1) * 4;
        *(uint2*)&th[base] = ph;
        *(uint2*)&tl[base] = pl;
    }
    __syncthreads();

    u16* dst = Kp + ((size_t)bh * 16 + kt) * 16384;
    uint4* d4 = (uint4*)dst;
    const uint4* s4h = (const uint4*)th;
    const uint4* s4l = (const uint4*)tl;
    #pragma unroll
    for (int i = 0; i < 4; ++i) d4[tid + 256 * i] = s4h[tid + 256 * i];
    #pragma unroll
    for (int i = 0; i < 4; ++i) d4[1024 + tid + 256 * i] = s4l[tid + 256 * i];
}

// ---------------------------------------------------------------------------
// Kernel C: sparsity scan from pre-packed K tiles. (passing round-5 version)
// ---------------------------------------------------------------------------
__global__ __launch_bounds__(256)
void sparsity_scan_kernel(const float* __restrict__ q, const u16* __restrict__ Kp,
                          const float* __restrict__ ksum,
                          const int* __restrict__ ncp, float* __restrict__ spars)
{
    alignas(16) __shared__ u16 KH[10240];   // q staging (256*40), then packed K hi (8192)
    alignas(16) __shared__ u16 KL[10240];
    __shared__ float ksm[64];
    __shared__ float smax[128];
    __shared__ float sdotL[128];

    const int tid = threadIdx.x;
    const int wg = blockIdx.x;
    const int swz = (wg & 7) * 64 + (wg >> 3);
    const int bh = swz >> 4;
    const int q0 = (swz & 15) * 128;
    const int w = tid >> 6, lane = tid & 63;
    const int lm = lane & 15, kq = lane >> 4;

    const float* qb = q + ((size_t)bh * T_LEN + q0) * HDIM;
    const int ntiles = (ncp[0] + 127) >> 7;

    if (tid < 64) ksm[tid] = ksum[bh * 64 + tid];

    // Stage q tile (128 rows x 64 d) as f16 hi/lo, chunked [c][row][40].
    #pragma unroll
    for (int s = 0; s < 8; ++s) {
        int u = tid + 256 * s;
        int row = u >> 4, c4 = u & 15;
        float4 f = *(const float4*)&qb[row * HDIM + c4 * 4];
        uint2 ph, pl;
        cvt4_hilo_h(f, ph, pl);
        int base = ((c4 >> 3) * 128 + row) * 40 + (c4 & 7) * 4;
        *(uint2*)&KH[base] = ph;
        *(uint2*)&KL[base] = pl;
    }
    __syncthreads();

    // Hoist A-fragments (32 q rows per wave) to registers.
    f16x8 qh[2][2], ql[2][2];
    #pragma unroll
    for (int i = 0; i < 2; ++i)
        #pragma unroll
        for (int c = 0; c < 2; ++c) {
            int ra = (c * 128 + w * 32 + i * 16 + lm) * 40 + kq * 8;
            qh[i][c] = *(const f16x8*)&KH[ra];
            ql[i][c] = *(const f16x8*)&KL[ra];
        }

    // sdot = q . ksum (hi+lo reconstruction, fp32 accumulate).
    {
        float4 k0a = *(const float4*)&ksm[kq * 8];
        float4 k0b = *(const float4*)&ksm[kq * 8 + 4];
        float4 k1a = *(const float4*)&ksm[32 + kq * 8];
        float4 k1b = *(const float4*)&ksm[32 + kq * 8 + 4];
        float kmv[2][8] = {{k0a.x, k0a.y, k0a.z, k0a.w, k0b.x, k0b.y, k0b.z, k0b.w},
                           {k1a.x, k1a.y, k1a.z, k1a.w, k1b.x, k1b.y, k1b.z, k1b.w}};
        #pragma unroll
        for (int i = 0; i < 2; ++i) {
            float sd = 0.f;
            #pragma unroll
            for (int c = 0; c < 2; ++c)
                #pragma unroll
                for (int e = 0; e < 8; ++e)
                    sd = fmaf((float)qh[i][c][e] + (float)ql[i][c][e], kmv[c][e], sd);
            sd += __shfl_xor(sd, 16, 64);
            sd += __shfl_xor(sd, 32, 64);
            if (kq == 0) sdotL[w * 32 + i * 16 + lm] = sd;
        }
    }

    float vmax[2][4];
    #pragma unroll
    for (int i = 0; i < 2; ++i)
        #pragma unroll
        for (int r = 0; r < 4; ++r) vmax[i][r] = -INFINITY;

    const u16* kpb = Kp + (size_t)bh * (16 * 16384);

    for (int kt = 0; kt < ntiles; ++kt) {
        __syncthreads();   // prior reads of KH/KL done
        const u16* kp = kpb + kt * 16384;
        const u16* gsrc; u16* ldst;
        if (w == 0)      { gsrc = kp;         ldst = KH; }
        else if (w == 1) { gsrc = kp + 4096;  ldst = KH + 4096; }
        else if (w == 2) { gsrc = kp + 8192;  ldst = KL; }
        else             { gsrc = kp + 12288; ldst = KL + 4096; }
        #pragma unroll
        for (int i = 0; i < 8; ++i)    // 8 x 1KB = the wave's full 8KB quarter
            __builtin_amdgcn_global_load_lds(
                (const __attribute__((address_space(1))) void*)(gsrc + (size_t)lane * 8 + i * 512),
                (__attribute__((address_space(3))) void*)(ldst + i * 512),
                16, 0, 0);
        __syncthreads();

        #pragma unroll
        for (int j = 0; j < 8; ++j) {
            int rb0 = kq * 1024 + (j * 16 + lm) * 8;          // chunk 0
            int rb1 = 4096 + kq * 1024 + (j * 16 + lm) * 8;   // chunk 1
            f16x8 bh0 = *(const f16x8*)&KH[rb0];
            f16x8 bl0 = *(const f16x8*)&KL[rb0];
            f16x8 bh1 = *(const f16x8*)&KH[rb1];
            f16x8 bl1 = *(const f16x8*)&KL[rb1];
            f32x4 a0 = {0.f, 0.f, 0.f, 0.f};
            f32x4 a1 = {0.f, 0.f, 0.f, 0.f};
            a0 = __builtin_amdgcn_mfma_f32_16x16x32_f16(qh[0][0], bh0, a0, 0, 0, 0);
            a1 = __builtin_amdgcn_mfma_f32_16x16x32_f16(qh[1][0], bh0, a1, 0, 0, 0);
            a0 = __builtin_amdgcn_mfma_f32_16x16x32_f16(qh[0][0], bl0, a0, 0, 0, 0);
            a1 = __builtin_amdgcn_mfma_f32_16x16x32_f16(qh[1][0], bl0, a1, 0, 0, 0);
            a0 = __builtin_amdgcn_mfma_f32_16x16x32_f16(ql[0][0], bh0, a0, 0, 0, 0);
            a1 = __builtin_amdgcn_mfma_f32_16x16x32_f16(ql[1][0], bh0, a1, 0, 0, 0);
            a0 = __builtin_amdgcn_mfma_f32_16x16x32_f16(qh[0][1], bh1, a0, 0, 0, 0);
            a1 = __builtin_amdgcn_mfma_f32_16x16x32_f16(qh[1][1], bh1, a1, 0, 0, 0);
            a0 = __builtin_amdgcn_mfma_f32_16x16x32_f16(qh[0][1], bl1, a0, 0, 0, 0);
            a1 = __builtin_amdgcn_mfma_f32_16x16x32_f16(qh[1][1], bl1, a1, 0, 0, 0);
            a0 = __builtin_amdgcn_mfma_f32_16x16x32_f16(ql[0][1], bh1, a0, 0, 0, 0);
            a1 = __builtin_amdgcn_mfma_f32_16x16x32_f16(ql[1][1], bh1, a1, 0, 0, 0);
            #pragma unroll
            for (int r = 0; r < 4; ++r) {
                vmax[0][r] = fmaxf(vmax[0][r], a0[r]);
                vmax[1][r] = fmaxf(vmax[1][r], a1[r]);
            }
        }
    }

    #pragma unroll
    for (int i = 0; i < 2; ++i)
        #pragma unroll
        for (int r = 0; r < 4; ++r) {
            float m = vmax[i][r];
            m = fmaxf(m, __shfl_xor(m, 1, 64));
            m = fmaxf(m, __shfl_xor(m, 2, 64));
            m = fmaxf(m, __shfl_xor(m, 4, 64));
            m = fmaxf(m, __shfl_xor(m, 8, 64));
            if (lm == 0) smax[w * 32 + i * 16 + kq * 4 + r] = m;
        }
    __syncthreads();

    if (tid < 128)
        spars[bh * T_LEN + q0 + tid] = smax[tid] - sdotL[tid] * (1.0f / 2048.0f);
}

// ---------------------------------------------------------------------------
// Kernel C-fallback: round-2 scan (gather+cvt per tile), used when ws too
// small for the pack buffers.
// ---------------------------------------------------------------------------
__global__ __launch_bounds__(256)
void sparsity_scan_fb_kernel(const float* __restrict__ q, const float* __restrict__ k,
                             const float* __restrict__ ksum, const int* __restrict__ klist,
                             const int* __restrict__ ncp, float* __restrict__ spars)
{
    alignas(16) __shared__ u16 KH[256 * 40];
    alignas(16) __shared__ u16 KL[256 * 40];
    __shared__ float ksm[64];
    __shared__ float smax[128];
    __shared__ float sdotL[128];

    const int tid = threadIdx.x;
    const int bh = blockIdx.y;
    const int q0 = blockIdx.x * 128;
    const int w = tid >> 6, lane = tid & 63;
    const int lm = lane & 15, kq = lane >> 4;

    const float* qb = q + ((size_t)bh * T_LEN + q0) * HDIM;
    const float4* kb4 = (const float4*)(k + (size_t)bh * T_LEN * HDIM);
    const int ntiles = (ncp[0] + 127) >> 7;

    if (tid < 64) ksm[tid] = ksum[bh * 64 + tid];

    #pragma unroll
    for (int s = 0; s < 8; ++s) {
        int u = tid + 256 * s;
        int row = u >> 4, c4 = u & 15;
        float4 f = *(const float4*)&qb[row * HDIM + c4 * 4];
        uint2 ph, pl;
        cvt4_hilo_h(f, ph, pl);
        int base = ((c4 >> 3) * 128 + row) * 40 + (c4 & 7) * 4;
        *(uint2*)&KH[base] = ph;
        *(uint2*)&KL[base] = pl;
    }
    __syncthreads();

    f16x8 qh[2][2], ql[2][2];
    #pragma unroll
    for (int i = 0; i < 2; ++i)
        #pragma unroll
        for (int c = 0; c < 2; ++c) {
            int ra = (c * 128 + w * 32 + i * 16 + lm) * 40 + kq * 8;
            qh[i][c] = *(const f16x8*)&KH[ra];
            ql[i][c] = *(const f16x8*)&KL[ra];
        }

    {
        float4 k0a = *(const float4*)&ksm[kq * 8];
        float4 k0b = *(const float4*)&ksm[kq * 8 + 4];
        float4 k1a = *(const float4*)&ksm[32 + kq * 8];
        float4 k1b = *(const float4*)&ksm[32 + kq * 8 + 4];
        float kmv[2][8] = {{k0a.x, k0a.y, k0a.z, k0a.w, k0b.x, k0b.y, k0b.z, k0b.w},
                           {k1a.x, k1a.y, k1a.z, k1a.w, k1b.x, k1b.y, k1b.z, k1b.w}};
        #pragma unroll
        for (int i = 0; i < 2; ++i) {
            float sd = 0.f;
            #pragma unroll
            for (int c = 0; c < 2; ++c)
                #pragma unroll
                for (int e = 0; e < 8; ++e)
                    sd = fmaf((float)qh[i][c][e] + (float)ql[i][c][e], kmv[c][e], sd);
            sd += __shfl_xor(sd, 16, 64);
            sd += __shfl_xor(sd, 32, 64);
            if (kq == 0) sdotL[w * 32 + i * 16 + lm] = sd;
        }
    }

    float vmax[2][4];
    #pragma unroll
    for (int i = 0; i < 2; ++i)
        #pragma unroll
        for (int r = 0; r < 4; ++r) vmax[i][r] = -INFINITY;

    for (int kt = 0; kt < ntiles; ++kt) {
        __syncthreads();
        #pragma unroll
        for (int s = 0; s < 8; ++s) {
            int u = tid + 256 * s;
            int row = u >> 4, c4 = u & 15;
            int krow = klist[kt * 128 + row];
            float4 f = kb4[krow * 16 + c4];
            uint2 ph, pl;
            cvt4_hilo_h(f, ph, pl);
            int base = ((c4 >> 3) * 128 + row) * 40 + (c4 & 7) * 4;
            *(uint2*)&KH[base] = ph;
            *(uint2*)&KL[base] = pl;
        }
        __syncthreads();

        #pragma unroll
        for (int j = 0; j < 8; ++j) {
            int rb0 = (j * 16 + lm) * 40 + kq * 8;
            int rb1 = (128 + j * 16 + lm) * 40 + kq * 8;
            f16x8 bh0 = *(const f16x8*)&KH[rb0];
            f16x8 bl0 = *(const f16x8*)&KL[rb0];
            f16x8 bh1 = *(const f16x8*)&KH[rb1];
            f16x8 bl1 = *(const f16x8*)&KL[rb1];
            f32x4 a0 = {0.f, 0.f, 0.f, 0.f};
            f32x4 a1 = {0.f, 0.f, 0.f, 0.f};
            a0 = __builtin_amdgcn_mfma_f32_16x16x32_f16(qh[0][0], bh0, a0, 0, 0, 0);
            a1 = __builtin_amdgcn_mfma_f32_16x16x32_f16(qh[1][0], bh0, a1, 0, 0, 0);
            a0 = __builtin_amdgcn_mfma_f32_16x16x32_f16(qh[0][0], bl0, a0, 0, 0, 0);
            a1 = __builtin_amdgcn_mfma_f32_16x16x32_f16(qh[1][0], bl0, a1, 0, 0, 0);
            a0 = __builtin_amdgcn_mfma_f32_16x16x32_f16(ql[0][0], bh0, a0, 0, 0, 0);
            a1 = __builtin_amdgcn_mfma_f32_16x16x32_f16(ql[1][0], bh0, a1, 0, 0, 0);
            a0 = __builtin_amdgcn_mfma_f32_16x16x32_f16(qh[0][1], bh1, a0, 0, 0, 0);
            a1 = __builtin_amdgcn_mfma_f32_16x16x32_f16(qh[1][1], bh1, a1, 0, 0, 0);
            a0 = __builtin_amdgcn_mfma_f32_16x16x32_f16(qh[0][1], bl1, a0, 0, 0, 0);
            a1 = __builtin_amdgcn_mfma_f32_16x16x32_f16(qh[1][1], bl1, a1, 0, 0, 0);
            a0 = __builtin_amdgcn_mfma_f32_16x16x32_f16(ql[0][1], bh1, a0, 0, 0, 0);
            a1 = __builtin_amdgcn_mfma_f32_16x16x32_f16(ql[1][1], bh1, a1, 0, 0, 0);
            #pragma unroll
            for (int r = 0; r < 4; ++r) {
                vmax[0][r] = fmaxf(vmax[0][r], a0[r]);
                vmax[1][r] = fmaxf(vmax[1][r], a1[r]);
            }
        }
    }

    #pragma unroll
    for (int i = 0; i < 2; ++i)
        #pragma unroll
        for (int r = 0; r < 4; ++r) {
            float m = vmax[i][r];
            m = fmaxf(m, __shfl_xor(m, 1, 64));
            m = fmaxf(m, __shfl_xor(m, 2, 64));
            m = fmaxf(m, __shfl_xor(m, 4, 64));
            m = fmaxf(m, __shfl_xor(m, 8, 64));
            if (lm == 0) smax[w * 32 + i * 16 + kq * 4 + r] = m;
        }
    __syncthreads();

    if (tid < 128)
        spars[bh * T_LEN + q0 + tid] = smax[tid] - sdotL[tid] * (1.0f / 2048.0f);
}

// ---------------------------------------------------------------------------
// Kernel D: exact top-40 per bh via 4-level radix select on order-preserving
// u32 keys (f>=0 -> u|0x80000000, f<0 -> ~u). Replaces 40-iteration argmax
// (46.9 us, 0.45% VALUBusy, ~360 barriers of latency). Output SET identical
// (ties at the rank-40 boundary -> smallest indices, = lax.top_k), and all
// downstream uses of topi are u-slot-consistent, so the final output is
// bitwise unchanged under any slot permutation.
// ---------------------------------------------------------------------------
__global__ __launch_bounds__(256)
void topk_kernel(const float* __restrict__ spars, int* __restrict__ topi)
{
    __shared__ unsigned keys[T_LEN];   // 8 KB
    __shared__ int hist[256];
    __shared__ int sfx[257];
    __shared__ int sh_need, sh_bin, nsel, neq, cnt2;
    const int bh = blockIdx.x, tid = threadIdx.x;

    #pragma unroll
    for (int s = 0; s < 8; ++s) {
        int j = tid + 256 * s;
        unsigned u = __float_as_uint(spars[bh * T_LEN + j]);
        keys[j] = (u & 0x80000000u) ? ~u : (u | 0x80000000u);
    }
    if (tid == 0) { sh_need = USEL; nsel = 0; neq = 0; cnt2 = 0; }
    __syncthreads();

    unsigned kpref = 0;
    int shift = 24;
    #pragma unroll
    for (int level = 0; level < 4; ++level) {
        const unsigned hi_mask = (shift == 24) ? 0u : (0xFFFFFFFFu << (shift + 8));
        hist[tid] = 0;
        __syncthreads();
        #pragma unroll
        for (int s = 0; s < 8; ++s) {
            unsigned kk = keys[tid + 256 * s];
            if ((kk & hi_mask) == kpref)
                atomicAdd(&hist[(kk >> shift) & 255], 1);
        }
        __syncthreads();
        // suffix sums: sfx[i] = sum of hist[i..255]; sfx[256] = 0.
        sfx[tid] = hist[tid];
        if (tid == 0) sfx[256] = 0;
        __syncthreads();
        for (int off = 1; off < 256; off <<= 1) {
            int v = (tid + off < 256) ? sfx[tid + off] : 0;
            __syncthreads();
            sfx[tid] += v;
            __syncthreads();
        }
        const int need = sh_need;
        const int A = (tid == 255) ? 0 : sfx[tid + 1];   // count strictly above bin tid
        const int here = sfx[tid];
        __syncthreads();
        if (A < need && here >= need) {   // exactly one bin satisfies
            sh_bin = tid;
            sh_need = need - A;
        }
        __syncthreads();
        kpref |= (unsigned)sh_bin << shift;
        shift -= 8;
    }

    const unsigned K = kpref;
    const int need_eq = sh_need;

    // Collect strictly-greater keys (count = USEL - need_eq by construction)
    // and count equals in the same pass.
    #pragma unroll
    for (int s = 0; s < 8; ++s) {
        int j = tid + 256 * s;
        unsigned kk = keys[j];
        if (kk > K) {
            int pos = atomicAdd(&nsel, 1);
            if (pos < USEL) topi[bh * USEL + pos] = j;
        } else if (kk == K) {
            atomicAdd(&neq, 1);
        }
    }
    __syncthreads();
    const int base = nsel;
    const int E = neq;
    __syncthreads();

    if (E == need_eq) {
        // Fast path (no exact-duplicate tie at the boundary): take all equals.
        #pragma unroll
        for (int s = 0; s < 8; ++s) {
            int j = tid + 256 * s;
            if (keys[j] == K) {
                int pos = atomicAdd(&cnt2, 1);
                if (base + pos < USEL) topi[bh * USEL + base + pos] = j;
            }
        }
    } else {
        // Rare tie path: among equals, take the need_eq smallest indices.
        #pragma unroll
        for (int s = 0; s < 8; ++s) {
            int j = tid + 256 * s;
            if (keys[j] == K) {
                int rank = 0;
                for (int j2 = 0; j2 < j; ++j2) rank += (keys[j2] == K);
                if (rank < need_eq && base + rank < USEL)
                    topi[bh * USEL + base + rank] = j;
            }
        }
    }
}

// ---------------------------------------------------------------------------
// Kernel E1: gather selected q rows -> qsel[bh][u][d]. (q dead afterwards)
// ---------------------------------------------------------------------------
__global__ __launch_bounds__(256)
void gather_q_kernel(const float* __restrict__ q, const int* __restrict__ topi,
                     float* __restrict__ qsel)
{
    const int bh = blockIdx.x, tid = threadIdx.x;
    for (int i = tid; i < USEL * HDIM; i += 256) {
        int u = i >> 6, d = i & 63;
        int t = topi[bh * USEL + u] & (T_LEN - 1);
        qsel[(size_t)bh * USEL * HDIM + i] = q[((size_t)bh * T_LEN + t) * HDIM + d];
    }
}

// ---------------------------------------------------------------------------
// Kernel E2: S[bh][u][t] = qsel[bh][u] . k[bh][t]. Grid (8 t-slices, 32 bh).
// ---------------------------------------------------------------------------
__global__ __launch_bounds__(256)
void sel_scores_kernel(const float* __restrict__ qsel, const float* __restrict__ k,
                       float* __restrict__ S)
{
    __shared__ float qsT[64 * 41];    // [d][u] stride 41
    __shared__ float ksT[64 * 257];   // [d][t] stride 257

    const int sl = blockIdx.x, bh = blockIdx.y, tid = threadIdx.x;
    const int t0 = sl * 256;

    for (int i = tid; i < USEL * HDIM; i += 256) {
        int u = i >> 6, d = i & 63;
        qsT[d * 41 + u] = qsel[(size_t)bh * USEL * HDIM + i];
    }
    const float4* k4 = (const float4*)(k + (size_t)bh * T_LEN * HDIM);
    #pragma unroll
    for (int s = 0; s < 16; ++s) {
        int u = tid + 256 * s;
        int c4 = u & 15, t = u >> 4;
        float4 f = k4[(t0 + t) * 16 + c4];
        ksT[(c4 * 4 + 0) * 257 + t] = f.x;
        ksT[(c4 * 4 + 1) * 257 + t] = f.y;
        ksT[(c4 * 4 + 2) * 257 + t] = f.z;
        ksT[(c4 * 4 + 3) * 257 + t] = f.w;
    }
    __syncthreads();

    const int qg = tid >> 5;
    const int kg = tid & 31;

    float acc[5][8];
    #pragma unroll
    for (int i = 0; i < 5; ++i)
        #pragma unroll
        for (int j = 0; j < 8; ++j) acc[i][j] = 0.0f;

    #pragma unroll 4
    for (int d = 0; d < 64; ++d) {
        float qv[5], kv[8];
        #pragma unroll
        for (int i = 0; i < 5; ++i) qv[i] = qsT[d * 41 + qg * 5 + i];
        #pragma unroll
        for (int j = 0; j < 8; ++j) kv[j] = ksT[d * 257 + kg + 32 * j];
        #pragma unroll
        for (int i = 0; i < 5; ++i)
            #pragma unroll
            for (int j = 0; j < 8; ++j)
                acc[i][j] = fmaf(qv[i], kv[j], acc[i][j]);
    }

    #pragma unroll
    for (int i = 0; i < 5; ++i) {
        float* sp = &S[((size_t)bh * USEL + qg * 5 + i) * T_LEN + t0 + kg];
        #pragma unroll
        for (int j = 0; j < 8; ++j) sp[32 * j] = acc[i][j];
    }
}

// ---------------------------------------------------------------------------
// Kernel E3: in-place softmax over each S row (1280 rows of 2048).
// ---------------------------------------------------------------------------
__global__ __launch_bounds__(256)
void sel_softmax_kernel(float* __restrict__ S)
{
    __shared__ float red[256];
    const int row = blockIdx.x, tid = threadIdx.x;
    float* sr = S + (size_t)row * T_LEN;

    float x[8];
    float m = -INFINITY;
    #pragma unroll
    for (int s = 0; s < 8; ++s) { x[s] = sr[tid + 256 * s]; m = fmaxf(m, x[s]); }
    red[tid] = m;
    __syncthreads();
    for (int s = 128; s > 0; s >>= 1) {
        if (tid < s) red[tid] = fmaxf(red[tid], red[tid + s]);
        __syncthreads();
    }
    m = red[0];
    __syncthreads();

    float sum = 0.f;
    #pragma unroll
    for (int s = 0; s < 8; ++s) { x[s] = __expf(x[s] - m); sum += x[s]; }
    red[tid] = sum;
    __syncthreads();
    for (int s = 128; s > 0; s >>= 1) {
        if (tid < s) red[tid] += red[tid + s];
        __syncthreads();
    }
    float inv = 1.0f / red[0];
    #pragma unroll
    for (int s = 0; s < 8; ++s) sr[tid + 256 * s] = x[s] * inv;
}

// ---------------------------------------------------------------------------
// Kernel E4: PV partial. Grid (16 t-slices, 32 bh).
// ---------------------------------------------------------------------------
__global__ __launch_bounds__(256)
void pv_part_kernel(const float* __restrict__ S, const float* __restrict__ v,
                    float* __restrict__ part)
{
    __shared__ float ps[USEL * 128];      // [q][t]
    __shared__ float vs[128 * 69];        // [t][d] stride 69
    __shared__ float obuf[128 * 20];

    const int sl = blockIdx.x, bh = blockIdx.y, tid = threadIdx.x;
    const int t0 = sl * 128;

    for (int i = tid; i < USEL * 128; i += 256) {
        int q = i >> 7, t = i & 127;
        ps[q * 128 + t] = S[((size_t)bh * USEL + q) * T_LEN + t0 + t];
    }
    const float4* v4 = (const float4*)(v + (size_t)bh * T_LEN * HDIM);
    #pragma unroll
    for (int s = 0; s < 8; ++s) {
        int u = tid + 256 * s;
        int c4 = u & 15, t = u >> 4;
        float4 f = v4[(t0 + t) * 16 + c4];
        vs[t * 69 + c4 * 4 + 0] = f.x;
        vs[t * 69 + c4 * 4 + 1] = f.y;
        vs[t * 69 + c4 * 4 + 2] = f.z;
        vs[t * 69 + c4 * 4 + 3] = f.w;
    }
    __syncthreads();

    const int qg = tid >> 5, r = tid & 31;
    const int dg = r >> 1, th = r & 1;
    const int tb = th * 64;

    float o[5][4];
    #pragma unroll
    for (int i = 0; i < 5; ++i)
        #pragma unroll
        for (int j = 0; j < 4; ++j) o[i][j] = 0.0f;

    #pragma unroll 4
    for (int tt = 0; tt < 64; ++tt) {
        int t = tb + tt;
        float pv[5];
        #pragma unroll
        for (int i = 0; i < 5; ++i) pv[i] = ps[(qg * 5 + i) * 128 + t];
        float4 vv = *(const float4*)&vs[t * 69 + dg * 4];
        #pragma unroll
        for (int i = 0; i < 5; ++i) {
            o[i][0] = fmaf(pv[i], vv.x, o[i][0]);
            o[i][1] = fmaf(pv[i], vv.y, o[i][1]);
            o[i][2] = fmaf(pv[i], vv.z, o[i][2]);
            o[i][3] = fmaf(pv[i], vv.w, o[i][3]);
        }
    }

    const int p = qg * 16 + dg;
    if (th == 1) {
        #pragma unroll
        for (int i = 0; i < 5; ++i)
            #pragma unroll
            for (int j = 0; j < 4; ++j) obuf[p * 20 + i * 4 + j] = o[i][j];
    }
    __syncthreads();
    if (th == 0) {
        float* pb = part + ((size_t)bh * 16 + sl) * (USEL * HDIM);
        #pragma unroll
        for (int i = 0; i < 5; ++i)
            #pragma unroll
            for (int j = 0; j < 4; ++j)
                pb[(qg * 5 + i) * HDIM + dg * 4 + j] = o[i][j] + obuf[p * 20 + i * 4 + j];
    }
}

// ---------------------------------------------------------------------------
// Kernel E5: deterministic merge of 16 PV partials -> attn[bh][u][d].
// ---------------------------------------------------------------------------
__global__ __launch_bounds__(256)
void pv_merge_kernel(const float* __restrict__ part, float* __restrict__ attn)
{
    const int bh = blockIdx.x, tid = threadIdx.x;
    for (int i = tid; i < USEL * HDIM; i += 256) {
        float s = 0.f;
        #pragma unroll
        for (int sl = 0; sl < 16; ++sl)
            s += part[((size_t)bh * 16 + sl) * (USEL * HDIM) + i];
        attn[(size_t)bh * USEL * HDIM + i] = s;
    }
}

// ---------------------------------------------------------------------------
// Kernel F1: fill context (B,T,E layout, fp32) with per-head vmean.
// ---------------------------------------------------------------------------
__global__ __launch_bounds__(256)
void ctx_fill_kernel(const float* __restrict__ vmean, float* __restrict__ ctx)
{
    int flat = blockIdx.x * 256 + threadIdx.x;
    int d = flat & 63, h = (flat >> 6) & 7, b = flat >> 20;
    int bh = (b << 3) | h;
    ctx[flat] = vmean[bh * 64 + d];
}

// ---------------------------------------------------------------------------
// Kernel F2: scatter attn rows into context at top_idx positions.
// ---------------------------------------------------------------------------
__global__ void ctx_scatter_kernel(const float* __restrict__ attn, const int* __restrict__ topi,
                                   float* __restrict__ ctx)
{
    const int u = blockIdx.x, bh = blockIdx.y, d = threadIdx.x;
    const int b = bh >> 3, h = bh & 7;
    const int t = topi[bh * USEL + u] & (T_LEN - 1);
    ctx[(size_t)(b * T_LEN + t) * EMB + h * 64 + d] =
        attn[((size_t)bh * USEL + u) * HDIM + d];
}

// ---------------------------------------------------------------------------
// Kernel G: out = ctx @ Wo^T + bo via bf16 hi+lo 3-pass MFMA (16x16x32).
// ---------------------------------------------------------------------------
__global__ __launch_bounds__(256)
void out_proj_kernel(const float* __restrict__ A, const float* __restrict__ Wo,
                     const float* __restrict__ bo, float* __restrict__ out)
{
    alignas(16) __shared__ u16 Ah[128 * 40];
    alignas(16) __shared__ u16 Al[128 * 40];
    alignas(16) __shared__ u16 Bh[128 * 40];
    alignas(16) __shared__ u16 Bl[128 * 40];

    const int tid = threadIdx.x;
    const int m0 = blockIdx.x * 128;
    const int n0 = blockIdx.y * 128;
    const int w = tid >> 6, lane = tid & 63;
    const int wm = w & 1, wn = w >> 1;
    const int lm = lane & 15, kq = lane >> 4;

    f32x4 acc[4][4];
    #pragma unroll
    for (int i = 0; i < 4; ++i)
        #pragma unroll
        for (int j = 0; j < 4; ++j)
            #pragma unroll
            for (int r = 0; r < 4; ++r) acc[i][j][r] = 0.0f;

    for (int kc = 0; kc < EMB; kc += 32) {
        __syncthreads();
        #pragma unroll
        for (int s = 0; s < 4; ++s) {
            int u = tid + 256 * s;
            int row = u >> 3, c4 = u & 7;
            float4 fa = *(const float4*)&A[(size_t)(m0 + row) * EMB + kc + c4 * 4];
            float4 fb = *(const float4*)&Wo[(n0 + row) * EMB + kc + c4 * 4];
            uint2 ph, pl;
            cvt4_hilo(fa, ph, pl);
            *(uint2*)&Ah[row * 40 + c4 * 4] = ph;
            *(uint2*)&Al[row * 40 + c4 * 4] = pl;
            cvt4_hilo(fb, ph, pl);
            *(uint2*)&Bh[row * 40 + c4 * 4] = ph;
            *(uint2*)&Bl[row * 40 + c4 * 4] = pl;
        }
        __syncthreads();

        bf16v8 ah[4], al[4], bh[4], bl[4];
        #pragma unroll
        for (int i = 0; i < 4; ++i) {
            int ra = (wm * 64 + i * 16 + lm) * 40 + kq * 8;
            ah[i] = *(const bf16v8*)&Ah[ra];
            al[i] = *(const bf16v8*)&Al[ra];
            int rb = (wn * 64 + i * 16 + lm) * 40 + kq * 8;
            bh[i] = *(const bf16v8*)&Bh[rb];
            bl[i] = *(const bf16v8*)&Bl[rb];
        }
        #pragma unroll
        for (int i = 0; i < 4; ++i)
            #pragma unroll
            for (int j = 0; j < 4; ++j) {
                acc[i][j] = __builtin_amdgcn_mfma_f32_16x16x32_bf16(ah[i], bh[j], acc[i][j], 0, 0, 0);
                acc[i][j] = __builtin_amdgcn_mfma_f32_16x16x32_bf16(ah[i], bl[j], acc[i][j], 0, 0, 0);
                acc[i][j] = __builtin_amdgcn_mfma_f32_16x16x32_bf16(al[i], bh[j], acc[i][j], 0, 0, 0);
            }
    }

    #pragma unroll
    for (int j = 0; j < 4; ++j) {
        int ng = n0 + wn * 64 + j * 16 + lm;
        float bias = bo[ng];
        #pragma unroll
        for (int i = 0; i < 4; ++i)
            #pragma unroll
            for (int r = 0; r < 4; ++r) {
                int mg = m0 + wm * 64 + i * 16 + kq * 4 + r;
                out[(size_t)mg * EMB + ng] = acc[i][j][r] + bias;
            }
    }
}

// ---------------------------------------------------------------------------
// Diagnostic: if ws_size is too small, report it via d_out (absmax ~= MiB).
// ---------------------------------------------------------------------------
__global__ __launch_bounds__(256)
void ws_diag_kernel(float* __restrict__ out, int n, float mib)
{
    int flat = blockIdx.x * 256 + threadIdx.x;
    if (flat < n) out[flat] = mib;
}

// ---------------------------------------------------------------------------
extern "C" void kernel_launch(void* const* d_in, const int* in_sizes, int n_in,
                              void* d_out, int out_size, void* d_ws, size_t ws_size,
                              hipStream_t stream)
{
    const float* X = nullptr; const int* idxs = nullptr;
    const float* Wseen[4] = {nullptr, nullptr, nullptr, nullptr};
    const float* bseen[4] = {nullptr, nullptr, nullptr, nullptr};
    int nw = 0, nb = 0, u_part = 2048;
    for (int i = 0; i < n_in; ++i) {
        int sz = in_sizes[i];
        if (sz == EMB * EMB * 16) { if (!X) X = (const float*)d_in[i]; }
        else if (sz == T_LEN)     { if (!idxs) { idxs = (const int*)d_in[i]; u_part = sz; } }
        else if (sz == EMB * EMB) { if (nw < 4) Wseen[nw++] = (const float*)d_in[i]; }
        else if (sz == EMB)       { if (nb < 4) bseen[nb++] = (const float*)d_in[i]; }
    }
    if (!X || !idxs || nw < 4 || nb < 4) {
        X = (const float*)d_in[0]; idxs = (const int*)d_in[1];
        Wseen[0] = (const float*)d_in[2]; bseen[0] = (const float*)d_in[3];
        Wseen[1] = (const float*)d_in[4]; bseen[1] = (const float*)d_in[5];
        Wseen[2] = (const float*)d_in[6]; bseen[2] = (const float*)d_in[7];
        Wseen[3] = (const float*)d_in[8]; bseen[3] = (const float*)d_in[9];
        u_part = in_sizes[1];
    }
    const float *Wq = Wseen[0], *Wk = Wseen[1], *Wv = Wseen[2], *Wo = Wseen[3];
    const float *bq = bseen[0], *bk = bseen[1], *bv = bseen[2], *bo = bseen[3];

    // Base workspace layout (peak 50,951,168 B, unchanged). Pack buffers for
    // the fast paths live beyond it: Xp 16 MB (reused as packed K) + Wp 3 MB.
    const size_t NEED      = 50951168ULL;
    const size_t NEED_BIG  = NEED + 16777216ULL + 3145728ULL;   // 70,874,112
    if (ws_size < NEED) {
        ws_diag_kernel<<<(out_size + 255) / 256, 256, 0, stream>>>(
            (float*)d_out, out_size, (float)(ws_size >> 20));
        return;
    }

    float* ws    = (float*)d_ws;
    float* qw    = ws;                    // 4,194,304 floats
    float* kw    = qw + 4194304;
    float* vw    = kw + 4194304;
    float* tail  = vw + 4194304;
    float* slotA = tail;                  // 81920: qsel, later attn
    float* spars = tail + 81920;          // 65536
    int*   count = (int*)(tail + 147456); // 2048
    float* ksum  = tail + 149504;         // 2048
    float* vmean = tail + 151552;         // 2048
    int*   topi  = (int*)(tail + 153600); // 1280
    float* kpart = tail;                  // overlays in slotA (disjoint liveness)
    float* vpart = tail + 16384;
    int*   klist = (int*)(tail + 32768);
    int*   ncp   = (int*)(tail + 34816);
    float* S     = qw;                    // q dead after gather
    float* pvp   = qw + 2621440;
    float* qsel  = slotA;
    float* attn  = slotA;
    float* ctx   = (float*)d_ws;
    u16*   Xp    = (u16*)((char*)d_ws + NEED);   // 8,388,608 u16 (16 MB)
    u16*   Wp    = Xp + 8388608;                 // 1,572,864 u16 (3 MB)
    u16*   Kp    = Xp;                           // packed K overlays Xp (dead after qkv)

    const bool big = (ws_size >= NEED_BIG);

    if (big) {
        pack_hilo_kernel<<<1216, 256, 0, stream>>>(X, Wq, Wk, Wv, Xp, Wp);
        qkv_mfma_kernel<<<dim3(64, 4, 3), 256, 0, stream>>>(Xp, Wp, bq, bk, bv, qw, kw, vw);
    } else {
        qkv_proj_kernel<<<dim3(64, 4, 3), 256, 0, stream>>>(X, Wq, bq, Wk, bk, Wv, bv, qw, kw, vw);
    }
    count_compact_kernel<<<1, 256, 0, stream>>>(idxs, u_part, count, klist, ncp);
    ksum_vmean_part_kernel<<<dim3(8, 32), 256, 0, stream>>>(count, kw, vw, kpart, vpart);
    ksum_vmean_reduce_kernel<<<32, 64, 0, stream>>>(kpart, vpart, ksum, vmean);
    if (big) {
        pack_k_kernel<<<512, 256, 0, stream>>>(kw, klist, ncp, Kp);
        sparsity_scan_kernel<<<512, 256, 0, stream>>>(qw, Kp, ksum, ncp, spars);
    } else {
        sparsity_scan_fb_kernel<<<dim3(16, 32), 256, 0, stream>>>(qw, kw, ksum, klist, ncp, spars);
    }
    topk_kernel<<<32, 256, 0, stream>>>(spars, topi);
    gather_q_kernel<<<32, 256, 0, stream>>>(qw, topi, qsel);
    // qw dead; S/pvp take over that region.
    sel_scores_kernel<<<dim3(8, 32), 256, 0, stream>>>(qsel, kw, S);
    sel_softmax_kernel<<<1280, 256, 0, stream>>>(S);
    pv_part_kernel<<<dim3(16, 32), 256, 0, stream>>>(S, vw, pvp);
    pv_merge_kernel<<<32, 256, 0, stream>>>(pvp, attn);
    // S/pvp dead; ctx takes over the whole front region.
    ctx_fill_kernel<<<16384, 256, 0, stream>>>(vmean, ctx);
    ctx_scatter_kernel<<<dim3(USEL, BHEADS), 64, 0, stream>>>(attn, topi, ctx);
    out_proj_kernel<<<dim3(64, 4), 256, 0, stream>>>(ctx, Wo, bo, (float*)d_out);
}

// Round 7
// 277.006 us; speedup vs baseline: 1.9130x; 1.0107x over previous
//
#include <hip/hip_runtime.h>
#include <hip/hip_bf16.h>
#include <math.h>

#define T_LEN 2048
#define EMB   512
#define NHEAD 8
#define HDIM  64
#define BHEADS 32
#define USEL  40

typedef __bf16 bf16v8 __attribute__((ext_vector_type(8)));
typedef _Float16 f16x8 __attribute__((ext_vector_type(8)));
typedef float f32x4 __attribute__((ext_vector_type(4)));
typedef unsigned short u16;

// Split a float4 into bf16 hi + lo halves, packed as uint2 (4 x u16 each).
__device__ __forceinline__ void cvt4_hilo(const float4 f, uint2& ph, uint2& pl)
{
    __hip_bfloat16 h0 = __float2bfloat16(f.x);
    __hip_bfloat16 h1 = __float2bfloat16(f.y);
    __hip_bfloat16 h2 = __float2bfloat16(f.z);
    __hip_bfloat16 h3 = __float2bfloat16(f.w);
    __hip_bfloat16 l0 = __float2bfloat16(f.x - __bfloat162float(h0));
    __hip_bfloat16 l1 = __float2bfloat16(f.y - __bfloat162float(h1));
    __hip_bfloat16 l2 = __float2bfloat16(f.z - __bfloat162float(h2));
    __hip_bfloat16 l3 = __float2bfloat16(f.w - __bfloat162float(h3));
    ph.x = (unsigned)*(const u16*)&h0 | ((unsigned)*(const u16*)&h1 << 16);
    ph.y = (unsigned)*(const u16*)&h2 | ((unsigned)*(const u16*)&h3 << 16);
    pl.x = (unsigned)*(const u16*)&l0 | ((unsigned)*(const u16*)&l1 << 16);
    pl.y = (unsigned)*(const u16*)&l2 | ((unsigned)*(const u16*)&l3 << 16);
}

// Split a float4 into FP16 hi + lo halves, packed as uint2 (4 x u16 each).
// fp16 has 11-bit mantissa: h+l captures ~22 bits, residual <= 2^-22*|x|.
// Dropped Al*Bl term in the 3-pass GEMM is <= 2^-22*|ab| -> the f16 hi/lo
// 3-pass GEMM is fp32-rounding-equivalent (~1e-6), unlike bf16 hi/lo (~2^-16).
__device__ __forceinline__ void cvt4_hilo_h(const float4 f, uint2& ph, uint2& pl)
{
    _Float16 h0 = (_Float16)f.x;
    _Float16 h1 = (_Float16)f.y;
    _Float16 h2 = (_Float16)f.z;
    _Float16 h3 = (_Float16)f.w;
    _Float16 l0 = (_Float16)(f.x - (float)h0);
    _Float16 l1 = (_Float16)(f.y - (float)h1);
    _Float16 l2 = (_Float16)(f.z - (float)h2);
    _Float16 l3 = (_Float16)(f.w - (float)h3);
    ph.x = (unsigned)*(const u16*)&h0 | ((unsigned)*(const u16*)&h1 << 16);
    ph.y = (unsigned)*(const u16*)&h2 | ((unsigned)*(const u16*)&h3 << 16);
    pl.x = (unsigned)*(const u16*)&l0 | ((unsigned)*(const u16*)&l1 << 16);
    pl.y = (unsigned)*(const u16*)&l2 | ((unsigned)*(const u16*)&l3 << 16);
}

// ---------------------------------------------------------------------------
// Kernel A0: pack X and Wq/Wk/Wv into f16 hi/lo tiles, pre-blocked in MFMA
// fragment order so the GEMM stages them with linear global_load_lds.
// ---------------------------------------------------------------------------
__global__ __launch_bounds__(256)
void pack_hilo_kernel(const float* __restrict__ X,
                      const float* __restrict__ Wq, const float* __restrict__ Wk,
                      const float* __restrict__ Wv,
                      u16* __restrict__ Xp, u16* __restrict__ Wp)
{
    alignas(16) __shared__ u16 th[4096];
    alignas(16) __shared__ u16 tl[4096];
    const int b = blockIdx.x, tid = threadIdx.x;

    const float* src; u16* dst;
    if (b < 1024) {                       // X tile: mt = b>>4, kt = b&15
        int mt = b >> 4, kt = b & 15;
        src = X + (size_t)(mt * 128) * EMB + kt * 32;
        dst = Xp + (size_t)b * 8192;
    } else {                              // W tile
        int wdx = b - 1024;               // wdx = (z*4 + nt)*16 + kt
        int z = wdx >> 6, nt = (wdx >> 4) & 3, kt = wdx & 15;
        const float* W = (z == 0) ? Wq : (z == 1) ? Wk : Wv;
        src = W + (size_t)(nt * 128) * EMB + kt * 32;
        dst = Wp + (size_t)wdx * 8192;
    }

    #pragma unroll
    for (int s = 0; s < 4; ++s) {
        int u = tid + 256 * s;            // 0..1023 float4s
        int row = u >> 3, c4 = u & 7;     // 128 rows x 8 float4
        float4 f = *(const float4*)&src[(size_t)row * EMB + c4 * 4];
        uint2 ph, pl;
        cvt4_hilo_h(f, ph, pl);
        int kq = c4 >> 1, e4 = (c4 & 1) * 4;
        *(uint2*)&th[kq * 1024 + row * 8 + e4] = ph;
        *(uint2*)&tl[kq * 1024 + row * 8 + e4] = pl;
    }
    __syncthreads();

    uint4* d4 = (uint4*)dst;
    const uint4* s4h = (const uint4*)th;
    const uint4* s4l = (const uint4*)tl;
    d4[tid]       = s4h[tid];
    d4[tid + 256] = s4h[tid + 256];
    d4[tid + 512] = s4l[tid];
    d4[tid + 768] = s4l[tid + 256];
}

// ---------------------------------------------------------------------------
// Kernel A1: QKV projection GEMM from pre-packed hi/lo tiles.
// v2: double-buffered staging with counted vmcnt (T3 minimum 2-phase).
// Per iter: issue next tile's 8 global_load_lds into buf^1 BEFORE compute,
// then inline-asm s_waitcnt vmcnt(8) (the 8 newest stay in flight) + raw
// s_barrier + sched_barrier(0), MFMA from buf, end barrier. Last iter drains
// vmcnt(0). Values/LDS offsets/MFMA order unchanged -> q/k/v bitwise
// identical to the single-buffered version. LDS 64 KB (2 blocks/CU).
// Safety: buf b is re-staged only after the end-barrier of the iteration
// that read it (ds_reads consumed before MFMA issue, which precedes the
// barrier); non-staging waves (v case, w odd) see vmcnt(8) as a no-op.
// ---------------------------------------------------------------------------
__global__ __launch_bounds__(256)
void qkv_mfma_kernel(const u16* __restrict__ Xp, const u16* __restrict__ Wp,
                     const float* __restrict__ bq, const float* __restrict__ bk,
                     const float* __restrict__ bv,
                     float* __restrict__ qo, float* __restrict__ ko, float* __restrict__ vo)
{
    alignas(16) __shared__ u16 Ah[2][4096];
    alignas(16) __shared__ u16 Al[2][4096];
    alignas(16) __shared__ u16 Bh[2][4096];
    alignas(16) __shared__ u16 Bl[2][4096];

    const int z = blockIdx.z;
    const float* bias; float* dst; float scale;
    if (z == 0)      { bias = bq; dst = qo; scale = 0.125f; }
    else if (z == 1) { bias = bk; dst = ko; scale = 1.0f;   }
    else             { bias = bv; dst = vo; scale = 1.0f;   }
    const bool three = (z != 2);

    const int tid = threadIdx.x;
    const int mt = blockIdx.x;
    const int nt = blockIdx.y;
    const int w = tid >> 6, lane = tid & 63;
    const int wm = w & 1, wn = w >> 1;
    const int lm = lane & 15, kq = lane >> 4;

    const u16* Abase = Xp + (size_t)mt * (16 * 8192);
    const u16* Bbase = Wp + (size_t)(z * 4 + nt) * (16 * 8192);

    f32x4 acc[4][4];
    #pragma unroll
    for (int i = 0; i < 4; ++i)
        #pragma unroll
        for (int j = 0; j < 4; ++j)
            #pragma unroll
            for (int r = 0; r < 4; ++r) acc[i][j][r] = 0.0f;

    // Stage tile kt into buffer buf (8 x 1KB per staging wave).
    auto stage = [&](int kt, int buf) {
        const u16* at = Abase + kt * 8192;
        const u16* bt = Bbase + kt * 8192;
        const u16* gsrc; u16* ldst;
        if (w == 0)      { gsrc = at;        ldst = &Ah[buf][0]; }
        else if (w == 1) { gsrc = at + 4096; ldst = &Al[buf][0]; }
        else if (w == 2) { gsrc = bt;        ldst = &Bh[buf][0]; }
        else             { gsrc = bt + 4096; ldst = &Bl[buf][0]; }
        if (three || (w & 1) == 0) {
            #pragma unroll
            for (int i = 0; i < 8; ++i)
                __builtin_amdgcn_global_load_lds(
                    (const __attribute__((address_space(1))) void*)(gsrc + (size_t)lane * 8 + i * 512),
                    (__attribute__((address_space(3))) void*)(ldst + i * 512),
                    16, 0, 0);
        }
    };

    stage(0, 0);   // prologue: tile 0 in flight

    for (int kt = 0; kt < 16; ++kt) {
        const int cur = kt & 1;
        if (kt + 1 < 16) {
            stage(kt + 1, cur ^ 1);                      // next tile in flight
            asm volatile("s_waitcnt vmcnt(8)" ::: "memory");   // cur complete
        } else {
            asm volatile("s_waitcnt vmcnt(0)" ::: "memory");   // drain
        }
        __builtin_amdgcn_s_barrier();
        __builtin_amdgcn_sched_barrier(0);

        f16x8 ah[4], al[4], bh[4], bl[4];
        #pragma unroll
        for (int i = 0; i < 4; ++i) {
            int ar = (wm * 64 + i * 16 + lm) * 8 + kq * 1024;
            int br = (wn * 64 + i * 16 + lm) * 8 + kq * 1024;
            ah[i] = *(const f16x8*)&Ah[cur][ar];
            bh[i] = *(const f16x8*)&Bh[cur][br];
            if (three) {
                al[i] = *(const f16x8*)&Al[cur][ar];
                bl[i] = *(const f16x8*)&Bl[cur][br];
            }
        }
        #pragma unroll
        for (int i = 0; i < 4; ++i)
            #pragma unroll
            for (int j = 0; j < 4; ++j) {
                acc[i][j] = __builtin_amdgcn_mfma_f32_16x16x32_f16(ah[i], bh[j], acc[i][j], 0, 0, 0);
                if (three) {
                    acc[i][j] = __builtin_amdgcn_mfma_f32_16x16x32_f16(ah[i], bl[j], acc[i][j], 0, 0, 0);
                    acc[i][j] = __builtin_amdgcn_mfma_f32_16x16x32_f16(al[i], bh[j], acc[i][j], 0, 0, 0);
                }
            }
        __builtin_amdgcn_s_barrier();   // all waves done reading cur
    }

    // C/D layout: col = lane&15 (n), row = (lane>>4)*4 + r (m).
    #pragma unroll
    for (int j = 0; j < 4; ++j) {
        int ng = nt * 128 + wn * 64 + j * 16 + lm;
        int h = ng >> 6, d = ng & 63;
        float bv_ = bias[ng];
        #pragma unroll
        for (int i = 0; i < 4; ++i) {
            #pragma unroll
            for (int r = 0; r < 4; ++r) {
                int mg = mt * 128 + wm * 64 + i * 16 + kq * 4 + r;
                int b = mg >> 11, t = mg & 2047;
                dst[((size_t)((b * NHEAD + h) * T_LEN + t)) * HDIM + d] =
                    (acc[i][j][r] + bv_) * scale;
            }
        }
    }
}

// ---------------------------------------------------------------------------
// Kernel A-fallback: prior f16 hi/lo 3-pass qkv (used when ws too small for
// the pack buffers).
// ---------------------------------------------------------------------------
__global__ __launch_bounds__(256)
void qkv_proj_kernel(const float* __restrict__ X,
                     const float* __restrict__ Wq, const float* __restrict__ bq,
                     const float* __restrict__ Wk, const float* __restrict__ bk,
                     const float* __restrict__ Wv, const float* __restrict__ bv,
                     float* __restrict__ qo, float* __restrict__ ko, float* __restrict__ vo)
{
    alignas(16) __shared__ u16 Ah[128 * 40];
    alignas(16) __shared__ u16 Al[128 * 40];
    alignas(16) __shared__ u16 Bh[128 * 40];
    alignas(16) __shared__ u16 Bl[128 * 40];

    const int z = blockIdx.z;
    const float* W; const float* bias; float* dst; float scale;
    if (z == 0)      { W = Wq; bias = bq; dst = qo; scale = 0.125f; }
    else if (z == 1) { W = Wk; bias = bk; dst = ko; scale = 1.0f;   }
    else             { W = Wv; bias = bv; dst = vo; scale = 1.0f;   }

    const int tid = threadIdx.x;
    const int m0 = blockIdx.x * 128;
    const int n0 = blockIdx.y * 128;
    const int w = tid >> 6, lane = tid & 63;
    const int wm = w & 1, wn = w >> 1;
    const int lm = lane & 15, kq = lane >> 4;

    f32x4 acc[4][4];
    #pragma unroll
    for (int i = 0; i < 4; ++i)
        #pragma unroll
        for (int j = 0; j < 4; ++j)
            #pragma unroll
            for (int r = 0; r < 4; ++r) acc[i][j][r] = 0.0f;

    for (int kc = 0; kc < EMB; kc += 32) {
        __syncthreads();
        #pragma unroll
        for (int s = 0; s < 4; ++s) {
            int u = tid + 256 * s;
            int row = u >> 3, c4 = u & 7;
            float4 fa = *(const float4*)&X[(size_t)(m0 + row) * EMB + kc + c4 * 4];
            float4 fb = *(const float4*)&W[(n0 + row) * EMB + kc + c4 * 4];
            uint2 ph, pl;
            cvt4_hilo_h(fa, ph, pl);
            *(uint2*)&Ah[row * 40 + c4 * 4] = ph;
            *(uint2*)&Al[row * 40 + c4 * 4] = pl;
            cvt4_hilo_h(fb, ph, pl);
            *(uint2*)&Bh[row * 40 + c4 * 4] = ph;
            *(uint2*)&Bl[row * 40 + c4 * 4] = pl;
        }
        __syncthreads();

        f16x8 ah[4], al[4], bh[4], bl[4];
        #pragma unroll
        for (int i = 0; i < 4; ++i) {
            int ra = (wm * 64 + i * 16 + lm) * 40 + kq * 8;
            ah[i] = *(const f16x8*)&Ah[ra];
            al[i] = *(const f16x8*)&Al[ra];
            int rb = (wn * 64 + i * 16 + lm) * 40 + kq * 8;
            bh[i] = *(const f16x8*)&Bh[rb];
            bl[i] = *(const f16x8*)&Bl[rb];
        }
        #pragma unroll
        for (int i = 0; i < 4; ++i)
            #pragma unroll
            for (int j = 0; j < 4; ++j) {
                acc[i][j] = __builtin_amdgcn_mfma_f32_16x16x32_f16(ah[i], bh[j], acc[i][j], 0, 0, 0);
                acc[i][j] = __builtin_amdgcn_mfma_f32_16x16x32_f16(ah[i], bl[j], acc[i][j], 0, 0, 0);
                acc[i][j] = __builtin_amdgcn_mfma_f32_16x16x32_f16(al[i], bh[j], acc[i][j], 0, 0, 0);
            }
    }

    #pragma unroll
    for (int j = 0; j < 4; ++j) {
        int ng = n0 + wn * 64 + j * 16 + lm;
        int h = ng >> 6, d = ng & 63;
        float bv_ = bias[ng];
        #pragma unroll
        for (int i = 0; i < 4; ++i) {
            #pragma unroll
            for (int r = 0; r < 4; ++r) {
                int mg = m0 + wm * 64 + i * 16 + kq * 4 + r;
                int b = mg >> 11, t = mg & 2047;
                dst[((size_t)((b * NHEAD + h) * T_LEN + t)) * HDIM + d] =
                    (acc[i][j][r] + bv_) * scale;
            }
        }
    }
}

// ---------------------------------------------------------------------------
// Kernel B1: count + compact distinct sampled indices (single block).
// ---------------------------------------------------------------------------
__global__ __launch_bounds__(256)
void count_compact_kernel(const int* __restrict__ idxs, int n,
                          int* __restrict__ count, int* __restrict__ klist,
                          int* __restrict__ ncp)
{
    __shared__ int cnt[T_LEN];
    __shared__ int th_tot[256];
    __shared__ int th_off[256];
    __shared__ int ncs;
    const int tid = threadIdx.x;
    for (int j = tid; j < T_LEN; j += 256) cnt[j] = 0;
    __syncthreads();
    for (int i = tid; i < n; i += 256) atomicAdd(&cnt[idxs[i] & (T_LEN - 1)], 1);
    __syncthreads();
    const int base = tid * 8;
    int flags[8]; int loc = 0;
    #pragma unroll
    for (int j = 0; j < 8; ++j) {
        int c = cnt[base + j];
        count[base + j] = c;
        flags[j] = (c > 0); loc += flags[j];
    }
    th_tot[tid] = loc;
    __syncthreads();
    if (tid == 0) {
        int run = 0;
        for (int i = 0; i < 256; ++i) { th_off[i] = run; run += th_tot[i]; }
        ncs = run;
        ncp[0] = run;
    }
    __syncthreads();
    int off = th_off[tid];
    #pragma unroll
    for (int j = 0; j < 8; ++j)
        if (flags[j]) klist[off++] = base + j;
    __syncthreads();
    const int nc = ncs;
    const int nt = (nc + 127) & ~127;
    const int k0 = klist[0];
    for (int j = nc + tid; j < nt; j += 256) klist[j] = k0;
}

// ---------------------------------------------------------------------------
// Kernel B2a: partial ksum/vsum per (bh, slice). Coalesced float4 streaming.
// ---------------------------------------------------------------------------
__global__ __launch_bounds__(256)
void ksum_vmean_part_kernel(const int* __restrict__ count,
                            const float* __restrict__ k, const float* __restrict__ v,
                            float* __restrict__ kpart, float* __restrict__ vpart)
{
    __shared__ int cs[256];
    alignas(16) __shared__ float rk[16 * 64];
    alignas(16) __shared__ float rv[16 * 64];

    const int sl = blockIdx.x, bh = blockIdx.y, tid = threadIdx.x;
    const int f4 = tid & 15, tg = tid >> 4;
    const int t0 = sl * 256;

    cs[tid] = count[t0 + tid];
    __syncthreads();

    const float4* k4 = (const float4*)(k + (size_t)bh * T_LEN * HDIM) + t0 * 16;
    const float4* v4 = (const float4*)(v + (size_t)bh * T_LEN * HDIM) + t0 * 16;

    float4 ak = {0.f, 0.f, 0.f, 0.f}, av = {0.f, 0.f, 0.f, 0.f};
    #pragma unroll
    for (int s = 0; s < 16; ++s) {
        int t = tg + s * 16;
        float c = (float)cs[t];
        float4 kf = k4[t * 16 + f4];
        float4 vf = v4[t * 16 + f4];
        ak.x = fmaf(c, kf.x, ak.x); ak.y = fmaf(c, kf.y, ak.y);
        ak.z = fmaf(c, kf.z, ak.z); ak.w = fmaf(c, kf.w, ak.w);
        av.x += vf.x; av.y += vf.y; av.z += vf.z; av.w += vf.w;
    }
    *(float4*)&rk[tg * 64 + f4 * 4] = ak;
    *(float4*)&rv[tg * 64 + f4 * 4] = av;
    __syncthreads();

    if (tid < 64) {
        float sk = 0.f, sv = 0.f;
        #pragma unroll
        for (int g = 0; g < 16; ++g) { sk += rk[g * 64 + tid]; sv += rv[g * 64 + tid]; }
        kpart[((size_t)bh * 8 + sl) * 64 + tid] = sk;
        vpart[((size_t)bh * 8 + sl) * 64 + tid] = sv;
    }
}

// ---------------------------------------------------------------------------
// Kernel B2b: reduce 8 slice-partials -> ksum[bh][d], vmean[bh][d].
// ---------------------------------------------------------------------------
__global__ __launch_bounds__(64)
void ksum_vmean_reduce_kernel(const float* __restrict__ kpart, const float* __restrict__ vpart,
                              float* __restrict__ ksum, float* __restrict__ vmean)
{
    const int bh = blockIdx.x, d = threadIdx.x;
    float sk = 0.f, sv = 0.f;
    #pragma unroll
    for (int sl = 0; sl < 8; ++sl) {
        sk += kpart[((size_t)bh * 8 + sl) * 64 + d];
        sv += vpart[((size_t)bh * 8 + sl) * 64 + d];
    }
    ksum[bh * 64 + d]  = sk;
    vmean[bh * 64 + d] = sv * (1.0f / 2048.0f);
}

// ---------------------------------------------------------------------------
// Kernel C0: pack gathered K rows ONCE per bh into f16 hi/lo fragment-order
// tiles [chunk(2)][kq(4)][row(128)][8] (hi 8192 u16, then lo 8192), so the
// scan stages them with linear global_load_lds. Lives in the dead Xp region.
// ---------------------------------------------------------------------------
__global__ __launch_bounds__(256)
void pack_k_kernel(const float* __restrict__ k, const int* __restrict__ klist,
                   const int* __restrict__ ncp, u16* __restrict__ Kp)
{
    alignas(16) __shared__ u16 th[8192];
    alignas(16) __shared__ u16 tl[8192];
    const int wg = blockIdx.x, tid = threadIdx.x;
    const int swz = (wg & 7) * 64 + (wg >> 3);   // XCD-chunked bijection (512%8==0)
    const int bh = swz >> 4, kt = swz & 15;
    const int ntiles = (ncp[0] + 127) >> 7;
    if (kt >= ntiles) return;

    const float4* kb4 = (const float4*)(k + (size_t)bh * T_LEN * HDIM);
    #pragma unroll
    for (int s = 0; s < 8; ++s) {
        int u = tid + 256 * s;            // 0..2047 float4s
        int row = u >> 4, c4 = u & 15;    // row 0..127, c4 0..15 (d-quad)
        int krow = klist[kt * 128 + row];
        float4 f = kb4[krow * 16 + c4];
        uint2 ph, pl;
        cvt4_hilo_h(f, ph, pl);
        int base = (c4 >> 3) * 4096 + ((c4 >> 1) & 3) * 1024 + row * 8 + (c4 & 1) * 4;
        *(uint2*)&th[base] = ph;
        *(uint2*)&tl[base] = pl;
    }
    __syncthreads();

    u16* dst = Kp + ((size_t)bh * 16 + kt) * 16384;
    uint4* d4 = (uint4*)dst;
    const uint4* s4h = (const uint4*)th;
    const uint4* s4l = (const uint4*)tl;
    #pragma unroll
    for (int i = 0; i < 4; ++i) d4[tid + 256 * i] = s4h[tid + 256 * i];
    #pragma unroll
    for (int i = 0; i < 4; ++i) d4[1024 + tid + 256 * i] = s4l[tid + 256 * i];
}

// ---------------------------------------------------------------------------
// Kernel C: sparsity scan from pre-packed K tiles. (passing round-5 version)
// ---------------------------------------------------------------------------
__global__ __launch_bounds__(256)
void sparsity_scan_kernel(const float* __restrict__ q, const u16* __restrict__ Kp,
                          const float* __restrict__ ksum,
                          const int* __restrict__ ncp, float* __restrict__ spars)
{
    alignas(16) __shared__ u16 KH[10240];   // q staging (256*40), then packed K hi (8192)
    alignas(16) __shared__ u16 KL[10240];
    __shared__ float ksm[64];
    __shared__ float smax[128];
    __shared__ float sdotL[128];

    const int tid = threadIdx.x;
    const int wg = blockIdx.x;
    const int swz = (wg & 7) * 64 + (wg >> 3);
    const int bh = swz >> 4;
    const int q0 = (swz & 15) * 128;
    const int w = tid >> 6, lane = tid & 63;
    const int lm = lane & 15, kq = lane >> 4;

    const float* qb = q + ((size_t)bh * T_LEN + q0) * HDIM;
    const int ntiles = (ncp[0] + 127) >> 7;

    if (tid < 64) ksm[tid] = ksum[bh * 64 + tid];

    // Stage q tile (128 rows x 64 d) as f16 hi/lo, chunked [c][row][40].
    #pragma unroll
    for (int s = 0; s < 8; ++s) {
        int u = tid + 256 * s;
        int row = u >> 4, c4 = u & 15;
        float4 f = *(const float4*)&qb[row * HDIM + c4 * 4];
        uint2 ph, pl;
        cvt4_hilo_h(f, ph, pl);
        int base = ((c4 >> 3) * 128 + row) * 40 + (c4 & 7) * 4;
        *(uint2*)&KH[base] = ph;
        *(uint2*)&KL[base] = pl;
    }
    __syncthreads();

    // Hoist A-fragments (32 q rows per wave) to registers.
    f16x8 qh[2][2], ql[2][2];
    #pragma unroll
    for (int i = 0; i < 2; ++i)
        #pragma unroll
        for (int c = 0; c < 2; ++c) {
            int ra = (c * 128 + w * 32 + i * 16 + lm) * 40 + kq * 8;
            qh[i][c] = *(const f16x8*)&KH[ra];
            ql[i][c] = *(const f16x8*)&KL[ra];
        }

    // sdot = q . ksum (hi+lo reconstruction, fp32 accumulate).
    {
        float4 k0a = *(const float4*)&ksm[kq * 8];
        float4 k0b = *(const float4*)&ksm[kq * 8 + 4];
        float4 k1a = *(const float4*)&ksm[32 + kq * 8];
        float4 k1b = *(const float4*)&ksm[32 + kq * 8 + 4];
        float kmv[2][8] = {{k0a.x, k0a.y, k0a.z, k0a.w, k0b.x, k0b.y, k0b.z, k0b.w},
                           {k1a.x, k1a.y, k1a.z, k1a.w, k1b.x, k1b.y, k1b.z, k1b.w}};
        #pragma unroll
        for (int i = 0; i < 2; ++i) {
            float sd = 0.f;
            #pragma unroll
            for (int c = 0; c < 2; ++c)
                #pragma unroll
                for (int e = 0; e < 8; ++e)
                    sd = fmaf((float)qh[i][c][e] + (float)ql[i][c][e], kmv[c][e], sd);
            sd += __shfl_xor(sd, 16, 64);
            sd += __shfl_xor(sd, 32, 64);
            if (kq == 0) sdotL[w * 32 + i * 16 + lm] = sd;
        }
    }

    float vmax[2][4];
    #pragma unroll
    for (int i = 0; i < 2; ++i)
        #pragma unroll
        for (int r = 0; r < 4; ++r) vmax[i][r] = -INFINITY;

    const u16* kpb = Kp + (size_t)bh * (16 * 16384);

    for (int kt = 0; kt < ntiles; ++kt) {
        __syncthreads();   // prior reads of KH/KL done
        const u16* kp = kpb + kt * 16384;
        const u16* gsrc; u16* ldst;
        if (w == 0)      { gsrc = kp;         ldst = KH; }
        else if (w == 1) { gsrc = kp + 4096;  ldst = KH + 4096; }
        else if (w == 2) { gsrc = kp + 8192;  ldst = KL; }
        else             { gsrc = kp + 12288; ldst = KL + 4096; }
        #pragma unroll
        for (int i = 0; i < 8; ++i)    // 8 x 1KB = the wave's full 8KB quarter
            __builtin_amdgcn_global_load_lds(
                (const __attribute__((address_space(1))) void*)(gsrc + (size_t)lane * 8 + i * 512),
                (__attribute__((address_space(3))) void*)(ldst + i * 512),
                16, 0, 0);
        __syncthreads();

        #pragma unroll
        for (int j = 0; j < 8; ++j) {
            int rb0 = kq * 1024 + (j * 16 + lm) * 8;          // chunk 0
            int rb1 = 4096 + kq * 1024 + (j * 16 + lm) * 8;   // chunk 1
            f16x8 bh0 = *(const f16x8*)&KH[rb0];
            f16x8 bl0 = *(const f16x8*)&KL[rb0];
            f16x8 bh1 = *(const f16x8*)&KH[rb1];
            f16x8 bl1 = *(const f16x8*)&KL[rb1];
            f32x4 a0 = {0.f, 0.f, 0.f, 0.f};
            f32x4 a1 = {0.f, 0.f, 0.f, 0.f};
            a0 = __builtin_amdgcn_mfma_f32_16x16x32_f16(qh[0][0], bh0, a0, 0, 0, 0);
            a1 = __builtin_amdgcn_mfma_f32_16x16x32_f16(qh[1][0], bh0, a1, 0, 0, 0);
            a0 = __builtin_amdgcn_mfma_f32_16x16x32_f16(qh[0][0], bl0, a0, 0, 0, 0);
            a1 = __builtin_amdgcn_mfma_f32_16x16x32_f16(qh[1][0], bl0, a1, 0, 0, 0);
            a0 = __builtin_amdgcn_mfma_f32_16x16x32_f16(ql[0][0], bh0, a0, 0, 0, 0);
            a1 = __builtin_amdgcn_mfma_f32_16x16x32_f16(ql[1][0], bh0, a1, 0, 0, 0);
            a0 = __builtin_amdgcn_mfma_f32_16x16x32_f16(qh[0][1], bh1, a0, 0, 0, 0);
            a1 = __builtin_amdgcn_mfma_f32_16x16x32_f16(qh[1][1], bh1, a1, 0, 0, 0);
            a0 = __builtin_amdgcn_mfma_f32_16x16x32_f16(qh[0][1], bl1, a0, 0, 0, 0);
            a1 = __builtin_amdgcn_mfma_f32_16x16x32_f16(qh[1][1], bl1, a1, 0, 0, 0);
            a0 = __builtin_amdgcn_mfma_f32_16x16x32_f16(ql[0][1], bh1, a0, 0, 0, 0);
            a1 = __builtin_amdgcn_mfma_f32_16x16x32_f16(ql[1][1], bh1, a1, 0, 0, 0);
            #pragma unroll
            for (int r = 0; r < 4; ++r) {
                vmax[0][r] = fmaxf(vmax[0][r], a0[r]);
                vmax[1][r] = fmaxf(vmax[1][r], a1[r]);
            }
        }
    }

    #pragma unroll
    for (int i = 0; i < 2; ++i)
        #pragma unroll
        for (int r = 0; r < 4; ++r) {
            float m = vmax[i][r];
            m = fmaxf(m, __shfl_xor(m, 1, 64));
            m = fmaxf(m, __shfl_xor(m, 2, 64));
            m = fmaxf(m, __shfl_xor(m, 4, 64));
            m = fmaxf(m, __shfl_xor(m, 8, 64));
            if (lm == 0) smax[w * 32 + i * 16 + kq * 4 + r] = m;
        }
    __syncthreads();

    if (tid < 128)
        spars[bh * T_LEN + q0 + tid] = smax[tid] - sdotL[tid] * (1.0f / 2048.0f);
}

// ---------------------------------------------------------------------------
// Kernel C-fallback: round-2 scan (gather+cvt per tile), used when ws too
// small for the pack buffers.
// ---------------------------------------------------------------------------
__global__ __launch_bounds__(256)
void sparsity_scan_fb_kernel(const float* __restrict__ q, const float* __restrict__ k,
                             const float* __restrict__ ksum, const int* __restrict__ klist,
                             const int* __restrict__ ncp, float* __restrict__ spars)
{
    alignas(16) __shared__ u16 KH[256 * 40];
    alignas(16) __shared__ u16 KL[256 * 40];
    __shared__ float ksm[64];
    __shared__ float smax[128];
    __shared__ float sdotL[128];

    const int tid = threadIdx.x;
    const int bh = blockIdx.y;
    const int q0 = blockIdx.x * 128;
    const int w = tid >> 6, lane = tid & 63;
    const int lm = lane & 15, kq = lane >> 4;

    const float* qb = q + ((size_t)bh * T_LEN + q0) * HDIM;
    const float4* kb4 = (const float4*)(k + (size_t)bh * T_LEN * HDIM);
    const int ntiles = (ncp[0] + 127) >> 7;

    if (tid < 64) ksm[tid] = ksum[bh * 64 + tid];

    #pragma unroll
    for (int s = 0; s < 8; ++s) {
        int u = tid + 256 * s;
        int row = u >> 4, c4 = u & 15;
        float4 f = *(const float4*)&qb[row * HDIM + c4 * 4];
        uint2 ph, pl;
        cvt4_hilo_h(f, ph, pl);
        int base = ((c4 >> 3) * 128 + row) * 40 + (c4 & 7) * 4;
        *(uint2*)&KH[base] = ph;
        *(uint2*)&KL[base] = pl;
    }
    __syncthreads();

    f16x8 qh[2][2], ql[2][2];
    #pragma unroll
    for (int i = 0; i < 2; ++i)
        #pragma unroll
        for (int c = 0; c < 2; ++c) {
            int ra = (c * 128 + w * 32 + i * 16 + lm) * 40 + kq * 8;
            qh[i][c] = *(const f16x8*)&KH[ra];
            ql[i][c] = *(const f16x8*)&KL[ra];
        }

    {
        float4 k0a = *(const float4*)&ksm[kq * 8];
        float4 k0b = *(const float4*)&ksm[kq * 8 + 4];
        float4 k1a = *(const float4*)&ksm[32 + kq * 8];
        float4 k1b = *(const float4*)&ksm[32 + kq * 8 + 4];
        float kmv[2][8] = {{k0a.x, k0a.y, k0a.z, k0a.w, k0b.x, k0b.y, k0b.z, k0b.w},
                           {k1a.x, k1a.y, k1a.z, k1a.w, k1b.x, k1b.y, k1b.z, k1b.w}};
        #pragma unroll
        for (int i = 0; i < 2; ++i) {
            float sd = 0.f;
            #pragma unroll
            for (int c = 0; c < 2; ++c)
                #pragma unroll
                for (int e = 0; e < 8; ++e)
                    sd = fmaf((float)qh[i][c][e] + (float)ql[i][c][e], kmv[c][e], sd);
            sd += __shfl_xor(sd, 16, 64);
            sd += __shfl_xor(sd, 32, 64);
            if (kq == 0) sdotL[w * 32 + i * 16 + lm] = sd;
        }
    }

    float vmax[2][4];
    #pragma unroll
    for (int i = 0; i < 2; ++i)
        #pragma unroll
        for (int r = 0; r < 4; ++r) vmax[i][r] = -INFINITY;

    for (int kt = 0; kt < ntiles; ++kt) {
        __syncthreads();
        #pragma unroll
        for (int s = 0; s < 8; ++s) {
            int u = tid + 256 * s;
            int row = u >> 4, c4 = u & 15;
            int krow = klist[kt * 128 + row];
            float4 f = kb4[krow * 16 + c4];
            uint2 ph, pl;
            cvt4_hilo_h(f, ph, pl);
            int base = ((c4 >> 3) * 128 + row) * 40 + (c4 & 7) * 4;
            *(uint2*)&KH[base] = ph;
            *(uint2*)&KL[base] = pl;
        }
        __syncthreads();

        #pragma unroll
        for (int j = 0; j < 8; ++j) {
            int rb0 = (j * 16 + lm) * 40 + kq * 8;
            int rb1 = (128 + j * 16 + lm) * 40 + kq * 8;
            f16x8 bh0 = *(const f16x8*)&KH[rb0];
            f16x8 bl0 = *(const f16x8*)&KL[rb0];
            f16x8 bh1 = *(const f16x8*)&KH[rb1];
            f16x8 bl1 = *(const f16x8*)&KL[rb1];
            f32x4 a0 = {0.f, 0.f, 0.f, 0.f};
            f32x4 a1 = {0.f, 0.f, 0.f, 0.f};
            a0 = __builtin_amdgcn_mfma_f32_16x16x32_f16(qh[0][0], bh0, a0, 0, 0, 0);
            a1 = __builtin_amdgcn_mfma_f32_16x16x32_f16(qh[1][0], bh0, a1, 0, 0, 0);
            a0 = __builtin_amdgcn_mfma_f32_16x16x32_f16(qh[0][0], bl0, a0, 0, 0, 0);
            a1 = __builtin_amdgcn_mfma_f32_16x16x32_f16(qh[1][0], bl0, a1, 0, 0, 0);
            a0 = __builtin_amdgcn_mfma_f32_16x16x32_f16(ql[0][0], bh0, a0, 0, 0, 0);
            a1 = __builtin_amdgcn_mfma_f32_16x16x32_f16(ql[1][0], bh0, a1, 0, 0, 0);
            a0 = __builtin_amdgcn_mfma_f32_16x16x32_f16(qh[0][1], bh1, a0, 0, 0, 0);
            a1 = __builtin_amdgcn_mfma_f32_16x16x32_f16(qh[1][1], bh1, a1, 0, 0, 0);
            a0 = __builtin_amdgcn_mfma_f32_16x16x32_f16(qh[0][1], bl1, a0, 0, 0, 0);
            a1 = __builtin_amdgcn_mfma_f32_16x16x32_f16(qh[1][1], bl1, a1, 0, 0, 0);
            a0 = __builtin_amdgcn_mfma_f32_16x16x32_f16(ql[0][1], bh1, a0, 0, 0, 0);
            a1 = __builtin_amdgcn_mfma_f32_16x16x32_f16(ql[1][1], bh1, a1, 0, 0, 0);
            #pragma unroll
            for (int r = 0; r < 4; ++r) {
                vmax[0][r] = fmaxf(vmax[0][r], a0[r]);
                vmax[1][r] = fmaxf(vmax[1][r], a1[r]);
            }
        }
    }

    #pragma unroll
    for (int i = 0; i < 2; ++i)
        #pragma unroll
        for (int r = 0; r < 4; ++r) {
            float m = vmax[i][r];
            m = fmaxf(m, __shfl_xor(m, 1, 64));
            m = fmaxf(m, __shfl_xor(m, 2, 64));
            m = fmaxf(m, __shfl_xor(m, 4, 64));
            m = fmaxf(m, __shfl_xor(m, 8, 64));
            if (lm == 0) smax[w * 32 + i * 16 + kq * 4 + r] = m;
        }
    __syncthreads();

    if (tid < 128)
        spars[bh * T_LEN + q0 + tid] = smax[tid] - sdotL[tid] * (1.0f / 2048.0f);
}

// ---------------------------------------------------------------------------
// Kernel D: exact top-40 per bh via 4-level radix select on order-preserving
// u32 keys (f>=0 -> u|0x80000000, f<0 -> ~u). Output SET identical
// (ties at the rank-40 boundary -> smallest indices, = lax.top_k).
// ---------------------------------------------------------------------------
__global__ __launch_bounds__(256)
void topk_kernel(const float* __restrict__ spars, int* __restrict__ topi)
{
    __shared__ unsigned keys[T_LEN];   // 8 KB
    __shared__ int hist[256];
    __shared__ int sfx[257];
    __shared__ int sh_need, sh_bin, nsel, neq, cnt2;
    const int bh = blockIdx.x, tid = threadIdx.x;

    #pragma unroll
    for (int s = 0; s < 8; ++s) {
        int j = tid + 256 * s;
        unsigned u = __float_as_uint(spars[bh * T_LEN + j]);
        keys[j] = (u & 0x80000000u) ? ~u : (u | 0x80000000u);
    }
    if (tid == 0) { sh_need = USEL; nsel = 0; neq = 0; cnt2 = 0; }
    __syncthreads();

    unsigned kpref = 0;
    int shift = 24;
    #pragma unroll
    for (int level = 0; level < 4; ++level) {
        const unsigned hi_mask = (shift == 24) ? 0u : (0xFFFFFFFFu << (shift + 8));
        hist[tid] = 0;
        __syncthreads();
        #pragma unroll
        for (int s = 0; s < 8; ++s) {
            unsigned kk = keys[tid + 256 * s];
            if ((kk & hi_mask) == kpref)
                atomicAdd(&hist[(kk >> shift) & 255], 1);
        }
        __syncthreads();
        // suffix sums: sfx[i] = sum of hist[i..255]; sfx[256] = 0.
        sfx[tid] = hist[tid];
        if (tid == 0) sfx[256] = 0;
        __syncthreads();
        for (int off = 1; off < 256; off <<= 1) {
            int v = (tid + off < 256) ? sfx[tid + off] : 0;
            __syncthreads();
            sfx[tid] += v;
            __syncthreads();
        }
        const int need = sh_need;
        const int A = (tid == 255) ? 0 : sfx[tid + 1];   // count strictly above bin tid
        const int here = sfx[tid];
        __syncthreads();
        if (A < need && here >= need) {   // exactly one bin satisfies
            sh_bin = tid;
            sh_need = need - A;
        }
        __syncthreads();
        kpref |= (unsigned)sh_bin << shift;
        shift -= 8;
    }

    const unsigned K = kpref;
    const int need_eq = sh_need;

    // Collect strictly-greater keys (count = USEL - need_eq by construction)
    // and count equals in the same pass.
    #pragma unroll
    for (int s = 0; s < 8; ++s) {
        int j = tid + 256 * s;
        unsigned kk = keys[j];
        if (kk > K) {
            int pos = atomicAdd(&nsel, 1);
            if (pos < USEL) topi[bh * USEL + pos] = j;
        } else if (kk == K) {
            atomicAdd(&neq, 1);
        }
    }
    __syncthreads();
    const int base = nsel;
    const int E = neq;
    __syncthreads();

    if (E == need_eq) {
        // Fast path (no exact-duplicate tie at the boundary): take all equals.
        #pragma unroll
        for (int s = 0; s < 8; ++s) {
            int j = tid + 256 * s;
            if (keys[j] == K) {
                int pos = atomicAdd(&cnt2, 1);
                if (base + pos < USEL) topi[bh * USEL + base + pos] = j;
            }
        }
    } else {
        // Rare tie path: among equals, take the need_eq smallest indices.
        #pragma unroll
        for (int s = 0; s < 8; ++s) {
            int j = tid + 256 * s;
            if (keys[j] == K) {
                int rank = 0;
                for (int j2 = 0; j2 < j; ++j2) rank += (keys[j2] == K);
                if (rank < need_eq && base + rank < USEL)
                    topi[bh * USEL + base + rank] = j;
            }
        }
    }
}

// ---------------------------------------------------------------------------
// Kernel E1: gather selected q rows -> qsel[bh][u][d]. (q dead afterwards)
// ---------------------------------------------------------------------------
__global__ __launch_bounds__(256)
void gather_q_kernel(const float* __restrict__ q, const int* __restrict__ topi,
                     float* __restrict__ qsel)
{
    const int bh = blockIdx.x, tid = threadIdx.x;
    for (int i = tid; i < USEL * HDIM; i += 256) {
        int u = i >> 6, d = i & 63;
        int t = topi[bh * USEL + u] & (T_LEN - 1);
        qsel[(size_t)bh * USEL * HDIM + i] = q[((size_t)bh * T_LEN + t) * HDIM + d];
    }
}

// ---------------------------------------------------------------------------
// Kernel E2: S[bh][u][t] = qsel[bh][u] . k[bh][t]. Grid (8 t-slices, 32 bh).
// ---------------------------------------------------------------------------
__global__ __launch_bounds__(256)
void sel_scores_kernel(const float* __restrict__ qsel, const float* __restrict__ k,
                       float* __restrict__ S)
{
    __shared__ float qsT[64 * 41];    // [d][u] stride 41
    __shared__ float ksT[64 * 257];   // [d][t] stride 257

    const int sl = blockIdx.x, bh = blockIdx.y, tid = threadIdx.x;
    const int t0 = sl * 256;

    for (int i = tid; i < USEL * HDIM; i += 256) {
        int u = i >> 6, d = i & 63;
        qsT[d * 41 + u] = qsel[(size_t)bh * USEL * HDIM + i];
    }
    const float4* k4 = (const float4*)(k + (size_t)bh * T_LEN * HDIM);
    #pragma unroll
    for (int s = 0; s < 16; ++s) {
        int u = tid + 256 * s;
        int c4 = u & 15, t = u >> 4;
        float4 f = k4[(t0 + t) * 16 + c4];
        ksT[(c4 * 4 + 0) * 257 + t] = f.x;
        ksT[(c4 * 4 + 1) * 257 + t] = f.y;
        ksT[(c4 * 4 + 2) * 257 + t] = f.z;
        ksT[(c4 * 4 + 3) * 257 + t] = f.w;
    }
    __syncthreads();

    const int qg = tid >> 5;
    const int kg = tid & 31;

    float acc[5][8];
    #pragma unroll
    for (int i = 0; i < 5; ++i)
        #pragma unroll
        for (int j = 0; j < 8; ++j) acc[i][j] = 0.0f;

    #pragma unroll 4
    for (int d = 0; d < 64; ++d) {
        float qv[5], kv[8];
        #pragma unroll
        for (int i = 0; i < 5; ++i) qv[i] = qsT[d * 41 + qg * 5 + i];
        #pragma unroll
        for (int j = 0; j < 8; ++j) kv[j] = ksT[d * 257 + kg + 32 * j];
        #pragma unroll
        for (int i = 0; i < 5; ++i)
            #pragma unroll
            for (int j = 0; j < 8; ++j)
                acc[i][j] = fmaf(qv[i], kv[j], acc[i][j]);
    }

    #pragma unroll
    for (int i = 0; i < 5; ++i) {
        float* sp = &S[((size_t)bh * USEL + qg * 5 + i) * T_LEN + t0 + kg];
        #pragma unroll
        for (int j = 0; j < 8; ++j) sp[32 * j] = acc[i][j];
    }
}

// ---------------------------------------------------------------------------
// Kernel E3: in-place softmax over each S row (1280 rows of 2048).
// ---------------------------------------------------------------------------
__global__ __launch_bounds__(256)
void sel_softmax_kernel(float* __restrict__ S)
{
    __shared__ float red[256];
    const int row = blockIdx.x, tid = threadIdx.x;
    float* sr = S + (size_t)row * T_LEN;

    float x[8];
    float m = -INFINITY;
    #pragma unroll
    for (int s = 0; s < 8; ++s) { x[s] = sr[tid + 256 * s]; m = fmaxf(m, x[s]); }
    red[tid] = m;
    __syncthreads();
    for (int s = 128; s > 0; s >>= 1) {
        if (tid < s) red[tid] = fmaxf(red[tid], red[tid + s]);
        __syncthreads();
    }
    m = red[0];
    __syncthreads();

    float sum = 0.f;
    #pragma unroll
    for (int s = 0; s < 8; ++s) { x[s] = __expf(x[s] - m); sum += x[s]; }
    red[tid] = sum;
    __syncthreads();
    for (int s = 128; s > 0; s >>= 1) {
        if (tid < s) red[tid] += red[tid + s];
        __syncthreads();
    }
    float inv = 1.0f / red[0];
    #pragma unroll
    for (int s = 0; s < 8; ++s) sr[tid + 256 * s] = x[s] * inv;
}

// ---------------------------------------------------------------------------
// Kernel E4: PV partial. Grid (16 t-slices, 32 bh).
// ---------------------------------------------------------------------------
__global__ __launch_bounds__(256)
void pv_part_kernel(const float* __restrict__ S, const float* __restrict__ v,
                    float* __restrict__ part)
{
    __shared__ float ps[USEL * 128];      // [q][t]
    __shared__ float vs[128 * 69];        // [t][d] stride 69
    __shared__ float obuf[128 * 20];

    const int sl = blockIdx.x, bh = blockIdx.y, tid = threadIdx.x;
    const int t0 = sl * 128;

    for (int i = tid; i < USEL * 128; i += 256) {
        int q = i >> 7, t = i & 127;
        ps[q * 128 + t] = S[((size_t)bh * USEL + q) * T_LEN + t0 + t];
    }
    const float4* v4 = (const float4*)(v + (size_t)bh * T_LEN * HDIM);
    #pragma unroll
    for (int s = 0; s < 8; ++s) {
        int u = tid + 256 * s;
        int c4 = u & 15, t = u >> 4;
        float4 f = v4[(t0 + t) * 16 + c4];
        vs[t * 69 + c4 * 4 + 0] = f.x;
        vs[t * 69 + c4 * 4 + 1] = f.y;
        vs[t * 69 + c4 * 4 + 2] = f.z;
        vs[t * 69 + c4 * 4 + 3] = f.w;
    }
    __syncthreads();

    const int qg = tid >> 5, r = tid & 31;
    const int dg = r >> 1, th = r & 1;
    const int tb = th * 64;

    float o[5][4];
    #pragma unroll
    for (int i = 0; i < 5; ++i)
        #pragma unroll
        for (int j = 0; j < 4; ++j) o[i][j] = 0.0f;

    #pragma unroll 4
    for (int tt = 0; tt < 64; ++tt) {
        int t = tb + tt;
        float pv[5];
        #pragma unroll
        for (int i = 0; i < 5; ++i) pv[i] = ps[(qg * 5 + i) * 128 + t];
        float4 vv = *(const float4*)&vs[t * 69 + dg * 4];
        #pragma unroll
        for (int i = 0; i < 5; ++i) {
            o[i][0] = fmaf(pv[i], vv.x, o[i][0]);
            o[i][1] = fmaf(pv[i], vv.y, o[i][1]);
            o[i][2] = fmaf(pv[i], vv.z, o[i][2]);
            o[i][3] = fmaf(pv[i], vv.w, o[i][3]);
        }
    }

    const int p = qg * 16 + dg;
    if (th == 1) {
        #pragma unroll
        for (int i = 0; i < 5; ++i)
            #pragma unroll
            for (int j = 0; j < 4; ++j) obuf[p * 20 + i * 4 + j] = o[i][j];
    }
    __syncthreads();
    if (th == 0) {
        float* pb = part + ((size_t)bh * 16 + sl) * (USEL * HDIM);
        #pragma unroll
        for (int i = 0; i < 5; ++i)
            #pragma unroll
            for (int j = 0; j < 4; ++j)
                pb[(qg * 5 + i) * HDIM + dg * 4 + j] = o[i][j] + obuf[p * 20 + i * 4 + j];
    }
}

// ---------------------------------------------------------------------------
// Kernel E5: deterministic merge of 16 PV partials -> attn[bh][u][d].
// ---------------------------------------------------------------------------
__global__ __launch_bounds__(256)
void pv_merge_kernel(const float* __restrict__ part, float* __restrict__ attn)
{
    const int bh = blockIdx.x, tid = threadIdx.x;
    for (int i = tid; i < USEL * HDIM; i += 256) {
        float s = 0.f;
        #pragma unroll
        for (int sl = 0; sl < 16; ++sl)
            s += part[((size_t)bh * 16 + sl) * (USEL * HDIM) + i];
        attn[(size_t)bh * USEL * HDIM + i] = s;
    }
}

// ---------------------------------------------------------------------------
// Kernel F1: fill context (B,T,E layout, fp32) with per-head vmean.
// ---------------------------------------------------------------------------
__global__ __launch_bounds__(256)
void ctx_fill_kernel(const float* __restrict__ vmean, float* __restrict__ ctx)
{
    int flat = blockIdx.x * 256 + threadIdx.x;
    int d = flat & 63, h = (flat >> 6) & 7, b = flat >> 20;
    int bh = (b << 3) | h;
    ctx[flat] = vmean[bh * 64 + d];
}

// ---------------------------------------------------------------------------
// Kernel F2: scatter attn rows into context at top_idx positions.
// ---------------------------------------------------------------------------
__global__ void ctx_scatter_kernel(const float* __restrict__ attn, const int* __restrict__ topi,
                                   float* __restrict__ ctx)
{
    const int u = blockIdx.x, bh = blockIdx.y, d = threadIdx.x;
    const int b = bh >> 3, h = bh & 7;
    const int t = topi[bh * USEL + u] & (T_LEN - 1);
    ctx[(size_t)(b * T_LEN + t) * EMB + h * 64 + d] =
        attn[((size_t)bh * USEL + u) * HDIM + d];
}

// ---------------------------------------------------------------------------
// Kernel G: out = ctx @ Wo^T + bo via bf16 hi+lo 3-pass MFMA (16x16x32).
// ---------------------------------------------------------------------------
__global__ __launch_bounds__(256)
void out_proj_kernel(const float* __restrict__ A, const float* __restrict__ Wo,
                     const float* __restrict__ bo, float* __restrict__ out)
{
    alignas(16) __shared__ u16 Ah[128 * 40];
    alignas(16) __shared__ u16 Al[128 * 40];
    alignas(16) __shared__ u16 Bh[128 * 40];
    alignas(16) __shared__ u16 Bl[128 * 40];

    const int tid = threadIdx.x;
    const int m0 = blockIdx.x * 128;
    const int n0 = blockIdx.y * 128;
    const int w = tid >> 6, lane = tid & 63;
    const int wm = w & 1, wn = w >> 1;
    const int lm = lane & 15, kq = lane >> 4;

    f32x4 acc[4][4];
    #pragma unroll
    for (int i = 0; i < 4; ++i)
        #pragma unroll
        for (int j = 0; j < 4; ++j)
            #pragma unroll
            for (int r = 0; r < 4; ++r) acc[i][j][r] = 0.0f;

    for (int kc = 0; kc < EMB; kc += 32) {
        __syncthreads();
        #pragma unroll
        for (int s = 0; s < 4; ++s) {
            int u = tid + 256 * s;
            int row = u >> 3, c4 = u & 7;
            float4 fa = *(const float4*)&A[(size_t)(m0 + row) * EMB + kc + c4 * 4];
            float4 fb = *(const float4*)&Wo[(n0 + row) * EMB + kc + c4 * 4];
            uint2 ph, pl;
            cvt4_hilo(fa, ph, pl);
            *(uint2*)&Ah[row * 40 + c4 * 4] = ph;
            *(uint2*)&Al[row * 40 + c4 * 4] = pl;
            cvt4_hilo(fb, ph, pl);
            *(uint2*)&Bh[row * 40 + c4 * 4] = ph;
            *(uint2*)&Bl[row * 40 + c4 * 4] = pl;
        }
        __syncthreads();

        bf16v8 ah[4], al[4], bh[4], bl[4];
        #pragma unroll
        for (int i = 0; i < 4; ++i) {
            int ra = (wm * 64 + i * 16 + lm) * 40 + kq * 8;
            ah[i] = *(const bf16v8*)&Ah[ra];
            al[i] = *(const bf16v8*)&Al[ra];
            int rb = (wn * 64 + i * 16 + lm) * 40 + kq * 8;
            bh[i] = *(const bf16v8*)&Bh[rb];
            bl[i] = *(const bf16v8*)&Bl[rb];
        }
        #pragma unroll
        for (int i = 0; i < 4; ++i)
            #pragma unroll
            for (int j = 0; j < 4; ++j) {
                acc[i][j] = __builtin_amdgcn_mfma_f32_16x16x32_bf16(ah[i], bh[j], acc[i][j], 0, 0, 0);
                acc[i][j] = __builtin_amdgcn_mfma_f32_16x16x32_bf16(ah[i], bl[j], acc[i][j], 0, 0, 0);
                acc[i][j] = __builtin_amdgcn_mfma_f32_16x16x32_bf16(al[i], bh[j], acc[i][j], 0, 0, 0);
            }
    }

    #pragma unroll
    for (int j = 0; j < 4; ++j) {
        int ng = n0 + wn * 64 + j * 16 + lm;
        float bias = bo[ng];
        #pragma unroll
        for (int i = 0; i < 4; ++i)
            #pragma unroll
            for (int r = 0; r < 4; ++r) {
                int mg = m0 + wm * 64 + i * 16 + kq * 4 + r;
                out[(size_t)mg * EMB + ng] = acc[i][j][r] + bias;
            }
    }
}

// ---------------------------------------------------------------------------
// Diagnostic: if ws_size is too small, report it via d_out (absmax ~= MiB).
// ---------------------------------------------------------------------------
__global__ __launch_bounds__(256)
void ws_diag_kernel(float* __restrict__ out, int n, float mib)
{
    int flat = blockIdx.x * 256 + threadIdx.x;
    if (flat < n) out[flat] = mib;
}

// ---------------------------------------------------------------------------
extern "C" void kernel_launch(void* const* d_in, const int* in_sizes, int n_in,
                              void* d_out, int out_size, void* d_ws, size_t ws_size,
                              hipStream_t stream)
{
    const float* X = nullptr; const int* idxs = nullptr;
    const float* Wseen[4] = {nullptr, nullptr, nullptr, nullptr};
    const float* bseen[4] = {nullptr, nullptr, nullptr, nullptr};
    int nw = 0, nb = 0, u_part = 2048;
    for (int i = 0; i < n_in; ++i) {
        int sz = in_sizes[i];
        if (sz == EMB * EMB * 16) { if (!X) X = (const float*)d_in[i]; }
        else if (sz == T_LEN)     { if (!idxs) { idxs = (const int*)d_in[i]; u_part = sz; } }
        else if (sz == EMB * EMB) { if (nw < 4) Wseen[nw++] = (const float*)d_in[i]; }
        else if (sz == EMB)       { if (nb < 4) bseen[nb++] = (const float*)d_in[i]; }
    }
    if (!X || !idxs || nw < 4 || nb < 4) {
        X = (const float*)d_in[0]; idxs = (const int*)d_in[1];
        Wseen[0] = (const float*)d_in[2]; bseen[0] = (const float*)d_in[3];
        Wseen[1] = (const float*)d_in[4]; bseen[1] = (const float*)d_in[5];
        Wseen[2] = (const float*)d_in[6]; bseen[2] = (const float*)d_in[7];
        Wseen[3] = (const float*)d_in[8]; bseen[3] = (const float*)d_in[9];
        u_part = in_sizes[1];
    }
    const float *Wq = Wseen[0], *Wk = Wseen[1], *Wv = Wseen[2], *Wo = Wseen[3];
    const float *bq = bseen[0], *bk = bseen[1], *bv = bseen[2], *bo = bseen[3];

    // Base workspace layout (peak 50,951,168 B, unchanged). Pack buffers for
    // the fast paths live beyond it: Xp 16 MB (reused as packed K) + Wp 3 MB.
    const size_t NEED      = 50951168ULL;
    const size_t NEED_BIG  = NEED + 16777216ULL + 3145728ULL;   // 70,874,112
    if (ws_size < NEED) {
        ws_diag_kernel<<<(out_size + 255) / 256, 256, 0, stream>>>(
            (float*)d_out, out_size, (float)(ws_size >> 20));
        return;
    }

    float* ws    = (float*)d_ws;
    float* qw    = ws;                    // 4,194,304 floats
    float* kw    = qw + 4194304;
    float* vw    = kw + 4194304;
    float* tail  = vw + 4194304;
    float* slotA = tail;                  // 81920: qsel, later attn
    float* spars = tail + 81920;          // 65536
    int*   count = (int*)(tail + 147456); // 2048
    float* ksum  = tail + 149504;         // 2048
    float* vmean = tail + 151552;         // 2048
    int*   topi  = (int*)(tail + 153600); // 1280
    float* kpart = tail;                  // overlays in slotA (disjoint liveness)
    float* vpart = tail + 16384;
    int*   klist = (int*)(tail + 32768);
    int*   ncp   = (int*)(tail + 34816);
    float* S     = qw;                    // q dead after gather
    float* pvp   = qw + 2621440;
    float* qsel  = slotA;
    float* attn  = slotA;
    float* ctx   = (float*)d_ws;
    u16*   Xp    = (u16*)((char*)d_ws + NEED);   // 8,388,608 u16 (16 MB)
    u16*   Wp    = Xp + 8388608;                 // 1,572,864 u16 (3 MB)
    u16*   Kp    = Xp;                           // packed K overlays Xp (dead after qkv)

    const bool big = (ws_size >= NEED_BIG);

    if (big) {
        pack_hilo_kernel<<<1216, 256, 0, stream>>>(X, Wq, Wk, Wv, Xp, Wp);
        qkv_mfma_kernel<<<dim3(64, 4, 3), 256, 0, stream>>>(Xp, Wp, bq, bk, bv, qw, kw, vw);
    } else {
        qkv_proj_kernel<<<dim3(64, 4, 3), 256, 0, stream>>>(X, Wq, bq, Wk, bk, Wv, bv, qw, kw, vw);
    }
    count_compact_kernel<<<1, 256, 0, stream>>>(idxs, u_part, count, klist, ncp);
    ksum_vmean_part_kernel<<<dim3(8, 32), 256, 0, stream>>>(count, kw, vw, kpart, vpart);
    ksum_vmean_reduce_kernel<<<32, 64, 0, stream>>>(kpart, vpart, ksum, vmean);
    if (big) {
        pack_k_kernel<<<512, 256, 0, stream>>>(kw, klist, ncp, Kp);
        sparsity_scan_kernel<<<512, 256, 0, stream>>>(qw, Kp, ksum, ncp, spars);
    } else {
        sparsity_scan_fb_kernel<<<dim3(16, 32), 256, 0, stream>>>(qw, kw, ksum, klist, ncp, spars);
    }
    topk_kernel<<<32, 256, 0, stream>>>(spars, topi);
    gather_q_kernel<<<32, 256, 0, stream>>>(qw, topi, qsel);
    // qw dead; S/pvp take over that region.
    sel_scores_kernel<<<dim3(8, 32), 256, 0, stream>>>(qsel, kw, S);
    sel_softmax_kernel<<<1280, 256, 0, stream>>>(S);
    pv_part_kernel<<<dim3(16, 32), 256, 0, stream>>>(S, vw, pvp);
    pv_merge_kernel<<<32, 256, 0, stream>>>(pvp, attn);
    // S/pvp dead; ctx takes over the whole front region.
    ctx_fill_kernel<<<16384, 256, 0, stream>>>(vmean, ctx);
    ctx_scatter_kernel<<<dim3(USEL, BHEADS), 64, 0, stream>>>(attn, topi, ctx);
    out_proj_kernel<<<dim3(64, 4), 256, 0, stream>>>(ctx, Wo, bo, (float*)d_out);
}

// Round 8
// 274.065 us; speedup vs baseline: 1.9335x; 1.0107x over previous
//
#include <hip/hip_runtime.h>
#include <hip/hip_bf16.h>
#include <math.h>

#define T_LEN 2048
#define EMB   512
#define NHEAD 8
#define HDIM  64
#define BHEADS 32
#define USEL  40

typedef __bf16 bf16v8 __attribute__((ext_vector_type(8)));
typedef _Float16 f16x8 __attribute__((ext_vector_type(8)));
typedef float f32x4 __attribute__((ext_vector_type(4)));
typedef unsigned short u16;

// Split a float4 into bf16 hi + lo halves, packed as uint2 (4 x u16 each).
__device__ __forceinline__ void cvt4_hilo(const float4 f, uint2& ph, uint2& pl)
{
    __hip_bfloat16 h0 = __float2bfloat16(f.x);
    __hip_bfloat16 h1 = __float2bfloat16(f.y);
    __hip_bfloat16 h2 = __float2bfloat16(f.z);
    __hip_bfloat16 h3 = __float2bfloat16(f.w);
    __hip_bfloat16 l0 = __float2bfloat16(f.x - __bfloat162float(h0));
    __hip_bfloat16 l1 = __float2bfloat16(f.y - __bfloat162float(h1));
    __hip_bfloat16 l2 = __float2bfloat16(f.z - __bfloat162float(h2));
    __hip_bfloat16 l3 = __float2bfloat16(f.w - __bfloat162float(h3));
    ph.x = (unsigned)*(const u16*)&h0 | ((unsigned)*(const u16*)&h1 << 16);
    ph.y = (unsigned)*(const u16*)&h2 | ((unsigned)*(const u16*)&h3 << 16);
    pl.x = (unsigned)*(const u16*)&l0 | ((unsigned)*(const u16*)&l1 << 16);
    pl.y = (unsigned)*(const u16*)&l2 | ((unsigned)*(const u16*)&l3 << 16);
}

// Split a float4 into FP16 hi + lo halves, packed as uint2 (4 x u16 each).
// fp16 has 11-bit mantissa: h+l captures ~22 bits, residual <= 2^-22*|x|.
// Dropped Al*Bl term in the 3-pass GEMM is <= 2^-22*|ab| -> the f16 hi/lo
// 3-pass GEMM is fp32-rounding-equivalent (~1e-6), unlike bf16 hi/lo (~2^-16).
__device__ __forceinline__ void cvt4_hilo_h(const float4 f, uint2& ph, uint2& pl)
{
    _Float16 h0 = (_Float16)f.x;
    _Float16 h1 = (_Float16)f.y;
    _Float16 h2 = (_Float16)f.z;
    _Float16 h3 = (_Float16)f.w;
    _Float16 l0 = (_Float16)(f.x - (float)h0);
    _Float16 l1 = (_Float16)(f.y - (float)h1);
    _Float16 l2 = (_Float16)(f.z - (float)h2);
    _Float16 l3 = (_Float16)(f.w - (float)h3);
    ph.x = (unsigned)*(const u16*)&h0 | ((unsigned)*(const u16*)&h1 << 16);
    ph.y = (unsigned)*(const u16*)&h2 | ((unsigned)*(const u16*)&h3 << 16);
    pl.x = (unsigned)*(const u16*)&l0 | ((unsigned)*(const u16*)&l1 << 16);
    pl.y = (unsigned)*(const u16*)&l2 | ((unsigned)*(const u16*)&l3 << 16);
}

__device__ __forceinline__ void cvt1_hilo_h(float f, u16& h, u16& l)
{
    _Float16 hh = (_Float16)f;
    _Float16 ll = (_Float16)(f - (float)hh);
    h = *(const u16*)&hh;
    l = *(const u16*)&ll;
}

// ---------------------------------------------------------------------------
// Kernel A0: pack X and Wq/Wk/Wv/Wo into f16 hi/lo tiles, pre-blocked in MFMA
// fragment order ([kq(4)][row(128)][8] per hi/lo half; tile = 8192 u16) so
// the GEMMs stage them with linear global_load_lds. Grid 1280: 1024 X tiles,
// 256 W tiles (z = 0..3 -> Wq, Wk, Wv, Wo).
// ---------------------------------------------------------------------------
__global__ __launch_bounds__(256)
void pack_hilo_kernel(const float* __restrict__ X,
                      const float* __restrict__ Wq, const float* __restrict__ Wk,
                      const float* __restrict__ Wv, const float* __restrict__ Wo,
                      u16* __restrict__ Xp, u16* __restrict__ Wp)
{
    alignas(16) __shared__ u16 th[4096];
    alignas(16) __shared__ u16 tl[4096];
    const int b = blockIdx.x, tid = threadIdx.x;

    const float* src; u16* dst;
    if (b < 1024) {                       // X tile: mt = b>>4, kt = b&15
        int mt = b >> 4, kt = b & 15;
        src = X + (size_t)(mt * 128) * EMB + kt * 32;
        dst = Xp + (size_t)b * 8192;
    } else {                              // W tile
        int wdx = b - 1024;               // wdx = (z*4 + nt)*16 + kt
        int z = wdx >> 6, nt = (wdx >> 4) & 3, kt = wdx & 15;
        const float* W = (z == 0) ? Wq : (z == 1) ? Wk : (z == 2) ? Wv : Wo;
        src = W + (size_t)(nt * 128) * EMB + kt * 32;
        dst = Wp + (size_t)wdx * 8192;
    }

    #pragma unroll
    for (int s = 0; s < 4; ++s) {
        int u = tid + 256 * s;            // 0..1023 float4s
        int row = u >> 3, c4 = u & 7;     // 128 rows x 8 float4
        float4 f = *(const float4*)&src[(size_t)row * EMB + c4 * 4];
        uint2 ph, pl;
        cvt4_hilo_h(f, ph, pl);
        int kq = c4 >> 1, e4 = (c4 & 1) * 4;
        *(uint2*)&th[kq * 1024 + row * 8 + e4] = ph;
        *(uint2*)&tl[kq * 1024 + row * 8 + e4] = pl;
    }
    __syncthreads();

    uint4* d4 = (uint4*)dst;
    const uint4* s4h = (const uint4*)th;
    const uint4* s4l = (const uint4*)tl;
    d4[tid]       = s4h[tid];
    d4[tid + 256] = s4h[tid + 256];
    d4[tid + 512] = s4l[tid];
    d4[tid + 768] = s4l[tid + 256];
}

// ---------------------------------------------------------------------------
// Kernel A1: QKV projection GEMM from pre-packed hi/lo tiles.
// Double-buffered staging with counted vmcnt (round-6 passing version).
// ---------------------------------------------------------------------------
__global__ __launch_bounds__(256)
void qkv_mfma_kernel(const u16* __restrict__ Xp, const u16* __restrict__ Wp,
                     const float* __restrict__ bq, const float* __restrict__ bk,
                     const float* __restrict__ bv,
                     float* __restrict__ qo, float* __restrict__ ko, float* __restrict__ vo)
{
    alignas(16) __shared__ u16 Ah[2][4096];
    alignas(16) __shared__ u16 Al[2][4096];
    alignas(16) __shared__ u16 Bh[2][4096];
    alignas(16) __shared__ u16 Bl[2][4096];

    const int z = blockIdx.z;
    const float* bias; float* dst; float scale;
    if (z == 0)      { bias = bq; dst = qo; scale = 0.125f; }
    else if (z == 1) { bias = bk; dst = ko; scale = 1.0f;   }
    else             { bias = bv; dst = vo; scale = 1.0f;   }
    const bool three = (z != 2);

    const int tid = threadIdx.x;
    const int mt = blockIdx.x;
    const int nt = blockIdx.y;
    const int w = tid >> 6, lane = tid & 63;
    const int wm = w & 1, wn = w >> 1;
    const int lm = lane & 15, kq = lane >> 4;

    const u16* Abase = Xp + (size_t)mt * (16 * 8192);
    const u16* Bbase = Wp + (size_t)(z * 4 + nt) * (16 * 8192);

    f32x4 acc[4][4];
    #pragma unroll
    for (int i = 0; i < 4; ++i)
        #pragma unroll
        for (int j = 0; j < 4; ++j)
            #pragma unroll
            for (int r = 0; r < 4; ++r) acc[i][j][r] = 0.0f;

    auto stage = [&](int kt, int buf) {
        const u16* at = Abase + kt * 8192;
        const u16* bt = Bbase + kt * 8192;
        const u16* gsrc; u16* ldst;
        if (w == 0)      { gsrc = at;        ldst = &Ah[buf][0]; }
        else if (w == 1) { gsrc = at + 4096; ldst = &Al[buf][0]; }
        else if (w == 2) { gsrc = bt;        ldst = &Bh[buf][0]; }
        else             { gsrc = bt + 4096; ldst = &Bl[buf][0]; }
        if (three || (w & 1) == 0) {
            #pragma unroll
            for (int i = 0; i < 8; ++i)
                __builtin_amdgcn_global_load_lds(
                    (const __attribute__((address_space(1))) void*)(gsrc + (size_t)lane * 8 + i * 512),
                    (__attribute__((address_space(3))) void*)(ldst + i * 512),
                    16, 0, 0);
        }
    };

    stage(0, 0);

    for (int kt = 0; kt < 16; ++kt) {
        const int cur = kt & 1;
        if (kt + 1 < 16) {
            stage(kt + 1, cur ^ 1);
            asm volatile("s_waitcnt vmcnt(8)" ::: "memory");
        } else {
            asm volatile("s_waitcnt vmcnt(0)" ::: "memory");
        }
        __builtin_amdgcn_s_barrier();
        __builtin_amdgcn_sched_barrier(0);

        f16x8 ah[4], al[4], bh[4], bl[4];
        #pragma unroll
        for (int i = 0; i < 4; ++i) {
            int ar = (wm * 64 + i * 16 + lm) * 8 + kq * 1024;
            int br = (wn * 64 + i * 16 + lm) * 8 + kq * 1024;
            ah[i] = *(const f16x8*)&Ah[cur][ar];
            bh[i] = *(const f16x8*)&Bh[cur][br];
            if (three) {
                al[i] = *(const f16x8*)&Al[cur][ar];
                bl[i] = *(const f16x8*)&Bl[cur][br];
            }
        }
        #pragma unroll
        for (int i = 0; i < 4; ++i)
            #pragma unroll
            for (int j = 0; j < 4; ++j) {
                acc[i][j] = __builtin_amdgcn_mfma_f32_16x16x32_f16(ah[i], bh[j], acc[i][j], 0, 0, 0);
                if (three) {
                    acc[i][j] = __builtin_amdgcn_mfma_f32_16x16x32_f16(ah[i], bl[j], acc[i][j], 0, 0, 0);
                    acc[i][j] = __builtin_amdgcn_mfma_f32_16x16x32_f16(al[i], bh[j], acc[i][j], 0, 0, 0);
                }
            }
        __builtin_amdgcn_s_barrier();
    }

    // C/D layout: col = lane&15 (n), row = (lane>>4)*4 + r (m).
    #pragma unroll
    for (int j = 0; j < 4; ++j) {
        int ng = nt * 128 + wn * 64 + j * 16 + lm;
        int h = ng >> 6, d = ng & 63;
        float bv_ = bias[ng];
        #pragma unroll
        for (int i = 0; i < 4; ++i) {
            #pragma unroll
            for (int r = 0; r < 4; ++r) {
                int mg = mt * 128 + wm * 64 + i * 16 + kq * 4 + r;
                int b = mg >> 11, t = mg & 2047;
                dst[((size_t)((b * NHEAD + h) * T_LEN + t)) * HDIM + d] =
                    (acc[i][j][r] + bv_) * scale;
            }
        }
    }
}

// ---------------------------------------------------------------------------
// Kernel A-fallback: f16 hi/lo 3-pass qkv from global fp32 (small-ws path).
// ---------------------------------------------------------------------------
__global__ __launch_bounds__(256)
void qkv_proj_kernel(const float* __restrict__ X,
                     const float* __restrict__ Wq, const float* __restrict__ bq,
                     const float* __restrict__ Wk, const float* __restrict__ bk,
                     const float* __restrict__ Wv, const float* __restrict__ bv,
                     float* __restrict__ qo, float* __restrict__ ko, float* __restrict__ vo)
{
    alignas(16) __shared__ u16 Ah[128 * 40];
    alignas(16) __shared__ u16 Al[128 * 40];
    alignas(16) __shared__ u16 Bh[128 * 40];
    alignas(16) __shared__ u16 Bl[128 * 40];

    const int z = blockIdx.z;
    const float* W; const float* bias; float* dst; float scale;
    if (z == 0)      { W = Wq; bias = bq; dst = qo; scale = 0.125f; }
    else if (z == 1) { W = Wk; bias = bk; dst = ko; scale = 1.0f;   }
    else             { W = Wv; bias = bv; dst = vo; scale = 1.0f;   }

    const int tid = threadIdx.x;
    const int m0 = blockIdx.x * 128;
    const int n0 = blockIdx.y * 128;
    const int w = tid >> 6, lane = tid & 63;
    const int wm = w & 1, wn = w >> 1;
    const int lm = lane & 15, kq = lane >> 4;

    f32x4 acc[4][4];
    #pragma unroll
    for (int i = 0; i < 4; ++i)
        #pragma unroll
        for (int j = 0; j < 4; ++j)
            #pragma unroll
            for (int r = 0; r < 4; ++r) acc[i][j][r] = 0.0f;

    for (int kc = 0; kc < EMB; kc += 32) {
        __syncthreads();
        #pragma unroll
        for (int s = 0; s < 4; ++s) {
            int u = tid + 256 * s;
            int row = u >> 3, c4 = u & 7;
            float4 fa = *(const float4*)&X[(size_t)(m0 + row) * EMB + kc + c4 * 4];
            float4 fb = *(const float4*)&W[(n0 + row) * EMB + kc + c4 * 4];
            uint2 ph, pl;
            cvt4_hilo_h(fa, ph, pl);
            *(uint2*)&Ah[row * 40 + c4 * 4] = ph;
            *(uint2*)&Al[row * 40 + c4 * 4] = pl;
            cvt4_hilo_h(fb, ph, pl);
            *(uint2*)&Bh[row * 40 + c4 * 4] = ph;
            *(uint2*)&Bl[row * 40 + c4 * 4] = pl;
        }
        __syncthreads();

        f16x8 ah[4], al[4], bh[4], bl[4];
        #pragma unroll
        for (int i = 0; i < 4; ++i) {
            int ra = (wm * 64 + i * 16 + lm) * 40 + kq * 8;
            ah[i] = *(const f16x8*)&Ah[ra];
            al[i] = *(const f16x8*)&Al[ra];
            int rb = (wn * 64 + i * 16 + lm) * 40 + kq * 8;
            bh[i] = *(const f16x8*)&Bh[rb];
            bl[i] = *(const f16x8*)&Bl[rb];
        }
        #pragma unroll
        for (int i = 0; i < 4; ++i)
            #pragma unroll
            for (int j = 0; j < 4; ++j) {
                acc[i][j] = __builtin_amdgcn_mfma_f32_16x16x32_f16(ah[i], bh[j], acc[i][j], 0, 0, 0);
                acc[i][j] = __builtin_amdgcn_mfma_f32_16x16x32_f16(ah[i], bl[j], acc[i][j], 0, 0, 0);
                acc[i][j] = __builtin_amdgcn_mfma_f32_16x16x32_f16(al[i], bh[j], acc[i][j], 0, 0, 0);
            }
    }

    #pragma unroll
    for (int j = 0; j < 4; ++j) {
        int ng = n0 + wn * 64 + j * 16 + lm;
        int h = ng >> 6, d = ng & 63;
        float bv_ = bias[ng];
        #pragma unroll
        for (int i = 0; i < 4; ++i) {
            #pragma unroll
            for (int r = 0; r < 4; ++r) {
                int mg = m0 + wm * 64 + i * 16 + kq * 4 + r;
                int b = mg >> 11, t = mg & 2047;
                dst[((size_t)((b * NHEAD + h) * T_LEN + t)) * HDIM + d] =
                    (acc[i][j][r] + bv_) * scale;
            }
        }
    }
}

// ---------------------------------------------------------------------------
// Kernel B1: count + compact distinct sampled indices (single block).
// ---------------------------------------------------------------------------
__global__ __launch_bounds__(256)
void count_compact_kernel(const int* __restrict__ idxs, int n,
                          int* __restrict__ count, int* __restrict__ klist,
                          int* __restrict__ ncp)
{
    __shared__ int cnt[T_LEN];
    __shared__ int th_tot[256];
    __shared__ int th_off[256];
    __shared__ int ncs;
    const int tid = threadIdx.x;
    for (int j = tid; j < T_LEN; j += 256) cnt[j] = 0;
    __syncthreads();
    for (int i = tid; i < n; i += 256) atomicAdd(&cnt[idxs[i] & (T_LEN - 1)], 1);
    __syncthreads();
    const int base = tid * 8;
    int flags[8]; int loc = 0;
    #pragma unroll
    for (int j = 0; j < 8; ++j) {
        int c = cnt[base + j];
        count[base + j] = c;
        flags[j] = (c > 0); loc += flags[j];
    }
    th_tot[tid] = loc;
    __syncthreads();
    if (tid == 0) {
        int run = 0;
        for (int i = 0; i < 256; ++i) { th_off[i] = run; run += th_tot[i]; }
        ncs = run;
        ncp[0] = run;
    }
    __syncthreads();
    int off = th_off[tid];
    #pragma unroll
    for (int j = 0; j < 8; ++j)
        if (flags[j]) klist[off++] = base + j;
    __syncthreads();
    const int nc = ncs;
    const int nt = (nc + 127) & ~127;
    const int k0 = klist[0];
    for (int j = nc + tid; j < nt; j += 256) klist[j] = k0;
}

// ---------------------------------------------------------------------------
// Kernel B2a: partial ksum/vsum per (bh, slice). Coalesced float4 streaming.
// ---------------------------------------------------------------------------
__global__ __launch_bounds__(256)
void ksum_vmean_part_kernel(const int* __restrict__ count,
                            const float* __restrict__ k, const float* __restrict__ v,
                            float* __restrict__ kpart, float* __restrict__ vpart)
{
    __shared__ int cs[256];
    alignas(16) __shared__ float rk[16 * 64];
    alignas(16) __shared__ float rv[16 * 64];

    const int sl = blockIdx.x, bh = blockIdx.y, tid = threadIdx.x;
    const int f4 = tid & 15, tg = tid >> 4;
    const int t0 = sl * 256;

    cs[tid] = count[t0 + tid];
    __syncthreads();

    const float4* k4 = (const float4*)(k + (size_t)bh * T_LEN * HDIM) + t0 * 16;
    const float4* v4 = (const float4*)(v + (size_t)bh * T_LEN * HDIM) + t0 * 16;

    float4 ak = {0.f, 0.f, 0.f, 0.f}, av = {0.f, 0.f, 0.f, 0.f};
    #pragma unroll
    for (int s = 0; s < 16; ++s) {
        int t = tg + s * 16;
        float c = (float)cs[t];
        float4 kf = k4[t * 16 + f4];
        float4 vf = v4[t * 16 + f4];
        ak.x = fmaf(c, kf.x, ak.x); ak.y = fmaf(c, kf.y, ak.y);
        ak.z = fmaf(c, kf.z, ak.z); ak.w = fmaf(c, kf.w, ak.w);
        av.x += vf.x; av.y += vf.y; av.z += vf.z; av.w += vf.w;
    }
    *(float4*)&rk[tg * 64 + f4 * 4] = ak;
    *(float4*)&rv[tg * 64 + f4 * 4] = av;
    __syncthreads();

    if (tid < 64) {
        float sk = 0.f, sv = 0.f;
        #pragma unroll
        for (int g = 0; g < 16; ++g) { sk += rk[g * 64 + tid]; sv += rv[g * 64 + tid]; }
        kpart[((size_t)bh * 8 + sl) * 64 + tid] = sk;
        vpart[((size_t)bh * 8 + sl) * 64 + tid] = sv;
    }
}

// ---------------------------------------------------------------------------
// Kernel B2b: reduce 8 slice-partials -> ksum[bh][d], vmean[bh][d].
// ---------------------------------------------------------------------------
__global__ __launch_bounds__(64)
void ksum_vmean_reduce_kernel(const float* __restrict__ kpart, const float* __restrict__ vpart,
                              float* __restrict__ ksum, float* __restrict__ vmean)
{
    const int bh = blockIdx.x, d = threadIdx.x;
    float sk = 0.f, sv = 0.f;
    #pragma unroll
    for (int sl = 0; sl < 8; ++sl) {
        sk += kpart[((size_t)bh * 8 + sl) * 64 + d];
        sv += vpart[((size_t)bh * 8 + sl) * 64 + d];
    }
    ksum[bh * 64 + d]  = sk;
    vmean[bh * 64 + d] = sv * (1.0f / 2048.0f);
}

// ---------------------------------------------------------------------------
// Kernel C0: pack gathered K rows ONCE per bh into f16 hi/lo fragment-order
// tiles [chunk(2)][kq(4)][row(128)][8] (hi 8192 u16, then lo 8192).
// ---------------------------------------------------------------------------
__global__ __launch_bounds__(256)
void pack_k_kernel(const float* __restrict__ k, const int* __restrict__ klist,
                   const int* __restrict__ ncp, u16* __restrict__ Kp)
{
    alignas(16) __shared__ u16 th[8192];
    alignas(16) __shared__ u16 tl[8192];
    const int wg = blockIdx.x, tid = threadIdx.x;
    const int swz = (wg & 7) * 64 + (wg >> 3);   // XCD-chunked bijection (512%8==0)
    const int bh = swz >> 4, kt = swz & 15;
    const int ntiles = (ncp[0] + 127) >> 7;
    if (kt >= ntiles) return;

    const float4* kb4 = (const float4*)(k + (size_t)bh * T_LEN * HDIM);
    #pragma unroll
    for (int s = 0; s < 8; ++s) {
        int u = tid + 256 * s;
        int row = u >> 4, c4 = u & 15;
        int krow = klist[kt * 128 + row];
        float4 f = kb4[krow * 16 + c4];
        uint2 ph, pl;
        cvt4_hilo_h(f, ph, pl);
        int base = (c4 >> 3) * 4096 + ((c4 >> 1) & 3) * 1024 + row * 8 + (c4 & 1) * 4;
        *(uint2*)&th[base] = ph;
        *(uint2*)&tl[base] = pl;
    }
    __syncthreads();

    u16* dst = Kp + ((size_t)bh * 16 + kt) * 16384;
    uint4* d4 = (uint4*)dst;
    const uint4* s4h = (const uint4*)th;
    const uint4* s4l = (const uint4*)tl;
    #pragma unroll
    for (int i = 0; i < 4; ++i) d4[tid + 256 * i] = s4h[tid + 256 * i];
    #pragma unroll
    for (int i = 0; i < 4; ++i) d4[1024 + tid + 256 * i] = s4l[tid + 256 * i];
}

// ---------------------------------------------------------------------------
// Kernel C: sparsity scan from pre-packed K tiles. (passing round-5 version)
// ---------------------------------------------------------------------------
__global__ __launch_bounds__(256)
void sparsity_scan_kernel(const float* __restrict__ q, const u16* __restrict__ Kp,
                          const float* __restrict__ ksum,
                          const int* __restrict__ ncp, float* __restrict__ spars)
{
    alignas(16) __shared__ u16 KH[10240];
    alignas(16) __shared__ u16 KL[10240];
    __shared__ float ksm[64];
    __shared__ float smax[128];
    __shared__ float sdotL[128];

    const int tid = threadIdx.x;
    const int wg = blockIdx.x;
    const int swz = (wg & 7) * 64 + (wg >> 3);
    const int bh = swz >> 4;
    const int q0 = (swz & 15) * 128;
    const int w = tid >> 6, lane = tid & 63;
    const int lm = lane & 15, kq = lane >> 4;

    const float* qb = q + ((size_t)bh * T_LEN + q0) * HDIM;
    const int ntiles = (ncp[0] + 127) >> 7;

    if (tid < 64) ksm[tid] = ksum[bh * 64 + tid];

    #pragma unroll
    for (int s = 0; s < 8; ++s) {
        int u = tid + 256 * s;
        int row = u >> 4, c4 = u & 15;
        float4 f = *(const float4*)&qb[row * HDIM + c4 * 4];
        uint2 ph, pl;
        cvt4_hilo_h(f, ph, pl);
        int base = ((c4 >> 3) * 128 + row) * 40 + (c4 & 7) * 4;
        *(uint2*)&KH[base] = ph;
        *(uint2*)&KL[base] = pl;
    }
    __syncthreads();

    f16x8 qh[2][2], ql[2][2];
    #pragma unroll
    for (int i = 0; i < 2; ++i)
        #pragma unroll
        for (int c = 0; c < 2; ++c) {
            int ra = (c * 128 + w * 32 + i * 16 + lm) * 40 + kq * 8;
            qh[i][c] = *(const f16x8*)&KH[ra];
            ql[i][c] = *(const f16x8*)&KL[ra];
        }

    {
        float4 k0a = *(const float4*)&ksm[kq * 8];
        float4 k0b = *(const float4*)&ksm[kq * 8 + 4];
        float4 k1a = *(const float4*)&ksm[32 + kq * 8];
        float4 k1b = *(const float4*)&ksm[32 + kq * 8 + 4];
        float kmv[2][8] = {{k0a.x, k0a.y, k0a.z, k0a.w, k0b.x, k0b.y, k0b.z, k0b.w},
                           {k1a.x, k1a.y, k1a.z, k1a.w, k1b.x, k1b.y, k1b.z, k1b.w}};
        #pragma unroll
        for (int i = 0; i < 2; ++i) {
            float sd = 0.f;
            #pragma unroll
            for (int c = 0; c < 2; ++c)
                #pragma unroll
                for (int e = 0; e < 8; ++e)
                    sd = fmaf((float)qh[i][c][e] + (float)ql[i][c][e], kmv[c][e], sd);
            sd += __shfl_xor(sd, 16, 64);
            sd += __shfl_xor(sd, 32, 64);
            if (kq == 0) sdotL[w * 32 + i * 16 + lm] = sd;
        }
    }

    float vmax[2][4];
    #pragma unroll
    for (int i = 0; i < 2; ++i)
        #pragma unroll
        for (int r = 0; r < 4; ++r) vmax[i][r] = -INFINITY;

    const u16* kpb = Kp + (size_t)bh * (16 * 16384);

    for (int kt = 0; kt < ntiles; ++kt) {
        __syncthreads();
        const u16* kp = kpb + kt * 16384;
        const u16* gsrc; u16* ldst;
        if (w == 0)      { gsrc = kp;         ldst = KH; }
        else if (w == 1) { gsrc = kp + 4096;  ldst = KH + 4096; }
        else if (w == 2) { gsrc = kp + 8192;  ldst = KL; }
        else             { gsrc = kp + 12288; ldst = KL + 4096; }
        #pragma unroll
        for (int i = 0; i < 8; ++i)
            __builtin_amdgcn_global_load_lds(
                (const __attribute__((address_space(1))) void*)(gsrc + (size_t)lane * 8 + i * 512),
                (__attribute__((address_space(3))) void*)(ldst + i * 512),
                16, 0, 0);
        __syncthreads();

        #pragma unroll
        for (int j = 0; j < 8; ++j) {
            int rb0 = kq * 1024 + (j * 16 + lm) * 8;
            int rb1 = 4096 + kq * 1024 + (j * 16 + lm) * 8;
            f16x8 bh0 = *(const f16x8*)&KH[rb0];
            f16x8 bl0 = *(const f16x8*)&KL[rb0];
            f16x8 bh1 = *(const f16x8*)&KH[rb1];
            f16x8 bl1 = *(const f16x8*)&KL[rb1];
            f32x4 a0 = {0.f, 0.f, 0.f, 0.f};
            f32x4 a1 = {0.f, 0.f, 0.f, 0.f};
            a0 = __builtin_amdgcn_mfma_f32_16x16x32_f16(qh[0][0], bh0, a0, 0, 0, 0);
            a1 = __builtin_amdgcn_mfma_f32_16x16x32_f16(qh[1][0], bh0, a1, 0, 0, 0);
            a0 = __builtin_amdgcn_mfma_f32_16x16x32_f16(qh[0][0], bl0, a0, 0, 0, 0);
            a1 = __builtin_amdgcn_mfma_f32_16x16x32_f16(qh[1][0], bl0, a1, 0, 0, 0);
            a0 = __builtin_amdgcn_mfma_f32_16x16x32_f16(ql[0][0], bh0, a0, 0, 0, 0);
            a1 = __builtin_amdgcn_mfma_f32_16x16x32_f16(ql[1][0], bh0, a1, 0, 0, 0);
            a0 = __builtin_amdgcn_mfma_f32_16x16x32_f16(qh[0][1], bh1, a0, 0, 0, 0);
            a1 = __builtin_amdgcn_mfma_f32_16x16x32_f16(qh[1][1], bh1, a1, 0, 0, 0);
            a0 = __builtin_amdgcn_mfma_f32_16x16x32_f16(qh[0][1], bl1, a0, 0, 0, 0);
            a1 = __builtin_amdgcn_mfma_f32_16x16x32_f16(qh[1][1], bl1, a1, 0, 0, 0);
            a0 = __builtin_amdgcn_mfma_f32_16x16x32_f16(ql[0][1], bh1, a0, 0, 0, 0);
            a1 = __builtin_amdgcn_mfma_f32_16x16x32_f16(ql[1][1], bh1, a1, 0, 0, 0);
            #pragma unroll
            for (int r = 0; r < 4; ++r) {
                vmax[0][r] = fmaxf(vmax[0][r], a0[r]);
                vmax[1][r] = fmaxf(vmax[1][r], a1[r]);
            }
        }
    }

    #pragma unroll
    for (int i = 0; i < 2; ++i)
        #pragma unroll
        for (int r = 0; r < 4; ++r) {
            float m = vmax[i][r];
            m = fmaxf(m, __shfl_xor(m, 1, 64));
            m = fmaxf(m, __shfl_xor(m, 2, 64));
            m = fmaxf(m, __shfl_xor(m, 4, 64));
            m = fmaxf(m, __shfl_xor(m, 8, 64));
            if (lm == 0) smax[w * 32 + i * 16 + kq * 4 + r] = m;
        }
    __syncthreads();

    if (tid < 128)
        spars[bh * T_LEN + q0 + tid] = smax[tid] - sdotL[tid] * (1.0f / 2048.0f);
}

// ---------------------------------------------------------------------------
// Kernel C-fallback: round-2 scan (gather+cvt per tile), small-ws path.
// ---------------------------------------------------------------------------
__global__ __launch_bounds__(256)
void sparsity_scan_fb_kernel(const float* __restrict__ q, const float* __restrict__ k,
                             const float* __restrict__ ksum, const int* __restrict__ klist,
                             const int* __restrict__ ncp, float* __restrict__ spars)
{
    alignas(16) __shared__ u16 KH[256 * 40];
    alignas(16) __shared__ u16 KL[256 * 40];
    __shared__ float ksm[64];
    __shared__ float smax[128];
    __shared__ float sdotL[128];

    const int tid = threadIdx.x;
    const int bh = blockIdx.y;
    const int q0 = blockIdx.x * 128;
    const int w = tid >> 6, lane = tid & 63;
    const int lm = lane & 15, kq = lane >> 4;

    const float* qb = q + ((size_t)bh * T_LEN + q0) * HDIM;
    const float4* kb4 = (const float4*)(k + (size_t)bh * T_LEN * HDIM);
    const int ntiles = (ncp[0] + 127) >> 7;

    if (tid < 64) ksm[tid] = ksum[bh * 64 + tid];

    #pragma unroll
    for (int s = 0; s < 8; ++s) {
        int u = tid + 256 * s;
        int row = u >> 4, c4 = u & 15;
        float4 f = *(const float4*)&qb[row * HDIM + c4 * 4];
        uint2 ph, pl;
        cvt4_hilo_h(f, ph, pl);
        int base = ((c4 >> 3) * 128 + row) * 40 + (c4 & 7) * 4;
        *(uint2*)&KH[base] = ph;
        *(uint2*)&KL[base] = pl;
    }
    __syncthreads();

    f16x8 qh[2][2], ql[2][2];
    #pragma unroll
    for (int i = 0; i < 2; ++i)
        #pragma unroll
        for (int c = 0; c < 2; ++c) {
            int ra = (c * 128 + w * 32 + i * 16 + lm) * 40 + kq * 8;
            qh[i][c] = *(const f16x8*)&KH[ra];
            ql[i][c] = *(const f16x8*)&KL[ra];
        }

    {
        float4 k0a = *(const float4*)&ksm[kq * 8];
        float4 k0b = *(const float4*)&ksm[kq * 8 + 4];
        float4 k1a = *(const float4*)&ksm[32 + kq * 8];
        float4 k1b = *(const float4*)&ksm[32 + kq * 8 + 4];
        float kmv[2][8] = {{k0a.x, k0a.y, k0a.z, k0a.w, k0b.x, k0b.y, k0b.z, k0b.w},
                           {k1a.x, k1a.y, k1a.z, k1a.w, k1b.x, k1b.y, k1b.z, k1b.w}};
        #pragma unroll
        for (int i = 0; i < 2; ++i) {
            float sd = 0.f;
            #pragma unroll
            for (int c = 0; c < 2; ++c)
                #pragma unroll
                for (int e = 0; e < 8; ++e)
                    sd = fmaf((float)qh[i][c][e] + (float)ql[i][c][e], kmv[c][e], sd);
            sd += __shfl_xor(sd, 16, 64);
            sd += __shfl_xor(sd, 32, 64);
            if (kq == 0) sdotL[w * 32 + i * 16 + lm] = sd;
        }
    }

    float vmax[2][4];
    #pragma unroll
    for (int i = 0; i < 2; ++i)
        #pragma unroll
        for (int r = 0; r < 4; ++r) vmax[i][r] = -INFINITY;

    for (int kt = 0; kt < ntiles; ++kt) {
        __syncthreads();
        #pragma unroll
        for (int s = 0; s < 8; ++s) {
            int u = tid + 256 * s;
            int row = u >> 4, c4 = u & 15;
            int krow = klist[kt * 128 + row];
            float4 f = kb4[krow * 16 + c4];
            uint2 ph, pl;
            cvt4_hilo_h(f, ph, pl);
            int base = ((c4 >> 3) * 128 + row) * 40 + (c4 & 7) * 4;
            *(uint2*)&KH[base] = ph;
            *(uint2*)&KL[base] = pl;
        }
        __syncthreads();

        #pragma unroll
        for (int j = 0; j < 8; ++j) {
            int rb0 = (j * 16 + lm) * 40 + kq * 8;
            int rb1 = (128 + j * 16 + lm) * 40 + kq * 8;
            f16x8 bh0 = *(const f16x8*)&KH[rb0];
            f16x8 bl0 = *(const f16x8*)&KL[rb0];
            f16x8 bh1 = *(const f16x8*)&KH[rb1];
            f16x8 bl1 = *(const f16x8*)&KL[rb1];
            f32x4 a0 = {0.f, 0.f, 0.f, 0.f};
            f32x4 a1 = {0.f, 0.f, 0.f, 0.f};
            a0 = __builtin_amdgcn_mfma_f32_16x16x32_f16(qh[0][0], bh0, a0, 0, 0, 0);
            a1 = __builtin_amdgcn_mfma_f32_16x16x32_f16(qh[1][0], bh0, a1, 0, 0, 0);
            a0 = __builtin_amdgcn_mfma_f32_16x16x32_f16(qh[0][0], bl0, a0, 0, 0, 0);
            a1 = __builtin_amdgcn_mfma_f32_16x16x32_f16(qh[1][0], bl0, a1, 0, 0, 0);
            a0 = __builtin_amdgcn_mfma_f32_16x16x32_f16(ql[0][0], bh0, a0, 0, 0, 0);
            a1 = __builtin_amdgcn_mfma_f32_16x16x32_f16(ql[1][0], bh0, a1, 0, 0, 0);
            a0 = __builtin_amdgcn_mfma_f32_16x16x32_f16(qh[0][1], bh1, a0, 0, 0, 0);
            a1 = __builtin_amdgcn_mfma_f32_16x16x32_f16(qh[1][1], bh1, a1, 0, 0, 0);
            a0 = __builtin_amdgcn_mfma_f32_16x16x32_f16(qh[0][1], bl1, a0, 0, 0, 0);
            a1 = __builtin_amdgcn_mfma_f32_16x16x32_f16(qh[1][1], bl1, a1, 0, 0, 0);
            a0 = __builtin_amdgcn_mfma_f32_16x16x32_f16(ql[0][1], bh1, a0, 0, 0, 0);
            a1 = __builtin_amdgcn_mfma_f32_16x16x32_f16(ql[1][1], bh1, a1, 0, 0, 0);
            #pragma unroll
            for (int r = 0; r < 4; ++r) {
                vmax[0][r] = fmaxf(vmax[0][r], a0[r]);
                vmax[1][r] = fmaxf(vmax[1][r], a1[r]);
            }
        }
    }

    #pragma unroll
    for (int i = 0; i < 2; ++i)
        #pragma unroll
        for (int r = 0; r < 4; ++r) {
            float m = vmax[i][r];
            m = fmaxf(m, __shfl_xor(m, 1, 64));
            m = fmaxf(m, __shfl_xor(m, 2, 64));
            m = fmaxf(m, __shfl_xor(m, 4, 64));
            m = fmaxf(m, __shfl_xor(m, 8, 64));
            if (lm == 0) smax[w * 32 + i * 16 + kq * 4 + r] = m;
        }
    __syncthreads();

    if (tid < 128)
        spars[bh * T_LEN + q0 + tid] = smax[tid] - sdotL[tid] * (1.0f / 2048.0f);
}

// ---------------------------------------------------------------------------
// Kernel D: exact top-40 per bh via 4-level radix select.
// ---------------------------------------------------------------------------
__global__ __launch_bounds__(256)
void topk_kernel(const float* __restrict__ spars, int* __restrict__ topi)
{
    __shared__ unsigned keys[T_LEN];
    __shared__ int hist[256];
    __shared__ int sfx[257];
    __shared__ int sh_need, sh_bin, nsel, neq, cnt2;
    const int bh = blockIdx.x, tid = threadIdx.x;

    #pragma unroll
    for (int s = 0; s < 8; ++s) {
        int j = tid + 256 * s;
        unsigned u = __float_as_uint(spars[bh * T_LEN + j]);
        keys[j] = (u & 0x80000000u) ? ~u : (u | 0x80000000u);
    }
    if (tid == 0) { sh_need = USEL; nsel = 0; neq = 0; cnt2 = 0; }
    __syncthreads();

    unsigned kpref = 0;
    int shift = 24;
    #pragma unroll
    for (int level = 0; level < 4; ++level) {
        const unsigned hi_mask = (shift == 24) ? 0u : (0xFFFFFFFFu << (shift + 8));
        hist[tid] = 0;
        __syncthreads();
        #pragma unroll
        for (int s = 0; s < 8; ++s) {
            unsigned kk = keys[tid + 256 * s];
            if ((kk & hi_mask) == kpref)
                atomicAdd(&hist[(kk >> shift) & 255], 1);
        }
        __syncthreads();
        sfx[tid] = hist[tid];
        if (tid == 0) sfx[256] = 0;
        __syncthreads();
        for (int off = 1; off < 256; off <<= 1) {
            int v = (tid + off < 256) ? sfx[tid + off] : 0;
            __syncthreads();
            sfx[tid] += v;
            __syncthreads();
        }
        const int need = sh_need;
        const int A = (tid == 255) ? 0 : sfx[tid + 1];
        const int here = sfx[tid];
        __syncthreads();
        if (A < need && here >= need) {
            sh_bin = tid;
            sh_need = need - A;
        }
        __syncthreads();
        kpref |= (unsigned)sh_bin << shift;
        shift -= 8;
    }

    const unsigned K = kpref;
    const int need_eq = sh_need;

    #pragma unroll
    for (int s = 0; s < 8; ++s) {
        int j = tid + 256 * s;
        unsigned kk = keys[j];
        if (kk > K) {
            int pos = atomicAdd(&nsel, 1);
            if (pos < USEL) topi[bh * USEL + pos] = j;
        } else if (kk == K) {
            atomicAdd(&neq, 1);
        }
    }
    __syncthreads();
    const int base = nsel;
    const int E = neq;
    __syncthreads();

    if (E == need_eq) {
        #pragma unroll
        for (int s = 0; s < 8; ++s) {
            int j = tid + 256 * s;
            if (keys[j] == K) {
                int pos = atomicAdd(&cnt2, 1);
                if (base + pos < USEL) topi[bh * USEL + base + pos] = j;
            }
        }
    } else {
        #pragma unroll
        for (int s = 0; s < 8; ++s) {
            int j = tid + 256 * s;
            if (keys[j] == K) {
                int rank = 0;
                for (int j2 = 0; j2 < j; ++j2) rank += (keys[j2] == K);
                if (rank < need_eq && base + rank < USEL)
                    topi[bh * USEL + base + rank] = j;
            }
        }
    }
}

// ---------------------------------------------------------------------------
// Kernel E1: gather selected q rows -> qsel[bh][u][d]. (q dead afterwards)
// ---------------------------------------------------------------------------
__global__ __launch_bounds__(256)
void gather_q_kernel(const float* __restrict__ q, const int* __restrict__ topi,
                     float* __restrict__ qsel)
{
    const int bh = blockIdx.x, tid = threadIdx.x;
    for (int i = tid; i < USEL * HDIM; i += 256) {
        int u = i >> 6, d = i & 63;
        int t = topi[bh * USEL + u] & (T_LEN - 1);
        qsel[(size_t)bh * USEL * HDIM + i] = q[((size_t)bh * T_LEN + t) * HDIM + d];
    }
}

// ---------------------------------------------------------------------------
// Kernel E2: S[bh][u][t] = qsel[bh][u] . k[bh][t]. Grid (8 t-slices, 32 bh).
// ---------------------------------------------------------------------------
__global__ __launch_bounds__(256)
void sel_scores_kernel(const float* __restrict__ qsel, const float* __restrict__ k,
                       float* __restrict__ S)
{
    __shared__ float qsT[64 * 41];
    __shared__ float ksT[64 * 257];

    const int sl = blockIdx.x, bh = blockIdx.y, tid = threadIdx.x;
    const int t0 = sl * 256;

    for (int i = tid; i < USEL * HDIM; i += 256) {
        int u = i >> 6, d = i & 63;
        qsT[d * 41 + u] = qsel[(size_t)bh * USEL * HDIM + i];
    }
    const float4* k4 = (const float4*)(k + (size_t)bh * T_LEN * HDIM);
    #pragma unroll
    for (int s = 0; s < 16; ++s) {
        int u = tid + 256 * s;
        int c4 = u & 15, t = u >> 4;
        float4 f = k4[(t0 + t) * 16 + c4];
        ksT[(c4 * 4 + 0) * 257 + t] = f.x;
        ksT[(c4 * 4 + 1) * 257 + t] = f.y;
        ksT[(c4 * 4 + 2) * 257 + t] = f.z;
        ksT[(c4 * 4 + 3) * 257 + t] = f.w;
    }
    __syncthreads();

    const int qg = tid >> 5;
    const int kg = tid & 31;

    float acc[5][8];
    #pragma unroll
    for (int i = 0; i < 5; ++i)
        #pragma unroll
        for (int j = 0; j < 8; ++j) acc[i][j] = 0.0f;

    #pragma unroll 4
    for (int d = 0; d < 64; ++d) {
        float qv[5], kv[8];
        #pragma unroll
        for (int i = 0; i < 5; ++i) qv[i] = qsT[d * 41 + qg * 5 + i];
        #pragma unroll
        for (int j = 0; j < 8; ++j) kv[j] = ksT[d * 257 + kg + 32 * j];
        #pragma unroll
        for (int i = 0; i < 5; ++i)
            #pragma unroll
            for (int j = 0; j < 8; ++j)
                acc[i][j] = fmaf(qv[i], kv[j], acc[i][j]);
    }

    #pragma unroll
    for (int i = 0; i < 5; ++i) {
        float* sp = &S[((size_t)bh * USEL + qg * 5 + i) * T_LEN + t0 + kg];
        #pragma unroll
        for (int j = 0; j < 8; ++j) sp[32 * j] = acc[i][j];
    }
}

// ---------------------------------------------------------------------------
// Kernel E3: in-place softmax over each S row (1280 rows of 2048).
// ---------------------------------------------------------------------------
__global__ __launch_bounds__(256)
void sel_softmax_kernel(float* __restrict__ S)
{
    __shared__ float red[256];
    const int row = blockIdx.x, tid = threadIdx.x;
    float* sr = S + (size_t)row * T_LEN;

    float x[8];
    float m = -INFINITY;
    #pragma unroll
    for (int s = 0; s < 8; ++s) { x[s] = sr[tid + 256 * s]; m = fmaxf(m, x[s]); }
    red[tid] = m;
    __syncthreads();
    for (int s = 128; s > 0; s >>= 1) {
        if (tid < s) red[tid] = fmaxf(red[tid], red[tid + s]);
        __syncthreads();
    }
    m = red[0];
    __syncthreads();

    float sum = 0.f;
    #pragma unroll
    for (int s = 0; s < 8; ++s) { x[s] = __expf(x[s] - m); sum += x[s]; }
    red[tid] = sum;
    __syncthreads();
    for (int s = 128; s > 0; s >>= 1) {
        if (tid < s) red[tid] += red[tid + s];
        __syncthreads();
    }
    float inv = 1.0f / red[0];
    #pragma unroll
    for (int s = 0; s < 8; ++s) sr[tid + 256 * s] = x[s] * inv;
}

// ---------------------------------------------------------------------------
// Kernel E4: PV partial. Grid (16 t-slices, 32 bh).
// ---------------------------------------------------------------------------
__global__ __launch_bounds__(256)
void pv_part_kernel(const float* __restrict__ S, const float* __restrict__ v,
                    float* __restrict__ part)
{
    __shared__ float ps[USEL * 128];
    __shared__ float vs[128 * 69];
    __shared__ float obuf[128 * 20];

    const int sl = blockIdx.x, bh = blockIdx.y, tid = threadIdx.x;
    const int t0 = sl * 128;

    for (int i = tid; i < USEL * 128; i += 256) {
        int q = i >> 7, t = i & 127;
        ps[q * 128 + t] = S[((size_t)bh * USEL + q) * T_LEN + t0 + t];
    }
    const float4* v4 = (const float4*)(v + (size_t)bh * T_LEN * HDIM);
    #pragma unroll
    for (int s = 0; s < 8; ++s) {
        int u = tid + 256 * s;
        int c4 = u & 15, t = u >> 4;
        float4 f = v4[(t0 + t) * 16 + c4];
        vs[t * 69 + c4 * 4 + 0] = f.x;
        vs[t * 69 + c4 * 4 + 1] = f.y;
        vs[t * 69 + c4 * 4 + 2] = f.z;
        vs[t * 69 + c4 * 4 + 3] = f.w;
    }
    __syncthreads();

    const int qg = tid >> 5, r = tid & 31;
    const int dg = r >> 1, th = r & 1;
    const int tb = th * 64;

    float o[5][4];
    #pragma unroll
    for (int i = 0; i < 5; ++i)
        #pragma unroll
        for (int j = 0; j < 4; ++j) o[i][j] = 0.0f;

    #pragma unroll 4
    for (int tt = 0; tt < 64; ++tt) {
        int t = tb + tt;
        float pv[5];
        #pragma unroll
        for (int i = 0; i < 5; ++i) pv[i] = ps[(qg * 5 + i) * 128 + t];
        float4 vv = *(const float4*)&vs[t * 69 + dg * 4];
        #pragma unroll
        for (int i = 0; i < 5; ++i) {
            o[i][0] = fmaf(pv[i], vv.x, o[i][0]);
            o[i][1] = fmaf(pv[i], vv.y, o[i][1]);
            o[i][2] = fmaf(pv[i], vv.z, o[i][2]);
            o[i][3] = fmaf(pv[i], vv.w, o[i][3]);
        }
    }

    const int p = qg * 16 + dg;
    if (th == 1) {
        #pragma unroll
        for (int i = 0; i < 5; ++i)
            #pragma unroll
            for (int j = 0; j < 4; ++j) obuf[p * 20 + i * 4 + j] = o[i][j];
    }
    __syncthreads();
    if (th == 0) {
        float* pb = part + ((size_t)bh * 16 + sl) * (USEL * HDIM);
        #pragma unroll
        for (int i = 0; i < 5; ++i)
            #pragma unroll
            for (int j = 0; j < 4; ++j)
                pb[(qg * 5 + i) * HDIM + dg * 4 + j] = o[i][j] + obuf[p * 20 + i * 4 + j];
    }
}

// ---------------------------------------------------------------------------
// Kernel E5: deterministic merge of 16 PV partials -> attn[bh][u][d].
// ---------------------------------------------------------------------------
__global__ __launch_bounds__(256)
void pv_merge_kernel(const float* __restrict__ part, float* __restrict__ attn)
{
    const int bh = blockIdx.x, tid = threadIdx.x;
    for (int i = tid; i < USEL * HDIM; i += 256) {
        float s = 0.f;
        #pragma unroll
        for (int sl = 0; sl < 16; ++sl)
            s += part[((size_t)bh * 16 + sl) * (USEL * HDIM) + i];
        attn[(size_t)bh * USEL * HDIM + i] = s;
    }
}

// ---------------------------------------------------------------------------
// Kernel F1p: fill packed ctx tiles (f16 hi/lo, [kq][row][8] layout) with
// per-head vmean. Tile = (mt,kt): 128 m-rows x 32 embed cols; value depends
// only on the col -> per-kq broadcast uint4. Same byte volume as the old
// fp32 ctx fill (4 B/elem), so ~same cost; removes the need to re-read and
// convert ctx in out_proj.
// ---------------------------------------------------------------------------
__global__ __launch_bounds__(256)
void ctx_fill_pack_kernel(const float* __restrict__ vmean, u16* __restrict__ CXp)
{
    const int tile = blockIdx.x;          // mt*16 + kt
    const int tid = threadIdx.x;
    const int mt = tile >> 4, kt = tile & 15;
    const int bh = ((mt >> 4) << 3) | (kt >> 1);    // b = mt>>4, h = kt>>1
    const int dbase = (kt & 1) * 32;

    uint4 vh[4], vl[4];
    #pragma unroll
    for (int kq = 0; kq < 4; ++kq) {
        unsigned hw[4], lw[4];
        #pragma unroll
        for (int p = 0; p < 4; ++p) {
            u16 h0, l0, h1, l1;
            cvt1_hilo_h(vmean[bh * 64 + dbase + kq * 8 + p * 2],     h0, l0);
            cvt1_hilo_h(vmean[bh * 64 + dbase + kq * 8 + p * 2 + 1], h1, l1);
            hw[p] = (unsigned)h0 | ((unsigned)h1 << 16);
            lw[p] = (unsigned)l0 | ((unsigned)l1 << 16);
        }
        vh[kq] = make_uint4(hw[0], hw[1], hw[2], hw[3]);
        vl[kq] = make_uint4(lw[0], lw[1], lw[2], lw[3]);
    }

    u16* dst = CXp + (size_t)tile * 8192;
    uint4* dh = (uint4*)dst;              // hi half: 512 uint4
    uint4* dl = (uint4*)(dst + 4096);     // lo half: 512 uint4
    #pragma unroll
    for (int s = 0; s < 2; ++s) {
        int u = tid + 256 * s;            // 0..511; kq = u>>7
        dh[u] = vh[u >> 7];
        dl[u] = vl[u >> 7];
    }
}

// ---------------------------------------------------------------------------
// Kernel F2p: scatter attn rows into the packed ctx tiles at top_idx rows.
// Per (u,bh): 64 embed cols -> hi/lo u16 at [tile][kq][row][i]; overwrites
// the fill (same semantics as .at[].set). topi rows are distinct per bh.
// ---------------------------------------------------------------------------
__global__ void ctx_scatter_pack_kernel(const float* __restrict__ attn,
                                        const int* __restrict__ topi,
                                        u16* __restrict__ CXp)
{
    const int u = blockIdx.x, bh = blockIdx.y, d = threadIdx.x;   // d 0..63
    const int b = bh >> 3, h = bh & 7;
    const int t = topi[bh * USEL + u] & (T_LEN - 1);
    const int m = b * T_LEN + t;
    const int mt = m >> 7, row = m & 127;
    const int e = h * 64 + d;
    const int kt = e >> 5;
    const int c = e & 31, kq = c >> 3, i = c & 7;
    u16 hh, ll;
    cvt1_hilo_h(attn[((size_t)bh * USEL + u) * HDIM + d], hh, ll);
    u16* base = CXp + (size_t)(mt * 16 + kt) * 8192 + kq * 1024 + row * 8 + i;
    base[0]    = hh;
    base[4096] = ll;
}

// ---------------------------------------------------------------------------
// Kernel G': out = ctx @ Wo^T + bo from pre-packed tiles (CXp = packed ctx,
// Wp z=3 = packed Wo). Clone of qkv_mfma v2: dbuf + counted vmcnt + linear
// global_load_lds, f16 hi/lo 3-pass (fp32-equivalent; tighter than the old
// bf16 3-pass). Replaces the per-block-cvt out_proj (Wo re-converted by all
// 64 m-blocks, conflicted ds_writes, no dbuf).
// ---------------------------------------------------------------------------
__global__ __launch_bounds__(256)
void out_mfma_kernel(const u16* __restrict__ CXp, const u16* __restrict__ Wp,
                     const float* __restrict__ bo, float* __restrict__ out)
{
    alignas(16) __shared__ u16 Ah[2][4096];
    alignas(16) __shared__ u16 Al[2][4096];
    alignas(16) __shared__ u16 Bh[2][4096];
    alignas(16) __shared__ u16 Bl[2][4096];

    const int tid = threadIdx.x;
    const int mt = blockIdx.x;
    const int nt = blockIdx.y;
    const int w = tid >> 6, lane = tid & 63;
    const int wm = w & 1, wn = w >> 1;
    const int lm = lane & 15, kq = lane >> 4;

    const u16* Abase = CXp + (size_t)mt * (16 * 8192);
    const u16* Bbase = Wp + (size_t)(3 * 4 + nt) * (16 * 8192);

    f32x4 acc[4][4];
    #pragma unroll
    for (int i = 0; i < 4; ++i)
        #pragma unroll
        for (int j = 0; j < 4; ++j)
            #pragma unroll
            for (int r = 0; r < 4; ++r) acc[i][j][r] = 0.0f;

    auto stage = [&](int kt, int buf) {
        const u16* at = Abase + kt * 8192;
        const u16* bt = Bbase + kt * 8192;
        const u16* gsrc; u16* ldst;
        if (w == 0)      { gsrc = at;        ldst = &Ah[buf][0]; }
        else if (w == 1) { gsrc = at + 4096; ldst = &Al[buf][0]; }
        else if (w == 2) { gsrc = bt;        ldst = &Bh[buf][0]; }
        else             { gsrc = bt + 4096; ldst = &Bl[buf][0]; }
        #pragma unroll
        for (int i = 0; i < 8; ++i)
            __builtin_amdgcn_global_load_lds(
                (const __attribute__((address_space(1))) void*)(gsrc + (size_t)lane * 8 + i * 512),
                (__attribute__((address_space(3))) void*)(ldst + i * 512),
                16, 0, 0);
    };

    stage(0, 0);

    for (int kt = 0; kt < 16; ++kt) {
        const int cur = kt & 1;
        if (kt + 1 < 16) {
            stage(kt + 1, cur ^ 1);
            asm volatile("s_waitcnt vmcnt(8)" ::: "memory");
        } else {
            asm volatile("s_waitcnt vmcnt(0)" ::: "memory");
        }
        __builtin_amdgcn_s_barrier();
        __builtin_amdgcn_sched_barrier(0);

        f16x8 ah[4], al[4], bh[4], bl[4];
        #pragma unroll
        for (int i = 0; i < 4; ++i) {
            int ar = (wm * 64 + i * 16 + lm) * 8 + kq * 1024;
            int br = (wn * 64 + i * 16 + lm) * 8 + kq * 1024;
            ah[i] = *(const f16x8*)&Ah[cur][ar];
            al[i] = *(const f16x8*)&Al[cur][ar];
            bh[i] = *(const f16x8*)&Bh[cur][br];
            bl[i] = *(const f16x8*)&Bl[cur][br];
        }
        #pragma unroll
        for (int i = 0; i < 4; ++i)
            #pragma unroll
            for (int j = 0; j < 4; ++j) {
                acc[i][j] = __builtin_amdgcn_mfma_f32_16x16x32_f16(ah[i], bh[j], acc[i][j], 0, 0, 0);
                acc[i][j] = __builtin_amdgcn_mfma_f32_16x16x32_f16(ah[i], bl[j], acc[i][j], 0, 0, 0);
                acc[i][j] = __builtin_amdgcn_mfma_f32_16x16x32_f16(al[i], bh[j], acc[i][j], 0, 0, 0);
            }
        __builtin_amdgcn_s_barrier();
    }

    // C/D layout: col = lane&15 (n), row = (lane>>4)*4 + r (m).
    #pragma unroll
    for (int j = 0; j < 4; ++j) {
        int ng = nt * 128 + wn * 64 + j * 16 + lm;
        float bias = bo[ng];
        #pragma unroll
        for (int i = 0; i < 4; ++i)
            #pragma unroll
            for (int r = 0; r < 4; ++r) {
                int mg = mt * 128 + wm * 64 + i * 16 + kq * 4 + r;
                out[(size_t)mg * EMB + ng] = acc[i][j][r] + bias;
            }
    }
}

// ---------------------------------------------------------------------------
// Fallback F1/F2/G (small-ws path): fp32 ctx + bf16 3-pass out_proj.
// ---------------------------------------------------------------------------
__global__ __launch_bounds__(256)
void ctx_fill_kernel(const float* __restrict__ vmean, float* __restrict__ ctx)
{
    int flat = blockIdx.x * 256 + threadIdx.x;
    int d = flat & 63, h = (flat >> 6) & 7, b = flat >> 20;
    int bh = (b << 3) | h;
    ctx[flat] = vmean[bh * 64 + d];
}

__global__ void ctx_scatter_kernel(const float* __restrict__ attn, const int* __restrict__ topi,
                                   float* __restrict__ ctx)
{
    const int u = blockIdx.x, bh = blockIdx.y, d = threadIdx.x;
    const int b = bh >> 3, h = bh & 7;
    const int t = topi[bh * USEL + u] & (T_LEN - 1);
    ctx[(size_t)(b * T_LEN + t) * EMB + h * 64 + d] =
        attn[((size_t)bh * USEL + u) * HDIM + d];
}

__global__ __launch_bounds__(256)
void out_proj_kernel(const float* __restrict__ A, const float* __restrict__ Wo,
                     const float* __restrict__ bo, float* __restrict__ out)
{
    alignas(16) __shared__ u16 Ah[128 * 40];
    alignas(16) __shared__ u16 Al[128 * 40];
    alignas(16) __shared__ u16 Bh[128 * 40];
    alignas(16) __shared__ u16 Bl[128 * 40];

    const int tid = threadIdx.x;
    const int m0 = blockIdx.x * 128;
    const int n0 = blockIdx.y * 128;
    const int w = tid >> 6, lane = tid & 63;
    const int wm = w & 1, wn = w >> 1;
    const int lm = lane & 15, kq = lane >> 4;

    f32x4 acc[4][4];
    #pragma unroll
    for (int i = 0; i < 4; ++i)
        #pragma unroll
        for (int j = 0; j < 4; ++j)
            #pragma unroll
            for (int r = 0; r < 4; ++r) acc[i][j][r] = 0.0f;

    for (int kc = 0; kc < EMB; kc += 32) {
        __syncthreads();
        #pragma unroll
        for (int s = 0; s < 4; ++s) {
            int u = tid + 256 * s;
            int row = u >> 3, c4 = u & 7;
            float4 fa = *(const float4*)&A[(size_t)(m0 + row) * EMB + kc + c4 * 4];
            float4 fb = *(const float4*)&Wo[(n0 + row) * EMB + kc + c4 * 4];
            uint2 ph, pl;
            cvt4_hilo(fa, ph, pl);
            *(uint2*)&Ah[row * 40 + c4 * 4] = ph;
            *(uint2*)&Al[row * 40 + c4 * 4] = pl;
            cvt4_hilo(fb, ph, pl);
            *(uint2*)&Bh[row * 40 + c4 * 4] = ph;
            *(uint2*)&Bl[row * 40 + c4 * 4] = pl;
        }
        __syncthreads();

        bf16v8 ah[4], al[4], bh[4], bl[4];
        #pragma unroll
        for (int i = 0; i < 4; ++i) {
            int ra = (wm * 64 + i * 16 + lm) * 40 + kq * 8;
            ah[i] = *(const bf16v8*)&Ah[ra];
            al[i] = *(const bf16v8*)&Al[ra];
            int rb = (wn * 64 + i * 16 + lm) * 40 + kq * 8;
            bh[i] = *(const bf16v8*)&Bh[rb];
            bl[i] = *(const bf16v8*)&Bl[rb];
        }
        #pragma unroll
        for (int i = 0; i < 4; ++i)
            #pragma unroll
            for (int j = 0; j < 4; ++j) {
                acc[i][j] = __builtin_amdgcn_mfma_f32_16x16x32_bf16(ah[i], bh[j], acc[i][j], 0, 0, 0);
                acc[i][j] = __builtin_amdgcn_mfma_f32_16x16x32_bf16(ah[i], bl[j], acc[i][j], 0, 0, 0);
                acc[i][j] = __builtin_amdgcn_mfma_f32_16x16x32_bf16(al[i], bh[j], acc[i][j], 0, 0, 0);
            }
    }

    #pragma unroll
    for (int j = 0; j < 4; ++j) {
        int ng = n0 + wn * 64 + j * 16 + lm;
        float bias = bo[ng];
        #pragma unroll
        for (int i = 0; i < 4; ++i)
            #pragma unroll
            for (int r = 0; r < 4; ++r) {
                int mg = m0 + wm * 64 + i * 16 + kq * 4 + r;
                out[(size_t)mg * EMB + ng] = acc[i][j][r] + bias;
            }
    }
}

// ---------------------------------------------------------------------------
// Diagnostic: if ws_size is too small, report it via d_out (absmax ~= MiB).
// ---------------------------------------------------------------------------
__global__ __launch_bounds__(256)
void ws_diag_kernel(float* __restrict__ out, int n, float mib)
{
    int flat = blockIdx.x * 256 + threadIdx.x;
    if (flat < n) out[flat] = mib;
}

// ---------------------------------------------------------------------------
extern "C" void kernel_launch(void* const* d_in, const int* in_sizes, int n_in,
                              void* d_out, int out_size, void* d_ws, size_t ws_size,
                              hipStream_t stream)
{
    const float* X = nullptr; const int* idxs = nullptr;
    const float* Wseen[4] = {nullptr, nullptr, nullptr, nullptr};
    const float* bseen[4] = {nullptr, nullptr, nullptr, nullptr};
    int nw = 0, nb = 0, u_part = 2048;
    for (int i = 0; i < n_in; ++i) {
        int sz = in_sizes[i];
        if (sz == EMB * EMB * 16) { if (!X) X = (const float*)d_in[i]; }
        else if (sz == T_LEN)     { if (!idxs) { idxs = (const int*)d_in[i]; u_part = sz; } }
        else if (sz == EMB * EMB) { if (nw < 4) Wseen[nw++] = (const float*)d_in[i]; }
        else if (sz == EMB)       { if (nb < 4) bseen[nb++] = (const float*)d_in[i]; }
    }
    if (!X || !idxs || nw < 4 || nb < 4) {
        X = (const float*)d_in[0]; idxs = (const int*)d_in[1];
        Wseen[0] = (const float*)d_in[2]; bseen[0] = (const float*)d_in[3];
        Wseen[1] = (const float*)d_in[4]; bseen[1] = (const float*)d_in[5];
        Wseen[2] = (const float*)d_in[6]; bseen[2] = (const float*)d_in[7];
        Wseen[3] = (const float*)d_in[8]; bseen[3] = (const float*)d_in[9];
        u_part = in_sizes[1];
    }
    const float *Wq = Wseen[0], *Wk = Wseen[1], *Wv = Wseen[2], *Wo = Wseen[3];
    const float *bq = bseen[0], *bk = bseen[1], *bv = bseen[2], *bo = bseen[3];

    // Base workspace layout (peak 50,951,168 B, unchanged). Pack buffers for
    // the fast paths beyond it: Xp 16 MB (reused as packed K) + Wp 4 MB
    // (Wq/Wk/Wv/Wo) + CXp 16 MB (packed ctx). Measured ws is ~256 MiB
    // (harness fill WRITE_SIZE), so the big path always applies in practice.
    const size_t NEED      = 50951168ULL;
    const size_t XP_B      = 16777216ULL;
    const size_t WP_B      = 4194304ULL;
    const size_t CXP_B     = 16777216ULL;
    const size_t NEED_BIG  = NEED + XP_B + WP_B + CXP_B;   // 88,699,904
    if (ws_size < NEED) {
        ws_diag_kernel<<<(out_size + 255) / 256, 256, 0, stream>>>(
            (float*)d_out, out_size, (float)(ws_size >> 20));
        return;
    }

    float* ws    = (float*)d_ws;
    float* qw    = ws;                    // 4,194,304 floats
    float* kw    = qw + 4194304;
    float* vw    = kw + 4194304;
    float* tail  = vw + 4194304;
    float* slotA = tail;                  // 81920: qsel, later attn
    float* spars = tail + 81920;          // 65536
    int*   count = (int*)(tail + 147456); // 2048
    float* ksum  = tail + 149504;         // 2048
    float* vmean = tail + 151552;         // 2048
    int*   topi  = (int*)(tail + 153600); // 1280
    float* kpart = tail;                  // overlays in slotA (disjoint liveness)
    float* vpart = tail + 16384;
    int*   klist = (int*)(tail + 32768);
    int*   ncp   = (int*)(tail + 34816);
    float* S     = qw;                    // q dead after gather
    float* pvp   = qw + 2621440;
    float* qsel  = slotA;
    float* attn  = slotA;
    float* ctx   = (float*)d_ws;                     // fp32 ctx (fallback only)
    u16*   Xp    = (u16*)((char*)d_ws + NEED);       // 16 MB
    u16*   Wp    = (u16*)((char*)d_ws + NEED + XP_B);            // 4 MB
    u16*   CXp   = (u16*)((char*)d_ws + NEED + XP_B + WP_B);     // 16 MB
    u16*   Kp    = Xp;                               // packed K overlays Xp

    const bool big = (ws_size >= NEED_BIG);

    if (big) {
        pack_hilo_kernel<<<1280, 256, 0, stream>>>(X, Wq, Wk, Wv, Wo, Xp, Wp);
        qkv_mfma_kernel<<<dim3(64, 4, 3), 256, 0, stream>>>(Xp, Wp, bq, bk, bv, qw, kw, vw);
    } else {
        qkv_proj_kernel<<<dim3(64, 4, 3), 256, 0, stream>>>(X, Wq, bq, Wk, bk, Wv, bv, qw, kw, vw);
    }
    count_compact_kernel<<<1, 256, 0, stream>>>(idxs, u_part, count, klist, ncp);
    ksum_vmean_part_kernel<<<dim3(8, 32), 256, 0, stream>>>(count, kw, vw, kpart, vpart);
    ksum_vmean_reduce_kernel<<<32, 64, 0, stream>>>(kpart, vpart, ksum, vmean);
    if (big) {
        pack_k_kernel<<<512, 256, 0, stream>>>(kw, klist, ncp, Kp);
        sparsity_scan_kernel<<<512, 256, 0, stream>>>(qw, Kp, ksum, ncp, spars);
    } else {
        sparsity_scan_fb_kernel<<<dim3(16, 32), 256, 0, stream>>>(qw, kw, ksum, klist, ncp, spars);
    }
    topk_kernel<<<32, 256, 0, stream>>>(spars, topi);
    gather_q_kernel<<<32, 256, 0, stream>>>(qw, topi, qsel);
    // qw dead; S/pvp take over that region.
    sel_scores_kernel<<<dim3(8, 32), 256, 0, stream>>>(qsel, kw, S);
    sel_softmax_kernel<<<1280, 256, 0, stream>>>(S);
    pv_part_kernel<<<dim3(16, 32), 256, 0, stream>>>(S, vw, pvp);
    pv_merge_kernel<<<32, 256, 0, stream>>>(pvp, attn);
    if (big) {
        // ctx produced directly in packed f16 hi/lo fragment tiles.
        ctx_fill_pack_kernel<<<1024, 256, 0, stream>>>(vmean, CXp);
        ctx_scatter_pack_kernel<<<dim3(USEL, BHEADS), 64, 0, stream>>>(attn, topi, CXp);
        out_mfma_kernel<<<dim3(64, 4), 256, 0, stream>>>(CXp, Wp, bo, (float*)d_out);
    } else {
        ctx_fill_kernel<<<16384, 256, 0, stream>>>(vmean, ctx);
        ctx_scatter_kernel<<<dim3(USEL, BHEADS), 64, 0, stream>>>(attn, topi, ctx);
        out_proj_kernel<<<dim3(64, 4), 256, 0, stream>>>(ctx, Wo, bo, (float*)d_out);
    }
}

// Round 9
// 262.404 us; speedup vs baseline: 2.0195x; 1.0444x over previous
//
#include <hip/hip_runtime.h>
#include <hip/hip_bf16.h>
#include <math.h>

#define T_LEN 2048
#define EMB   512
#define NHEAD 8
#define HDIM  64
#define BHEADS 32
#define USEL  40

typedef __bf16 bf16v8 __attribute__((ext_vector_type(8)));
typedef _Float16 f16x8 __attribute__((ext_vector_type(8)));
typedef float f32x4 __attribute__((ext_vector_type(4)));
typedef unsigned short u16;

// Split a float4 into bf16 hi + lo halves, packed as uint2 (4 x u16 each).
__device__ __forceinline__ void cvt4_hilo(const float4 f, uint2& ph, uint2& pl)
{
    __hip_bfloat16 h0 = __float2bfloat16(f.x);
    __hip_bfloat16 h1 = __float2bfloat16(f.y);
    __hip_bfloat16 h2 = __float2bfloat16(f.z);
    __hip_bfloat16 h3 = __float2bfloat16(f.w);
    __hip_bfloat16 l0 = __float2bfloat16(f.x - __bfloat162float(h0));
    __hip_bfloat16 l1 = __float2bfloat16(f.y - __bfloat162float(h1));
    __hip_bfloat16 l2 = __float2bfloat16(f.z - __bfloat162float(h2));
    __hip_bfloat16 l3 = __float2bfloat16(f.w - __bfloat162float(h3));
    ph.x = (unsigned)*(const u16*)&h0 | ((unsigned)*(const u16*)&h1 << 16);
    ph.y = (unsigned)*(const u16*)&h2 | ((unsigned)*(const u16*)&h3 << 16);
    pl.x = (unsigned)*(const u16*)&l0 | ((unsigned)*(const u16*)&l1 << 16);
    pl.y = (unsigned)*(const u16*)&l2 | ((unsigned)*(const u16*)&l3 << 16);
}

// Split a float4 into FP16 hi + lo halves, packed as uint2 (4 x u16 each).
// fp16 has 11-bit mantissa: h+l captures ~22 bits, residual <= 2^-22*|x|.
// Dropped Al*Bl term in the 3-pass GEMM is <= 2^-22*|ab| -> fp32-equivalent.
__device__ __forceinline__ void cvt4_hilo_h(const float4 f, uint2& ph, uint2& pl)
{
    _Float16 h0 = (_Float16)f.x;
    _Float16 h1 = (_Float16)f.y;
    _Float16 h2 = (_Float16)f.z;
    _Float16 h3 = (_Float16)f.w;
    _Float16 l0 = (_Float16)(f.x - (float)h0);
    _Float16 l1 = (_Float16)(f.y - (float)h1);
    _Float16 l2 = (_Float16)(f.z - (float)h2);
    _Float16 l3 = (_Float16)(f.w - (float)h3);
    ph.x = (unsigned)*(const u16*)&h0 | ((unsigned)*(const u16*)&h1 << 16);
    ph.y = (unsigned)*(const u16*)&h2 | ((unsigned)*(const u16*)&h3 << 16);
    pl.x = (unsigned)*(const u16*)&l0 | ((unsigned)*(const u16*)&l1 << 16);
    pl.y = (unsigned)*(const u16*)&l2 | ((unsigned)*(const u16*)&l3 << 16);
}

__device__ __forceinline__ void cvt1_hilo_h(float f, u16& h, u16& l)
{
    _Float16 hh = (_Float16)f;
    _Float16 ll = (_Float16)(f - (float)hh);
    h = *(const u16*)&hh;
    l = *(const u16*)&ll;
}

// ---------------------------------------------------------------------------
// Kernel A0: pack X and Wq/Wk/Wv/Wo into f16 hi/lo tiles, MFMA fragment order
// ([kq(4)][row(128)][8] per hi/lo half; tile = 8192 u16). Grid 1280.
// ---------------------------------------------------------------------------
__global__ __launch_bounds__(256)
void pack_hilo_kernel(const float* __restrict__ X,
                      const float* __restrict__ Wq, const float* __restrict__ Wk,
                      const float* __restrict__ Wv, const float* __restrict__ Wo,
                      u16* __restrict__ Xp, u16* __restrict__ Wp)
{
    alignas(16) __shared__ u16 th[4096];
    alignas(16) __shared__ u16 tl[4096];
    const int b = blockIdx.x, tid = threadIdx.x;

    const float* src; u16* dst;
    if (b < 1024) {                       // X tile: mt = b>>4, kt = b&15
        int mt = b >> 4, kt = b & 15;
        src = X + (size_t)(mt * 128) * EMB + kt * 32;
        dst = Xp + (size_t)b * 8192;
    } else {                              // W tile
        int wdx = b - 1024;               // wdx = (z*4 + nt)*16 + kt
        int z = wdx >> 6, nt = (wdx >> 4) & 3, kt = wdx & 15;
        const float* W = (z == 0) ? Wq : (z == 1) ? Wk : (z == 2) ? Wv : Wo;
        src = W + (size_t)(nt * 128) * EMB + kt * 32;
        dst = Wp + (size_t)wdx * 8192;
    }

    #pragma unroll
    for (int s = 0; s < 4; ++s) {
        int u = tid + 256 * s;            // 0..1023 float4s
        int row = u >> 3, c4 = u & 7;     // 128 rows x 8 float4
        float4 f = *(const float4*)&src[(size_t)row * EMB + c4 * 4];
        uint2 ph, pl;
        cvt4_hilo_h(f, ph, pl);
        int kq = c4 >> 1, e4 = (c4 & 1) * 4;
        *(uint2*)&th[kq * 1024 + row * 8 + e4] = ph;
        *(uint2*)&tl[kq * 1024 + row * 8 + e4] = pl;
    }
    __syncthreads();

    uint4* d4 = (uint4*)dst;
    const uint4* s4h = (const uint4*)th;
    const uint4* s4l = (const uint4*)tl;
    d4[tid]       = s4h[tid];
    d4[tid + 256] = s4h[tid + 256];
    d4[tid + 512] = s4l[tid];
    d4[tid + 768] = s4l[tid + 256];
}

// ---------------------------------------------------------------------------
// Kernel A1: QKV projection GEMM from pre-packed hi/lo tiles (dbuf + counted
// vmcnt; round-6 passing version).
// ---------------------------------------------------------------------------
__global__ __launch_bounds__(256)
void qkv_mfma_kernel(const u16* __restrict__ Xp, const u16* __restrict__ Wp,
                     const float* __restrict__ bq, const float* __restrict__ bk,
                     const float* __restrict__ bv,
                     float* __restrict__ qo, float* __restrict__ ko, float* __restrict__ vo)
{
    alignas(16) __shared__ u16 Ah[2][4096];
    alignas(16) __shared__ u16 Al[2][4096];
    alignas(16) __shared__ u16 Bh[2][4096];
    alignas(16) __shared__ u16 Bl[2][4096];

    const int z = blockIdx.z;
    const float* bias; float* dst; float scale;
    if (z == 0)      { bias = bq; dst = qo; scale = 0.125f; }
    else if (z == 1) { bias = bk; dst = ko; scale = 1.0f;   }
    else             { bias = bv; dst = vo; scale = 1.0f;   }
    const bool three = (z != 2);

    const int tid = threadIdx.x;
    const int mt = blockIdx.x;
    const int nt = blockIdx.y;
    const int w = tid >> 6, lane = tid & 63;
    const int wm = w & 1, wn = w >> 1;
    const int lm = lane & 15, kq = lane >> 4;

    const u16* Abase = Xp + (size_t)mt * (16 * 8192);
    const u16* Bbase = Wp + (size_t)(z * 4 + nt) * (16 * 8192);

    f32x4 acc[4][4];
    #pragma unroll
    for (int i = 0; i < 4; ++i)
        #pragma unroll
        for (int j = 0; j < 4; ++j)
            #pragma unroll
            for (int r = 0; r < 4; ++r) acc[i][j][r] = 0.0f;

    auto stage = [&](int kt, int buf) {
        const u16* at = Abase + kt * 8192;
        const u16* bt = Bbase + kt * 8192;
        const u16* gsrc; u16* ldst;
        if (w == 0)      { gsrc = at;        ldst = &Ah[buf][0]; }
        else if (w == 1) { gsrc = at + 4096; ldst = &Al[buf][0]; }
        else if (w == 2) { gsrc = bt;        ldst = &Bh[buf][0]; }
        else             { gsrc = bt + 4096; ldst = &Bl[buf][0]; }
        if (three || (w & 1) == 0) {
            #pragma unroll
            for (int i = 0; i < 8; ++i)
                __builtin_amdgcn_global_load_lds(
                    (const __attribute__((address_space(1))) void*)(gsrc + (size_t)lane * 8 + i * 512),
                    (__attribute__((address_space(3))) void*)(ldst + i * 512),
                    16, 0, 0);
        }
    };

    stage(0, 0);

    for (int kt = 0; kt < 16; ++kt) {
        const int cur = kt & 1;
        if (kt + 1 < 16) {
            stage(kt + 1, cur ^ 1);
            asm volatile("s_waitcnt vmcnt(8)" ::: "memory");
        } else {
            asm volatile("s_waitcnt vmcnt(0)" ::: "memory");
        }
        __builtin_amdgcn_s_barrier();
        __builtin_amdgcn_sched_barrier(0);

        f16x8 ah[4], al[4], bh[4], bl[4];
        #pragma unroll
        for (int i = 0; i < 4; ++i) {
            int ar = (wm * 64 + i * 16 + lm) * 8 + kq * 1024;
            int br = (wn * 64 + i * 16 + lm) * 8 + kq * 1024;
            ah[i] = *(const f16x8*)&Ah[cur][ar];
            bh[i] = *(const f16x8*)&Bh[cur][br];
            if (three) {
                al[i] = *(const f16x8*)&Al[cur][ar];
                bl[i] = *(const f16x8*)&Bl[cur][br];
            }
        }
        #pragma unroll
        for (int i = 0; i < 4; ++i)
            #pragma unroll
            for (int j = 0; j < 4; ++j) {
                acc[i][j] = __builtin_amdgcn_mfma_f32_16x16x32_f16(ah[i], bh[j], acc[i][j], 0, 0, 0);
                if (three) {
                    acc[i][j] = __builtin_amdgcn_mfma_f32_16x16x32_f16(ah[i], bl[j], acc[i][j], 0, 0, 0);
                    acc[i][j] = __builtin_amdgcn_mfma_f32_16x16x32_f16(al[i], bh[j], acc[i][j], 0, 0, 0);
                }
            }
        __builtin_amdgcn_s_barrier();
    }

    // C/D layout: col = lane&15 (n), row = (lane>>4)*4 + r (m).
    #pragma unroll
    for (int j = 0; j < 4; ++j) {
        int ng = nt * 128 + wn * 64 + j * 16 + lm;
        int h = ng >> 6, d = ng & 63;
        float bv_ = bias[ng];
        #pragma unroll
        for (int i = 0; i < 4; ++i) {
            #pragma unroll
            for (int r = 0; r < 4; ++r) {
                int mg = mt * 128 + wm * 64 + i * 16 + kq * 4 + r;
                int b = mg >> 11, t = mg & 2047;
                dst[((size_t)((b * NHEAD + h) * T_LEN + t)) * HDIM + d] =
                    (acc[i][j][r] + bv_) * scale;
            }
        }
    }
}

// ---------------------------------------------------------------------------
// Kernel A-fallback: f16 hi/lo 3-pass qkv from global fp32 (small-ws path).
// ---------------------------------------------------------------------------
__global__ __launch_bounds__(256)
void qkv_proj_kernel(const float* __restrict__ X,
                     const float* __restrict__ Wq, const float* __restrict__ bq,
                     const float* __restrict__ Wk, const float* __restrict__ bk,
                     const float* __restrict__ Wv, const float* __restrict__ bv,
                     float* __restrict__ qo, float* __restrict__ ko, float* __restrict__ vo)
{
    alignas(16) __shared__ u16 Ah[128 * 40];
    alignas(16) __shared__ u16 Al[128 * 40];
    alignas(16) __shared__ u16 Bh[128 * 40];
    alignas(16) __shared__ u16 Bl[128 * 40];

    const int z = blockIdx.z;
    const float* W; const float* bias; float* dst; float scale;
    if (z == 0)      { W = Wq; bias = bq; dst = qo; scale = 0.125f; }
    else if (z == 1) { W = Wk; bias = bk; dst = ko; scale = 1.0f;   }
    else             { W = Wv; bias = bv; dst = vo; scale = 1.0f;   }

    const int tid = threadIdx.x;
    const int m0 = blockIdx.x * 128;
    const int n0 = blockIdx.y * 128;
    const int w = tid >> 6, lane = tid & 63;
    const int wm = w & 1, wn = w >> 1;
    const int lm = lane & 15, kq = lane >> 4;

    f32x4 acc[4][4];
    #pragma unroll
    for (int i = 0; i < 4; ++i)
        #pragma unroll
        for (int j = 0; j < 4; ++j)
            #pragma unroll
            for (int r = 0; r < 4; ++r) acc[i][j][r] = 0.0f;

    for (int kc = 0; kc < EMB; kc += 32) {
        __syncthreads();
        #pragma unroll
        for (int s = 0; s < 4; ++s) {
            int u = tid + 256 * s;
            int row = u >> 3, c4 = u & 7;
            float4 fa = *(const float4*)&X[(size_t)(m0 + row) * EMB + kc + c4 * 4];
            float4 fb = *(const float4*)&W[(n0 + row) * EMB + kc + c4 * 4];
            uint2 ph, pl;
            cvt4_hilo_h(fa, ph, pl);
            *(uint2*)&Ah[row * 40 + c4 * 4] = ph;
            *(uint2*)&Al[row * 40 + c4 * 4] = pl;
            cvt4_hilo_h(fb, ph, pl);
            *(uint2*)&Bh[row * 40 + c4 * 4] = ph;
            *(uint2*)&Bl[row * 40 + c4 * 4] = pl;
        }
        __syncthreads();

        f16x8 ah[4], al[4], bh[4], bl[4];
        #pragma unroll
        for (int i = 0; i < 4; ++i) {
            int ra = (wm * 64 + i * 16 + lm) * 40 + kq * 8;
            ah[i] = *(const f16x8*)&Ah[ra];
            al[i] = *(const f16x8*)&Al[ra];
            int rb = (wn * 64 + i * 16 + lm) * 40 + kq * 8;
            bh[i] = *(const f16x8*)&Bh[rb];
            bl[i] = *(const f16x8*)&Bl[rb];
        }
        #pragma unroll
        for (int i = 0; i < 4; ++i)
            #pragma unroll
            for (int j = 0; j < 4; ++j) {
                acc[i][j] = __builtin_amdgcn_mfma_f32_16x16x32_f16(ah[i], bh[j], acc[i][j], 0, 0, 0);
                acc[i][j] = __builtin_amdgcn_mfma_f32_16x16x32_f16(ah[i], bl[j], acc[i][j], 0, 0, 0);
                acc[i][j] = __builtin_amdgcn_mfma_f32_16x16x32_f16(al[i], bh[j], acc[i][j], 0, 0, 0);
            }
    }

    #pragma unroll
    for (int j = 0; j < 4; ++j) {
        int ng = n0 + wn * 64 + j * 16 + lm;
        int h = ng >> 6, d = ng & 63;
        float bv_ = bias[ng];
        #pragma unroll
        for (int i = 0; i < 4; ++i) {
            #pragma unroll
            for (int r = 0; r < 4; ++r) {
                int mg = m0 + wm * 64 + i * 16 + kq * 4 + r;
                int b = mg >> 11, t = mg & 2047;
                dst[((size_t)((b * NHEAD + h) * T_LEN + t)) * HDIM + d] =
                    (acc[i][j][r] + bv_) * scale;
            }
        }
    }
}

// ---------------------------------------------------------------------------
// Kernel B1: count + compact distinct sampled indices (single block).
// ---------------------------------------------------------------------------
__global__ __launch_bounds__(256)
void count_compact_kernel(const int* __restrict__ idxs, int n,
                          int* __restrict__ count, int* __restrict__ klist,
                          int* __restrict__ ncp)
{
    __shared__ int cnt[T_LEN];
    __shared__ int th_tot[256];
    __shared__ int th_off[256];
    __shared__ int ncs;
    const int tid = threadIdx.x;
    for (int j = tid; j < T_LEN; j += 256) cnt[j] = 0;
    __syncthreads();
    for (int i = tid; i < n; i += 256) atomicAdd(&cnt[idxs[i] & (T_LEN - 1)], 1);
    __syncthreads();
    const int base = tid * 8;
    int flags[8]; int loc = 0;
    #pragma unroll
    for (int j = 0; j < 8; ++j) {
        int c = cnt[base + j];
        count[base + j] = c;
        flags[j] = (c > 0); loc += flags[j];
    }
    th_tot[tid] = loc;
    __syncthreads();
    if (tid == 0) {
        int run = 0;
        for (int i = 0; i < 256; ++i) { th_off[i] = run; run += th_tot[i]; }
        ncs = run;
        ncp[0] = run;
    }
    __syncthreads();
    int off = th_off[tid];
    #pragma unroll
    for (int j = 0; j < 8; ++j)
        if (flags[j]) klist[off++] = base + j;
    __syncthreads();
    const int nc = ncs;
    const int nt = (nc + 127) & ~127;
    const int k0 = klist[0];
    for (int j = nc + tid; j < nt; j += 256) klist[j] = k0;
}

// ---------------------------------------------------------------------------
// Kernel B2a: partial ksum/vsum per (bh, slice). Coalesced float4 streaming.
// ---------------------------------------------------------------------------
__global__ __launch_bounds__(256)
void ksum_vmean_part_kernel(const int* __restrict__ count,
                            const float* __restrict__ k, const float* __restrict__ v,
                            float* __restrict__ kpart, float* __restrict__ vpart)
{
    __shared__ int cs[256];
    alignas(16) __shared__ float rk[16 * 64];
    alignas(16) __shared__ float rv[16 * 64];

    const int sl = blockIdx.x, bh = blockIdx.y, tid = threadIdx.x;
    const int f4 = tid & 15, tg = tid >> 4;
    const int t0 = sl * 256;

    cs[tid] = count[t0 + tid];
    __syncthreads();

    const float4* k4 = (const float4*)(k + (size_t)bh * T_LEN * HDIM) + t0 * 16;
    const float4* v4 = (const float4*)(v + (size_t)bh * T_LEN * HDIM) + t0 * 16;

    float4 ak = {0.f, 0.f, 0.f, 0.f}, av = {0.f, 0.f, 0.f, 0.f};
    #pragma unroll
    for (int s = 0; s < 16; ++s) {
        int t = tg + s * 16;
        float c = (float)cs[t];
        float4 kf = k4[t * 16 + f4];
        float4 vf = v4[t * 16 + f4];
        ak.x = fmaf(c, kf.x, ak.x); ak.y = fmaf(c, kf.y, ak.y);
        ak.z = fmaf(c, kf.z, ak.z); ak.w = fmaf(c, kf.w, ak.w);
        av.x += vf.x; av.y += vf.y; av.z += vf.z; av.w += vf.w;
    }
    *(float4*)&rk[tg * 64 + f4 * 4] = ak;
    *(float4*)&rv[tg * 64 + f4 * 4] = av;
    __syncthreads();

    if (tid < 64) {
        float sk = 0.f, sv = 0.f;
        #pragma unroll
        for (int g = 0; g < 16; ++g) { sk += rk[g * 64 + tid]; sv += rv[g * 64 + tid]; }
        kpart[((size_t)bh * 8 + sl) * 64 + tid] = sk;
        vpart[((size_t)bh * 8 + sl) * 64 + tid] = sv;
    }
}

// ---------------------------------------------------------------------------
// Kernel B2b: reduce 8 slice-partials -> ksum[bh][d], vmean[bh][d].
// ---------------------------------------------------------------------------
__global__ __launch_bounds__(64)
void ksum_vmean_reduce_kernel(const float* __restrict__ kpart, const float* __restrict__ vpart,
                              float* __restrict__ ksum, float* __restrict__ vmean)
{
    const int bh = blockIdx.x, d = threadIdx.x;
    float sk = 0.f, sv = 0.f;
    #pragma unroll
    for (int sl = 0; sl < 8; ++sl) {
        sk += kpart[((size_t)bh * 8 + sl) * 64 + d];
        sv += vpart[((size_t)bh * 8 + sl) * 64 + d];
    }
    ksum[bh * 64 + d]  = sk;
    vmean[bh * 64 + d] = sv * (1.0f / 2048.0f);
}

// ---------------------------------------------------------------------------
// Kernel C0: pack gathered K rows ONCE per bh into f16 hi/lo fragment-order
// tiles [chunk(2)][kq(4)][row(128)][8] (hi 8192 u16, then lo 8192).
// ---------------------------------------------------------------------------
__global__ __launch_bounds__(256)
void pack_k_kernel(const float* __restrict__ k, const int* __restrict__ klist,
                   const int* __restrict__ ncp, u16* __restrict__ Kp)
{
    alignas(16) __shared__ u16 th[8192];
    alignas(16) __shared__ u16 tl[8192];
    const int wg = blockIdx.x, tid = threadIdx.x;
    const int swz = (wg & 7) * 64 + (wg >> 3);   // XCD-chunked bijection (512%8==0)
    const int bh = swz >> 4, kt = swz & 15;
    const int ntiles = (ncp[0] + 127) >> 7;
    if (kt >= ntiles) return;

    const float4* kb4 = (const float4*)(k + (size_t)bh * T_LEN * HDIM);
    #pragma unroll
    for (int s = 0; s < 8; ++s) {
        int u = tid + 256 * s;
        int row = u >> 4, c4 = u & 15;
        int krow = klist[kt * 128 + row];
        float4 f = kb4[krow * 16 + c4];
        uint2 ph, pl;
        cvt4_hilo_h(f, ph, pl);
        int base = (c4 >> 3) * 4096 + ((c4 >> 1) & 3) * 1024 + row * 8 + (c4 & 1) * 4;
        *(uint2*)&th[base] = ph;
        *(uint2*)&tl[base] = pl;
    }
    __syncthreads();

    u16* dst = Kp + ((size_t)bh * 16 + kt) * 16384;
    uint4* d4 = (uint4*)dst;
    const uint4* s4h = (const uint4*)th;
    const uint4* s4l = (const uint4*)tl;
    #pragma unroll
    for (int i = 0; i < 4; ++i) d4[tid + 256 * i] = s4h[tid + 256 * i];
    #pragma unroll
    for (int i = 0; i < 4; ++i) d4[1024 + tid + 256 * i] = s4l[tid + 256 * i];
}

// ---------------------------------------------------------------------------
// Kernel C: sparsity scan from pre-packed K tiles. (passing round-5 version)
// ---------------------------------------------------------------------------
__global__ __launch_bounds__(256)
void sparsity_scan_kernel(const float* __restrict__ q, const u16* __restrict__ Kp,
                          const float* __restrict__ ksum,
                          const int* __restrict__ ncp, float* __restrict__ spars)
{
    alignas(16) __shared__ u16 KH[10240];
    alignas(16) __shared__ u16 KL[10240];
    __shared__ float ksm[64];
    __shared__ float smax[128];
    __shared__ float sdotL[128];

    const int tid = threadIdx.x;
    const int wg = blockIdx.x;
    const int swz = (wg & 7) * 64 + (wg >> 3);
    const int bh = swz >> 4;
    const int q0 = (swz & 15) * 128;
    const int w = tid >> 6, lane = tid & 63;
    const int lm = lane & 15, kq = lane >> 4;

    const float* qb = q + ((size_t)bh * T_LEN + q0) * HDIM;
    const int ntiles = (ncp[0] + 127) >> 7;

    if (tid < 64) ksm[tid] = ksum[bh * 64 + tid];

    #pragma unroll
    for (int s = 0; s < 8; ++s) {
        int u = tid + 256 * s;
        int row = u >> 4, c4 = u & 15;
        float4 f = *(const float4*)&qb[row * HDIM + c4 * 4];
        uint2 ph, pl;
        cvt4_hilo_h(f, ph, pl);
        int base = ((c4 >> 3) * 128 + row) * 40 + (c4 & 7) * 4;
        *(uint2*)&KH[base] = ph;
        *(uint2*)&KL[base] = pl;
    }
    __syncthreads();

    f16x8 qh[2][2], ql[2][2];
    #pragma unroll
    for (int i = 0; i < 2; ++i)
        #pragma unroll
        for (int c = 0; c < 2; ++c) {
            int ra = (c * 128 + w * 32 + i * 16 + lm) * 40 + kq * 8;
            qh[i][c] = *(const f16x8*)&KH[ra];
            ql[i][c] = *(const f16x8*)&KL[ra];
        }

    {
        float4 k0a = *(const float4*)&ksm[kq * 8];
        float4 k0b = *(const float4*)&ksm[kq * 8 + 4];
        float4 k1a = *(const float4*)&ksm[32 + kq * 8];
        float4 k1b = *(const float4*)&ksm[32 + kq * 8 + 4];
        float kmv[2][8] = {{k0a.x, k0a.y, k0a.z, k0a.w, k0b.x, k0b.y, k0b.z, k0b.w},
                           {k1a.x, k1a.y, k1a.z, k1a.w, k1b.x, k1b.y, k1b.z, k1b.w}};
        #pragma unroll
        for (int i = 0; i < 2; ++i) {
            float sd = 0.f;
            #pragma unroll
            for (int c = 0; c < 2; ++c)
                #pragma unroll
                for (int e = 0; e < 8; ++e)
                    sd = fmaf((float)qh[i][c][e] + (float)ql[i][c][e], kmv[c][e], sd);
            sd += __shfl_xor(sd, 16, 64);
            sd += __shfl_xor(sd, 32, 64);
            if (kq == 0) sdotL[w * 32 + i * 16 + lm] = sd;
        }
    }

    float vmax[2][4];
    #pragma unroll
    for (int i = 0; i < 2; ++i)
        #pragma unroll
        for (int r = 0; r < 4; ++r) vmax[i][r] = -INFINITY;

    const u16* kpb = Kp + (size_t)bh * (16 * 16384);

    for (int kt = 0; kt < ntiles; ++kt) {
        __syncthreads();
        const u16* kp = kpb + kt * 16384;
        const u16* gsrc; u16* ldst;
        if (w == 0)      { gsrc = kp;         ldst = KH; }
        else if (w == 1) { gsrc = kp + 4096;  ldst = KH + 4096; }
        else if (w == 2) { gsrc = kp + 8192;  ldst = KL; }
        else             { gsrc = kp + 12288; ldst = KL + 4096; }
        #pragma unroll
        for (int i = 0; i < 8; ++i)
            __builtin_amdgcn_global_load_lds(
                (const __attribute__((address_space(1))) void*)(gsrc + (size_t)lane * 8 + i * 512),
                (__attribute__((address_space(3))) void*)(ldst + i * 512),
                16, 0, 0);
        __syncthreads();

        #pragma unroll
        for (int j = 0; j < 8; ++j) {
            int rb0 = kq * 1024 + (j * 16 + lm) * 8;
            int rb1 = 4096 + kq * 1024 + (j * 16 + lm) * 8;
            f16x8 bh0 = *(const f16x8*)&KH[rb0];
            f16x8 bl0 = *(const f16x8*)&KL[rb0];
            f16x8 bh1 = *(const f16x8*)&KH[rb1];
            f16x8 bl1 = *(const f16x8*)&KL[rb1];
            f32x4 a0 = {0.f, 0.f, 0.f, 0.f};
            f32x4 a1 = {0.f, 0.f, 0.f, 0.f};
            a0 = __builtin_amdgcn_mfma_f32_16x16x32_f16(qh[0][0], bh0, a0, 0, 0, 0);
            a1 = __builtin_amdgcn_mfma_f32_16x16x32_f16(qh[1][0], bh0, a1, 0, 0, 0);
            a0 = __builtin_amdgcn_mfma_f32_16x16x32_f16(qh[0][0], bl0, a0, 0, 0, 0);
            a1 = __builtin_amdgcn_mfma_f32_16x16x32_f16(qh[1][0], bl0, a1, 0, 0, 0);
            a0 = __builtin_amdgcn_mfma_f32_16x16x32_f16(ql[0][0], bh0, a0, 0, 0, 0);
            a1 = __builtin_amdgcn_mfma_f32_16x16x32_f16(ql[1][0], bh0, a1, 0, 0, 0);
            a0 = __builtin_amdgcn_mfma_f32_16x16x32_f16(qh[0][1], bh1, a0, 0, 0, 0);
            a1 = __builtin_amdgcn_mfma_f32_16x16x32_f16(qh[1][1], bh1, a1, 0, 0, 0);
            a0 = __builtin_amdgcn_mfma_f32_16x16x32_f16(qh[0][1], bl1, a0, 0, 0, 0);
            a1 = __builtin_amdgcn_mfma_f32_16x16x32_f16(qh[1][1], bl1, a1, 0, 0, 0);
            a0 = __builtin_amdgcn_mfma_f32_16x16x32_f16(ql[0][1], bh1, a0, 0, 0, 0);
            a1 = __builtin_amdgcn_mfma_f32_16x16x32_f16(ql[1][1], bh1, a1, 0, 0, 0);
            #pragma unroll
            for (int r = 0; r < 4; ++r) {
                vmax[0][r] = fmaxf(vmax[0][r], a0[r]);
                vmax[1][r] = fmaxf(vmax[1][r], a1[r]);
            }
        }
    }

    #pragma unroll
    for (int i = 0; i < 2; ++i)
        #pragma unroll
        for (int r = 0; r < 4; ++r) {
            float m = vmax[i][r];
            m = fmaxf(m, __shfl_xor(m, 1, 64));
            m = fmaxf(m, __shfl_xor(m, 2, 64));
            m = fmaxf(m, __shfl_xor(m, 4, 64));
            m = fmaxf(m, __shfl_xor(m, 8, 64));
            if (lm == 0) smax[w * 32 + i * 16 + kq * 4 + r] = m;
        }
    __syncthreads();

    if (tid < 128)
        spars[bh * T_LEN + q0 + tid] = smax[tid] - sdotL[tid] * (1.0f / 2048.0f);
}

// ---------------------------------------------------------------------------
// Kernel C-fallback: round-2 scan (gather+cvt per tile), small-ws path.
// ---------------------------------------------------------------------------
__global__ __launch_bounds__(256)
void sparsity_scan_fb_kernel(const float* __restrict__ q, const float* __restrict__ k,
                             const float* __restrict__ ksum, const int* __restrict__ klist,
                             const int* __restrict__ ncp, float* __restrict__ spars)
{
    alignas(16) __shared__ u16 KH[256 * 40];
    alignas(16) __shared__ u16 KL[256 * 40];
    __shared__ float ksm[64];
    __shared__ float smax[128];
    __shared__ float sdotL[128];

    const int tid = threadIdx.x;
    const int bh = blockIdx.y;
    const int q0 = blockIdx.x * 128;
    const int w = tid >> 6, lane = tid & 63;
    const int lm = lane & 15, kq = lane >> 4;

    const float* qb = q + ((size_t)bh * T_LEN + q0) * HDIM;
    const float4* kb4 = (const float4*)(k + (size_t)bh * T_LEN * HDIM);
    const int ntiles = (ncp[0] + 127) >> 7;

    if (tid < 64) ksm[tid] = ksum[bh * 64 + tid];

    #pragma unroll
    for (int s = 0; s < 8; ++s) {
        int u = tid + 256 * s;
        int row = u >> 4, c4 = u & 15;
        float4 f = *(const float4*)&qb[row * HDIM + c4 * 4];
        uint2 ph, pl;
        cvt4_hilo_h(f, ph, pl);
        int base = ((c4 >> 3) * 128 + row) * 40 + (c4 & 7) * 4;
        *(uint2*)&KH[base] = ph;
        *(uint2*)&KL[base] = pl;
    }
    __syncthreads();

    f16x8 qh[2][2], ql[2][2];
    #pragma unroll
    for (int i = 0; i < 2; ++i)
        #pragma unroll
        for (int c = 0; c < 2; ++c) {
            int ra = (c * 128 + w * 32 + i * 16 + lm) * 40 + kq * 8;
            qh[i][c] = *(const f16x8*)&KH[ra];
            ql[i][c] = *(const f16x8*)&KL[ra];
        }

    {
        float4 k0a = *(const float4*)&ksm[kq * 8];
        float4 k0b = *(const float4*)&ksm[kq * 8 + 4];
        float4 k1a = *(const float4*)&ksm[32 + kq * 8];
        float4 k1b = *(const float4*)&ksm[32 + kq * 8 + 4];
        float kmv[2][8] = {{k0a.x, k0a.y, k0a.z, k0a.w, k0b.x, k0b.y, k0b.z, k0b.w},
                           {k1a.x, k1a.y, k1a.z, k1a.w, k1b.x, k1b.y, k1b.z, k1b.w}};
        #pragma unroll
        for (int i = 0; i < 2; ++i) {
            float sd = 0.f;
            #pragma unroll
            for (int c = 0; c < 2; ++c)
                #pragma unroll
                for (int e = 0; e < 8; ++e)
                    sd = fmaf((float)qh[i][c][e] + (float)ql[i][c][e], kmv[c][e], sd);
            sd += __shfl_xor(sd, 16, 64);
            sd += __shfl_xor(sd, 32, 64);
            if (kq == 0) sdotL[w * 32 + i * 16 + lm] = sd;
        }
    }

    float vmax[2][4];
    #pragma unroll
    for (int i = 0; i < 2; ++i)
        #pragma unroll
        for (int r = 0; r < 4; ++r) vmax[i][r] = -INFINITY;

    for (int kt = 0; kt < ntiles; ++kt) {
        __syncthreads();
        #pragma unroll
        for (int s = 0; s < 8; ++s) {
            int u = tid + 256 * s;
            int row = u >> 4, c4 = u & 15;
            int krow = klist[kt * 128 + row];
            float4 f = kb4[krow * 16 + c4];
            uint2 ph, pl;
            cvt4_hilo_h(f, ph, pl);
            int base = ((c4 >> 3) * 128 + row) * 40 + (c4 & 7) * 4;
            *(uint2*)&KH[base] = ph;
            *(uint2*)&KL[base] = pl;
        }
        __syncthreads();

        #pragma unroll
        for (int j = 0; j < 8; ++j) {
            int rb0 = (j * 16 + lm) * 40 + kq * 8;
            int rb1 = (128 + j * 16 + lm) * 40 + kq * 8;
            f16x8 bh0 = *(const f16x8*)&KH[rb0];
            f16x8 bl0 = *(const f16x8*)&KL[rb0];
            f16x8 bh1 = *(const f16x8*)&KH[rb1];
            f16x8 bl1 = *(const f16x8*)&KL[rb1];
            f32x4 a0 = {0.f, 0.f, 0.f, 0.f};
            f32x4 a1 = {0.f, 0.f, 0.f, 0.f};
            a0 = __builtin_amdgcn_mfma_f32_16x16x32_f16(qh[0][0], bh0, a0, 0, 0, 0);
            a1 = __builtin_amdgcn_mfma_f32_16x16x32_f16(qh[1][0], bh0, a1, 0, 0, 0);
            a0 = __builtin_amdgcn_mfma_f32_16x16x32_f16(qh[0][0], bl0, a0, 0, 0, 0);
            a1 = __builtin_amdgcn_mfma_f32_16x16x32_f16(qh[1][0], bl0, a1, 0, 0, 0);
            a0 = __builtin_amdgcn_mfma_f32_16x16x32_f16(ql[0][0], bh0, a0, 0, 0, 0);
            a1 = __builtin_amdgcn_mfma_f32_16x16x32_f16(ql[1][0], bh0, a1, 0, 0, 0);
            a0 = __builtin_amdgcn_mfma_f32_16x16x32_f16(qh[0][1], bh1, a0, 0, 0, 0);
            a1 = __builtin_amdgcn_mfma_f32_16x16x32_f16(qh[1][1], bh1, a1, 0, 0, 0);
            a0 = __builtin_amdgcn_mfma_f32_16x16x32_f16(qh[0][1], bl1, a0, 0, 0, 0);
            a1 = __builtin_amdgcn_mfma_f32_16x16x32_f16(qh[1][1], bl1, a1, 0, 0, 0);
            a0 = __builtin_amdgcn_mfma_f32_16x16x32_f16(ql[0][1], bh1, a0, 0, 0, 0);
            a1 = __builtin_amdgcn_mfma_f32_16x16x32_f16(ql[1][1], bh1, a1, 0, 0, 0);
            #pragma unroll
            for (int r = 0; r < 4; ++r) {
                vmax[0][r] = fmaxf(vmax[0][r], a0[r]);
                vmax[1][r] = fmaxf(vmax[1][r], a1[r]);
            }
        }
    }

    #pragma unroll
    for (int i = 0; i < 2; ++i)
        #pragma unroll
        for (int r = 0; r < 4; ++r) {
            float m = vmax[i][r];
            m = fmaxf(m, __shfl_xor(m, 1, 64));
            m = fmaxf(m, __shfl_xor(m, 2, 64));
            m = fmaxf(m, __shfl_xor(m, 4, 64));
            m = fmaxf(m, __shfl_xor(m, 8, 64));
            if (lm == 0) smax[w * 32 + i * 16 + kq * 4 + r] = m;
        }
    __syncthreads();

    if (tid < 128)
        spars[bh * T_LEN + q0 + tid] = smax[tid] - sdotL[tid] * (1.0f / 2048.0f);
}

// ---------------------------------------------------------------------------
// Kernel D: exact top-40 per bh via 4-level radix select.
// ---------------------------------------------------------------------------
__global__ __launch_bounds__(256)
void topk_kernel(const float* __restrict__ spars, int* __restrict__ topi)
{
    __shared__ unsigned keys[T_LEN];
    __shared__ int hist[256];
    __shared__ int sfx[257];
    __shared__ int sh_need, sh_bin, nsel, neq, cnt2;
    const int bh = blockIdx.x, tid = threadIdx.x;

    #pragma unroll
    for (int s = 0; s < 8; ++s) {
        int j = tid + 256 * s;
        unsigned u = __float_as_uint(spars[bh * T_LEN + j]);
        keys[j] = (u & 0x80000000u) ? ~u : (u | 0x80000000u);
    }
    if (tid == 0) { sh_need = USEL; nsel = 0; neq = 0; cnt2 = 0; }
    __syncthreads();

    unsigned kpref = 0;
    int shift = 24;
    #pragma unroll
    for (int level = 0; level < 4; ++level) {
        const unsigned hi_mask = (shift == 24) ? 0u : (0xFFFFFFFFu << (shift + 8));
        hist[tid] = 0;
        __syncthreads();
        #pragma unroll
        for (int s = 0; s < 8; ++s) {
            unsigned kk = keys[tid + 256 * s];
            if ((kk & hi_mask) == kpref)
                atomicAdd(&hist[(kk >> shift) & 255], 1);
        }
        __syncthreads();
        sfx[tid] = hist[tid];
        if (tid == 0) sfx[256] = 0;
        __syncthreads();
        for (int off = 1; off < 256; off <<= 1) {
            int v = (tid + off < 256) ? sfx[tid + off] : 0;
            __syncthreads();
            sfx[tid] += v;
            __syncthreads();
        }
        const int need = sh_need;
        const int A = (tid == 255) ? 0 : sfx[tid + 1];
        const int here = sfx[tid];
        __syncthreads();
        if (A < need && here >= need) {
            sh_bin = tid;
            sh_need = need - A;
        }
        __syncthreads();
        kpref |= (unsigned)sh_bin << shift;
        shift -= 8;
    }

    const unsigned K = kpref;
    const int need_eq = sh_need;

    #pragma unroll
    for (int s = 0; s < 8; ++s) {
        int j = tid + 256 * s;
        unsigned kk = keys[j];
        if (kk > K) {
            int pos = atomicAdd(&nsel, 1);
            if (pos < USEL) topi[bh * USEL + pos] = j;
        } else if (kk == K) {
            atomicAdd(&neq, 1);
        }
    }
    __syncthreads();
    const int base = nsel;
    const int E = neq;
    __syncthreads();

    if (E == need_eq) {
        #pragma unroll
        for (int s = 0; s < 8; ++s) {
            int j = tid + 256 * s;
            if (keys[j] == K) {
                int pos = atomicAdd(&cnt2, 1);
                if (base + pos < USEL) topi[bh * USEL + base + pos] = j;
            }
        }
    } else {
        #pragma unroll
        for (int s = 0; s < 8; ++s) {
            int j = tid + 256 * s;
            if (keys[j] == K) {
                int rank = 0;
                for (int j2 = 0; j2 < j; ++j2) rank += (keys[j2] == K);
                if (rank < need_eq && base + rank < USEL)
                    topi[bh * USEL + base + rank] = j;
            }
        }
    }
}

// ---------------------------------------------------------------------------
// Kernel E1 (fallback only): gather selected q rows -> qsel[bh][u][d].
// ---------------------------------------------------------------------------
__global__ __launch_bounds__(256)
void gather_q_kernel(const float* __restrict__ q, const int* __restrict__ topi,
                     float* __restrict__ qsel)
{
    const int bh = blockIdx.x, tid = threadIdx.x;
    for (int i = tid; i < USEL * HDIM; i += 256) {
        int u = i >> 6, d = i & 63;
        int t = topi[bh * USEL + u] & (T_LEN - 1);
        qsel[(size_t)bh * USEL * HDIM + i] = q[((size_t)bh * T_LEN + t) * HDIM + d];
    }
}

// ---------------------------------------------------------------------------
// Kernel E2: S[bh][u][t] = q[bh][topi[u]] . k[bh][t]. Grid (8 slices, 32 bh).
// Big path: gathers q rows directly via topi at staging time (values
// identical to the old qsel path -> S bitwise unchanged); gather_q launch
// and the qsel buffer are eliminated. S lives in its own region (q stays
// live through this kernel).
// ---------------------------------------------------------------------------
__global__ __launch_bounds__(256)
void sel_scores_direct_kernel(const float* __restrict__ q, const float* __restrict__ k,
                              const int* __restrict__ topi, float* __restrict__ S)
{
    __shared__ float qsT[64 * 41];    // [d][u] stride 41
    __shared__ float ksT[64 * 257];   // [d][t] stride 257

    const int sl = blockIdx.x, bh = blockIdx.y, tid = threadIdx.x;
    const int t0 = sl * 256;

    for (int i = tid; i < USEL * HDIM; i += 256) {
        int u = i >> 6, d = i & 63;
        int t = topi[bh * USEL + u] & (T_LEN - 1);
        qsT[d * 41 + u] = q[((size_t)bh * T_LEN + t) * HDIM + d];
    }
    const float4* k4 = (const float4*)(k + (size_t)bh * T_LEN * HDIM);
    #pragma unroll
    for (int s = 0; s < 16; ++s) {
        int u = tid + 256 * s;
        int c4 = u & 15, t = u >> 4;
        float4 f = k4[(t0 + t) * 16 + c4];
        ksT[(c4 * 4 + 0) * 257 + t] = f.x;
        ksT[(c4 * 4 + 1) * 257 + t] = f.y;
        ksT[(c4 * 4 + 2) * 257 + t] = f.z;
        ksT[(c4 * 4 + 3) * 257 + t] = f.w;
    }
    __syncthreads();

    const int qg = tid >> 5;
    const int kg = tid & 31;

    float acc[5][8];
    #pragma unroll
    for (int i = 0; i < 5; ++i)
        #pragma unroll
        for (int j = 0; j < 8; ++j) acc[i][j] = 0.0f;

    #pragma unroll 4
    for (int d = 0; d < 64; ++d) {
        float qv[5], kv[8];
        #pragma unroll
        for (int i = 0; i < 5; ++i) qv[i] = qsT[d * 41 + qg * 5 + i];
        #pragma unroll
        for (int j = 0; j < 8; ++j) kv[j] = ksT[d * 257 + kg + 32 * j];
        #pragma unroll
        for (int i = 0; i < 5; ++i)
            #pragma unroll
            for (int j = 0; j < 8; ++j)
                acc[i][j] = fmaf(qv[i], kv[j], acc[i][j]);
    }

    #pragma unroll
    for (int i = 0; i < 5; ++i) {
        float* sp = &S[((size_t)bh * USEL + qg * 5 + i) * T_LEN + t0 + kg];
        #pragma unroll
        for (int j = 0; j < 8; ++j) sp[32 * j] = acc[i][j];
    }
}

// Legacy qsel-based version (fallback path).
__global__ __launch_bounds__(256)
void sel_scores_kernel(const float* __restrict__ qsel, const float* __restrict__ k,
                       float* __restrict__ S)
{
    __shared__ float qsT[64 * 41];
    __shared__ float ksT[64 * 257];

    const int sl = blockIdx.x, bh = blockIdx.y, tid = threadIdx.x;
    const int t0 = sl * 256;

    for (int i = tid; i < USEL * HDIM; i += 256) {
        int u = i >> 6, d = i & 63;
        qsT[d * 41 + u] = qsel[(size_t)bh * USEL * HDIM + i];
    }
    const float4* k4 = (const float4*)(k + (size_t)bh * T_LEN * HDIM);
    #pragma unroll
    for (int s = 0; s < 16; ++s) {
        int u = tid + 256 * s;
        int c4 = u & 15, t = u >> 4;
        float4 f = k4[(t0 + t) * 16 + c4];
        ksT[(c4 * 4 + 0) * 257 + t] = f.x;
        ksT[(c4 * 4 + 1) * 257 + t] = f.y;
        ksT[(c4 * 4 + 2) * 257 + t] = f.z;
        ksT[(c4 * 4 + 3) * 257 + t] = f.w;
    }
    __syncthreads();

    const int qg = tid >> 5;
    const int kg = tid & 31;

    float acc[5][8];
    #pragma unroll
    for (int i = 0; i < 5; ++i)
        #pragma unroll
        for (int j = 0; j < 8; ++j) acc[i][j] = 0.0f;

    #pragma unroll 4
    for (int d = 0; d < 64; ++d) {
        float qv[5], kv[8];
        #pragma unroll
        for (int i = 0; i < 5; ++i) qv[i] = qsT[d * 41 + qg * 5 + i];
        #pragma unroll
        for (int j = 0; j < 8; ++j) kv[j] = ksT[d * 257 + kg + 32 * j];
        #pragma unroll
        for (int i = 0; i < 5; ++i)
            #pragma unroll
            for (int j = 0; j < 8; ++j)
                acc[i][j] = fmaf(qv[i], kv[j], acc[i][j]);
    }

    #pragma unroll
    for (int i = 0; i < 5; ++i) {
        float* sp = &S[((size_t)bh * USEL + qg * 5 + i) * T_LEN + t0 + kg];
        #pragma unroll
        for (int j = 0; j < 8; ++j) sp[32 * j] = acc[i][j];
    }
}

// ---------------------------------------------------------------------------
// Kernel E3: in-place softmax over each S row (1280 rows of 2048).
// ---------------------------------------------------------------------------
__global__ __launch_bounds__(256)
void sel_softmax_kernel(float* __restrict__ S)
{
    __shared__ float red[256];
    const int row = blockIdx.x, tid = threadIdx.x;
    float* sr = S + (size_t)row * T_LEN;

    float x[8];
    float m = -INFINITY;
    #pragma unroll
    for (int s = 0; s < 8; ++s) { x[s] = sr[tid + 256 * s]; m = fmaxf(m, x[s]); }
    red[tid] = m;
    __syncthreads();
    for (int s = 128; s > 0; s >>= 1) {
        if (tid < s) red[tid] = fmaxf(red[tid], red[tid + s]);
        __syncthreads();
    }
    m = red[0];
    __syncthreads();

    float sum = 0.f;
    #pragma unroll
    for (int s = 0; s < 8; ++s) { x[s] = __expf(x[s] - m); sum += x[s]; }
    red[tid] = sum;
    __syncthreads();
    for (int s = 128; s > 0; s >>= 1) {
        if (tid < s) red[tid] += red[tid + s];
        __syncthreads();
    }
    float inv = 1.0f / red[0];
    #pragma unroll
    for (int s = 0; s < 8; ++s) sr[tid + 256 * s] = x[s] * inv;
}

// ---------------------------------------------------------------------------
// Kernel E4: PV partial. Grid (16 t-slices, 32 bh).
// ---------------------------------------------------------------------------
__global__ __launch_bounds__(256)
void pv_part_kernel(const float* __restrict__ S, const float* __restrict__ v,
                    float* __restrict__ part)
{
    __shared__ float ps[USEL * 128];
    __shared__ float vs[128 * 69];
    __shared__ float obuf[128 * 20];

    const int sl = blockIdx.x, bh = blockIdx.y, tid = threadIdx.x;
    const int t0 = sl * 128;

    for (int i = tid; i < USEL * 128; i += 256) {
        int q = i >> 7, t = i & 127;
        ps[q * 128 + t] = S[((size_t)bh * USEL + q) * T_LEN + t0 + t];
    }
    const float4* v4 = (const float4*)(v + (size_t)bh * T_LEN * HDIM);
    #pragma unroll
    for (int s = 0; s < 8; ++s) {
        int u = tid + 256 * s;
        int c4 = u & 15, t = u >> 4;
        float4 f = v4[(t0 + t) * 16 + c4];
        vs[t * 69 + c4 * 4 + 0] = f.x;
        vs[t * 69 + c4 * 4 + 1] = f.y;
        vs[t * 69 + c4 * 4 + 2] = f.z;
        vs[t * 69 + c4 * 4 + 3] = f.w;
    }
    __syncthreads();

    const int qg = tid >> 5, r = tid & 31;
    const int dg = r >> 1, th = r & 1;
    const int tb = th * 64;

    float o[5][4];
    #pragma unroll
    for (int i = 0; i < 5; ++i)
        #pragma unroll
        for (int j = 0; j < 4; ++j) o[i][j] = 0.0f;

    #pragma unroll 4
    for (int tt = 0; tt < 64; ++tt) {
        int t = tb + tt;
        float pv[5];
        #pragma unroll
        for (int i = 0; i < 5; ++i) pv[i] = ps[(qg * 5 + i) * 128 + t];
        float4 vv = *(const float4*)&vs[t * 69 + dg * 4];
        #pragma unroll
        for (int i = 0; i < 5; ++i) {
            o[i][0] = fmaf(pv[i], vv.x, o[i][0]);
            o[i][1] = fmaf(pv[i], vv.y, o[i][1]);
            o[i][2] = fmaf(pv[i], vv.z, o[i][2]);
            o[i][3] = fmaf(pv[i], vv.w, o[i][3]);
        }
    }

    const int p = qg * 16 + dg;
    if (th == 1) {
        #pragma unroll
        for (int i = 0; i < 5; ++i)
            #pragma unroll
            for (int j = 0; j < 4; ++j) obuf[p * 20 + i * 4 + j] = o[i][j];
    }
    __syncthreads();
    if (th == 0) {
        float* pb = part + ((size_t)bh * 16 + sl) * (USEL * HDIM);
        #pragma unroll
        for (int i = 0; i < 5; ++i)
            #pragma unroll
            for (int j = 0; j < 4; ++j)
                pb[(qg * 5 + i) * HDIM + dg * 4 + j] = o[i][j] + obuf[p * 20 + i * 4 + j];
    }
}

// ---------------------------------------------------------------------------
// Kernel E5 (fallback only): merge 16 PV partials -> attn[bh][u][d].
// ---------------------------------------------------------------------------
__global__ __launch_bounds__(256)
void pv_merge_kernel(const float* __restrict__ part, float* __restrict__ attn)
{
    const int bh = blockIdx.x, tid = threadIdx.x;
    for (int i = tid; i < USEL * HDIM; i += 256) {
        float s = 0.f;
        #pragma unroll
        for (int sl = 0; sl < 16; ++sl)
            s += part[((size_t)bh * 16 + sl) * (USEL * HDIM) + i];
        attn[(size_t)bh * USEL * HDIM + i] = s;
    }
}

// ---------------------------------------------------------------------------
// Kernel F (big path): build packed ctx tiles in one pass. Per tile (mt,kt):
// fill with per-head vmean (hi/lo broadcast), __syncthreads (store ordering
// within block: hipcc drains vmcnt before s_barrier), then overwrite the
// selected rows falling inside this tile with the summed PV partials
// (sl=0..15 order = pv_merge order -> bitwise identical). Race-free: one
// block owns each tile. Replaces ctx_fill_pack + ctx_scatter_pack +
// pv_merge (and the attn buffer).
// ---------------------------------------------------------------------------
__global__ __launch_bounds__(256)
void ctx_build_pack_kernel(const float* __restrict__ vmean,
                           const float* __restrict__ part,
                           const int* __restrict__ topi,
                           u16* __restrict__ CXp)
{
    const int tile = blockIdx.x;          // mt*16 + kt
    const int tid = threadIdx.x;
    const int mt = tile >> 4, kt = tile & 15;
    const int b = mt >> 4, h = kt >> 1;
    const int bh = (b << 3) | h;
    const int dbase = (kt & 1) * 32;
    const int ttile = mt & 15;            // 128-row t-chunk of this b

    // Phase 1: vmean fill (hi/lo broadcast per kq).
    uint4 vh[4], vl[4];
    #pragma unroll
    for (int kq = 0; kq < 4; ++kq) {
        unsigned hw[4], lw[4];
        #pragma unroll
        for (int p = 0; p < 4; ++p) {
            u16 h0, l0, h1, l1;
            cvt1_hilo_h(vmean[bh * 64 + dbase + kq * 8 + p * 2],     h0, l0);
            cvt1_hilo_h(vmean[bh * 64 + dbase + kq * 8 + p * 2 + 1], h1, l1);
            hw[p] = (unsigned)h0 | ((unsigned)h1 << 16);
            lw[p] = (unsigned)l0 | ((unsigned)l1 << 16);
        }
        vh[kq] = make_uint4(hw[0], hw[1], hw[2], hw[3]);
        vl[kq] = make_uint4(lw[0], lw[1], lw[2], lw[3]);
    }
    u16* dst = CXp + (size_t)tile * 8192;
    uint4* dh = (uint4*)dst;
    uint4* dl = (uint4*)(dst + 4096);
    #pragma unroll
    for (int s = 0; s < 2; ++s) {
        int u = tid + 256 * s;            // 0..511; kq = u>>7
        dh[u] = vh[u >> 7];
        dl[u] = vl[u >> 7];
    }
    __syncthreads();                      // fill stores retired before scatter

    // Phase 2: overwrite selected rows in this tile with summed partials.
    for (int i = tid; i < USEL * 32; i += 256) {
        int u = i >> 5, c = i & 31;       // u 0..39, c = within-tile col 0..31
        int t = topi[bh * USEL + u] & (T_LEN - 1);
        if ((t >> 7) != ttile) continue;
        int row = t & 127;
        int d = dbase + c;                // head-dim col 0..63
        float s = 0.f;
        #pragma unroll
        for (int sl = 0; sl < 16; ++sl)
            s += part[((size_t)bh * 16 + sl) * (USEL * HDIM) + u * 64 + d];
        u16 hh, ll;
        cvt1_hilo_h(s, hh, ll);
        u16* base = dst + (c >> 3) * 1024 + row * 8 + (c & 7);
        base[0]    = hh;
        base[4096] = ll;
    }
}

// ---------------------------------------------------------------------------
// Kernel G': out = ctx @ Wo^T + bo from pre-packed tiles (dbuf + counted
// vmcnt, f16 hi/lo 3-pass). Round-7 passing version.
// ---------------------------------------------------------------------------
__global__ __launch_bounds__(256)
void out_mfma_kernel(const u16* __restrict__ CXp, const u16* __restrict__ Wp,
                     const float* __restrict__ bo, float* __restrict__ out)
{
    alignas(16) __shared__ u16 Ah[2][4096];
    alignas(16) __shared__ u16 Al[2][4096];
    alignas(16) __shared__ u16 Bh[2][4096];
    alignas(16) __shared__ u16 Bl[2][4096];

    const int tid = threadIdx.x;
    const int mt = blockIdx.x;
    const int nt = blockIdx.y;
    const int w = tid >> 6, lane = tid & 63;
    const int wm = w & 1, wn = w >> 1;
    const int lm = lane & 15, kq = lane >> 4;

    const u16* Abase = CXp + (size_t)mt * (16 * 8192);
    const u16* Bbase = Wp + (size_t)(3 * 4 + nt) * (16 * 8192);

    f32x4 acc[4][4];
    #pragma unroll
    for (int i = 0; i < 4; ++i)
        #pragma unroll
        for (int j = 0; j < 4; ++j)
            #pragma unroll
            for (int r = 0; r < 4; ++r) acc[i][j][r] = 0.0f;

    auto stage = [&](int kt, int buf) {
        const u16* at = Abase + kt * 8192;
        const u16* bt = Bbase + kt * 8192;
        const u16* gsrc; u16* ldst;
        if (w == 0)      { gsrc = at;        ldst = &Ah[buf][0]; }
        else if (w == 1) { gsrc = at + 4096; ldst = &Al[buf][0]; }
        else if (w == 2) { gsrc = bt;        ldst = &Bh[buf][0]; }
        else             { gsrc = bt + 4096; ldst = &Bl[buf][0]; }
        #pragma unroll
        for (int i = 0; i < 8; ++i)
            __builtin_amdgcn_global_load_lds(
                (const __attribute__((address_space(1))) void*)(gsrc + (size_t)lane * 8 + i * 512),
                (__attribute__((address_space(3))) void*)(ldst + i * 512),
                16, 0, 0);
    };

    stage(0, 0);

    for (int kt = 0; kt < 16; ++kt) {
        const int cur = kt & 1;
        if (kt + 1 < 16) {
            stage(kt + 1, cur ^ 1);
            asm volatile("s_waitcnt vmcnt(8)" ::: "memory");
        } else {
            asm volatile("s_waitcnt vmcnt(0)" ::: "memory");
        }
        __builtin_amdgcn_s_barrier();
        __builtin_amdgcn_sched_barrier(0);

        f16x8 ah[4], al[4], bh[4], bl[4];
        #pragma unroll
        for (int i = 0; i < 4; ++i) {
            int ar = (wm * 64 + i * 16 + lm) * 8 + kq * 1024;
            int br = (wn * 64 + i * 16 + lm) * 8 + kq * 1024;
            ah[i] = *(const f16x8*)&Ah[cur][ar];
            al[i] = *(const f16x8*)&Al[cur][ar];
            bh[i] = *(const f16x8*)&Bh[cur][br];
            bl[i] = *(const f16x8*)&Bl[cur][br];
        }
        #pragma unroll
        for (int i = 0; i < 4; ++i)
            #pragma unroll
            for (int j = 0; j < 4; ++j) {
                acc[i][j] = __builtin_amdgcn_mfma_f32_16x16x32_f16(ah[i], bh[j], acc[i][j], 0, 0, 0);
                acc[i][j] = __builtin_amdgcn_mfma_f32_16x16x32_f16(ah[i], bl[j], acc[i][j], 0, 0, 0);
                acc[i][j] = __builtin_amdgcn_mfma_f32_16x16x32_f16(al[i], bh[j], acc[i][j], 0, 0, 0);
            }
        __builtin_amdgcn_s_barrier();
    }

    // C/D layout: col = lane&15 (n), row = (lane>>4)*4 + r (m).
    #pragma unroll
    for (int j = 0; j < 4; ++j) {
        int ng = nt * 128 + wn * 64 + j * 16 + lm;
        float bias = bo[ng];
        #pragma unroll
        for (int i = 0; i < 4; ++i)
            #pragma unroll
            for (int r = 0; r < 4; ++r) {
                int mg = mt * 128 + wm * 64 + i * 16 + kq * 4 + r;
                out[(size_t)mg * EMB + ng] = acc[i][j][r] + bias;
            }
    }
}

// ---------------------------------------------------------------------------
// Fallback F1/F2/G (small-ws path): fp32 ctx + bf16 3-pass out_proj.
// ---------------------------------------------------------------------------
__global__ __launch_bounds__(256)
void ctx_fill_kernel(const float* __restrict__ vmean, float* __restrict__ ctx)
{
    int flat = blockIdx.x * 256 + threadIdx.x;
    int d = flat & 63, h = (flat >> 6) & 7, b = flat >> 20;
    int bh = (b << 3) | h;
    ctx[flat] = vmean[bh * 64 + d];
}

__global__ void ctx_scatter_kernel(const float* __restrict__ attn, const int* __restrict__ topi,
                                   float* __restrict__ ctx)
{
    const int u = blockIdx.x, bh = blockIdx.y, d = threadIdx.x;
    const int b = bh >> 3, h = bh & 7;
    const int t = topi[bh * USEL + u] & (T_LEN - 1);
    ctx[(size_t)(b * T_LEN + t) * EMB + h * 64 + d] =
        attn[((size_t)bh * USEL + u) * HDIM + d];
}

__global__ __launch_bounds__(256)
void out_proj_kernel(const float* __restrict__ A, const float* __restrict__ Wo,
                     const float* __restrict__ bo, float* __restrict__ out)
{
    alignas(16) __shared__ u16 Ah[128 * 40];
    alignas(16) __shared__ u16 Al[128 * 40];
    alignas(16) __shared__ u16 Bh[128 * 40];
    alignas(16) __shared__ u16 Bl[128 * 40];

    const int tid = threadIdx.x;
    const int m0 = blockIdx.x * 128;
    const int n0 = blockIdx.y * 128;
    const int w = tid >> 6, lane = tid & 63;
    const int wm = w & 1, wn = w >> 1;
    const int lm = lane & 15, kq = lane >> 4;

    f32x4 acc[4][4];
    #pragma unroll
    for (int i = 0; i < 4; ++i)
        #pragma unroll
        for (int j = 0; j < 4; ++j)
            #pragma unroll
            for (int r = 0; r < 4; ++r) acc[i][j][r] = 0.0f;

    for (int kc = 0; kc < EMB; kc += 32) {
        __syncthreads();
        #pragma unroll
        for (int s = 0; s < 4; ++s) {
            int u = tid + 256 * s;
            int row = u >> 3, c4 = u & 7;
            float4 fa = *(const float4*)&A[(size_t)(m0 + row) * EMB + kc + c4 * 4];
            float4 fb = *(const float4*)&Wo[(n0 + row) * EMB + kc + c4 * 4];
            uint2 ph, pl;
            cvt4_hilo(fa, ph, pl);
            *(uint2*)&Ah[row * 40 + c4 * 4] = ph;
            *(uint2*)&Al[row * 40 + c4 * 4] = pl;
            cvt4_hilo(fb, ph, pl);
            *(uint2*)&Bh[row * 40 + c4 * 4] = ph;
            *(uint2*)&Bl[row * 40 + c4 * 4] = pl;
        }
        __syncthreads();

        bf16v8 ah[4], al[4], bh[4], bl[4];
        #pragma unroll
        for (int i = 0; i < 4; ++i) {
            int ra = (wm * 64 + i * 16 + lm) * 40 + kq * 8;
            ah[i] = *(const bf16v8*)&Ah[ra];
            al[i] = *(const bf16v8*)&Al[ra];
            int rb = (wn * 64 + i * 16 + lm) * 40 + kq * 8;
            bh[i] = *(const bf16v8*)&Bh[rb];
            bl[i] = *(const bf16v8*)&Bl[rb];
        }
        #pragma unroll
        for (int i = 0; i < 4; ++i)
            #pragma unroll
            for (int j = 0; j < 4; ++j) {
                acc[i][j] = __builtin_amdgcn_mfma_f32_16x16x32_bf16(ah[i], bh[j], acc[i][j], 0, 0, 0);
                acc[i][j] = __builtin_amdgcn_mfma_f32_16x16x32_bf16(ah[i], bl[j], acc[i][j], 0, 0, 0);
                acc[i][j] = __builtin_amdgcn_mfma_f32_16x16x32_bf16(al[i], bh[j], acc[i][j], 0, 0, 0);
            }
    }

    #pragma unroll
    for (int j = 0; j < 4; ++j) {
        int ng = n0 + wn * 64 + j * 16 + lm;
        float bias = bo[ng];
        #pragma unroll
        for (int i = 0; i < 4; ++i)
            #pragma unroll
            for (int r = 0; r < 4; ++r) {
                int mg = m0 + wm * 64 + i * 16 + kq * 4 + r;
                out[(size_t)mg * EMB + ng] = acc[i][j][r] + bias;
            }
    }
}

// ---------------------------------------------------------------------------
// Diagnostic: if ws_size is too small, report it via d_out (absmax ~= MiB).
// ---------------------------------------------------------------------------
__global__ __launch_bounds__(256)
void ws_diag_kernel(float* __restrict__ out, int n, float mib)
{
    int flat = blockIdx.x * 256 + threadIdx.x;
    if (flat < n) out[flat] = mib;
}

// ---------------------------------------------------------------------------
extern "C" void kernel_launch(void* const* d_in, const int* in_sizes, int n_in,
                              void* d_out, int out_size, void* d_ws, size_t ws_size,
                              hipStream_t stream)
{
    const float* X = nullptr; const int* idxs = nullptr;
    const float* Wseen[4] = {nullptr, nullptr, nullptr, nullptr};
    const float* bseen[4] = {nullptr, nullptr, nullptr, nullptr};
    int nw = 0, nb = 0, u_part = 2048;
    for (int i = 0; i < n_in; ++i) {
        int sz = in_sizes[i];
        if (sz == EMB * EMB * 16) { if (!X) X = (const float*)d_in[i]; }
        else if (sz == T_LEN)     { if (!idxs) { idxs = (const int*)d_in[i]; u_part = sz; } }
        else if (sz == EMB * EMB) { if (nw < 4) Wseen[nw++] = (const float*)d_in[i]; }
        else if (sz == EMB)       { if (nb < 4) bseen[nb++] = (const float*)d_in[i]; }
    }
    if (!X || !idxs || nw < 4 || nb < 4) {
        X = (const float*)d_in[0]; idxs = (const int*)d_in[1];
        Wseen[0] = (const float*)d_in[2]; bseen[0] = (const float*)d_in[3];
        Wseen[1] = (const float*)d_in[4]; bseen[1] = (const float*)d_in[5];
        Wseen[2] = (const float*)d_in[6]; bseen[2] = (const float*)d_in[7];
        Wseen[3] = (const float*)d_in[8]; bseen[3] = (const float*)d_in[9];
        u_part = in_sizes[1];
    }
    const float *Wq = Wseen[0], *Wk = Wseen[1], *Wv = Wseen[2], *Wo = Wseen[3];
    const float *bq = bseen[0], *bk = bseen[1], *bv = bseen[2], *bo = bseen[3];

    // Base workspace layout (peak 50,951,168 B, unchanged). Big-path extras:
    // Xp 16 MB (reused as packed K) + Wp 4 MB + CXp 16 MB + S2 10 MB +
    // pvp2 5.25 MB. Measured ws ~256 MiB (harness fill) -> big path applies.
    const size_t NEED      = 50951168ULL;
    const size_t XP_B      = 16777216ULL;
    const size_t WP_B      = 4194304ULL;
    const size_t CXP_B     = 16777216ULL;
    const size_t S_B       = 10485760ULL;
    const size_t PVP_B     = 5242880ULL;
    const size_t NEED_BIG  = NEED + XP_B + WP_B + CXP_B + S_B + PVP_B; // 104,428,544
    if (ws_size < NEED) {
        ws_diag_kernel<<<(out_size + 255) / 256, 256, 0, stream>>>(
            (float*)d_out, out_size, (float)(ws_size >> 20));
        return;
    }

    float* ws    = (float*)d_ws;
    float* qw    = ws;                    // 4,194,304 floats
    float* kw    = qw + 4194304;
    float* vw    = kw + 4194304;
    float* tail  = vw + 4194304;
    float* slotA = tail;                  // 81920: qsel, later attn (fallback)
    float* spars = tail + 81920;          // 65536
    int*   count = (int*)(tail + 147456); // 2048
    float* ksum  = tail + 149504;         // 2048
    float* vmean = tail + 151552;         // 2048
    int*   topi  = (int*)(tail + 153600); // 1280
    float* kpart = tail;                  // overlays in slotA (disjoint liveness)
    float* vpart = tail + 16384;
    int*   klist = (int*)(tail + 32768);
    int*   ncp   = (int*)(tail + 34816);
    float* Sfb   = qw;                    // fallback S overlays qw
    float* pvpfb = qw + 2621440;
    float* qsel  = slotA;
    float* attn  = slotA;
    float* ctx   = (float*)d_ws;                     // fp32 ctx (fallback only)
    u16*   Xp    = (u16*)((char*)d_ws + NEED);
    u16*   Wp    = (u16*)((char*)d_ws + NEED + XP_B);
    u16*   CXp   = (u16*)((char*)d_ws + NEED + XP_B + WP_B);
    float* S2    = (float*)((char*)d_ws + NEED + XP_B + WP_B + CXP_B);
    float* pvp2  = S2 + 2621440;
    u16*   Kp    = Xp;                               // packed K overlays Xp

    const bool big = (ws_size >= NEED_BIG);

    if (big) {
        pack_hilo_kernel<<<1280, 256, 0, stream>>>(X, Wq, Wk, Wv, Wo, Xp, Wp);
        qkv_mfma_kernel<<<dim3(64, 4, 3), 256, 0, stream>>>(Xp, Wp, bq, bk, bv, qw, kw, vw);
    } else {
        qkv_proj_kernel<<<dim3(64, 4, 3), 256, 0, stream>>>(X, Wq, bq, Wk, bk, Wv, bv, qw, kw, vw);
    }
    count_compact_kernel<<<1, 256, 0, stream>>>(idxs, u_part, count, klist, ncp);
    ksum_vmean_part_kernel<<<dim3(8, 32), 256, 0, stream>>>(count, kw, vw, kpart, vpart);
    ksum_vmean_reduce_kernel<<<32, 64, 0, stream>>>(kpart, vpart, ksum, vmean);
    if (big) {
        pack_k_kernel<<<512, 256, 0, stream>>>(kw, klist, ncp, Kp);
        sparsity_scan_kernel<<<512, 256, 0, stream>>>(qw, Kp, ksum, ncp, spars);
    } else {
        sparsity_scan_fb_kernel<<<dim3(16, 32), 256, 0, stream>>>(qw, kw, ksum, klist, ncp, spars);
    }
    topk_kernel<<<32, 256, 0, stream>>>(spars, topi);
    if (big) {
        // q stays live (S in its own region); gather fused into sel_scores.
        sel_scores_direct_kernel<<<dim3(8, 32), 256, 0, stream>>>(qw, kw, topi, S2);
        sel_softmax_kernel<<<1280, 256, 0, stream>>>(S2);
        pv_part_kernel<<<dim3(16, 32), 256, 0, stream>>>(S2, vw, pvp2);
        // fill + merge + scatter fused; partials summed inline (sl order
        // identical to pv_merge -> bitwise same output).
        ctx_build_pack_kernel<<<1024, 256, 0, stream>>>(vmean, pvp2, topi, CXp);
        out_mfma_kernel<<<dim3(64, 4), 256, 0, stream>>>(CXp, Wp, bo, (float*)d_out);
    } else {
        gather_q_kernel<<<32, 256, 0, stream>>>(qw, topi, qsel);
        sel_scores_kernel<<<dim3(8, 32), 256, 0, stream>>>(qsel, kw, Sfb);
        sel_softmax_kernel<<<1280, 256, 0, stream>>>(Sfb);
        pv_part_kernel<<<dim3(16, 32), 256, 0, stream>>>(Sfb, vw, pvpfb);
        pv_merge_kernel<<<32, 256, 0, stream>>>(pvpfb, attn);
        ctx_fill_kernel<<<16384, 256, 0, stream>>>(vmean, ctx);
        ctx_scatter_kernel<<<dim3(USEL, BHEADS), 64, 0, stream>>>(attn, topi, ctx);
        out_proj_kernel<<<dim3(64, 4), 256, 0, stream>>>(ctx, Wo, bo, (float*)d_out);
    }
}